// Round 2
// baseline (5203.453 us; speedup 1.0000x reference)
//
#include <hip/hip_runtime.h>
#include <hip/hip_bf16.h>
#include <math.h>

using bf16 = __hip_bfloat16;

namespace {

constexpr int cH = 2048;
constexpr int cNH = 16;
constexpr int cHD = 128;
constexpr int cNFW = 4;
constexpr int cFD = 512;
constexpr int cCHUNK = 512;
constexpr int cS = 2048;
constexpr float cRSQRT_HD = 0.08838834764831845f;  // 1/sqrt(128)

__device__ __forceinline__ float sigmoidf_(float x) { return 1.0f / (1.0f + __expf(-x)); }
__device__ __forceinline__ float b2f(bf16 v) { return __bfloat162float(v); }
__device__ __forceinline__ bf16 f2b(float v) { return __float2bfloat16(v); }

__device__ __forceinline__ float4 ld4(const float* p) { return *(const float4*)p; }
__device__ __forceinline__ float4 ld4(const bf16* p) {
  ushort4 u = *(const ushort4*)p;
  return make_float4(__uint_as_float((unsigned)u.x << 16), __uint_as_float((unsigned)u.y << 16),
                     __uint_as_float((unsigned)u.z << 16), __uint_as_float((unsigned)u.w << 16));
}
__device__ __forceinline__ void st4(float* p, float4 v) { *(float4*)p = v; }
__device__ __forceinline__ void st4(bf16* p, float4 v) {
  p[0] = f2b(v.x); p[1] = f2b(v.y); p[2] = f2b(v.z); p[3] = f2b(v.w);
}
__device__ __forceinline__ void ld8f(const bf16* p, float* o) {
  ushort4 a = *(const ushort4*)p, b = *(const ushort4*)(p + 4);
  o[0] = __uint_as_float((unsigned)a.x << 16); o[1] = __uint_as_float((unsigned)a.y << 16);
  o[2] = __uint_as_float((unsigned)a.z << 16); o[3] = __uint_as_float((unsigned)a.w << 16);
  o[4] = __uint_as_float((unsigned)b.x << 16); o[5] = __uint_as_float((unsigned)b.y << 16);
  o[6] = __uint_as_float((unsigned)b.z << 16); o[7] = __uint_as_float((unsigned)b.w << 16);
}

// ---------------------------------------------------------------------------
// fp32-accum GEMM core: 64x64 tile, 256 threads, K-step 16, typed A/B loads.
// MODE 0 (NT): C[m,n] = sum_k A[m,k]*B[n,k]
// MODE 1 (NN): C[m,n] = sum_k A[m,k]*B[k,n]
// MODE 2 (TN): C[m,n] = sum_c s[c]*A[c,m]*B[c,n]
// ---------------------------------------------------------------------------
template <int MODE, typename TA, typename TB>
__device__ __forceinline__ void gemm_core(const TA* __restrict__ A, int lda,
                                          const TB* __restrict__ Bm, int ldb,
                                          int K, const float* __restrict__ scale,
                                          float acc[4][4]) {
  __shared__ float As[16][68];
  __shared__ float Bs[16][68];
  const int t = threadIdx.x;
  const int tx = t & 15, ty = t >> 4;
  const int lr = t >> 2, lq = t & 3;

  for (int k0 = 0; k0 < K; k0 += 16) {
    __syncthreads();
    if (MODE == 0 || MODE == 1) {
      float4 av = ld4(A + (size_t)lr * lda + k0 + lq * 4);
      As[lq * 4 + 0][lr] = av.x; As[lq * 4 + 1][lr] = av.y;
      As[lq * 4 + 2][lr] = av.z; As[lq * 4 + 3][lr] = av.w;
    } else {
      float s = scale[k0 + (t >> 4)];
      float4 av = ld4(A + (size_t)(k0 + (t >> 4)) * lda + (t & 15) * 4);
      av.x *= s; av.y *= s; av.z *= s; av.w *= s;
      *(float4*)&As[t >> 4][(t & 15) * 4] = av;
    }
    if (MODE == 0) {
      float4 bv = ld4(Bm + (size_t)lr * ldb + k0 + lq * 4);
      Bs[lq * 4 + 0][lr] = bv.x; Bs[lq * 4 + 1][lr] = bv.y;
      Bs[lq * 4 + 2][lr] = bv.z; Bs[lq * 4 + 3][lr] = bv.w;
    } else {
      float4 bv = ld4(Bm + (size_t)(k0 + (t >> 4)) * ldb + (t & 15) * 4);
      *(float4*)&Bs[t >> 4][(t & 15) * 4] = bv;
    }
    __syncthreads();
#pragma unroll
    for (int kk = 0; kk < 16; ++kk) {
      float4 a4 = *(const float4*)&As[kk][ty * 4];
      float4 b4 = *(const float4*)&Bs[kk][tx * 4];
      acc[0][0] += a4.x * b4.x; acc[0][1] += a4.x * b4.y; acc[0][2] += a4.x * b4.z; acc[0][3] += a4.x * b4.w;
      acc[1][0] += a4.y * b4.x; acc[1][1] += a4.y * b4.y; acc[1][2] += a4.y * b4.z; acc[1][3] += a4.y * b4.w;
      acc[2][0] += a4.z * b4.x; acc[2][1] += a4.z * b4.y; acc[2][2] += a4.z * b4.z; acc[2][3] += a4.z * b4.w;
      acc[3][0] += a4.w * b4.x; acc[3][1] += a4.w * b4.y; acc[3][2] += a4.w * b4.z; acc[3][3] += a4.w * b4.w;
    }
  }
}

// --------------------------- big NT GEMMs (qkv, o_proj) ---------------------
template <typename TA, typename TB, typename TC>
__global__ __launch_bounds__(256) void k_gemm_nt(const TA* __restrict__ A, const TB* __restrict__ Bm,
                                                 TC* __restrict__ C,
                                                 int K, int lda, int ldb, int ldc) {
  const int m0 = blockIdx.y * 64, n0 = blockIdx.x * 64;
  float acc[4][4] = {};
  gemm_core<0>(A + (size_t)m0 * lda, lda, Bm + (size_t)n0 * ldb, ldb, K, nullptr, acc);
  const int tx = threadIdx.x & 15, ty = threadIdx.x >> 4;
#pragma unroll
  for (int i = 0; i < 4; ++i) {
    st4(C + (size_t)(m0 + ty * 4 + i) * ldc + n0 + tx * 4,
        make_float4(acc[i][0], acc[i][1], acc[i][2], acc[i][3]));
  }
}

// --------------------------- TTT kernels -----------------------------------
__global__ __launch_bounds__(256) void k_ttt_stage1(const bf16* __restrict__ fq,
                                                    const bf16* __restrict__ fk,
                                                    const float* __restrict__ w0s,
                                                    const float* __restrict__ w2s,
                                                    bf16* t0, bf16* t1, bf16* t2, bf16* t3,
                                                    int chunk) {
  const int z = blockIdx.z, bh = z >> 2, var = z & 3;
  const bf16* A = ((var < 2) ? fq : fk) + ((size_t)(bh * cS + chunk * cCHUNK) + blockIdx.y * 64) * cFD;
  const float* Bm = ((var & 1) ? w2s : w0s) + (size_t)bh * cFD * cFD + (size_t)blockIdx.x * 64 * cFD;
  bf16* C = (var == 0 ? t0 : var == 1 ? t1 : var == 2 ? t2 : t3) + (size_t)bh * cFD * cFD;
  float acc[4][4] = {};
  gemm_core<0>(A, cFD, Bm, cFD, cFD, nullptr, acc);
  const int tx = threadIdx.x & 15, ty = threadIdx.x >> 4;
#pragma unroll
  for (int i = 0; i < 4; ++i)
    st4(C + (size_t)(blockIdx.y * 64 + ty * 4 + i) * cFD + blockIdx.x * 64 + tx * 4,
        make_float4(acc[i][0], acc[i][1], acc[i][2], acc[i][3]));
}

__global__ __launch_bounds__(256) void k_ttt_dh(const bf16* __restrict__ fv,
                                                const float* __restrict__ w1s,
                                                bf16* __restrict__ t4, int chunk) {
  const int bh = blockIdx.z;
  const bf16* A = fv + ((size_t)(bh * cS + chunk * cCHUNK) + blockIdx.y * 64) * cFD;
  const float* Bm = w1s + (size_t)bh * cFD * cFD + blockIdx.x * 64;
  float acc[4][4] = {};
  gemm_core<1>(A, cFD, Bm, cFD, cFD, nullptr, acc);
  bf16* C = t4 + (size_t)bh * cFD * cFD;
  const int tx = threadIdx.x & 15, ty = threadIdx.x >> 4;
#pragma unroll
  for (int i = 0; i < 4; ++i)
    st4(C + (size_t)(blockIdx.y * 64 + ty * 4 + i) * cFD + blockIdx.x * 64 + tx * 4,
        make_float4(acc[i][0], acc[i][1], acc[i][2], acc[i][3]));
}

__global__ __launch_bounds__(256) void k_ttt_elem(bf16* t0, const bf16* t1, bf16* t2, bf16* t3, bf16* t4) {
  const size_t i = (size_t)blockIdx.x * 256 + threadIdx.x;
  float hq1 = b2f(t0[i]), hq2 = b2f(t1[i]), g1 = b2f(t2[i]), g2 = b2f(t3[i]), dh = b2f(t4[i]);
  float s1 = sigmoidf_(hq1);
  t0[i] = f2b(hq1 * s1 * hq2);
  float sg = sigmoidf_(g1);
  float gate = g1 * sg;
  t3[i] = f2b(gate * g2);                                   // hidden
  t4[i] = f2b(dh * gate);                                   // dh2
  t2[i] = f2b(dh * g2 * (sg * (1.0f + g1 * (1.0f - sg)))); // dh1
}

__global__ __launch_bounds__(256) void k_ttt_oc(const bf16* __restrict__ t0,
                                                const float* __restrict__ w1s,
                                                bf16* __restrict__ o_ttt, int chunk) {
  const int bh = blockIdx.z;
  const bf16* A = t0 + (size_t)bh * cFD * cFD + (size_t)blockIdx.y * 64 * cFD;
  const float* Bm = w1s + (size_t)bh * cFD * cFD + (size_t)blockIdx.x * 64 * cFD;
  float acc[4][4] = {};
  gemm_core<0>(A, cFD, Bm, cFD, cFD, nullptr, acc);
  bf16* C = o_ttt + (size_t)(bh * cS + chunk * cCHUNK) * cFD;
  const int tx = threadIdx.x & 15, ty = threadIdx.x >> 4;
#pragma unroll
  for (int i = 0; i < 4; ++i)
    st4(C + (size_t)(blockIdx.y * 64 + ty * 4 + i) * cFD + blockIdx.x * 64 + tx * 4,
        make_float4(acc[i][0], acc[i][1], acc[i][2], acc[i][3]));
}

__global__ __launch_bounds__(256) void k_ttt_upd(const bf16* __restrict__ Abase, long strideA,
                                                 const bf16* __restrict__ Bbase, long strideB,
                                                 float* __restrict__ Wbase,
                                                 const float* __restrict__ scbase, long strideSc) {
  const int bh = blockIdx.z;
  const bf16* A = Abase + (size_t)bh * strideA + blockIdx.y * 64;
  const bf16* Bm = Bbase + (size_t)bh * strideB + blockIdx.x * 64;
  const float* sc = scbase + (size_t)bh * strideSc;
  float acc[4][4] = {};
  gemm_core<2>(A, cFD, Bm, cFD, cCHUNK, sc, acc);
  float* W = Wbase + (size_t)bh * cFD * cFD;
  const int tx = threadIdx.x & 15, ty = threadIdx.x >> 4;
#pragma unroll
  for (int i = 0; i < 4; ++i) {
    float* wp = W + (size_t)(blockIdx.y * 64 + ty * 4 + i) * cFD + blockIdx.x * 64 + tx * 4;
    float4 old = *(float4*)wp;
    old.x += acc[i][0]; old.y += acc[i][1]; old.z += acc[i][2]; old.w += acc[i][3];
    *(float4*)wp = old;
  }
}

// --------------------------- state init ------------------------------------
__global__ __launch_bounds__(256) void k_winit(const float* __restrict__ w0, const float* __restrict__ w1,
                                               const float* __restrict__ w2,
                                               float* __restrict__ w0s, float* __restrict__ w1s,
                                               float* __restrict__ w2s) {
  const size_t i = (size_t)blockIdx.x * 256 + threadIdx.x;  // 0..2097151
  const int bh = (int)(i >> 18);
  const int f = bh & 3;
  const size_t off = i & 262143;
  const float* src; float* dst;
  if (blockIdx.y == 0) { src = w0; dst = w0s; }
  else if (blockIdx.y == 1) { src = w1; dst = w1s; }
  else { src = w2; dst = w2s; }
  dst[i] = src[(size_t)f * 262144 + off];
}

// --------------------------- rope table ------------------------------------
__global__ __launch_bounds__(64) void k_rope_tab(float* __restrict__ ct, float* __restrict__ stb) {
  const int si = blockIdx.x, j = threadIdx.x;
  float inv = powf(500000.0f, -(float)j / 64.0f);
  float ang = (float)si * inv;
  ct[(size_t)si * 64 + j] = cosf(ang);
  stb[(size_t)si * 64 + j] = sinf(ang);
}

// --------------------------- learning rates --------------------------------
__global__ __launch_bounds__(256) void k_lr(const float* __restrict__ x, const float* __restrict__ lr_w,
                                            const float* __restrict__ lr_b,
                                            float* lr0, float* lr1, float* lr2, float base) {
  const int token = blockIdx.x, b_ = token >> 11, si = token & 2047;
  const int wv = threadIdx.x >> 6, lane = threadIdx.x & 63;
  const float* xr = x + (size_t)token * cH;
#pragma unroll
  for (int jj = 0; jj < 3; ++jj) {
    const int j = wv * 3 + jj;
    const float* wr = lr_w + (size_t)j * cH;
    float s = 0.f;
    for (int k = lane; k < cH; k += 64) s += xr[k] * wr[k];
    for (int d = 32; d; d >>= 1) s += __shfl_down(s, d);
    if (lane == 0) {
      float v = s + lr_b[j] + base;
      float sp = (v > 15.f) ? v : log1pf(expf(v));
      const int tt = j >> 2, f = j & 3;
      float* dst = (tt == 0 ? lr0 : tt == 1 ? lr1 : lr2);
      dst[(size_t)(b_ * cNFW + f) * cS + si] = sp;
    }
  }
}

// --------------------------- per-token postprocess --------------------------
// rmsnorm q/k in-place in qkvh (bf16), emit fq/fk (silu+l2norm) and fv=silu(v).
__global__ __launch_bounds__(256) void k_post(bf16* __restrict__ qkvh,
                                              const float* __restrict__ qnw, const float* __restrict__ knw,
                                              const float* __restrict__ qk_scale,
                                              const float* __restrict__ qk_offset,
                                              bf16* fq, bf16* fk, bf16* fv) {
  const int token = blockIdx.x, b_ = token >> 11, si = token & 2047;
  const int t = threadIdx.x;
  __shared__ float buf[cH];
  __shared__ float red[4];
  bf16* base = qkvh + (size_t)token * 3 * cH;

  for (int pass = 0; pass < 2; ++pass) {
    __syncthreads();
    bf16* src = base + pass * cH;
    const float* nw = pass ? knw : qnw;
    bf16* fdst = pass ? fk : fq;

    float ss = 0.f;
    for (int i = t; i < cH; i += 256) {
      float v = b2f(src[i]);
      buf[i] = v;
      ss += v * v;
    }
    for (int d = 32; d; d >>= 1) ss += __shfl_down(ss, d);
    if ((t & 63) == 0) red[t >> 6] = ss;
    __syncthreads();
    const float rstd = rsqrtf((red[0] + red[1] + red[2] + red[3]) / cH + 1e-6f);
    for (int i = t; i < cH; i += 256) {
      float v = buf[i] * rstd * nw[i];
      buf[i] = v;
      src[i] = f2b(v);  // normalized q/k back in place for attention
    }
    __syncthreads();

    {
      const int head = t >> 6, lane = t & 63;
      float f[8];
      float ss2 = 0.f;
#pragma unroll
      for (int k = 0; k < 8; ++k) {
        const int idx = head * cFD + lane + k * 64;
        float v = buf[idx];
        float u = v * qk_scale[idx * 2 + pass] + qk_offset[idx * 2 + pass];
        float fv_ = u * sigmoidf_(u);
        f[k] = fv_;
        ss2 += fv_ * fv_;
      }
      for (int d = 1; d < 64; d <<= 1) ss2 += __shfl_xor(ss2, d);
      const float sc2 = rsqrtf(ss2 + 1e-12f);
      bf16* dst = fdst + ((size_t)(b_ * cNFW + head) * cS + si) * cFD;
#pragma unroll
      for (int k = 0; k < 8; ++k) dst[lane + k * 64] = f2b(f[k] * sc2);
    }
  }

  const bf16* vr = base + 2 * cH;
  for (int i = t; i < cH; i += 256) {
    float v = b2f(vr[i]);
    fv[((size_t)(b_ * cNFW + (i >> 9)) * cS + si) * cFD + (i & 511)] = f2b(v * sigmoidf_(v));
  }
}

// --------------------------- attention (flash, fp32 math) -------------------
__global__ __launch_bounds__(256) void k_attn(const bf16* __restrict__ qkvh,
                                              const float* __restrict__ ct, const float* __restrict__ stb,
                                              bf16* __restrict__ y) {
  const int qt = blockIdx.x, h = blockIdx.y, b_ = blockIdx.z;
  const int q0 = qt * 32;
  __shared__ float qs[32][132], ks[32][132], vs[32][132];
  __shared__ float ps[32][33];
  const int t = threadIdx.x;
  const int r = t >> 3, g = t & 7, j0 = g * 8;
  {
    const int tok = q0 + r;
    const bf16* src = qkvh + ((size_t)(b_ * cS) + tok) * 3 * cH + h * cHD;
    float x1[8], x2[8];
    ld8f(src + j0, x1);
    ld8f(src + j0 + 64, x2);
    const float* cr = ct + (size_t)tok * 64 + j0;
    const float* sr = stb + (size_t)tok * 64 + j0;
#pragma unroll
    for (int i = 0; i < 8; ++i) {
      qs[r][j0 + i] = x1[i] * cr[i] - x2[i] * sr[i];
      qs[r][j0 + 64 + i] = x2[i] * cr[i] + x1[i] * sr[i];
    }
  }
  const int lane = t & 63, wv = t >> 6;
  const int row = wv * 8 + (lane >> 3), cg = lane & 7;
  float m = -1e30f, se = 0.f;
  float acc_o[16];
#pragma unroll
  for (int i = 0; i < 16; ++i) acc_o[i] = 0.f;

  for (int kt = 0; kt <= qt; ++kt) {
    __syncthreads();
    {
      const int tok = kt * 32 + r;
      const bf16* ksrc = qkvh + ((size_t)(b_ * cS) + tok) * 3 * cH + cH + h * cHD;
      const bf16* vsrc = ksrc + cH;
      float x1[8], x2[8];
      ld8f(ksrc + j0, x1);
      ld8f(ksrc + j0 + 64, x2);
      const float* cr = ct + (size_t)tok * 64 + j0;
      const float* sr = stb + (size_t)tok * 64 + j0;
#pragma unroll
      for (int i = 0; i < 8; ++i) {
        ks[r][j0 + i] = x1[i] * cr[i] - x2[i] * sr[i];
        ks[r][j0 + 64 + i] = x2[i] * cr[i] + x1[i] * sr[i];
      }
      ld8f(vsrc + j0, x1);
      ld8f(vsrc + j0 + 64, x2);
#pragma unroll
      for (int i = 0; i < 8; ++i) {
        vs[r][j0 + i] = x1[i];
        vs[r][j0 + 64 + i] = x2[i];
      }
    }
    __syncthreads();

    float sc[4] = {0.f, 0.f, 0.f, 0.f};
    for (int d4 = 0; d4 < 32; ++d4) {
      float4 q4 = *(const float4*)&qs[row][d4 * 4];
#pragma unroll
      for (int j = 0; j < 4; ++j) {
        float4 k4 = *(const float4*)&ks[cg + j * 8][d4 * 4];
        sc[j] += q4.x * k4.x + q4.y * k4.y + q4.z * k4.z + q4.w * k4.w;
      }
    }
#pragma unroll
    for (int j = 0; j < 4; ++j) {
      sc[j] *= cRSQRT_HD;
      if (kt == qt) {
        const int kc = kt * 32 + cg + j * 8;
        if (kc > q0 + row) sc[j] = -1e9f;
      }
    }
    float mx = fmaxf(fmaxf(sc[0], sc[1]), fmaxf(sc[2], sc[3]));
    for (int d = 1; d < 8; d <<= 1) mx = fmaxf(mx, __shfl_xor(mx, d));
    const float mnew = fmaxf(m, mx);
    const float corr = __expf(m - mnew);
    float p[4], psum = 0.f;
#pragma unroll
    for (int j = 0; j < 4; ++j) {
      p[j] = __expf(sc[j] - mnew);
      psum += p[j];
      ps[row][cg + j * 8] = p[j];
    }
    se = se * corr + psum;
    m = mnew;
#pragma unroll
    for (int i = 0; i < 16; ++i) acc_o[i] *= corr;
    for (int col = 0; col < 32; ++col) {
      const float pv = ps[row][col];
#pragma unroll
      for (int i4 = 0; i4 < 4; ++i4) {
        float4 v4 = *(const float4*)&vs[col][i4 * 32 + cg * 4];
        acc_o[i4 * 4 + 0] += pv * v4.x;
        acc_o[i4 * 4 + 1] += pv * v4.y;
        acc_o[i4 * 4 + 2] += pv * v4.z;
        acc_o[i4 * 4 + 3] += pv * v4.w;
      }
    }
  }
  for (int d = 1; d < 8; d <<= 1) se += __shfl_xor(se, d);
  const float inv = 1.f / se;
  bf16* dst = y + ((size_t)(b_ * cS) + q0 + row) * cH + h * cHD;
#pragma unroll
  for (int i4 = 0; i4 < 4; ++i4) {
    const int d0 = i4 * 32 + cg * 4;
    dst[d0 + 0] = f2b(acc_o[i4 * 4 + 0] * inv);
    dst[d0 + 1] = f2b(acc_o[i4 * 4 + 1] * inv);
    dst[d0 + 2] = f2b(acc_o[i4 * 4 + 2] * inv);
    dst[d0 + 3] = f2b(acc_o[i4 * 4 + 3] * inv);
  }
}

// --------------------------- o_ttt rmsnorm + add into y ---------------------
__global__ __launch_bounds__(256) void k_ttt_norm(const bf16* __restrict__ o_ttt,
                                                  const float* __restrict__ tw, bf16* __restrict__ y) {
  const int r = blockIdx.x;  // rows of (b, f, s)
  const int bh = r >> 11, si = r & 2047, b_ = bh >> 2, f = bh & 3;
  const bf16* src = o_ttt + (size_t)r * cFD;
  const int t = threadIdx.x;
  float v0 = b2f(src[t]), v1 = b2f(src[t + 256]);
  float ss = v0 * v0 + v1 * v1;
  __shared__ float red[4];
  for (int d = 32; d; d >>= 1) ss += __shfl_down(ss, d);
  if ((t & 63) == 0) red[t >> 6] = ss;
  __syncthreads();
  const float rstd = rsqrtf((red[0] + red[1] + red[2] + red[3]) / cFD + 1e-6f);
  bf16* dst = y + ((size_t)(b_ * cS) + si) * cH + f * cFD;
  dst[t] = f2b(b2f(dst[t]) + v0 * rstd * tw[t]);
  dst[t + 256] = f2b(b2f(dst[t + 256]) + v1 * rstd * tw[t + 256]);
}

}  // namespace

extern "C" void kernel_launch(void* const* d_in, const int* in_sizes, int n_in,
                              void* d_out, int out_size, void* d_ws, size_t ws_size,
                              hipStream_t stream) {
  (void)in_sizes; (void)n_in; (void)out_size; (void)ws_size;
  const float* x         = (const float*)d_in[0];
  const float* qkv_w     = (const float*)d_in[1];
  const float* q_norm_w  = (const float*)d_in[2];
  const float* k_norm_w  = (const float*)d_in[3];
  const float* qk_scale  = (const float*)d_in[4];
  const float* qk_offset = (const float*)d_in[5];
  const float* lr_w      = (const float*)d_in[6];
  const float* lr_b      = (const float*)d_in[7];
  const float* w0        = (const float*)d_in[8];
  const float* w1        = (const float*)d_in[9];
  const float* w2        = (const float*)d_in[10];
  const float* ttt_nw    = (const float*)d_in[11];
  const float* o_proj_w  = (const float*)d_in[12];
  float* out = (float*)d_out;

  // ---- workspace layout (bytes), total 143,851,520 ----
  char* Wb = (char*)d_ws;
  bf16* qkvh  = (bf16*)Wb;                       // 50,331,648 B (region A)
  // region A reuse after attention:
  bf16* o_ttt = (bf16*)Wb;                       // 16,777,216 B
  bf16* t0 = (bf16*)(Wb + 16777216UL);
  bf16* t1 = (bf16*)(Wb + 16777216UL + 1UL * 4194304UL);
  bf16* t2 = (bf16*)(Wb + 16777216UL + 2UL * 4194304UL);
  bf16* t3 = (bf16*)(Wb + 16777216UL + 3UL * 4194304UL);
  bf16* t4 = (bf16*)(Wb + 16777216UL + 4UL * 4194304UL);
  size_t off = 50331648UL;
  bf16* fq = (bf16*)(Wb + off); off += 16777216UL;
  bf16* fk = (bf16*)(Wb + off); off += 16777216UL;
  bf16* fv = (bf16*)(Wb + off); off += 16777216UL;
  float* w0s = (float*)(Wb + off); off += 8388608UL;
  float* w1s = (float*)(Wb + off); off += 8388608UL;
  float* w2s = (float*)(Wb + off); off += 8388608UL;
  float* lr0 = (float*)(Wb + off); off += 65536UL;
  float* lr1 = (float*)(Wb + off); off += 65536UL;
  float* lr2 = (float*)(Wb + off); off += 65536UL;
  bf16* y = (bf16*)(Wb + off); off += 16777216UL;
  float* ct  = (float*)(Wb + off); off += 524288UL;
  float* stb = (float*)(Wb + off); off += 524288UL;

  const float base_lr_inv = logf(expm1f(0.001f));
  dim3 blk(256);

  k_winit<<<dim3(8192, 3), blk, 0, stream>>>(w0, w1, w2, w0s, w1s, w2s);
  k_rope_tab<<<dim3(2048), dim3(64), 0, stream>>>(ct, stb);
  k_gemm_nt<float, float, bf16><<<dim3(96, 64), blk, 0, stream>>>(x, qkv_w, qkvh, 2048, 2048, 2048, 6144);
  k_lr<<<dim3(4096), blk, 0, stream>>>(x, lr_w, lr_b, lr0, lr1, lr2, base_lr_inv);
  k_post<<<dim3(4096), blk, 0, stream>>>(qkvh, q_norm_w, k_norm_w, qk_scale, qk_offset, fq, fk, fv);
  k_attn<<<dim3(64, 16, 2), blk, 0, stream>>>(qkvh, ct, stb, y);

  const long sA_glob = (long)cS * cFD;
  const long sA_loc  = (long)cFD * cFD;
  for (int c = 0; c < 4; ++c) {
    k_ttt_stage1<<<dim3(8, 8, 32), blk, 0, stream>>>(fq, fk, w0s, w2s, t0, t1, t2, t3, c);
    k_ttt_dh<<<dim3(8, 8, 8), blk, 0, stream>>>(fv, w1s, t4, c);
    k_ttt_elem<<<dim3(8192), blk, 0, stream>>>(t0, t1, t2, t3, t4);
    k_ttt_oc<<<dim3(8, 8, 8), blk, 0, stream>>>(t0, w1s, o_ttt, c);
    k_ttt_upd<<<dim3(8, 8, 8), blk, 0, stream>>>(fv + (size_t)c * cCHUNK * cFD, sA_glob,
                                                 t3, sA_loc, w1s, lr1 + c * cCHUNK, (long)cS);
    k_ttt_upd<<<dim3(8, 8, 8), blk, 0, stream>>>(t2, sA_loc,
                                                 fk + (size_t)c * cCHUNK * cFD, sA_glob,
                                                 w0s, lr0 + c * cCHUNK, (long)cS);
    k_ttt_upd<<<dim3(8, 8, 8), blk, 0, stream>>>(t4, sA_loc,
                                                 fk + (size_t)c * cCHUNK * cFD, sA_glob,
                                                 w2s, lr2 + c * cCHUNK, (long)cS);
  }
  k_ttt_norm<<<dim3(16384), blk, 0, stream>>>(o_ttt, ttt_nw, y);
  k_gemm_nt<bf16, float, float><<<dim3(32, 64), blk, 0, stream>>>(y, o_proj_w, out, 2048, 2048, 2048, 2048);
}

// Round 4
// 1953.840 us; speedup vs baseline: 2.6632x; 2.6632x over previous
//
#include <hip/hip_runtime.h>
#include <hip/hip_bf16.h>
#include <math.h>

using bf16 = __hip_bfloat16;

namespace {

constexpr int cH = 2048;
constexpr int cNH = 16;
constexpr int cHD = 128;
constexpr int cNFW = 4;
constexpr int cFD = 512;
constexpr int cCHUNK = 512;
constexpr int cS = 2048;
constexpr float cRSQRT_HD = 0.08838834764831845f;  // 1/sqrt(128)

typedef __attribute__((ext_vector_type(8))) short short8;
typedef __attribute__((ext_vector_type(4))) float f32x4;

__device__ __forceinline__ float sigmoidf_(float x) { return 1.0f / (1.0f + __expf(-x)); }
__device__ __forceinline__ float b2f(bf16 v) { return __bfloat162float(v); }
__device__ __forceinline__ bf16 f2b(float v) { return __float2bfloat16(v); }
__device__ __forceinline__ unsigned short f2bu(float f) {
  return __builtin_bit_cast(unsigned short, __float2bfloat16(f));
}
__device__ __forceinline__ float bu2f(unsigned u) { return __uint_as_float(u << 16); }

__device__ __forceinline__ float loadf(const float* p) { return *p; }
__device__ __forceinline__ float loadf(const bf16* p) { return b2f(*p); }

// load 16 bf16 -> 16 floats
__device__ __forceinline__ void ld16f(const bf16* p, float* o) {
  const uint4 a = *(const uint4*)p, b = *(const uint4*)(p + 8);
  o[0] = bu2f(a.x & 0xffffu); o[1] = bu2f(a.x >> 16);
  o[2] = bu2f(a.y & 0xffffu); o[3] = bu2f(a.y >> 16);
  o[4] = bu2f(a.z & 0xffffu); o[5] = bu2f(a.z >> 16);
  o[6] = bu2f(a.w & 0xffffu); o[7] = bu2f(a.w >> 16);
  o[8] = bu2f(b.x & 0xffffu); o[9] = bu2f(b.x >> 16);
  o[10] = bu2f(b.y & 0xffffu); o[11] = bu2f(b.y >> 16);
  o[12] = bu2f(b.z & 0xffffu); o[13] = bu2f(b.z >> 16);
  o[14] = bu2f(b.w & 0xffffu); o[15] = bu2f(b.w >> 16);
}

// stage 16 contiguous source elems as bf16 into LDS (dst 16B-aligned)
__device__ __forceinline__ void stage16(const float* src, short* dst) {
  float4 f0 = *(const float4*)src, f1 = *(const float4*)(src + 4);
  float4 f2 = *(const float4*)(src + 8), f3 = *(const float4*)(src + 12);
  unsigned short u[16] __attribute__((aligned(16)));
  u[0] = f2bu(f0.x); u[1] = f2bu(f0.y); u[2] = f2bu(f0.z); u[3] = f2bu(f0.w);
  u[4] = f2bu(f1.x); u[5] = f2bu(f1.y); u[6] = f2bu(f1.z); u[7] = f2bu(f1.w);
  u[8] = f2bu(f2.x); u[9] = f2bu(f2.y); u[10] = f2bu(f2.z); u[11] = f2bu(f2.w);
  u[12] = f2bu(f3.x); u[13] = f2bu(f3.y); u[14] = f2bu(f3.z); u[15] = f2bu(f3.w);
  *(uint4*)dst = *(uint4*)u;
  *(uint4*)(dst + 8) = *(uint4*)(u + 8);
}
__device__ __forceinline__ void stage16(const bf16* src, short* dst) {
  *(uint4*)dst = *(const uint4*)src;
  *(uint4*)(dst + 8) = *(const uint4*)(src + 8);
}

__device__ __forceinline__ void store1(float* p, float v) { *p = v; }
__device__ __forceinline__ void store1(bf16* p, float v) { *p = f2b(v); }

// ---------------------------------------------------------------------------
// MFMA bf16 GEMM: C[m,n] = sum_k A[m,k]*B'[n,k]; BT=false: B' = B (NT, both
// k-major). BT=true: B is [K][N] row-major (NN), transposed during staging.
// 128x128 tile, 4 waves (each 64x64 = 4x4 frags of 16x16), BK=32.
// ---------------------------------------------------------------------------
template <typename TA, typename TB, typename TC, bool ACC, bool BT>
__global__ __launch_bounds__(256) void k_mm(const TA* __restrict__ A, int lda, long zsa,
                                            const TB* __restrict__ B, int ldb, long zsb,
                                            TC* __restrict__ C, int ldc, long zsc, int K) {
  __shared__ short As[128 * 40];
  __shared__ short Bs[128 * 40];
  const int t = threadIdx.x, lane = t & 63, g = lane >> 4, c16 = lane & 15;
  const int wv = t >> 6, wm = (wv >> 1) * 64, wn = (wv & 1) * 64;
  const int z = blockIdx.z;
  const TA* Ab = A + (size_t)z * zsa + (size_t)blockIdx.y * 128 * lda;
  const TB* Bb = BT ? (B + (size_t)z * zsb + blockIdx.x * 128)
                    : (B + (size_t)z * zsb + (size_t)blockIdx.x * 128 * ldb);
  f32x4 acc[4][4];
  const f32x4 zero4 = {0.f, 0.f, 0.f, 0.f};
#pragma unroll
  for (int i = 0; i < 4; ++i)
#pragma unroll
    for (int j = 0; j < 4; ++j) acc[i][j] = zero4;

  for (int k0 = 0; k0 < K; k0 += 32) {
    __syncthreads();
    {
      const int r = t >> 1, sseg = (t & 1) * 16;
      stage16(Ab + (size_t)r * lda + k0 + sseg, &As[r * 40 + sseg]);
    }
    if (!BT) {
      const int r = t >> 1, sseg = (t & 1) * 16;
      stage16(Bb + (size_t)r * ldb + k0 + sseg, &Bs[r * 40 + sseg]);
    } else {
      const int kk = t >> 3, cseg = (t & 7) * 16;
      const TB* p = Bb + (size_t)(k0 + kk) * ldb + cseg;
#pragma unroll
      for (int i = 0; i < 16; ++i) Bs[(cseg + i) * 40 + kk] = (short)f2bu(loadf(p + i));
    }
    __syncthreads();
    short8 af[4], bfr[4];
#pragma unroll
    for (int mi = 0; mi < 4; ++mi) af[mi] = *(const short8*)&As[(wm + mi * 16 + c16) * 40 + g * 8];
#pragma unroll
    for (int ni = 0; ni < 4; ++ni) bfr[ni] = *(const short8*)&Bs[(wn + ni * 16 + c16) * 40 + g * 8];
#pragma unroll
    for (int mi = 0; mi < 4; ++mi)
#pragma unroll
      for (int ni = 0; ni < 4; ++ni)
        acc[mi][ni] = __builtin_amdgcn_mfma_f32_16x16x32_bf16(af[mi], bfr[ni], acc[mi][ni], 0, 0, 0);
  }
  TC* Cb = C + (size_t)z * zsc;
  const int rbase = blockIdx.y * 128 + wm, cbase = blockIdx.x * 128 + wn;
#pragma unroll
  for (int mi = 0; mi < 4; ++mi)
#pragma unroll
    for (int ni = 0; ni < 4; ++ni) {
      const int col = cbase + ni * 16 + c16;
#pragma unroll
      for (int r = 0; r < 4; ++r) {
        const int row = rbase + mi * 16 + g * 4 + r;
        TC* cp = Cb + (size_t)row * ldc + col;
        if constexpr (ACC) {
          *cp = *cp + acc[mi][ni][r];
        } else {
          store1(cp, acc[mi][ni][r]);
        }
      }
    }
}

// ---------------------------------------------------------------------------
// Transpose [bh][512][512] (opt. per-source-row scale) -> bf16 [bh][512][512]
// ---------------------------------------------------------------------------
template <typename TS, bool SCALE>
__global__ __launch_bounds__(256) void k_tr(const TS* __restrict__ src, long zs, int lds_,
                                            bf16* __restrict__ dst, long zd,
                                            const float* __restrict__ scale, long zscale) {
  __shared__ short Ts[64 * 72];
  const int z = blockIdx.z, t = threadIdx.x;
  const TS* sp = src + (size_t)z * zs + (size_t)(blockIdx.y * 64) * lds_ + blockIdx.x * 64;
  {
    const int r = t >> 2, cseg = (t & 3) * 16;
    float s = 1.f;
    if (SCALE) s = scale[(size_t)z * zscale + blockIdx.y * 64 + r];
    const TS* p = sp + (size_t)r * lds_ + cseg;
    unsigned short u[16] __attribute__((aligned(16)));
#pragma unroll
    for (int i = 0; i < 16; ++i) u[i] = f2bu(loadf(p + i) * s);
    *(uint4*)&Ts[r * 72 + cseg] = *(uint4*)u;
    *(uint4*)&Ts[r * 72 + cseg + 8] = *(uint4*)(u + 8);
  }
  __syncthreads();
  {
    const int oc_ = t >> 2, rseg = (t & 3) * 16;
    unsigned short u[16] __attribute__((aligned(16)));
#pragma unroll
    for (int i = 0; i < 16; ++i) u[i] = (unsigned short)Ts[(rseg + i) * 72 + oc_];
    bf16* dp = dst + (size_t)z * zd + (size_t)(blockIdx.x * 64 + oc_) * 512 + blockIdx.y * 64 + rseg;
    *(uint4*)dp = *(uint4*)u;
    *(uint4*)(dp + 8) = *(uint4*)(u + 8);
  }
}

// --------------------------- elementwise gates ------------------------------
__global__ __launch_bounds__(256) void k_elem(bf16* t0, const bf16* t1, bf16* t2, bf16* t3, bf16* t4) {
  const size_t i = (size_t)blockIdx.x * 256 + threadIdx.x;
  float hq1 = b2f(t0[i]), hq2 = b2f(t1[i]), g1 = b2f(t2[i]), g2 = b2f(t3[i]), dh = b2f(t4[i]);
  float s1 = sigmoidf_(hq1);
  t0[i] = f2b(hq1 * s1 * hq2);
  float sg = sigmoidf_(g1);
  float gate = g1 * sg;
  t3[i] = f2b(gate * g2);                                   // hidden
  t4[i] = f2b(dh * gate);                                   // dh2
  t2[i] = f2b(dh * g2 * (sg * (1.0f + g1 * (1.0f - sg)))); // dh1
}

// --------------------------- state init ------------------------------------
__global__ __launch_bounds__(256) void k_winit(const float* __restrict__ w0, const float* __restrict__ w1,
                                               const float* __restrict__ w2,
                                               float* __restrict__ w0s, float* __restrict__ w1s,
                                               float* __restrict__ w2s) {
  const size_t i = (size_t)blockIdx.x * 256 + threadIdx.x;  // 0..2097151
  const int bh = (int)(i >> 18);
  const int f = bh & 3;
  const size_t off = i & 262143;
  const float* src; float* dst;
  if (blockIdx.y == 0) { src = w0; dst = w0s; }
  else if (blockIdx.y == 1) { src = w1; dst = w1s; }
  else { src = w2; dst = w2s; }
  dst[i] = src[(size_t)f * 262144 + off];
}

// --------------------------- rope table ------------------------------------
__global__ __launch_bounds__(64) void k_rope_tab(float* __restrict__ ct, float* __restrict__ stb) {
  const int si = blockIdx.x, j = threadIdx.x;
  float inv = powf(500000.0f, -(float)j / 64.0f);
  float ang = (float)si * inv;
  ct[(size_t)si * 64 + j] = cosf(ang);
  stb[(size_t)si * 64 + j] = sinf(ang);
}

// --------------------------- learning rates --------------------------------
__global__ __launch_bounds__(256) void k_lr(const float* __restrict__ x, const float* __restrict__ lr_w,
                                            const float* __restrict__ lr_b,
                                            float* lr0, float* lr1, float* lr2, float base) {
  const int token = blockIdx.x, b_ = token >> 11, si = token & 2047;
  const int wv = threadIdx.x >> 6, lane = threadIdx.x & 63;
  const float* xr = x + (size_t)token * cH;
#pragma unroll
  for (int jj = 0; jj < 3; ++jj) {
    const int j = wv * 3 + jj;
    const float* wr = lr_w + (size_t)j * cH;
    float s = 0.f;
    for (int k = lane; k < cH; k += 64) s += xr[k] * wr[k];
    for (int d = 32; d; d >>= 1) s += __shfl_down(s, d);
    if (lane == 0) {
      float v = s + lr_b[j] + base;
      float sp = (v > 15.f) ? v : log1pf(expf(v));
      const int tt = j >> 2, f = j & 3;
      float* dst = (tt == 0 ? lr0 : tt == 1 ? lr1 : lr2);
      dst[(size_t)(b_ * cNFW + f) * cS + si] = sp;
    }
  }
}

// --------------------------- per-token postprocess --------------------------
__global__ __launch_bounds__(256) void k_post(bf16* __restrict__ qkvh,
                                              const float* __restrict__ qnw, const float* __restrict__ knw,
                                              const float* __restrict__ qk_scale,
                                              const float* __restrict__ qk_offset,
                                              bf16* fq, bf16* fk, bf16* fv) {
  const int token = blockIdx.x, b_ = token >> 11, si = token & 2047;
  const int t = threadIdx.x;
  __shared__ float buf[cH];
  __shared__ float red[4];
  bf16* base = qkvh + (size_t)token * 3 * cH;

  for (int pass = 0; pass < 2; ++pass) {
    __syncthreads();
    bf16* src = base + pass * cH;
    const float* nw = pass ? knw : qnw;
    bf16* fdst = pass ? fk : fq;

    float ss = 0.f;
    for (int i = t; i < cH; i += 256) {
      float v = b2f(src[i]);
      buf[i] = v;
      ss += v * v;
    }
    for (int d = 32; d; d >>= 1) ss += __shfl_down(ss, d);
    if ((t & 63) == 0) red[t >> 6] = ss;
    __syncthreads();
    const float rstd = rsqrtf((red[0] + red[1] + red[2] + red[3]) / cH + 1e-6f);
    for (int i = t; i < cH; i += 256) {
      float v = buf[i] * rstd * nw[i];
      buf[i] = v;
      src[i] = f2b(v);  // normalized q/k back in place for attention
    }
    __syncthreads();
    {
      const int head = t >> 6, lane = t & 63;
      float f[8];
      float ss2 = 0.f;
#pragma unroll
      for (int k = 0; k < 8; ++k) {
        const int idx = head * cFD + lane + k * 64;
        float v = buf[idx];
        float u = v * qk_scale[idx * 2 + pass] + qk_offset[idx * 2 + pass];
        float fv_ = u * sigmoidf_(u);
        f[k] = fv_;
        ss2 += fv_ * fv_;
      }
      for (int d = 1; d < 64; d <<= 1) ss2 += __shfl_xor(ss2, d);
      const float sc2 = rsqrtf(ss2 + 1e-12f);
      bf16* dst = fdst + ((size_t)(b_ * cNFW + head) * cS + si) * cFD;
#pragma unroll
      for (int k = 0; k < 8; ++k) dst[lane + k * 64] = f2b(f[k] * sc2);
    }
  }

  const bf16* vr = base + 2 * cH;
  for (int i = t; i < cH; i += 256) {
    float v = b2f(vr[i]);
    fv[((size_t)(b_ * cNFW + (i >> 9)) * cS + si) * cFD + (i & 511)] = f2b(v * sigmoidf_(v));
  }
}

// --------------------------- attention (flash, MFMA) ------------------------
// grid (32 qtiles of 64, 16 heads, 2 batch); 256 thr = 4 waves, wave owns 16 q rows.
__global__ __launch_bounds__(256) void k_attn_m(const bf16* __restrict__ qkvh,
                                                const float* __restrict__ ct,
                                                const float* __restrict__ stb,
                                                bf16* __restrict__ y) {
  const int qt = blockIdx.x, h = blockIdx.y, b_ = blockIdx.z;
  const int q0 = qt * 64;
  __shared__ short Qs[64 * 136];
  __shared__ short Ks[64 * 136];
  __shared__ short Vt[128 * 72];
  __shared__ short Ps[4 * 16 * 72];
  const int t = threadIdx.x, lane = t & 63, g = lane >> 4, c16 = lane & 15, wv = t >> 6;
  {
    const int r = t >> 2, d0 = (t & 3) * 16;
    const int tok = q0 + r;
    const bf16* src = qkvh + ((size_t)(b_ * cS) + tok) * 3 * cH + h * cHD;
    float x1[16], x2[16];
    ld16f(src + d0, x1);
    ld16f(src + d0 + 64, x2);
    unsigned short o1[16] __attribute__((aligned(16))), o2[16] __attribute__((aligned(16)));
    const float* cr = ct + (size_t)tok * 64 + d0;
    const float* sr = stb + (size_t)tok * 64 + d0;
#pragma unroll
    for (int i = 0; i < 16; ++i) {
      float c = cr[i], s = sr[i];
      o1[i] = f2bu((x1[i] * c - x2[i] * s) * cRSQRT_HD);
      o2[i] = f2bu((x2[i] * c + x1[i] * s) * cRSQRT_HD);
    }
    *(uint4*)&Qs[r * 136 + d0] = *(uint4*)o1;
    *(uint4*)&Qs[r * 136 + d0 + 8] = *(uint4*)(o1 + 8);
    *(uint4*)&Qs[r * 136 + d0 + 64] = *(uint4*)o2;
    *(uint4*)&Qs[r * 136 + d0 + 72] = *(uint4*)(o2 + 8);
  }
  f32x4 o[8];
  const f32x4 zero4 = {0.f, 0.f, 0.f, 0.f};
#pragma unroll
  for (int i = 0; i < 8; ++i) o[i] = zero4;
  float m[4], l[4];
#pragma unroll
  for (int r = 0; r < 4; ++r) { m[r] = -1e30f; l[r] = 0.f; }

  for (int kt = 0; kt <= qt; ++kt) {
    __syncthreads();
    {
      const int r = t >> 2, d0 = (t & 3) * 16;
      const int tok = kt * 64 + r;
      const bf16* src = qkvh + ((size_t)(b_ * cS) + tok) * 3 * cH + cH + h * cHD;
      float x1[16], x2[16];
      ld16f(src + d0, x1);
      ld16f(src + d0 + 64, x2);
      unsigned short o1[16] __attribute__((aligned(16))), o2[16] __attribute__((aligned(16)));
      const float* cr = ct + (size_t)tok * 64 + d0;
      const float* sr = stb + (size_t)tok * 64 + d0;
#pragma unroll
      for (int i = 0; i < 16; ++i) {
        float c = cr[i], s = sr[i];
        o1[i] = f2bu(x1[i] * c - x2[i] * s);
        o2[i] = f2bu(x2[i] * c + x1[i] * s);
      }
      *(uint4*)&Ks[r * 136 + d0] = *(uint4*)o1;
      *(uint4*)&Ks[r * 136 + d0 + 8] = *(uint4*)(o1 + 8);
      *(uint4*)&Ks[r * 136 + d0 + 64] = *(uint4*)o2;
      *(uint4*)&Ks[r * 136 + d0 + 72] = *(uint4*)(o2 + 8);
      // V transposed into Vt[d][kv]
      const bf16* vsrc = qkvh + ((size_t)(b_ * cS) + tok) * 3 * cH + 2 * cH + h * cHD;
      const int vd0 = (t & 3) * 32;
      unsigned short vv[32];
      *(uint4*)vv = *(const uint4*)(vsrc + vd0);
      *(uint4*)(vv + 8) = *(const uint4*)(vsrc + vd0 + 8);
      *(uint4*)(vv + 16) = *(const uint4*)(vsrc + vd0 + 16);
      *(uint4*)(vv + 24) = *(const uint4*)(vsrc + vd0 + 24);
#pragma unroll
      for (int i = 0; i < 32; ++i) {
        int ii = (i + t) & 31;
        Vt[(vd0 + ii) * 72 + r] = (short)vv[ii];
      }
    }
    __syncthreads();

    f32x4 s4[4];
#pragma unroll
    for (int ni = 0; ni < 4; ++ni) s4[ni] = zero4;
#pragma unroll
    for (int ks = 0; ks < 4; ++ks) {
      short8 a = *(const short8*)&Qs[(wv * 16 + c16) * 136 + ks * 32 + g * 8];
#pragma unroll
      for (int ni = 0; ni < 4; ++ni) {
        short8 bb = *(const short8*)&Ks[(ni * 16 + c16) * 136 + ks * 32 + g * 8];
        s4[ni] = __builtin_amdgcn_mfma_f32_16x16x32_bf16(a, bb, s4[ni], 0, 0, 0);
      }
    }
    if (kt == qt) {
#pragma unroll
      for (int ni = 0; ni < 4; ++ni) {
        const int kv = kt * 64 + ni * 16 + c16;
#pragma unroll
        for (int r = 0; r < 4; ++r) {
          const int qr = q0 + wv * 16 + g * 4 + r;
          if (kv > qr) s4[ni][r] = -1e9f;
        }
      }
    }
    float mx[4];
#pragma unroll
    for (int r = 0; r < 4; ++r)
      mx[r] = fmaxf(fmaxf(s4[0][r], s4[1][r]), fmaxf(s4[2][r], s4[3][r]));
#pragma unroll
    for (int d = 1; d < 16; d <<= 1)
#pragma unroll
      for (int r = 0; r < 4; ++r) mx[r] = fmaxf(mx[r], __shfl_xor(mx[r], d));
    float corr[4];
#pragma unroll
    for (int r = 0; r < 4; ++r) {
      float mn = fmaxf(m[r], mx[r]);
      corr[r] = __expf(m[r] - mn);
      m[r] = mn;
    }
    float psum[4] = {0.f, 0.f, 0.f, 0.f};
#pragma unroll
    for (int ni = 0; ni < 4; ++ni)
#pragma unroll
      for (int r = 0; r < 4; ++r) {
        float p = __expf(s4[ni][r] - m[r]);
        s4[ni][r] = p;
        psum[r] += p;
      }
#pragma unroll
    for (int d = 1; d < 16; d <<= 1)
#pragma unroll
      for (int r = 0; r < 4; ++r) psum[r] += __shfl_xor(psum[r], d);
#pragma unroll
    for (int r = 0; r < 4; ++r) l[r] = l[r] * corr[r] + psum[r];
#pragma unroll
    for (int nf = 0; nf < 8; ++nf)
#pragma unroll
      for (int r = 0; r < 4; ++r) o[nf][r] *= corr[r];
    short* pw = &Ps[wv * 1152];
#pragma unroll
    for (int ni = 0; ni < 4; ++ni)
#pragma unroll
      for (int r = 0; r < 4; ++r)
        pw[(g * 4 + r) * 72 + ni * 16 + c16] = (short)f2bu(s4[ni][r]);
    __syncthreads();
#pragma unroll
    for (int ks2 = 0; ks2 < 2; ++ks2) {
      short8 a = *(const short8*)&pw[c16 * 72 + ks2 * 32 + g * 8];
#pragma unroll
      for (int nf = 0; nf < 8; ++nf) {
        short8 bb = *(const short8*)&Vt[(nf * 16 + c16) * 72 + ks2 * 32 + g * 8];
        o[nf] = __builtin_amdgcn_mfma_f32_16x16x32_bf16(a, bb, o[nf], 0, 0, 0);
      }
    }
  }
  float inv[4];
#pragma unroll
  for (int r = 0; r < 4; ++r) inv[r] = 1.f / l[r];
#pragma unroll
  for (int nf = 0; nf < 8; ++nf)
#pragma unroll
    for (int r = 0; r < 4; ++r) {
      const size_t row = (size_t)(b_ * cS) + q0 + wv * 16 + g * 4 + r;
      y[row * cH + h * cHD + nf * 16 + c16] = f2b(o[nf][r] * inv[r]);
    }
}

// --------------------------- o_ttt rmsnorm + add into y ---------------------
__global__ __launch_bounds__(256) void k_ttt_norm(const bf16* __restrict__ o_ttt,
                                                  const float* __restrict__ tw, bf16* __restrict__ y) {
  const int r = blockIdx.x;  // rows of (b, f, s)
  const int bh = r >> 11, si = r & 2047, b_ = bh >> 2, f = bh & 3;
  const bf16* src = o_ttt + (size_t)r * cFD;
  const int t = threadIdx.x;
  float v0 = b2f(src[t]), v1 = b2f(src[t + 256]);
  float ss = v0 * v0 + v1 * v1;
  __shared__ float red[4];
  for (int d = 32; d; d >>= 1) ss += __shfl_down(ss, d);
  if ((t & 63) == 0) red[t >> 6] = ss;
  __syncthreads();
  const float rstd = rsqrtf((red[0] + red[1] + red[2] + red[3]) / cFD + 1e-6f);
  bf16* dst = y + ((size_t)(b_ * cS) + si) * cH + f * cFD;
  dst[t] = f2b(b2f(dst[t]) + v0 * rstd * tw[t]);
  dst[t + 256] = f2b(b2f(dst[t + 256]) + v1 * rstd * tw[t + 256]);
}

}  // namespace

extern "C" void kernel_launch(void* const* d_in, const int* in_sizes, int n_in,
                              void* d_out, int out_size, void* d_ws, size_t ws_size,
                              hipStream_t stream) {
  (void)in_sizes; (void)n_in; (void)out_size; (void)ws_size;
  const float* x         = (const float*)d_in[0];
  const float* qkv_w     = (const float*)d_in[1];
  const float* q_norm_w  = (const float*)d_in[2];
  const float* k_norm_w  = (const float*)d_in[3];
  const float* qk_scale  = (const float*)d_in[4];
  const float* qk_offset = (const float*)d_in[5];
  const float* lr_w      = (const float*)d_in[6];
  const float* lr_b      = (const float*)d_in[7];
  const float* w0        = (const float*)d_in[8];
  const float* w1        = (const float*)d_in[9];
  const float* w2        = (const float*)d_in[10];
  const float* ttt_nw    = (const float*)d_in[11];
  const float* o_proj_w  = (const float*)d_in[12];
  float* out = (float*)d_out;

  // ---- workspace layout (bytes), total 143,851,520 (same as proven run) ----
  char* Wb = (char*)d_ws;
  bf16* qkvh  = (bf16*)Wb;  // 50,331,648 B; reused during TTT:
  bf16* o_ttt = (bf16*)Wb;                                   // 16,777,216
  bf16* t0  = (bf16*)(Wb + 16777216UL);                      // 4,194,304 each
  bf16* t1  = (bf16*)(Wb + 16777216UL + 1UL * 4194304UL);
  bf16* t2  = (bf16*)(Wb + 16777216UL + 2UL * 4194304UL);
  bf16* t3  = (bf16*)(Wb + 16777216UL + 3UL * 4194304UL);
  bf16* t4  = (bf16*)(Wb + 16777216UL + 4UL * 4194304UL);
  bf16* trV = (bf16*)(Wb + 37748736UL);   // (l1*fv)^T
  bf16* trH = (bf16*)(Wb + 41943040UL);   // t3^T (hidden^T)
  bf16* trD1= (bf16*)(Wb + 46137344UL);   // (l0*dh1)^T
  bf16* trK = t0;                         // fk^T   (t0 dead after oc)
  bf16* trD2= t1;                         // (l2*dh2)^T (t1 dead after elem)
  size_t off = 50331648UL;
  bf16* fqb = (bf16*)(Wb + off); off += 16777216UL;
  bf16* fkb = (bf16*)(Wb + off); off += 16777216UL;
  bf16* fvb = (bf16*)(Wb + off); off += 16777216UL;
  float* w0s = (float*)(Wb + off); off += 8388608UL;
  float* w1s = (float*)(Wb + off); off += 8388608UL;
  float* w2s = (float*)(Wb + off); off += 8388608UL;
  float* lr0 = (float*)(Wb + off); off += 65536UL;
  float* lr1 = (float*)(Wb + off); off += 65536UL;
  float* lr2 = (float*)(Wb + off); off += 65536UL;
  bf16* y = (bf16*)(Wb + off); off += 16777216UL;
  float* ct  = (float*)(Wb + off); off += 524288UL;
  float* stb = (float*)(Wb + off); off += 524288UL;

  const float base_lr_inv = logf(expm1f(0.001f));
  dim3 blk(256);
  const long ZL = 262144, ZG = 1048576;

  k_winit<<<dim3(8192, 3), blk, 0, stream>>>(w0, w1, w2, w0s, w1s, w2s);
  k_rope_tab<<<dim3(2048), dim3(64), 0, stream>>>(ct, stb);
  // qkv = x @ qkv_w^T  (fp32 sources, bf16 out)
  k_mm<float, float, bf16, false, false><<<dim3(48, 32, 1), blk, 0, stream>>>(
      x, 2048, 0, qkv_w, 2048, 0, qkvh, 6144, 0, 2048);
  k_lr<<<dim3(4096), blk, 0, stream>>>(x, lr_w, lr_b, lr0, lr1, lr2, base_lr_inv);
  k_post<<<dim3(4096), blk, 0, stream>>>(qkvh, q_norm_w, k_norm_w, qk_scale, qk_offset, fqb, fkb, fvb);
  k_attn_m<<<dim3(32, 16, 2), blk, 0, stream>>>(qkvh, ct, stb, y);

  for (int c = 0; c < 4; ++c) {
    const size_t choff = (size_t)c * 262144;
    // stage1: t0=q@w0^T, t1=q@w2^T, t2=k@w0^T, t3=k@w2^T
    k_mm<bf16, float, bf16, false, false><<<dim3(4, 4, 8), blk, 0, stream>>>(
        fqb + choff, 512, ZG, w0s, 512, ZL, t0, 512, ZL, 512);
    k_mm<bf16, float, bf16, false, false><<<dim3(4, 4, 8), blk, 0, stream>>>(
        fqb + choff, 512, ZG, w2s, 512, ZL, t1, 512, ZL, 512);
    k_mm<bf16, float, bf16, false, false><<<dim3(4, 4, 8), blk, 0, stream>>>(
        fkb + choff, 512, ZG, w0s, 512, ZL, t2, 512, ZL, 512);
    k_mm<bf16, float, bf16, false, false><<<dim3(4, 4, 8), blk, 0, stream>>>(
        fkb + choff, 512, ZG, w2s, 512, ZL, t3, 512, ZL, 512);
    // dhidden = v @ w1 (NN: B transposed during staging)
    k_mm<bf16, float, bf16, false, true><<<dim3(4, 4, 8), blk, 0, stream>>>(
        fvb + choff, 512, ZG, w1s, 512, ZL, t4, 512, ZL, 512);
    k_elem<<<dim3(8192), blk, 0, stream>>>(t0, t1, t2, t3, t4);
    // oc = hq @ w1^T (old w1)
    k_mm<bf16, float, bf16, false, false><<<dim3(4, 4, 8), blk, 0, stream>>>(
        t0, 512, ZL, w1s, 512, ZL, o_ttt + choff, 512, ZG, 512);
    // transposes (lr scale folded where needed)
    k_tr<bf16, true><<<dim3(8, 8, 8), blk, 0, stream>>>(fvb + choff, ZG, 512, trV, ZL, lr1 + c * 512, 2048);
    k_tr<bf16, false><<<dim3(8, 8, 8), blk, 0, stream>>>(t3, ZL, 512, trH, ZL, nullptr, 0);
    k_tr<bf16, true><<<dim3(8, 8, 8), blk, 0, stream>>>(t2, ZL, 512, trD1, ZL, lr0 + c * 512, 2048);
    k_tr<bf16, false><<<dim3(8, 8, 8), blk, 0, stream>>>(fkb + choff, ZG, 512, trK, ZL, nullptr, 0);
    k_tr<bf16, true><<<dim3(8, 8, 8), blk, 0, stream>>>(t4, ZL, 512, trD2, ZL, lr2 + c * 512, 2048);
    // weight updates (accumulate fp32)
    k_mm<bf16, bf16, float, true, false><<<dim3(4, 4, 8), blk, 0, stream>>>(
        trV, 512, ZL, trH, 512, ZL, w1s, 512, ZL, 512);
    k_mm<bf16, bf16, float, true, false><<<dim3(4, 4, 8), blk, 0, stream>>>(
        trD1, 512, ZL, trK, 512, ZL, w0s, 512, ZL, 512);
    k_mm<bf16, bf16, float, true, false><<<dim3(4, 4, 8), blk, 0, stream>>>(
        trD2, 512, ZL, trK, 512, ZL, w2s, 512, ZL, 512);
  }
  k_ttt_norm<<<dim3(16384), blk, 0, stream>>>(o_ttt, ttt_nw, y);
  // out = y @ o_proj_w^T (fp32 out)
  k_mm<bf16, float, float, false, false><<<dim3(16, 32, 1), blk, 0, stream>>>(
      y, 2048, 0, o_proj_w, 2048, 0, out, 2048, 0, 2048);
}

// Round 5
// 1052.211 us; speedup vs baseline: 4.9453x; 1.8569x over previous
//
#include <hip/hip_runtime.h>
#include <hip/hip_bf16.h>
#include <math.h>

using bf16 = __hip_bfloat16;

namespace {

constexpr int cH = 2048;
constexpr int cNH = 16;
constexpr int cHD = 128;
constexpr int cNFW = 4;
constexpr int cFD = 512;
constexpr int cS = 2048;
constexpr float cRSQRT_HD = 0.08838834764831845f;  // 1/sqrt(128)
constexpr long ZL_ = 262144;   // 512*512
constexpr long ZG_ = 1048576;  // 2048*512

typedef __attribute__((ext_vector_type(8))) short short8;
typedef __attribute__((ext_vector_type(4))) float f32x4;

__device__ __forceinline__ float sigmoidf_(float x) { return 1.0f / (1.0f + __expf(-x)); }
__device__ __forceinline__ float b2f(bf16 v) { return __bfloat162float(v); }
__device__ __forceinline__ bf16 f2b(float v) { return __float2bfloat16(v); }
__device__ __forceinline__ unsigned short f2bu(float f) {
  return __builtin_bit_cast(unsigned short, __float2bfloat16(f));
}
__device__ __forceinline__ float bu2f(unsigned u) { return __uint_as_float(u << 16); }

__device__ __forceinline__ float loadf(const float* p) { return *p; }
__device__ __forceinline__ float loadf(const bf16* p) { return b2f(*p); }

// stage 16 contiguous source elems as bf16 into LDS (dst 16B-aligned)
__device__ __forceinline__ void stage16(const float* src, short* dst) {
  float4 f0 = *(const float4*)src, f1 = *(const float4*)(src + 4);
  float4 f2 = *(const float4*)(src + 8), f3 = *(const float4*)(src + 12);
  unsigned short u[16] __attribute__((aligned(16)));
  u[0] = f2bu(f0.x); u[1] = f2bu(f0.y); u[2] = f2bu(f0.z); u[3] = f2bu(f0.w);
  u[4] = f2bu(f1.x); u[5] = f2bu(f1.y); u[6] = f2bu(f1.z); u[7] = f2bu(f1.w);
  u[8] = f2bu(f2.x); u[9] = f2bu(f2.y); u[10] = f2bu(f2.z); u[11] = f2bu(f2.w);
  u[12] = f2bu(f3.x); u[13] = f2bu(f3.y); u[14] = f2bu(f3.z); u[15] = f2bu(f3.w);
  *(uint4*)dst = *(uint4*)u;
  *(uint4*)(dst + 8) = *(uint4*)(u + 8);
}
__device__ __forceinline__ void stage16(const bf16* src, short* dst) {
  *(uint4*)dst = *(const uint4*)src;
  *(uint4*)(dst + 8) = *(const uint4*)(src + 8);
}

__device__ __forceinline__ void store1(float* p, float v) { *p = v; }
__device__ __forceinline__ void store1(bf16* p, float v) { *p = f2b(v); }

// ---------------------------------------------------------------------------
// MFMA GEMM core: 128x128 tile, 4 waves (2x2 of 64x64), BK=32.
// BT=false: C[m,n]=sum_k A[m,k]*B[n,k] (NT).  BT=true: B is [K][N] (NN).
// ---------------------------------------------------------------------------
template <bool BT, typename TA, typename TB>
__device__ __forceinline__ void mm_core(const TA* __restrict__ Ab, int lda,
                                        const TB* __restrict__ Bb, int ldb, int K,
                                        short* As, short* Bs, f32x4 acc[4][4]) {
  const int t = threadIdx.x, lane = t & 63, g = lane >> 4, c16 = lane & 15;
  const int wv = t >> 6, wm = (wv >> 1) * 64, wn = (wv & 1) * 64;
  for (int k0 = 0; k0 < K; k0 += 32) {
    __syncthreads();
    {
      const int r = t >> 1, sseg = (t & 1) * 16;
      stage16(Ab + (size_t)r * lda + k0 + sseg, &As[r * 40 + sseg]);
    }
    if constexpr (!BT) {
      const int r = t >> 1, sseg = (t & 1) * 16;
      stage16(Bb + (size_t)r * ldb + k0 + sseg, &Bs[r * 40 + sseg]);
    } else {
      const int kk = t >> 3, cseg = (t & 7) * 16;
      const TB* p = Bb + (size_t)(k0 + kk) * ldb + cseg;
#pragma unroll
      for (int i = 0; i < 16; ++i) Bs[(cseg + i) * 40 + kk] = (short)f2bu(loadf(p + i));
    }
    __syncthreads();
    short8 af[4], bfr[4];
#pragma unroll
    for (int mi = 0; mi < 4; ++mi) af[mi] = *(const short8*)&As[(wm + mi * 16 + c16) * 40 + g * 8];
#pragma unroll
    for (int ni = 0; ni < 4; ++ni) bfr[ni] = *(const short8*)&Bs[(wn + ni * 16 + c16) * 40 + g * 8];
#pragma unroll
    for (int mi = 0; mi < 4; ++mi)
#pragma unroll
      for (int ni = 0; ni < 4; ++ni)
        acc[mi][ni] = __builtin_amdgcn_mfma_f32_16x16x32_bf16(af[mi], bfr[ni], acc[mi][ni], 0, 0, 0);
  }
}

template <bool ACC, typename TC>
__device__ __forceinline__ void mm_store(TC* Cb, int ldc, int rb, int cb, f32x4 acc[4][4]) {
  const int t = threadIdx.x, lane = t & 63, g = lane >> 4, c16 = lane & 15;
  const int wv = t >> 6, wm = (wv >> 1) * 64, wn = (wv & 1) * 64;
  const int rbase = rb + wm, cbase = cb + wn;
#pragma unroll
  for (int mi = 0; mi < 4; ++mi)
#pragma unroll
    for (int ni = 0; ni < 4; ++ni) {
      const int col = cbase + ni * 16 + c16;
#pragma unroll
      for (int r = 0; r < 4; ++r) {
        const int row = rbase + mi * 16 + g * 4 + r;
        TC* cp = Cb + (size_t)row * ldc + col;
        if constexpr (ACC) {
          *cp = *cp + acc[mi][ni][r];
        } else {
          store1(cp, acc[mi][ni][r]);
        }
      }
    }
}

template <typename TA, typename TB, typename TC, bool ACC, bool BT>
__global__ __launch_bounds__(256) void k_mm(const TA* __restrict__ A, int lda, long zsa,
                                            const TB* __restrict__ B, int ldb, long zsb,
                                            TC* __restrict__ C, int ldc, long zsc, int K) {
  __shared__ short As[128 * 40];
  __shared__ short Bs[128 * 40];
  const int z = blockIdx.z;
  const TA* Ab = A + (size_t)z * zsa + (size_t)blockIdx.y * 128 * lda;
  const TB* Bb = BT ? (B + (size_t)z * zsb + blockIdx.x * 128)
                    : (B + (size_t)z * zsb + (size_t)blockIdx.x * 128 * ldb);
  f32x4 acc[4][4];
  const f32x4 zero4 = {0.f, 0.f, 0.f, 0.f};
#pragma unroll
  for (int i = 0; i < 4; ++i)
#pragma unroll
    for (int j = 0; j < 4; ++j) acc[i][j] = zero4;
  mm_core<BT>(Ab, lda, Bb, ldb, K, As, Bs, acc);
  mm_store<ACC>(C + (size_t)z * zsc, ldc, blockIdx.y * 128, blockIdx.x * 128, acc);
}

// stage1 merged: z = bh*4+var: t0=q@w0^T t1=q@w2^T t2=k@w0^T t3=k@w2^T
__global__ __launch_bounds__(256) void k_stage1(const bf16* __restrict__ fq, const bf16* __restrict__ fk,
                                                const float* __restrict__ w0s, const float* __restrict__ w2s,
                                                bf16* t0, bf16* t1, bf16* t2, bf16* t3, int chunk) {
  __shared__ short As[128 * 40];
  __shared__ short Bs[128 * 40];
  const int z = blockIdx.z, bh = z >> 2, var = z & 3;
  const size_t choff = (size_t)chunk * 262144;
  const bf16* Ab = (var < 2 ? fq : fk) + (size_t)bh * ZG_ + choff + (size_t)blockIdx.y * 128 * cFD;
  const float* Bb = (var & 1 ? w2s : w0s) + (size_t)bh * ZL_ + (size_t)blockIdx.x * 128 * cFD;
  bf16* C = (var == 0 ? t0 : var == 1 ? t1 : var == 2 ? t2 : t3) + (size_t)bh * ZL_;
  f32x4 acc[4][4];
  const f32x4 zero4 = {0.f, 0.f, 0.f, 0.f};
#pragma unroll
  for (int i = 0; i < 4; ++i)
#pragma unroll
    for (int j = 0; j < 4; ++j) acc[i][j] = zero4;
  mm_core<false>(Ab, cFD, Bb, cFD, cFD, As, Bs, acc);
  mm_store<false>(C, cFD, blockIdx.y * 128, blockIdx.x * 128, acc);
}

// updates merged: z = var*8+bh: w1+=trV^..trH, w0+=trD1..trK, w2+=trD2..trK
__global__ __launch_bounds__(256) void k_upd3(const bf16* __restrict__ trV, const bf16* __restrict__ trH,
                                              const bf16* __restrict__ trD1, const bf16* __restrict__ trK,
                                              const bf16* __restrict__ trD2,
                                              float* w0s, float* w1s, float* w2s) {
  __shared__ short As[128 * 40];
  __shared__ short Bs[128 * 40];
  const int z = blockIdx.z, var = z >> 3, bh = z & 7;
  const bf16* Ab;
  const bf16* Bb;
  float* W;
  if (var == 0) { Ab = trV; Bb = trH; W = w1s; }
  else if (var == 1) { Ab = trD1; Bb = trK; W = w0s; }
  else { Ab = trD2; Bb = trK; W = w2s; }
  Ab += (size_t)bh * ZL_ + (size_t)blockIdx.y * 128 * cFD;
  Bb += (size_t)bh * ZL_ + (size_t)blockIdx.x * 128 * cFD;
  W += (size_t)bh * ZL_;
  f32x4 acc[4][4];
  const f32x4 zero4 = {0.f, 0.f, 0.f, 0.f};
#pragma unroll
  for (int i = 0; i < 4; ++i)
#pragma unroll
    for (int j = 0; j < 4; ++j) acc[i][j] = zero4;
  mm_core<false>(Ab, cFD, Bb, cFD, cFD, As, Bs, acc);
  mm_store<true>(W, cFD, blockIdx.y * 128, blockIdx.x * 128, acc);
}

// transposes merged: z = var*8+bh (5 variants), 64x64 tiles
__global__ __launch_bounds__(256) void k_tr5(const bf16* __restrict__ fvb, const bf16* __restrict__ fkb,
                                             const bf16* __restrict__ t2, const bf16* __restrict__ t3,
                                             const bf16* __restrict__ t4,
                                             bf16* trV, bf16* trH, bf16* trD1, bf16* trK, bf16* trD2,
                                             const float* __restrict__ lr0, const float* __restrict__ lr1,
                                             const float* __restrict__ lr2, int chunk) {
  __shared__ short Ts[64 * 72];
  const int z = blockIdx.z, var = z >> 3, bh = z & 7, t = threadIdx.x;
  const size_t choff = (size_t)chunk * 262144;
  const bf16* src;
  bf16* dst;
  const float* scale = nullptr;
  if (var == 0) { src = fvb + choff + (size_t)bh * ZG_; dst = trV + (size_t)bh * ZL_; scale = lr1 + bh * 2048 + chunk * 512; }
  else if (var == 1) { src = t3 + (size_t)bh * ZL_; dst = trH + (size_t)bh * ZL_; }
  else if (var == 2) { src = t2 + (size_t)bh * ZL_; dst = trD1 + (size_t)bh * ZL_; scale = lr0 + bh * 2048 + chunk * 512; }
  else if (var == 3) { src = fkb + choff + (size_t)bh * ZG_; dst = trK + (size_t)bh * ZL_; }
  else { src = t4 + (size_t)bh * ZL_; dst = trD2 + (size_t)bh * ZL_; scale = lr2 + bh * 2048 + chunk * 512; }
  {
    const int r = t >> 2, cseg = (t & 3) * 16;
    const float s = scale ? scale[blockIdx.y * 64 + r] : 1.f;
    const bf16* p = src + (size_t)(blockIdx.y * 64 + r) * cFD + blockIdx.x * 64 + cseg;
    unsigned short u[16] __attribute__((aligned(16)));
#pragma unroll
    for (int i = 0; i < 16; ++i) u[i] = f2bu(b2f(p[i]) * s);
    *(uint4*)&Ts[r * 72 + cseg] = *(uint4*)u;
    *(uint4*)&Ts[r * 72 + cseg + 8] = *(uint4*)(u + 8);
  }
  __syncthreads();
  {
    const int oc_ = t >> 2, rseg = (t & 3) * 16;
    unsigned short u[16] __attribute__((aligned(16)));
#pragma unroll
    for (int i = 0; i < 16; ++i) u[i] = (unsigned short)Ts[(rseg + i) * 72 + oc_];
    bf16* dp = dst + (size_t)(blockIdx.x * 64 + oc_) * cFD + blockIdx.y * 64 + rseg;
    *(uint4*)dp = *(uint4*)u;
    *(uint4*)(dp + 8) = *(uint4*)(u + 8);
  }
}

// --------------------------- elementwise gates ------------------------------
__global__ __launch_bounds__(256) void k_elem(bf16* t0, const bf16* t1, bf16* t2, bf16* t3, bf16* t4) {
  const size_t i = (size_t)blockIdx.x * 256 + threadIdx.x;
  float hq1 = b2f(t0[i]), hq2 = b2f(t1[i]), g1 = b2f(t2[i]), g2 = b2f(t3[i]), dh = b2f(t4[i]);
  float s1 = sigmoidf_(hq1);
  t0[i] = f2b(hq1 * s1 * hq2);
  float sg = sigmoidf_(g1);
  float gate = g1 * sg;
  t3[i] = f2b(gate * g2);
  t4[i] = f2b(dh * gate);
  t2[i] = f2b(dh * g2 * (sg * (1.0f + g1 * (1.0f - sg))));
}

// --------------------------- state init ------------------------------------
__global__ __launch_bounds__(256) void k_winit(const float* __restrict__ w0, const float* __restrict__ w1,
                                               const float* __restrict__ w2,
                                               float* __restrict__ w0s, float* __restrict__ w1s,
                                               float* __restrict__ w2s) {
  const size_t i = (size_t)blockIdx.x * 256 + threadIdx.x;
  const int bh = (int)(i >> 18);
  const int f = bh & 3;
  const size_t off = i & 262143;
  const float* src; float* dst;
  if (blockIdx.y == 0) { src = w0; dst = w0s; }
  else if (blockIdx.y == 1) { src = w1; dst = w1s; }
  else { src = w2; dst = w2s; }
  dst[i] = src[(size_t)f * 262144 + off];
}

// --------------------------- rope table ------------------------------------
__global__ __launch_bounds__(64) void k_rope_tab(float* __restrict__ ct, float* __restrict__ stb) {
  const int si = blockIdx.x, j = threadIdx.x;
  float inv = powf(500000.0f, -(float)j / 64.0f);
  float ang = (float)si * inv;
  ct[(size_t)si * 64 + j] = cosf(ang);
  stb[(size_t)si * 64 + j] = sinf(ang);
}

// --------------------------- learning rates --------------------------------
__global__ __launch_bounds__(256) void k_lr(const float* __restrict__ x, const float* __restrict__ lr_w,
                                            const float* __restrict__ lr_b,
                                            float* lr0, float* lr1, float* lr2, float base) {
  const int token = blockIdx.x, b_ = token >> 11, si = token & 2047;
  const int wv = threadIdx.x >> 6, lane = threadIdx.x & 63;
  const float* xr = x + (size_t)token * cH;
#pragma unroll
  for (int jj = 0; jj < 3; ++jj) {
    const int j = wv * 3 + jj;
    const float* wr = lr_w + (size_t)j * cH;
    float s = 0.f;
    for (int k = lane; k < cH; k += 64) s += xr[k] * wr[k];
    for (int d = 32; d; d >>= 1) s += __shfl_down(s, d);
    if (lane == 0) {
      float v = s + lr_b[j] + base;
      float sp = (v > 15.f) ? v : log1pf(expf(v));
      const int tt = j >> 2, f = j & 3;
      float* dst = (tt == 0 ? lr0 : tt == 1 ? lr1 : lr2);
      dst[(size_t)(b_ * cNFW + f) * cS + si] = sp;
    }
  }
}

// ------------------ rmsnorm q/k in place + rope -> qa/ka --------------------
__global__ __launch_bounds__(256) void k_normrope(bf16* __restrict__ qkvh,
                                                  const float* __restrict__ qnw, const float* __restrict__ knw,
                                                  const float* __restrict__ ct, const float* __restrict__ stb,
                                                  bf16* __restrict__ qa, bf16* __restrict__ ka) {
  const int token = blockIdx.x, b_ = token >> 11, si = token & 2047;
  const int t = threadIdx.x;
  __shared__ float buf[cH];
  __shared__ float red[4];
  bf16* base = qkvh + (size_t)token * 3 * cH;
  for (int pass = 0; pass < 2; ++pass) {
    __syncthreads();
    bf16* src = base + pass * cH;
    const float* nw = pass ? knw : qnw;
    float ss = 0.f;
    for (int i = t; i < cH; i += 256) {
      float v = b2f(src[i]);
      buf[i] = v;
      ss += v * v;
    }
    for (int d = 32; d; d >>= 1) ss += __shfl_down(ss, d);
    if ((t & 63) == 0) red[t >> 6] = ss;
    __syncthreads();
    const float rstd = rsqrtf((red[0] + red[1] + red[2] + red[3]) / cH + 1e-6f);
    for (int i = t; i < cH; i += 256) {
      float v = buf[i] * rstd * nw[i];
      buf[i] = v;
      src[i] = f2b(v);
    }
    __syncthreads();
    bf16* dst = pass ? ka : qa;
    const float scale = pass ? 1.f : cRSQRT_HD;
    const int hh = t >> 4, j0 = (t & 15) * 4;
    const float* cr = ct + (size_t)si * 64 + j0;
    const float* sr = stb + (size_t)si * 64 + j0;
    bf16* drow = dst + ((size_t)(b_ * cNH + hh) * cS + si) * cHD;
    unsigned short u1[4] __attribute__((aligned(8))), u2[4] __attribute__((aligned(8)));
#pragma unroll
    for (int i = 0; i < 4; ++i) {
      float x1 = buf[hh * cHD + j0 + i], x2 = buf[hh * cHD + 64 + j0 + i];
      u1[i] = f2bu((x1 * cr[i] - x2 * sr[i]) * scale);
      u2[i] = f2bu((x2 * cr[i] + x1 * sr[i]) * scale);
    }
    *(uint2*)(drow + j0) = *(uint2*)u1;
    *(uint2*)(drow + 64 + j0) = *(uint2*)u2;
  }
}

// ------------------ V transpose: qkvh v-part -> vt[b,h,d,s] -----------------
__global__ __launch_bounds__(256) void k_vtr(const bf16* __restrict__ qkvh, bf16* __restrict__ vt) {
  const int tile = blockIdx.x, h = blockIdx.y, b_ = blockIdx.z;
  __shared__ short Ts[64 * 136];
  const int t = threadIdx.x;
  {
    const int r = t >> 2, seg = (t & 3) * 32;
    const bf16* src = qkvh + ((size_t)(b_ * cS) + tile * 64 + r) * 3 * cH + 2 * cH + h * cHD + seg;
    stage16(src, &Ts[r * 136 + seg]);
    stage16(src + 16, &Ts[r * 136 + seg + 16]);
  }
  __syncthreads();
  {
    const int d = t >> 1, seg2 = (t & 1) * 32;
    unsigned short u[32] __attribute__((aligned(16)));
#pragma unroll
    for (int i = 0; i < 32; ++i) u[i] = (unsigned short)Ts[(seg2 + i) * 136 + d];
    bf16* dp = vt + ((size_t)(b_ * cNH + h) * cHD + d) * cS + tile * 64 + seg2;
    *(uint4*)dp = *(uint4*)u;
    *(uint4*)(dp + 8) = *(uint4*)(u + 8);
    *(uint4*)(dp + 16) = *(uint4*)(u + 16);
    *(uint4*)(dp + 24) = *(uint4*)(u + 24);
  }
}

// ------------------ fq/fk/fv from normalized qkvh ---------------------------
__global__ __launch_bounds__(256) void k_fqkv(const bf16* __restrict__ qkvh,
                                              const float* __restrict__ qk_scale,
                                              const float* __restrict__ qk_offset,
                                              bf16* fq, bf16* fk, bf16* fv) {
  const int token = blockIdx.x, b_ = token >> 11, si = token & 2047;
  const int t = threadIdx.x;
  const bf16* base = qkvh + (size_t)token * 3 * cH;
#pragma unroll
  for (int pass = 0; pass < 2; ++pass) {
    const bf16* src = base + pass * cH;
    bf16* fdst = pass ? fk : fq;
    const int head = t >> 6, lane = t & 63;
    float f[8];
    float ss2 = 0.f;
#pragma unroll
    for (int k = 0; k < 8; ++k) {
      const int idx = head * cFD + lane + k * 64;
      float v = b2f(src[idx]);
      float u = v * qk_scale[idx * 2 + pass] + qk_offset[idx * 2 + pass];
      float fv_ = u * sigmoidf_(u);
      f[k] = fv_;
      ss2 += fv_ * fv_;
    }
    for (int d = 1; d < 64; d <<= 1) ss2 += __shfl_xor(ss2, d);
    const float sc2 = rsqrtf(ss2 + 1e-12f);
    bf16* dst = fdst + ((size_t)(b_ * cNFW + head) * cS + si) * cFD;
#pragma unroll
    for (int k = 0; k < 8; ++k) dst[lane + k * 64] = f2b(f[k] * sc2);
  }
  const bf16* vr = base + 2 * cH;
  for (int i = t; i < cH; i += 256) {
    float v = b2f(vr[i]);
    fv[((size_t)(b_ * cNFW + (i >> 9)) * cS + si) * cFD + (i & 511)] = f2b(v * sigmoidf_(v));
  }
}

// --------------------------- attention (flash, MFMA, lean) ------------------
__global__ __launch_bounds__(256) void k_attn2(const bf16* __restrict__ qa, const bf16* __restrict__ ka,
                                               const bf16* __restrict__ vt, bf16* __restrict__ y) {
  const int qt = blockIdx.x, h = blockIdx.y, b_ = blockIdx.z;
  const int q0 = qt * 64;
  __shared__ short Ks[64 * 136];
  __shared__ short Vts[128 * 72];
  __shared__ short Ps[4 * 16 * 72];
  const int t = threadIdx.x, lane = t & 63, g = lane >> 4, c16 = lane & 15, wv = t >> 6;
  const size_t hb = (size_t)(b_ * cNH + h) * cS;
  const bf16* vb = vt + (size_t)(b_ * cNH + h) * (size_t)(cHD * cS);
  short8 qf[4];
  {
    const bf16* qsrc = qa + (hb + q0 + wv * 16 + c16) * cHD;
#pragma unroll
    for (int ks = 0; ks < 4; ++ks) qf[ks] = *(const short8*)(qsrc + ks * 32 + g * 8);
  }
  f32x4 o[8];
  const f32x4 zero4 = {0.f, 0.f, 0.f, 0.f};
#pragma unroll
  for (int i = 0; i < 8; ++i) o[i] = zero4;
  float m[4], l[4];
#pragma unroll
  for (int r = 0; r < 4; ++r) { m[r] = -1e30f; l[r] = 0.f; }

  for (int kt = 0; kt <= qt; ++kt) {
    __syncthreads();
    {
      const int r = t >> 2, seg = (t & 3) * 32;
      const bf16* ksrc = ka + (hb + kt * 64 + r) * cHD + seg;
      stage16(ksrc, &Ks[r * 136 + seg]);
      stage16(ksrc + 16, &Ks[r * 136 + seg + 16]);
      const int d = t >> 1, seg2 = (t & 1) * 32;
      const bf16* vsrc = vb + (size_t)d * cS + kt * 64 + seg2;
      stage16(vsrc, &Vts[d * 72 + seg2]);
      stage16(vsrc + 16, &Vts[d * 72 + seg2 + 16]);
    }
    __syncthreads();

    f32x4 s4[4];
#pragma unroll
    for (int ni = 0; ni < 4; ++ni) s4[ni] = zero4;
#pragma unroll
    for (int ks = 0; ks < 4; ++ks) {
#pragma unroll
      for (int ni = 0; ni < 4; ++ni) {
        short8 bb = *(const short8*)&Ks[(ni * 16 + c16) * 136 + ks * 32 + g * 8];
        s4[ni] = __builtin_amdgcn_mfma_f32_16x16x32_bf16(qf[ks], bb, s4[ni], 0, 0, 0);
      }
    }
    if (kt == qt) {
#pragma unroll
      for (int ni = 0; ni < 4; ++ni) {
        const int kv = kt * 64 + ni * 16 + c16;
#pragma unroll
        for (int r = 0; r < 4; ++r) {
          const int qr = q0 + wv * 16 + g * 4 + r;
          if (kv > qr) s4[ni][r] = -1e9f;
        }
      }
    }
    float mx[4];
#pragma unroll
    for (int r = 0; r < 4; ++r)
      mx[r] = fmaxf(fmaxf(s4[0][r], s4[1][r]), fmaxf(s4[2][r], s4[3][r]));
#pragma unroll
    for (int d = 1; d < 16; d <<= 1)
#pragma unroll
      for (int r = 0; r < 4; ++r) mx[r] = fmaxf(mx[r], __shfl_xor(mx[r], d));
    float corr[4];
#pragma unroll
    for (int r = 0; r < 4; ++r) {
      float mn = fmaxf(m[r], mx[r]);
      corr[r] = __expf(m[r] - mn);
      m[r] = mn;
    }
    float psum[4] = {0.f, 0.f, 0.f, 0.f};
#pragma unroll
    for (int ni = 0; ni < 4; ++ni)
#pragma unroll
      for (int r = 0; r < 4; ++r) {
        float p = __expf(s4[ni][r] - m[r]);
        s4[ni][r] = p;
        psum[r] += p;
      }
#pragma unroll
    for (int d = 1; d < 16; d <<= 1)
#pragma unroll
      for (int r = 0; r < 4; ++r) psum[r] += __shfl_xor(psum[r], d);
#pragma unroll
    for (int r = 0; r < 4; ++r) l[r] = l[r] * corr[r] + psum[r];
#pragma unroll
    for (int nf = 0; nf < 8; ++nf)
#pragma unroll
      for (int r = 0; r < 4; ++r) o[nf][r] *= corr[r];
    short* pw = &Ps[wv * 1152];
#pragma unroll
    for (int ni = 0; ni < 4; ++ni)
#pragma unroll
      for (int r = 0; r < 4; ++r)
        pw[(g * 4 + r) * 72 + ni * 16 + c16] = (short)f2bu(s4[ni][r]);
    // Ps is wave-private: no barrier needed; compiler orders LDS RAW in-wave.
#pragma unroll
    for (int ks2 = 0; ks2 < 2; ++ks2) {
      short8 a = *(const short8*)&pw[c16 * 72 + ks2 * 32 + g * 8];
#pragma unroll
      for (int nf = 0; nf < 8; ++nf) {
        short8 bb = *(const short8*)&Vts[(nf * 16 + c16) * 72 + ks2 * 32 + g * 8];
        o[nf] = __builtin_amdgcn_mfma_f32_16x16x32_bf16(a, bb, o[nf], 0, 0, 0);
      }
    }
  }
  float inv[4];
#pragma unroll
  for (int r = 0; r < 4; ++r) inv[r] = 1.f / l[r];
#pragma unroll
  for (int nf = 0; nf < 8; ++nf)
#pragma unroll
    for (int r = 0; r < 4; ++r) {
      const size_t row = (size_t)(b_ * cS) + q0 + wv * 16 + g * 4 + r;
      y[row * cH + h * cHD + nf * 16 + c16] = f2b(o[nf][r] * inv[r]);
    }
}

// --------------------------- o_ttt rmsnorm + add into y ---------------------
__global__ __launch_bounds__(256) void k_ttt_norm(const bf16* __restrict__ o_ttt,
                                                  const float* __restrict__ tw, bf16* __restrict__ y) {
  const int r = blockIdx.x;
  const int bh = r >> 11, si = r & 2047, b_ = bh >> 2, f = bh & 3;
  const bf16* src = o_ttt + (size_t)r * cFD;
  const int t = threadIdx.x;
  float v0 = b2f(src[t]), v1 = b2f(src[t + 256]);
  float ss = v0 * v0 + v1 * v1;
  __shared__ float red[4];
  for (int d = 32; d; d >>= 1) ss += __shfl_down(ss, d);
  if ((t & 63) == 0) red[t >> 6] = ss;
  __syncthreads();
  const float rstd = rsqrtf((red[0] + red[1] + red[2] + red[3]) / cFD + 1e-6f);
  bf16* dst = y + ((size_t)(b_ * cS) + si) * cH + f * cFD;
  dst[t] = f2b(b2f(dst[t]) + v0 * rstd * tw[t]);
  dst[t + 256] = f2b(b2f(dst[t + 256]) + v1 * rstd * tw[t + 256]);
}

}  // namespace

extern "C" void kernel_launch(void* const* d_in, const int* in_sizes, int n_in,
                              void* d_out, int out_size, void* d_ws, size_t ws_size,
                              hipStream_t stream) {
  (void)in_sizes; (void)n_in; (void)out_size; (void)ws_size;
  const float* x         = (const float*)d_in[0];
  const float* qkv_w     = (const float*)d_in[1];
  const float* q_norm_w  = (const float*)d_in[2];
  const float* k_norm_w  = (const float*)d_in[3];
  const float* qk_scale  = (const float*)d_in[4];
  const float* qk_offset = (const float*)d_in[5];
  const float* lr_w      = (const float*)d_in[6];
  const float* lr_b      = (const float*)d_in[7];
  const float* w0        = (const float*)d_in[8];
  const float* w1        = (const float*)d_in[9];
  const float* w2        = (const float*)d_in[10];
  const float* ttt_nw    = (const float*)d_in[11];
  const float* o_proj_w  = (const float*)d_in[12];
  float* out = (float*)d_out;

  // ---- workspace layout (bytes), total 143,851,520 (same as proven run) ----
  char* Wb = (char*)d_ws;
  bf16* qkvh  = (bf16*)Wb;  // 50,331,648 B; reused during TTT:
  bf16* o_ttt = (bf16*)Wb;                                   // 16,777,216
  bf16* t0  = (bf16*)(Wb + 16777216UL);                      // 4,194,304 each
  bf16* t1  = (bf16*)(Wb + 16777216UL + 1UL * 4194304UL);
  bf16* t2  = (bf16*)(Wb + 16777216UL + 2UL * 4194304UL);
  bf16* t3  = (bf16*)(Wb + 16777216UL + 3UL * 4194304UL);
  bf16* t4  = (bf16*)(Wb + 16777216UL + 4UL * 4194304UL);
  bf16* trV = (bf16*)(Wb + 37748736UL);
  bf16* trH = (bf16*)(Wb + 41943040UL);
  bf16* trD1= (bf16*)(Wb + 46137344UL);
  bf16* trK = t0;    // t0 dead after oc
  bf16* trD2= t1;    // t1 dead after elem
  size_t off = 50331648UL;
  bf16* fqb = (bf16*)(Wb + off); off += 16777216UL;  // = qa during attention
  bf16* fkb = (bf16*)(Wb + off); off += 16777216UL;  // = ka during attention
  bf16* fvb = (bf16*)(Wb + off); off += 16777216UL;  // = vt during attention
  float* w0s = (float*)(Wb + off); off += 8388608UL;
  float* w1s = (float*)(Wb + off); off += 8388608UL;
  float* w2s = (float*)(Wb + off); off += 8388608UL;
  float* lr0 = (float*)(Wb + off); off += 65536UL;
  float* lr1 = (float*)(Wb + off); off += 65536UL;
  float* lr2 = (float*)(Wb + off); off += 65536UL;
  bf16* y = (bf16*)(Wb + off); off += 16777216UL;
  float* ct  = (float*)(Wb + off); off += 524288UL;
  float* stb = (float*)(Wb + off); off += 524288UL;
  bf16* qa = fqb;
  bf16* ka = fkb;
  bf16* vt = fvb;

  const float base_lr_inv = logf(expm1f(0.001f));
  dim3 blk(256);

  k_winit<<<dim3(8192, 3), blk, 0, stream>>>(w0, w1, w2, w0s, w1s, w2s);
  k_rope_tab<<<dim3(2048), dim3(64), 0, stream>>>(ct, stb);
  k_mm<float, float, bf16, false, false><<<dim3(48, 32, 1), blk, 0, stream>>>(
      x, 2048, 0, qkv_w, 2048, 0, qkvh, 6144, 0, 2048);
  k_lr<<<dim3(4096), blk, 0, stream>>>(x, lr_w, lr_b, lr0, lr1, lr2, base_lr_inv);
  k_normrope<<<dim3(4096), blk, 0, stream>>>(qkvh, q_norm_w, k_norm_w, ct, stb, qa, ka);
  k_vtr<<<dim3(32, 16, 2), blk, 0, stream>>>(qkvh, vt);
  k_attn2<<<dim3(32, 16, 2), blk, 0, stream>>>(qa, ka, vt, y);
  k_fqkv<<<dim3(4096), blk, 0, stream>>>(qkvh, qk_scale, qk_offset, fqb, fkb, fvb);

  for (int c = 0; c < 4; ++c) {
    const size_t choff = (size_t)c * 262144;
    k_stage1<<<dim3(4, 4, 32), blk, 0, stream>>>(fqb, fkb, w0s, w2s, t0, t1, t2, t3, c);
    k_mm<bf16, float, bf16, false, true><<<dim3(4, 4, 8), blk, 0, stream>>>(
        fvb + choff, 512, ZG_, w1s, 512, ZL_, t4, 512, ZL_, 512);
    k_elem<<<dim3(8192), blk, 0, stream>>>(t0, t1, t2, t3, t4);
    k_mm<bf16, float, bf16, false, false><<<dim3(4, 4, 8), blk, 0, stream>>>(
        t0, 512, ZL_, w1s, 512, ZL_, o_ttt + choff, 512, ZG_, 512);
    k_tr5<<<dim3(8, 8, 40), blk, 0, stream>>>(fvb, fkb, t2, t3, t4,
                                              trV, trH, trD1, trK, trD2, lr0, lr1, lr2, c);
    k_upd3<<<dim3(4, 4, 24), blk, 0, stream>>>(trV, trH, trD1, trK, trD2, w0s, w1s, w2s);
  }
  k_ttt_norm<<<dim3(16384), blk, 0, stream>>>(o_ttt, ttt_nw, y);
  k_mm<bf16, float, float, false, false><<<dim3(16, 32, 1), blk, 0, stream>>>(
      y, 2048, 0, o_proj_w, 2048, 0, out, 2048, 0, 2048);
}

// Round 6
// 1011.108 us; speedup vs baseline: 5.1463x; 1.0407x over previous
//
#include <hip/hip_runtime.h>
#include <hip/hip_bf16.h>
#include <math.h>

using bf16 = __hip_bfloat16;

namespace {

constexpr int cH = 2048;
constexpr int cNH = 16;
constexpr int cHD = 128;
constexpr int cNFW = 4;
constexpr int cFD = 512;
constexpr int cS = 2048;
constexpr float cRSQRT_HD = 0.08838834764831845f;  // 1/sqrt(128)
constexpr long ZL_ = 262144;   // 512*512
constexpr long ZG_ = 1048576;  // 2048*512

typedef __attribute__((ext_vector_type(8))) short short8;
typedef __attribute__((ext_vector_type(4))) float f32x4;

__device__ __forceinline__ float sigmoidf_(float x) { return 1.0f / (1.0f + __expf(-x)); }
__device__ __forceinline__ float b2f(bf16 v) { return __bfloat162float(v); }
__device__ __forceinline__ bf16 f2b(float v) { return __float2bfloat16(v); }
__device__ __forceinline__ unsigned short f2bu(float f) {
  return __builtin_bit_cast(unsigned short, __float2bfloat16(f));
}

#if defined(__has_builtin)
#if __has_builtin(__builtin_amdgcn_global_load_lds)
#define HAVE_GLOAD 1
#endif
#endif

// async global->LDS: wave-uniform LDS base, HW adds lane*16B; per-lane global src
__device__ __forceinline__ void gload16(const bf16* g, short* ldsbase) {
#ifdef HAVE_GLOAD
  __builtin_amdgcn_global_load_lds((const __attribute__((address_space(1))) void*)g,
                                   (__attribute__((address_space(3))) void*)ldsbase, 16, 0, 0);
#else
  const int l = threadIdx.x & 63;
  *(uint4*)(ldsbase + l * 8) = *(const uint4*)g;
#endif
}

// stage 16 contiguous bf16 into LDS (vector path, used by attn/vtr)
__device__ __forceinline__ void stage16(const bf16* src, short* dst) {
  *(uint4*)dst = *(const uint4*)src;
  *(uint4*)(dst + 8) = *(const uint4*)(src + 8);
}

__device__ __forceinline__ void store1(float* p, float v) { *p = v; }
__device__ __forceinline__ void store1(bf16* p, float v) { *p = f2b(v); }

// ---------------------------------------------------------------------------
// MFMA GEMM core: 128x128 tile, 4 waves (2x2 of 64x64), BK=32, linear LDS.
// AMODE 0: A [M][K] bf16 row-major (global_load_lds).
// AMODE 1: A [K][M] bf16, scalar-transposed staging with per-k scale.
// BMODE 0: B [N][K] bf16 (NT, global_load_lds). BMODE 1: B [K][N] (NN, scalar).
// ---------------------------------------------------------------------------
template <int AMODE, int BMODE>
__device__ __forceinline__ void mm_core(const bf16* __restrict__ Ab, int lda,
                                        const bf16* __restrict__ Bb, int ldb, int K,
                                        const float* __restrict__ sc,
                                        short* As, short* Bs, f32x4 acc[4][4]) {
  const int t = threadIdx.x, lane = t & 63, g = lane >> 4, c16 = lane & 15;
  const int wv = t >> 6, wm = (wv >> 1) * 64, wn = (wv & 1) * 64;
  for (int k0 = 0; k0 < K; k0 += 32) {
    __syncthreads();
    if constexpr (AMODE == 0) {
      const int ch = wv * 2;
      const bf16* g0 = Ab + (size_t)(ch * 16 + (lane >> 2)) * lda + k0 + (lane & 3) * 8;
      gload16(g0, &As[ch * 512]);
      gload16(g0 + (size_t)16 * lda, &As[ch * 512 + 512]);
    } else {
      const int kk = t >> 3, mseg = (t & 7) * 16;
      const float s = sc[k0 + kk];
      const bf16* p = Ab + (size_t)(k0 + kk) * lda + mseg;
#pragma unroll
      for (int i = 0; i < 16; ++i) As[(mseg + i) * 32 + kk] = (short)f2bu(b2f(p[i]) * s);
    }
    if constexpr (BMODE == 0) {
      const int ch = wv * 2;
      const bf16* g0 = Bb + (size_t)(ch * 16 + (lane >> 2)) * ldb + k0 + (lane & 3) * 8;
      gload16(g0, &Bs[ch * 512]);
      gload16(g0 + (size_t)16 * ldb, &Bs[ch * 512 + 512]);
    } else {
      const int kk = t >> 3, cseg = (t & 7) * 16;
      const short* p = (const short*)(Bb + (size_t)(k0 + kk) * ldb + cseg);
#pragma unroll
      for (int i = 0; i < 16; ++i) Bs[(cseg + i) * 32 + kk] = p[i];
    }
    __syncthreads();
    short8 af[4], bfr[4];
#pragma unroll
    for (int mi = 0; mi < 4; ++mi) af[mi] = *(const short8*)&As[(wm + mi * 16 + c16) * 32 + g * 8];
#pragma unroll
    for (int ni = 0; ni < 4; ++ni) bfr[ni] = *(const short8*)&Bs[(wn + ni * 16 + c16) * 32 + g * 8];
#pragma unroll
    for (int mi = 0; mi < 4; ++mi)
#pragma unroll
      for (int ni = 0; ni < 4; ++ni)
        acc[mi][ni] = __builtin_amdgcn_mfma_f32_16x16x32_bf16(af[mi], bfr[ni], acc[mi][ni], 0, 0, 0);
  }
}

template <bool ACC, bool MIR, typename TC>
__device__ __forceinline__ void mm_store(TC* Cb, bf16* Mb, int ldc, int rb, int cb, f32x4 acc[4][4]) {
  const int t = threadIdx.x, lane = t & 63, g = lane >> 4, c16 = lane & 15;
  const int wv = t >> 6, wm = (wv >> 1) * 64, wn = (wv & 1) * 64;
  const int rbase = rb + wm, cbase = cb + wn;
#pragma unroll
  for (int mi = 0; mi < 4; ++mi)
#pragma unroll
    for (int ni = 0; ni < 4; ++ni) {
      const int col = cbase + ni * 16 + c16;
#pragma unroll
      for (int r = 0; r < 4; ++r) {
        const int row = rbase + mi * 16 + g * 4 + r;
        TC* cp = Cb + (size_t)row * ldc + col;
        if constexpr (ACC) {
          float nv = *cp + acc[mi][ni][r];
          *cp = nv;
          if constexpr (MIR) Mb[(size_t)row * ldc + col] = f2b(nv);
        } else {
          store1(cp, acc[mi][ni][r]);
        }
      }
    }
}

template <typename TC, int BMODE>
__global__ __launch_bounds__(256) void k_mm(const bf16* __restrict__ A, int lda, long zsa,
                                            const bf16* __restrict__ B, int ldb, long zsb,
                                            TC* __restrict__ C, int ldc, long zsc, int K) {
  __shared__ short As[128 * 32];
  __shared__ short Bs[128 * 32];
  const int z = blockIdx.z;
  const bf16* Ab = A + (size_t)z * zsa + (size_t)blockIdx.y * 128 * lda;
  const bf16* Bb = (BMODE == 0) ? (B + (size_t)z * zsb + (size_t)blockIdx.x * 128 * ldb)
                                : (B + (size_t)z * zsb + blockIdx.x * 128);
  f32x4 acc[4][4];
  const f32x4 zero4 = {0.f, 0.f, 0.f, 0.f};
#pragma unroll
  for (int i = 0; i < 4; ++i)
#pragma unroll
    for (int j = 0; j < 4; ++j) acc[i][j] = zero4;
  mm_core<0, BMODE>(Ab, lda, Bb, ldb, K, nullptr, As, Bs, acc);
  mm_store<false, false>(C + (size_t)z * zsc, (bf16*)nullptr, ldc, blockIdx.y * 128, blockIdx.x * 128, acc);
}

// stage1 merged: z = bh*4+var: t0=q@w0^T t1=q@w2^T t2=k@w0^T t3=k@w2^T (bf16 mirrors)
__global__ __launch_bounds__(256) void k_stage1(const bf16* __restrict__ fq, const bf16* __restrict__ fk,
                                                const bf16* __restrict__ w0b, const bf16* __restrict__ w2b,
                                                bf16* t0, bf16* t1, bf16* t2, bf16* t3, int chunk) {
  __shared__ short As[128 * 32];
  __shared__ short Bs[128 * 32];
  const int z = blockIdx.z, bh = z >> 2, var = z & 3;
  const size_t choff = (size_t)chunk * 262144;
  const bf16* Ab = (var < 2 ? fq : fk) + (size_t)bh * ZG_ + choff + (size_t)blockIdx.y * 128 * cFD;
  const bf16* Bb = (var & 1 ? w2b : w0b) + (size_t)bh * ZL_ + (size_t)blockIdx.x * 128 * cFD;
  bf16* C = (var == 0 ? t0 : var == 1 ? t1 : var == 2 ? t2 : t3) + (size_t)bh * ZL_;
  f32x4 acc[4][4];
  const f32x4 zero4 = {0.f, 0.f, 0.f, 0.f};
#pragma unroll
  for (int i = 0; i < 4; ++i)
#pragma unroll
    for (int j = 0; j < 4; ++j) acc[i][j] = zero4;
  mm_core<0, 0>(Ab, cFD, Bb, cFD, cFD, nullptr, As, Bs, acc);
  mm_store<false, false>(C, (bf16*)nullptr, cFD, blockIdx.y * 128, blockIdx.x * 128, acc);
}

// updates merged, TN-staged A with lr scale; masters fp32 += ; bf16 mirrors written through
__global__ __launch_bounds__(256) void k_upd3(const bf16* __restrict__ fvb, const bf16* __restrict__ t2,
                                              const bf16* __restrict__ t4,
                                              const bf16* __restrict__ trH, const bf16* __restrict__ trK,
                                              const float* __restrict__ lr0, const float* __restrict__ lr1,
                                              const float* __restrict__ lr2,
                                              float* w0s, float* w1s, float* w2s,
                                              bf16* w0b, bf16* w1b, bf16* w2b, int chunk) {
  __shared__ short As[128 * 32];
  __shared__ short Bs[128 * 32];
  const int z = blockIdx.z, var = z >> 3, bh = z & 7;
  const size_t choff = (size_t)chunk * 262144;
  const bf16 *Aa, *Bb;
  const float* sc;
  float* W;
  bf16* M;
  if (var == 0) {
    Aa = fvb + choff + (size_t)bh * ZG_; sc = lr1 + bh * 2048 + chunk * 512;
    Bb = trH + (size_t)bh * ZL_; W = w1s + (size_t)bh * ZL_; M = w1b + (size_t)bh * ZL_;
  } else if (var == 1) {
    Aa = t2 + (size_t)bh * ZL_; sc = lr0 + bh * 2048 + chunk * 512;
    Bb = trK + (size_t)bh * ZL_; W = w0s + (size_t)bh * ZL_; M = w0b + (size_t)bh * ZL_;
  } else {
    Aa = t4 + (size_t)bh * ZL_; sc = lr2 + bh * 2048 + chunk * 512;
    Bb = trK + (size_t)bh * ZL_; W = w2s + (size_t)bh * ZL_; M = w2b + (size_t)bh * ZL_;
  }
  Aa += blockIdx.y * 128;                       // m-columns of [K][M] source
  Bb += (size_t)blockIdx.x * 128 * cFD;
  f32x4 acc[4][4];
  const f32x4 zero4 = {0.f, 0.f, 0.f, 0.f};
#pragma unroll
  for (int i = 0; i < 4; ++i)
#pragma unroll
    for (int j = 0; j < 4; ++j) acc[i][j] = zero4;
  mm_core<1, 0>(Aa, cFD, Bb, cFD, cFD, sc, As, Bs, acc);
  mm_store<true, true>(W, M, cFD, blockIdx.y * 128, blockIdx.x * 128, acc);
}

// transposes: z = var*8+bh; var0: trH = t3^T, var1: trK = fk_chunk^T
__global__ __launch_bounds__(256) void k_tr2(const bf16* __restrict__ t3, const bf16* __restrict__ fkb,
                                             bf16* trH, bf16* trK, int chunk) {
  __shared__ short Ts[64 * 72];
  const int z = blockIdx.z, var = z >> 3, bh = z & 7, t = threadIdx.x;
  const size_t choff = (size_t)chunk * 262144;
  const bf16* src = (var == 0) ? (t3 + (size_t)bh * ZL_) : (fkb + choff + (size_t)bh * ZG_);
  bf16* dst = (var == 0) ? (trH + (size_t)bh * ZL_) : (trK + (size_t)bh * ZL_);
  {
    const int r = t >> 2, cseg = (t & 3) * 16;
    const bf16* p = src + (size_t)(blockIdx.y * 64 + r) * cFD + blockIdx.x * 64 + cseg;
    stage16(p, &Ts[r * 72 + cseg]);
  }
  __syncthreads();
  {
    const int oc_ = t >> 2, rseg = (t & 3) * 16;
    unsigned short u[16] __attribute__((aligned(16)));
#pragma unroll
    for (int i = 0; i < 16; ++i) u[i] = (unsigned short)Ts[(rseg + i) * 72 + oc_];
    bf16* dp = dst + (size_t)(blockIdx.x * 64 + oc_) * cFD + blockIdx.y * 64 + rseg;
    *(uint4*)dp = *(uint4*)u;
    *(uint4*)(dp + 8) = *(uint4*)(u + 8);
  }
}

// --------------------------- elementwise gates ------------------------------
__global__ __launch_bounds__(256) void k_elem(bf16* t0, const bf16* t1, bf16* t2, bf16* t3, bf16* t4) {
  const size_t i = (size_t)blockIdx.x * 256 + threadIdx.x;
  float hq1 = b2f(t0[i]), hq2 = b2f(t1[i]), g1 = b2f(t2[i]), g2 = b2f(t3[i]), dh = b2f(t4[i]);
  float s1 = sigmoidf_(hq1);
  t0[i] = f2b(hq1 * s1 * hq2);
  float sg = sigmoidf_(g1);
  float gate = g1 * sg;
  t3[i] = f2b(gate * g2);
  t4[i] = f2b(dh * gate);
  t2[i] = f2b(dh * g2 * (sg * (1.0f + g1 * (1.0f - sg))));
}

// --------------------------- fp32 -> bf16 flat convert ----------------------
__global__ __launch_bounds__(256) void k_cvt(const float* __restrict__ src, bf16* __restrict__ dst) {
  const size_t i = ((size_t)blockIdx.x * 256 + threadIdx.x) * 8;
  float4 a = *(const float4*)(src + i), b = *(const float4*)(src + i + 4);
  unsigned short u[8] __attribute__((aligned(16)));
  u[0] = f2bu(a.x); u[1] = f2bu(a.y); u[2] = f2bu(a.z); u[3] = f2bu(a.w);
  u[4] = f2bu(b.x); u[5] = f2bu(b.y); u[6] = f2bu(b.z); u[7] = f2bu(b.w);
  *(uint4*)(dst + i) = *(uint4*)u;
}

// --------------------------- state init ------------------------------------
__global__ __launch_bounds__(256) void k_winit(const float* __restrict__ w0, const float* __restrict__ w1,
                                               const float* __restrict__ w2,
                                               float* __restrict__ w0s, float* __restrict__ w1s,
                                               float* __restrict__ w2s) {
  const size_t i = (size_t)blockIdx.x * 256 + threadIdx.x;
  const int bh = (int)(i >> 18);
  const int f = bh & 3;
  const size_t off = i & 262143;
  const float* src; float* dst;
  if (blockIdx.y == 0) { src = w0; dst = w0s; }
  else if (blockIdx.y == 1) { src = w1; dst = w1s; }
  else { src = w2; dst = w2s; }
  dst[i] = src[(size_t)f * 262144 + off];
}

// --------------------------- rope table ------------------------------------
__global__ __launch_bounds__(64) void k_rope_tab(float* __restrict__ ct, float* __restrict__ stb) {
  const int si = blockIdx.x, j = threadIdx.x;
  float inv = powf(500000.0f, -(float)j / 64.0f);
  float ang = (float)si * inv;
  ct[(size_t)si * 64 + j] = cosf(ang);
  stb[(size_t)si * 64 + j] = sinf(ang);
}

// --------------------------- learning rates --------------------------------
__global__ __launch_bounds__(256) void k_lr(const float* __restrict__ x, const float* __restrict__ lr_w,
                                            const float* __restrict__ lr_b,
                                            float* lr0, float* lr1, float* lr2, float base) {
  const int token = blockIdx.x, b_ = token >> 11, si = token & 2047;
  const int wv = threadIdx.x >> 6, lane = threadIdx.x & 63;
  const float* xr = x + (size_t)token * cH;
#pragma unroll
  for (int jj = 0; jj < 3; ++jj) {
    const int j = wv * 3 + jj;
    const float* wr = lr_w + (size_t)j * cH;
    float s = 0.f;
    for (int k = lane; k < cH; k += 64) s += xr[k] * wr[k];
    for (int d = 32; d; d >>= 1) s += __shfl_down(s, d);
    if (lane == 0) {
      float v = s + lr_b[j] + base;
      float sp = (v > 15.f) ? v : log1pf(expf(v));
      const int tt = j >> 2, f = j & 3;
      float* dst = (tt == 0 ? lr0 : tt == 1 ? lr1 : lr2);
      dst[(size_t)(b_ * cNFW + f) * cS + si] = sp;
    }
  }
}

// ------------------ rmsnorm q/k in place + rope -> qa/ka --------------------
__global__ __launch_bounds__(256) void k_normrope(bf16* __restrict__ qkvh,
                                                  const float* __restrict__ qnw, const float* __restrict__ knw,
                                                  const float* __restrict__ ct, const float* __restrict__ stb,
                                                  bf16* __restrict__ qa, bf16* __restrict__ ka) {
  const int token = blockIdx.x, b_ = token >> 11, si = token & 2047;
  const int t = threadIdx.x;
  __shared__ float buf[cH];
  __shared__ float red[4];
  bf16* base = qkvh + (size_t)token * 3 * cH;
  for (int pass = 0; pass < 2; ++pass) {
    __syncthreads();
    bf16* src = base + pass * cH;
    const float* nw = pass ? knw : qnw;
    float ss = 0.f;
    for (int i = t; i < cH; i += 256) {
      float v = b2f(src[i]);
      buf[i] = v;
      ss += v * v;
    }
    for (int d = 32; d; d >>= 1) ss += __shfl_down(ss, d);
    if ((t & 63) == 0) red[t >> 6] = ss;
    __syncthreads();
    const float rstd = rsqrtf((red[0] + red[1] + red[2] + red[3]) / cH + 1e-6f);
    for (int i = t; i < cH; i += 256) {
      float v = buf[i] * rstd * nw[i];
      buf[i] = v;
      src[i] = f2b(v);
    }
    __syncthreads();
    bf16* dst = pass ? ka : qa;
    const float scale = pass ? 1.f : cRSQRT_HD;
    const int hh = t >> 4, j0 = (t & 15) * 4;
    const float* cr = ct + (size_t)si * 64 + j0;
    const float* sr = stb + (size_t)si * 64 + j0;
    bf16* drow = dst + ((size_t)(b_ * cNH + hh) * cS + si) * cHD;
    unsigned short u1[4] __attribute__((aligned(8))), u2[4] __attribute__((aligned(8)));
#pragma unroll
    for (int i = 0; i < 4; ++i) {
      float x1 = buf[hh * cHD + j0 + i], x2 = buf[hh * cHD + 64 + j0 + i];
      u1[i] = f2bu((x1 * cr[i] - x2 * sr[i]) * scale);
      u2[i] = f2bu((x2 * cr[i] + x1 * sr[i]) * scale);
    }
    *(uint2*)(drow + j0) = *(uint2*)u1;
    *(uint2*)(drow + 64 + j0) = *(uint2*)u2;
  }
}

// ------------------ V transpose: qkvh v-part -> vt[b,h,d,s] -----------------
__global__ __launch_bounds__(256) void k_vtr(const bf16* __restrict__ qkvh, bf16* __restrict__ vt) {
  const int tile = blockIdx.x, h = blockIdx.y, b_ = blockIdx.z;
  __shared__ short Ts[64 * 136];
  const int t = threadIdx.x;
  {
    const int r = t >> 2, seg = (t & 3) * 32;
    const bf16* src = qkvh + ((size_t)(b_ * cS) + tile * 64 + r) * 3 * cH + 2 * cH + h * cHD + seg;
    stage16(src, &Ts[r * 136 + seg]);
    stage16(src + 16, &Ts[r * 136 + seg + 16]);
  }
  __syncthreads();
  {
    const int d = t >> 1, seg2 = (t & 1) * 32;
    unsigned short u[32] __attribute__((aligned(16)));
#pragma unroll
    for (int i = 0; i < 32; ++i) u[i] = (unsigned short)Ts[(seg2 + i) * 136 + d];
    bf16* dp = vt + ((size_t)(b_ * cNH + h) * cHD + d) * cS + tile * 64 + seg2;
    *(uint4*)dp = *(uint4*)u;
    *(uint4*)(dp + 8) = *(uint4*)(u + 8);
    *(uint4*)(dp + 16) = *(uint4*)(u + 16);
    *(uint4*)(dp + 24) = *(uint4*)(u + 24);
  }
}

// ------------------ fq/fk/fv from normalized qkvh ---------------------------
__global__ __launch_bounds__(256) void k_fqkv(const bf16* __restrict__ qkvh,
                                              const float* __restrict__ qk_scale,
                                              const float* __restrict__ qk_offset,
                                              bf16* fq, bf16* fk, bf16* fv) {
  const int token = blockIdx.x, b_ = token >> 11, si = token & 2047;
  const int t = threadIdx.x;
  const bf16* base = qkvh + (size_t)token * 3 * cH;
#pragma unroll
  for (int pass = 0; pass < 2; ++pass) {
    const bf16* src = base + pass * cH;
    bf16* fdst = pass ? fk : fq;
    const int head = t >> 6, lane = t & 63;
    float f[8];
    float ss2 = 0.f;
#pragma unroll
    for (int k = 0; k < 8; ++k) {
      const int idx = head * cFD + lane + k * 64;
      float v = b2f(src[idx]);
      float u = v * qk_scale[idx * 2 + pass] + qk_offset[idx * 2 + pass];
      float fv_ = u * sigmoidf_(u);
      f[k] = fv_;
      ss2 += fv_ * fv_;
    }
    for (int d = 1; d < 64; d <<= 1) ss2 += __shfl_xor(ss2, d);
    const float sc2 = rsqrtf(ss2 + 1e-12f);
    bf16* dst = fdst + ((size_t)(b_ * cNFW + head) * cS + si) * cFD;
#pragma unroll
    for (int k = 0; k < 8; ++k) dst[lane + k * 64] = f2b(f[k] * sc2);
  }
  const bf16* vr = base + 2 * cH;
  for (int i = t; i < cH; i += 256) {
    float v = b2f(vr[i]);
    fv[((size_t)(b_ * cNFW + (i >> 9)) * cS + si) * cFD + (i & 511)] = f2b(v * sigmoidf_(v));
  }
}

// --------------------------- attention (flash, MFMA) ------------------------
__global__ __launch_bounds__(256) void k_attn2(const bf16* __restrict__ qa, const bf16* __restrict__ ka,
                                               const bf16* __restrict__ vt, bf16* __restrict__ y) {
  const int qt = blockIdx.x, h = blockIdx.y, b_ = blockIdx.z;
  const int q0 = qt * 64;
  __shared__ short Ks[64 * 136];
  __shared__ short Vts[128 * 72];
  __shared__ short Ps[4 * 16 * 72];
  const int t = threadIdx.x, lane = t & 63, g = lane >> 4, c16 = lane & 15, wv = t >> 6;
  const size_t hb = (size_t)(b_ * cNH + h) * cS;
  const bf16* vb = vt + (size_t)(b_ * cNH + h) * (size_t)(cHD * cS);
  short8 qf[4];
  {
    const bf16* qsrc = qa + (hb + q0 + wv * 16 + c16) * cHD;
#pragma unroll
    for (int ks = 0; ks < 4; ++ks) qf[ks] = *(const short8*)(qsrc + ks * 32 + g * 8);
  }
  f32x4 o[8];
  const f32x4 zero4 = {0.f, 0.f, 0.f, 0.f};
#pragma unroll
  for (int i = 0; i < 8; ++i) o[i] = zero4;
  float m[4], l[4];
#pragma unroll
  for (int r = 0; r < 4; ++r) { m[r] = -1e30f; l[r] = 0.f; }

  for (int kt = 0; kt <= qt; ++kt) {
    __syncthreads();
    {
      const int r = t >> 2, seg = (t & 3) * 32;
      const bf16* ksrc = ka + (hb + kt * 64 + r) * cHD + seg;
      stage16(ksrc, &Ks[r * 136 + seg]);
      stage16(ksrc + 16, &Ks[r * 136 + seg + 16]);
      const int d = t >> 1, seg2 = (t & 1) * 32;
      const bf16* vsrc = vb + (size_t)d * cS + kt * 64 + seg2;
      stage16(vsrc, &Vts[d * 72 + seg2]);
      stage16(vsrc + 16, &Vts[d * 72 + seg2 + 16]);
    }
    __syncthreads();

    f32x4 s4[4];
#pragma unroll
    for (int ni = 0; ni < 4; ++ni) s4[ni] = zero4;
#pragma unroll
    for (int ks = 0; ks < 4; ++ks) {
#pragma unroll
      for (int ni = 0; ni < 4; ++ni) {
        short8 bb = *(const short8*)&Ks[(ni * 16 + c16) * 136 + ks * 32 + g * 8];
        s4[ni] = __builtin_amdgcn_mfma_f32_16x16x32_bf16(qf[ks], bb, s4[ni], 0, 0, 0);
      }
    }
    if (kt == qt) {
#pragma unroll
      for (int ni = 0; ni < 4; ++ni) {
        const int kv = kt * 64 + ni * 16 + c16;
#pragma unroll
        for (int r = 0; r < 4; ++r) {
          const int qr = q0 + wv * 16 + g * 4 + r;
          if (kv > qr) s4[ni][r] = -1e9f;
        }
      }
    }
    float mx[4];
#pragma unroll
    for (int r = 0; r < 4; ++r)
      mx[r] = fmaxf(fmaxf(s4[0][r], s4[1][r]), fmaxf(s4[2][r], s4[3][r]));
#pragma unroll
    for (int d = 1; d < 16; d <<= 1)
#pragma unroll
      for (int r = 0; r < 4; ++r) mx[r] = fmaxf(mx[r], __shfl_xor(mx[r], d));
    float corr[4];
#pragma unroll
    for (int r = 0; r < 4; ++r) {
      float mn = fmaxf(m[r], mx[r]);
      corr[r] = __expf(m[r] - mn);
      m[r] = mn;
    }
    float psum[4] = {0.f, 0.f, 0.f, 0.f};
#pragma unroll
    for (int ni = 0; ni < 4; ++ni)
#pragma unroll
      for (int r = 0; r < 4; ++r) {
        float p = __expf(s4[ni][r] - m[r]);
        s4[ni][r] = p;
        psum[r] += p;
      }
#pragma unroll
    for (int d = 1; d < 16; d <<= 1)
#pragma unroll
      for (int r = 0; r < 4; ++r) psum[r] += __shfl_xor(psum[r], d);
#pragma unroll
    for (int r = 0; r < 4; ++r) l[r] = l[r] * corr[r] + psum[r];
#pragma unroll
    for (int nf = 0; nf < 8; ++nf)
#pragma unroll
      for (int r = 0; r < 4; ++r) o[nf][r] *= corr[r];
    short* pw = &Ps[wv * 1152];
#pragma unroll
    for (int ni = 0; ni < 4; ++ni)
#pragma unroll
      for (int r = 0; r < 4; ++r)
        pw[(g * 4 + r) * 72 + ni * 16 + c16] = (short)f2bu(s4[ni][r]);
    // Ps is wave-private: no barrier needed.
#pragma unroll
    for (int ks2 = 0; ks2 < 2; ++ks2) {
      short8 a = *(const short8*)&pw[c16 * 72 + ks2 * 32 + g * 8];
#pragma unroll
      for (int nf = 0; nf < 8; ++nf) {
        short8 bb = *(const short8*)&Vts[(nf * 16 + c16) * 72 + ks2 * 32 + g * 8];
        o[nf] = __builtin_amdgcn_mfma_f32_16x16x32_bf16(a, bb, o[nf], 0, 0, 0);
      }
    }
  }
  float inv[4];
#pragma unroll
  for (int r = 0; r < 4; ++r) inv[r] = 1.f / l[r];
#pragma unroll
  for (int nf = 0; nf < 8; ++nf)
#pragma unroll
    for (int r = 0; r < 4; ++r) {
      const size_t row = (size_t)(b_ * cS) + q0 + wv * 16 + g * 4 + r;
      y[row * cH + h * cHD + nf * 16 + c16] = f2b(o[nf][r] * inv[r]);
    }
}

// ------------- per-chunk oc rmsnorm + add into y ---------------------------
__global__ __launch_bounds__(256) void k_norm_add(const bf16* __restrict__ occ,
                                                  const float* __restrict__ tw, bf16* __restrict__ y,
                                                  int chunk) {
  const int r = blockIdx.x;  // bh*512 + rr
  const int bh = r >> 9, rr = r & 511;
  const bf16* src = occ + ((size_t)bh * 512 + rr) * 512;
  const int t = threadIdx.x;
  float v0 = b2f(src[t]), v1 = b2f(src[t + 256]);
  float ss = v0 * v0 + v1 * v1;
  __shared__ float red[4];
  for (int d = 32; d; d >>= 1) ss += __shfl_down(ss, d);
  if ((t & 63) == 0) red[t >> 6] = ss;
  __syncthreads();
  const float rstd = rsqrtf((red[0] + red[1] + red[2] + red[3]) / cFD + 1e-6f);
  const int si = chunk * 512 + rr;
  bf16* dst = y + ((size_t)((bh >> 2) * cS) + si) * cH + (bh & 3) * cFD;
  dst[t] = f2b(b2f(dst[t]) + v0 * rstd * tw[t]);
  dst[t + 256] = f2b(b2f(dst[t + 256]) + v1 * rstd * tw[t + 256]);
}

}  // namespace

extern "C" void kernel_launch(void* const* d_in, const int* in_sizes, int n_in,
                              void* d_out, int out_size, void* d_ws, size_t ws_size,
                              hipStream_t stream) {
  (void)in_sizes; (void)n_in; (void)out_size; (void)ws_size;
  const float* x         = (const float*)d_in[0];
  const float* qkv_w     = (const float*)d_in[1];
  const float* q_norm_w  = (const float*)d_in[2];
  const float* k_norm_w  = (const float*)d_in[3];
  const float* qk_scale  = (const float*)d_in[4];
  const float* qk_offset = (const float*)d_in[5];
  const float* lr_w      = (const float*)d_in[6];
  const float* lr_b      = (const float*)d_in[7];
  const float* w0        = (const float*)d_in[8];
  const float* w1        = (const float*)d_in[9];
  const float* w2        = (const float*)d_in[10];
  const float* ttt_nw    = (const float*)d_in[11];
  const float* o_proj_w  = (const float*)d_in[12];
  float* out = (float*)d_out;

  // ---- workspace layout (bytes), total 143,851,520 (proven footprint) ----
  char* Wb = (char*)d_ws;
  // Region A (0..50,331,648): phase-1 = qkvh; TTT phase:
  bf16* qkvh = (bf16*)Wb;
  bf16* t0  = (bf16*)(Wb + 0UL);
  bf16* t1  = (bf16*)(Wb + 4194304UL);
  bf16* t2  = (bf16*)(Wb + 8388608UL);
  bf16* t3  = (bf16*)(Wb + 12582912UL);
  bf16* t4  = (bf16*)(Wb + 16777216UL);
  bf16* trH = (bf16*)(Wb + 20971520UL);
  bf16* trK = (bf16*)(Wb + 25165824UL);
  bf16* occ = (bf16*)(Wb + 29360128UL);
  bf16* w0b = (bf16*)(Wb + 33554432UL);   // contiguous mirrors
  bf16* w1b = (bf16*)(Wb + 37748736UL);
  bf16* w2b = (bf16*)(Wb + 41943040UL);
  bf16* opwb = (bf16*)(Wb + 0UL);         // after TTT loop (t-region dead)
  size_t off = 50331648UL;
  bf16* fqb = (bf16*)(Wb + off); off += 16777216UL;  // xb, then qa, then fq
  bf16* fkb = (bf16*)(Wb + off); off += 16777216UL;  // qkvwb(head), ka, fk
  bf16* fvb = (bf16*)(Wb + off); off += 16777216UL;  // qkvwb(tail), vt, fv
  float* w0s = (float*)(Wb + off); off += 8388608UL;
  float* w1s = (float*)(Wb + off); off += 8388608UL;
  float* w2s = (float*)(Wb + off); off += 8388608UL;
  float* lr0 = (float*)(Wb + off); off += 65536UL;
  float* lr1 = (float*)(Wb + off); off += 65536UL;
  float* lr2 = (float*)(Wb + off); off += 65536UL;
  bf16* y = (bf16*)(Wb + off); off += 16777216UL;
  float* ct  = (float*)(Wb + off); off += 524288UL;
  float* stb = (float*)(Wb + off); off += 524288UL;
  bf16* xb = fqb;            // 8.4M elems
  bf16* qkvwb = fkb;         // 12.6M elems (spans fkb + half fvb)
  bf16* qa = fqb;
  bf16* ka = fkb;
  bf16* vt = fvb;

  const float base_lr_inv = logf(expm1f(0.001f));
  dim3 blk(256);

  k_winit<<<dim3(8192, 3), blk, 0, stream>>>(w0, w1, w2, w0s, w1s, w2s);
  k_rope_tab<<<dim3(2048), dim3(64), 0, stream>>>(ct, stb);
  k_cvt<<<dim3(4096), blk, 0, stream>>>(x, xb);
  k_cvt<<<dim3(6144), blk, 0, stream>>>(qkv_w, qkvwb);
  // qkv = x @ qkv_w^T (all bf16, gload staging)
  k_mm<bf16, 0><<<dim3(48, 32, 1), blk, 0, stream>>>(xb, 2048, 0, qkvwb, 2048, 0, qkvh, 6144, 0, 2048);
  k_lr<<<dim3(4096), blk, 0, stream>>>(x, lr_w, lr_b, lr0, lr1, lr2, base_lr_inv);
  k_normrope<<<dim3(4096), blk, 0, stream>>>(qkvh, q_norm_w, k_norm_w, ct, stb, qa, ka);
  k_vtr<<<dim3(32, 16, 2), blk, 0, stream>>>(qkvh, vt);
  k_attn2<<<dim3(32, 16, 2), blk, 0, stream>>>(qa, ka, vt, y);
  k_fqkv<<<dim3(4096), blk, 0, stream>>>(qkvh, qk_scale, qk_offset, fqb, fkb, fvb);
  // bf16 mirrors of w masters (contiguous 6.29M elems)
  k_cvt<<<dim3(3072), blk, 0, stream>>>(w0s, w0b);

  for (int c = 0; c < 4; ++c) {
    const size_t choff = (size_t)c * 262144;
    k_stage1<<<dim3(4, 4, 32), blk, 0, stream>>>(fqb, fkb, w0b, w2b, t0, t1, t2, t3, c);
    k_mm<bf16, 1><<<dim3(4, 4, 8), blk, 0, stream>>>(fvb + choff, 512, ZG_, w1b, 512, ZL_, t4, 512, ZL_, 512);
    k_elem<<<dim3(8192), blk, 0, stream>>>(t0, t1, t2, t3, t4);
    k_mm<bf16, 0><<<dim3(4, 4, 8), blk, 0, stream>>>(t0, 512, ZL_, w1b, 512, ZL_, occ, 512, ZL_, 512);
    k_norm_add<<<dim3(4096), blk, 0, stream>>>(occ, ttt_nw, y, c);
    k_tr2<<<dim3(8, 8, 16), blk, 0, stream>>>(t3, fkb, trH, trK, c);
    k_upd3<<<dim3(4, 4, 24), blk, 0, stream>>>(fvb, t2, t4, trH, trK, lr0, lr1, lr2,
                                               w0s, w1s, w2s, w0b, w1b, w2b, c);
  }
  k_cvt<<<dim3(2048), blk, 0, stream>>>(o_proj_w, opwb);
  k_mm<float, 0><<<dim3(16, 32, 1), blk, 0, stream>>>(y, 2048, 0, opwb, 2048, 0, out, 2048, 0, 2048);
}

// Round 7
// 900.562 us; speedup vs baseline: 5.7780x; 1.1228x over previous
//
#include <hip/hip_runtime.h>
#include <hip/hip_bf16.h>
#include <math.h>

using bf16 = __hip_bfloat16;

namespace {

constexpr int cH = 2048;
constexpr int cNH = 16;
constexpr int cHD = 128;
constexpr int cNFW = 4;
constexpr int cFD = 512;
constexpr int cS = 2048;
constexpr float cRSQRT_HD = 0.08838834764831845f;  // 1/sqrt(128)
constexpr long ZL_ = 262144;   // 512*512
constexpr long ZG_ = 1048576;  // 2048*512

typedef __attribute__((ext_vector_type(8))) short short8;
typedef __attribute__((ext_vector_type(4))) float f32x4;

__device__ __forceinline__ float sigmoidf_(float x) { return 1.0f / (1.0f + __expf(-x)); }
__device__ __forceinline__ float b2f(bf16 v) { return __bfloat162float(v); }
__device__ __forceinline__ bf16 f2b(float v) { return __float2bfloat16(v); }
__device__ __forceinline__ unsigned short f2bu(float f) {
  return __builtin_bit_cast(unsigned short, __float2bfloat16(f));
}

#if defined(__has_builtin)
#if __has_builtin(__builtin_amdgcn_global_load_lds)
#define HAVE_GLOAD 1
#endif
#endif

// async global->LDS: wave-uniform LDS base, HW adds lane*16B; per-lane global src
__device__ __forceinline__ void gload16(const bf16* g, short* ldsbase) {
#ifdef HAVE_GLOAD
  __builtin_amdgcn_global_load_lds((const __attribute__((address_space(1))) void*)g,
                                   (__attribute__((address_space(3))) void*)ldsbase, 16, 0, 0);
#else
  const int l = threadIdx.x & 63;
  *(uint4*)(ldsbase + l * 8) = *(const uint4*)g;
#endif
}

// stage 16 contiguous bf16 into LDS (vector path)
__device__ __forceinline__ void stage16(const bf16* src, short* dst) {
  *(uint4*)dst = *(const uint4*)src;
  *(uint4*)(dst + 8) = *(const uint4*)(src + 8);
}

__device__ __forceinline__ void store1(float* p, float v) { *p = v; }
__device__ __forceinline__ void store1(bf16* p, float v) { *p = f2b(v); }

// ---------------------------------------------------------------------------
// MFMA GEMM core: 128x128 tile, 4 waves (2x2 of 64x64), BK=32, linear LDS.
// AMODE 0: A [M][K] bf16 row-major (global_load_lds).
// AMODE 1: A [K][M] bf16, scalar-transposed staging with per-k scale.
// BMODE 0: B [N][K] bf16 (NT, global_load_lds). BMODE 1: B [K][N] (NN, scalar).
// ---------------------------------------------------------------------------
template <int AMODE, int BMODE>
__device__ __forceinline__ void mm_core(const bf16* __restrict__ Ab, int lda,
                                        const bf16* __restrict__ Bb, int ldb, int K,
                                        const float* __restrict__ sc,
                                        short* As, short* Bs, f32x4 acc[4][4]) {
  const int t = threadIdx.x, lane = t & 63, g = lane >> 4, c16 = lane & 15;
  const int wv = t >> 6, wm = (wv >> 1) * 64, wn = (wv & 1) * 64;
  for (int k0 = 0; k0 < K; k0 += 32) {
    __syncthreads();
    if constexpr (AMODE == 0) {
      const int ch = wv * 2;
      const bf16* g0 = Ab + (size_t)(ch * 16 + (lane >> 2)) * lda + k0 + (lane & 3) * 8;
      gload16(g0, &As[ch * 512]);
      gload16(g0 + (size_t)16 * lda, &As[ch * 512 + 512]);
    } else {
      const int kk = t >> 3, mseg = (t & 7) * 16;
      const float s = sc[k0 + kk];
      const bf16* p = Ab + (size_t)(k0 + kk) * lda + mseg;
#pragma unroll
      for (int i = 0; i < 16; ++i) As[(mseg + i) * 32 + kk] = (short)f2bu(b2f(p[i]) * s);
    }
    if constexpr (BMODE == 0) {
      const int ch = wv * 2;
      const bf16* g0 = Bb + (size_t)(ch * 16 + (lane >> 2)) * ldb + k0 + (lane & 3) * 8;
      gload16(g0, &Bs[ch * 512]);
      gload16(g0 + (size_t)16 * ldb, &Bs[ch * 512 + 512]);
    } else {
      const int kk = t >> 3, cseg = (t & 7) * 16;
      const short* p = (const short*)(Bb + (size_t)(k0 + kk) * ldb + cseg);
#pragma unroll
      for (int i = 0; i < 16; ++i) Bs[(cseg + i) * 32 + kk] = p[i];
    }
    __syncthreads();
    short8 af[4], bfr[4];
#pragma unroll
    for (int mi = 0; mi < 4; ++mi) af[mi] = *(const short8*)&As[(wm + mi * 16 + c16) * 32 + g * 8];
#pragma unroll
    for (int ni = 0; ni < 4; ++ni) bfr[ni] = *(const short8*)&Bs[(wn + ni * 16 + c16) * 32 + g * 8];
#pragma unroll
    for (int mi = 0; mi < 4; ++mi)
#pragma unroll
      for (int ni = 0; ni < 4; ++ni)
        acc[mi][ni] = __builtin_amdgcn_mfma_f32_16x16x32_bf16(af[mi], bfr[ni], acc[mi][ni], 0, 0, 0);
  }
}

template <bool ACC, bool MIR, typename TC>
__device__ __forceinline__ void mm_store(TC* Cb, bf16* Mb, int ldc, int rb, int cb, f32x4 acc[4][4]) {
  const int t = threadIdx.x, lane = t & 63, g = lane >> 4, c16 = lane & 15;
  const int wv = t >> 6, wm = (wv >> 1) * 64, wn = (wv & 1) * 64;
  const int rbase = rb + wm, cbase = cb + wn;
#pragma unroll
  for (int mi = 0; mi < 4; ++mi)
#pragma unroll
    for (int ni = 0; ni < 4; ++ni) {
      const int col = cbase + ni * 16 + c16;
#pragma unroll
      for (int r = 0; r < 4; ++r) {
        const int row = rbase + mi * 16 + g * 4 + r;
        TC* cp = Cb + (size_t)row * ldc + col;
        if constexpr (ACC) {
          float nv = *cp + acc[mi][ni][r];
          *cp = nv;
          if constexpr (MIR) Mb[(size_t)row * ldc + col] = f2b(nv);
        } else {
          store1(cp, acc[mi][ni][r]);
        }
      }
    }
}

template <typename TC, int BMODE>
__global__ __launch_bounds__(256) void k_mm(const bf16* __restrict__ A, int lda, long zsa,
                                            const bf16* __restrict__ B, int ldb, long zsb,
                                            TC* __restrict__ C, int ldc, long zsc, int K) {
  __shared__ short As[128 * 32];
  __shared__ short Bs[128 * 32];
  const int z = blockIdx.z;
  const bf16* Ab = A + (size_t)z * zsa + (size_t)blockIdx.y * 128 * lda;
  const bf16* Bb = (BMODE == 0) ? (B + (size_t)z * zsb + (size_t)blockIdx.x * 128 * ldb)
                                : (B + (size_t)z * zsb + blockIdx.x * 128);
  f32x4 acc[4][4];
  const f32x4 zero4 = {0.f, 0.f, 0.f, 0.f};
#pragma unroll
  for (int i = 0; i < 4; ++i)
#pragma unroll
    for (int j = 0; j < 4; ++j) acc[i][j] = zero4;
  mm_core<0, BMODE>(Ab, lda, Bb, ldb, K, nullptr, As, Bs, acc);
  mm_store<false, false>(C + (size_t)z * zsc, (bf16*)nullptr, ldc, blockIdx.y * 128, blockIdx.x * 128, acc);
}

// stage1+dh merged: z = bh*5+var: t0=q@w0^T t1=q@w2^T t2=k@w0^T t3=k@w2^T t4=v@w1
__global__ __launch_bounds__(256) void k_stage1(const bf16* __restrict__ fq, const bf16* __restrict__ fk,
                                                const bf16* __restrict__ fv,
                                                const bf16* __restrict__ w0b, const bf16* __restrict__ w1b,
                                                const bf16* __restrict__ w2b,
                                                bf16* t0, bf16* t1, bf16* t2, bf16* t3, bf16* t4, int chunk) {
  __shared__ short As[128 * 32];
  __shared__ short Bs[128 * 32];
  const int z = blockIdx.z, bh = z / 5, var = z % 5;
  const size_t choff = (size_t)chunk * 262144;
  const bf16* Ab = (var < 2 ? fq : (var < 4 ? fk : fv)) + (size_t)bh * ZG_ + choff +
                   (size_t)blockIdx.y * 128 * cFD;
  f32x4 acc[4][4];
  const f32x4 zero4 = {0.f, 0.f, 0.f, 0.f};
#pragma unroll
  for (int i = 0; i < 4; ++i)
#pragma unroll
    for (int j = 0; j < 4; ++j) acc[i][j] = zero4;
  bf16* C;
  if (var == 4) {
    const bf16* Bb = w1b + (size_t)bh * ZL_ + blockIdx.x * 128;
    C = t4 + (size_t)bh * ZL_;
    mm_core<0, 1>(Ab, cFD, Bb, cFD, cFD, nullptr, As, Bs, acc);
  } else {
    const bf16* Bb = (var & 1 ? w2b : w0b) + (size_t)bh * ZL_ + (size_t)blockIdx.x * 128 * cFD;
    C = (var == 0 ? t0 : var == 1 ? t1 : var == 2 ? t2 : t3) + (size_t)bh * ZL_;
    mm_core<0, 0>(Ab, cFD, Bb, cFD, cFD, nullptr, As, Bs, acc);
  }
  mm_store<false, false>(C, (bf16*)nullptr, cFD, blockIdx.y * 128, blockIdx.x * 128, acc);
}

// oc GEMM + trH/trK transposes merged, 1D grid 1152
__global__ __launch_bounds__(256) void k_octr(const bf16* __restrict__ t0, const bf16* __restrict__ w1b,
                                              bf16* __restrict__ occ,
                                              const bf16* __restrict__ t3, const bf16* __restrict__ fkb,
                                              bf16* trH, bf16* trK, int chunk) {
  __shared__ short Sh[8192];
  const int id = blockIdx.x, t = threadIdx.x;
  if (id < 128) {
    short* As = Sh;
    short* Bs = Sh + 4096;
    const int bh = id >> 4, by = (id >> 2) & 3, bx = id & 3;
    const bf16* Ab = t0 + (size_t)bh * ZL_ + (size_t)by * 128 * cFD;
    const bf16* Bb = w1b + (size_t)bh * ZL_ + (size_t)bx * 128 * cFD;
    f32x4 acc[4][4];
    const f32x4 zero4 = {0.f, 0.f, 0.f, 0.f};
#pragma unroll
    for (int i = 0; i < 4; ++i)
#pragma unroll
      for (int j = 0; j < 4; ++j) acc[i][j] = zero4;
    mm_core<0, 0>(Ab, cFD, Bb, cFD, cFD, nullptr, As, Bs, acc);
    mm_store<false, false>(occ + (size_t)bh * ZL_, (bf16*)nullptr, cFD, by * 128, bx * 128, acc);
  } else {
    short* Ts = Sh;  // 64*72 = 4608 shorts
    const int id2 = id - 128;
    const int var = id2 >> 9, bh = (id2 >> 6) & 7, by = (id2 >> 3) & 7, bx = id2 & 7;
    const size_t choff = (size_t)chunk * 262144;
    const bf16* src = (var == 0) ? (t3 + (size_t)bh * ZL_) : (fkb + choff + (size_t)bh * ZG_);
    bf16* dst = (var == 0) ? (trH + (size_t)bh * ZL_) : (trK + (size_t)bh * ZL_);
    {
      const int rr = t >> 2, cseg = (t & 3) * 16;
      const bf16* p = src + (size_t)(by * 64 + rr) * cFD + bx * 64 + cseg;
      stage16(p, &Ts[rr * 72 + cseg]);
    }
    __syncthreads();
    {
      const int oc_ = t >> 2, rseg = (t & 3) * 16;
      unsigned short u[16] __attribute__((aligned(16)));
#pragma unroll
      for (int i = 0; i < 16; ++i) u[i] = (unsigned short)Ts[(rseg + i) * 72 + oc_];
      bf16* dp = dst + (size_t)(bx * 64 + oc_) * cFD + by * 64 + rseg;
      *(uint4*)dp = *(uint4*)u;
      *(uint4*)(dp + 8) = *(uint4*)(u + 8);
    }
  }
}

// upd3 + norm_add merged, 1D grid 4480 (384 upd tiles + 4096 norm rows)
__global__ __launch_bounds__(256) void k_updna(const bf16* __restrict__ fvb, const bf16* __restrict__ t2,
                                               const bf16* __restrict__ t4,
                                               const bf16* __restrict__ trH, const bf16* __restrict__ trK,
                                               const float* __restrict__ lr0, const float* __restrict__ lr1,
                                               const float* __restrict__ lr2,
                                               float* w0s, float* w1s, float* w2s,
                                               bf16* w0b, bf16* w1b, bf16* w2b,
                                               const bf16* __restrict__ occ, const float* __restrict__ tw,
                                               bf16* __restrict__ y, int chunk) {
  __shared__ short Sh[8192];
  __shared__ float red[4];
  const int id = blockIdx.x, t = threadIdx.x;
  if (id < 384) {
    short* As = Sh;
    short* Bs = Sh + 4096;
    const int z = id >> 4, tile = id & 15, by = tile >> 2, bx = tile & 3;
    const int var = z >> 3, bh = z & 7;
    const size_t choff = (size_t)chunk * 262144;
    const bf16 *Aa, *Bb;
    const float* sc;
    float* W;
    bf16* M;
    if (var == 0) {
      Aa = fvb + choff + (size_t)bh * ZG_; sc = lr1 + bh * 2048 + chunk * 512;
      Bb = trH + (size_t)bh * ZL_; W = w1s + (size_t)bh * ZL_; M = w1b + (size_t)bh * ZL_;
    } else if (var == 1) {
      Aa = t2 + (size_t)bh * ZL_; sc = lr0 + bh * 2048 + chunk * 512;
      Bb = trK + (size_t)bh * ZL_; W = w0s + (size_t)bh * ZL_; M = w0b + (size_t)bh * ZL_;
    } else {
      Aa = t4 + (size_t)bh * ZL_; sc = lr2 + bh * 2048 + chunk * 512;
      Bb = trK + (size_t)bh * ZL_; W = w2s + (size_t)bh * ZL_; M = w2b + (size_t)bh * ZL_;
    }
    Aa += by * 128;
    Bb += (size_t)bx * 128 * cFD;
    f32x4 acc[4][4];
    const f32x4 zero4 = {0.f, 0.f, 0.f, 0.f};
#pragma unroll
    for (int i = 0; i < 4; ++i)
#pragma unroll
      for (int j = 0; j < 4; ++j) acc[i][j] = zero4;
    mm_core<1, 0>(Aa, cFD, Bb, cFD, cFD, sc, As, Bs, acc);
    mm_store<true, true>(W, M, cFD, by * 128, bx * 128, acc);
  } else {
    const int rrow = id - 384;
    const int bh = rrow >> 9, rr = rrow & 511;
    const bf16* src = occ + ((size_t)bh * 512 + rr) * 512;
    float v0 = b2f(src[t]), v1 = b2f(src[t + 256]);
    float ss = v0 * v0 + v1 * v1;
    for (int d = 32; d; d >>= 1) ss += __shfl_down(ss, d);
    if ((t & 63) == 0) red[t >> 6] = ss;
    __syncthreads();
    const float rstd = rsqrtf((red[0] + red[1] + red[2] + red[3]) / cFD + 1e-6f);
    const int si = chunk * 512 + rr;
    bf16* dst = y + ((size_t)((bh >> 2) * cS) + si) * cH + (bh & 3) * cFD;
    dst[t] = f2b(b2f(dst[t]) + v0 * rstd * tw[t]);
    dst[t + 256] = f2b(b2f(dst[t + 256]) + v1 * rstd * tw[t + 256]);
  }
}

// --------------------------- elementwise gates ------------------------------
__global__ __launch_bounds__(256) void k_elem(bf16* t0, const bf16* t1, bf16* t2, bf16* t3, bf16* t4) {
  const size_t i = (size_t)blockIdx.x * 256 + threadIdx.x;
  float hq1 = b2f(t0[i]), hq2 = b2f(t1[i]), g1 = b2f(t2[i]), g2 = b2f(t3[i]), dh = b2f(t4[i]);
  float s1 = sigmoidf_(hq1);
  t0[i] = f2b(hq1 * s1 * hq2);
  float sg = sigmoidf_(g1);
  float gate = g1 * sg;
  t3[i] = f2b(gate * g2);
  t4[i] = f2b(dh * gate);
  t2[i] = f2b(dh * g2 * (sg * (1.0f + g1 * (1.0f - sg))));
}

// --------------------------- fp32 -> bf16 flat convert ----------------------
__global__ __launch_bounds__(256) void k_cvt(const float* __restrict__ src, bf16* __restrict__ dst) {
  const size_t i = ((size_t)blockIdx.x * 256 + threadIdx.x) * 8;
  float4 a = *(const float4*)(src + i), b = *(const float4*)(src + i + 4);
  unsigned short u[8] __attribute__((aligned(16)));
  u[0] = f2bu(a.x); u[1] = f2bu(a.y); u[2] = f2bu(a.z); u[3] = f2bu(a.w);
  u[4] = f2bu(b.x); u[5] = f2bu(b.y); u[6] = f2bu(b.z); u[7] = f2bu(b.w);
  *(uint4*)(dst + i) = *(uint4*)u;
}

// --------------------------- state init ------------------------------------
__global__ __launch_bounds__(256) void k_winit(const float* __restrict__ w0, const float* __restrict__ w1,
                                               const float* __restrict__ w2,
                                               float* __restrict__ w0s, float* __restrict__ w1s,
                                               float* __restrict__ w2s) {
  const size_t i = (size_t)blockIdx.x * 256 + threadIdx.x;
  const int bh = (int)(i >> 18);
  const int f = bh & 3;
  const size_t off = i & 262143;
  const float* src; float* dst;
  if (blockIdx.y == 0) { src = w0; dst = w0s; }
  else if (blockIdx.y == 1) { src = w1; dst = w1s; }
  else { src = w2; dst = w2s; }
  dst[i] = src[(size_t)f * 262144 + off];
}

// --------------------------- rope table ------------------------------------
__global__ __launch_bounds__(64) void k_rope_tab(float* __restrict__ ct, float* __restrict__ stb) {
  const int si = blockIdx.x, j = threadIdx.x;
  float inv = powf(500000.0f, -(float)j / 64.0f);
  float ang = (float)si * inv;
  ct[(size_t)si * 64 + j] = cosf(ang);
  stb[(size_t)si * 64 + j] = sinf(ang);
}

// --------------------------- learning rates --------------------------------
__global__ __launch_bounds__(256) void k_lr(const float* __restrict__ x, const float* __restrict__ lr_w,
                                            const float* __restrict__ lr_b,
                                            float* lr0, float* lr1, float* lr2, float base) {
  const int token = blockIdx.x, b_ = token >> 11, si = token & 2047;
  const int wv = threadIdx.x >> 6, lane = threadIdx.x & 63;
  const float* xr = x + (size_t)token * cH;
#pragma unroll
  for (int jj = 0; jj < 3; ++jj) {
    const int j = wv * 3 + jj;
    const float* wr = lr_w + (size_t)j * cH;
    float s = 0.f;
    for (int k = lane; k < cH; k += 64) s += xr[k] * wr[k];
    for (int d = 32; d; d >>= 1) s += __shfl_down(s, d);
    if (lane == 0) {
      float v = s + lr_b[j] + base;
      float sp = (v > 15.f) ? v : log1pf(expf(v));
      const int tt = j >> 2, f = j & 3;
      float* dst = (tt == 0 ? lr0 : tt == 1 ? lr1 : lr2);
      dst[(size_t)(b_ * cNFW + f) * cS + si] = sp;
    }
  }
}

// ------------------ rmsnorm q/k in place + rope -> qa/ka --------------------
__global__ __launch_bounds__(256) void k_normrope(bf16* __restrict__ qkvh,
                                                  const float* __restrict__ qnw, const float* __restrict__ knw,
                                                  const float* __restrict__ ct, const float* __restrict__ stb,
                                                  bf16* __restrict__ qa, bf16* __restrict__ ka) {
  const int token = blockIdx.x, b_ = token >> 11, si = token & 2047;
  const int t = threadIdx.x;
  __shared__ float buf[cH];
  __shared__ float red[4];
  bf16* base = qkvh + (size_t)token * 3 * cH;
  for (int pass = 0; pass < 2; ++pass) {
    __syncthreads();
    bf16* src = base + pass * cH;
    const float* nw = pass ? knw : qnw;
    float ss = 0.f;
    for (int i = t; i < cH; i += 256) {
      float v = b2f(src[i]);
      buf[i] = v;
      ss += v * v;
    }
    for (int d = 32; d; d >>= 1) ss += __shfl_down(ss, d);
    if ((t & 63) == 0) red[t >> 6] = ss;
    __syncthreads();
    const float rstd = rsqrtf((red[0] + red[1] + red[2] + red[3]) / cH + 1e-6f);
    for (int i = t; i < cH; i += 256) {
      float v = buf[i] * rstd * nw[i];
      buf[i] = v;
      src[i] = f2b(v);
    }
    __syncthreads();
    bf16* dst = pass ? ka : qa;
    const float scale = pass ? 1.f : cRSQRT_HD;
    const int hh = t >> 4, j0 = (t & 15) * 4;
    const float* cr = ct + (size_t)si * 64 + j0;
    const float* sr = stb + (size_t)si * 64 + j0;
    bf16* drow = dst + ((size_t)(b_ * cNH + hh) * cS + si) * cHD;
    unsigned short u1[4] __attribute__((aligned(8))), u2[4] __attribute__((aligned(8)));
#pragma unroll
    for (int i = 0; i < 4; ++i) {
      float x1 = buf[hh * cHD + j0 + i], x2 = buf[hh * cHD + 64 + j0 + i];
      u1[i] = f2bu((x1 * cr[i] - x2 * sr[i]) * scale);
      u2[i] = f2bu((x2 * cr[i] + x1 * sr[i]) * scale);
    }
    *(uint2*)(drow + j0) = *(uint2*)u1;
    *(uint2*)(drow + 64 + j0) = *(uint2*)u2;
  }
}

// ------------------ V transpose: qkvh v-part -> vt[b,h,d,s] -----------------
__global__ __launch_bounds__(256) void k_vtr(const bf16* __restrict__ qkvh, bf16* __restrict__ vt) {
  const int tile = blockIdx.x, h = blockIdx.y, b_ = blockIdx.z;
  __shared__ short Ts[64 * 136];
  const int t = threadIdx.x;
  {
    const int r = t >> 2, seg = (t & 3) * 32;
    const bf16* src = qkvh + ((size_t)(b_ * cS) + tile * 64 + r) * 3 * cH + 2 * cH + h * cHD + seg;
    stage16(src, &Ts[r * 136 + seg]);
    stage16(src + 16, &Ts[r * 136 + seg + 16]);
  }
  __syncthreads();
  {
    const int d = t >> 1, seg2 = (t & 1) * 32;
    unsigned short u[32] __attribute__((aligned(16)));
#pragma unroll
    for (int i = 0; i < 32; ++i) u[i] = (unsigned short)Ts[(seg2 + i) * 136 + d];
    bf16* dp = vt + ((size_t)(b_ * cNH + h) * cHD + d) * cS + tile * 64 + seg2;
    *(uint4*)dp = *(uint4*)u;
    *(uint4*)(dp + 8) = *(uint4*)(u + 8);
    *(uint4*)(dp + 16) = *(uint4*)(u + 16);
    *(uint4*)(dp + 24) = *(uint4*)(u + 24);
  }
}

// ------------------ fq/fk/fv from normalized qkvh ---------------------------
__global__ __launch_bounds__(256) void k_fqkv(const bf16* __restrict__ qkvh,
                                              const float* __restrict__ qk_scale,
                                              const float* __restrict__ qk_offset,
                                              bf16* fq, bf16* fk, bf16* fv) {
  const int token = blockIdx.x, b_ = token >> 11, si = token & 2047;
  const int t = threadIdx.x;
  const bf16* base = qkvh + (size_t)token * 3 * cH;
#pragma unroll
  for (int pass = 0; pass < 2; ++pass) {
    const bf16* src = base + pass * cH;
    bf16* fdst = pass ? fk : fq;
    const int head = t >> 6, lane = t & 63;
    float f[8];
    float ss2 = 0.f;
#pragma unroll
    for (int k = 0; k < 8; ++k) {
      const int idx = head * cFD + lane + k * 64;
      float v = b2f(src[idx]);
      float u = v * qk_scale[idx * 2 + pass] + qk_offset[idx * 2 + pass];
      float fv_ = u * sigmoidf_(u);
      f[k] = fv_;
      ss2 += fv_ * fv_;
    }
    for (int d = 1; d < 64; d <<= 1) ss2 += __shfl_xor(ss2, d);
    const float sc2 = rsqrtf(ss2 + 1e-12f);
    bf16* dst = fdst + ((size_t)(b_ * cNFW + head) * cS + si) * cFD;
#pragma unroll
    for (int k = 0; k < 8; ++k) dst[lane + k * 64] = f2b(f[k] * sc2);
  }
  const bf16* vr = base + 2 * cH;
  for (int i = t; i < cH; i += 256) {
    float v = b2f(vr[i]);
    fv[((size_t)(b_ * cNFW + (i >> 9)) * cS + si) * cFD + (i & 511)] = f2b(v * sigmoidf_(v));
  }
}

// ------------- attention (flash, MFMA, XCD-swizzled + reg prefetch) ---------
// 1D grid 1024: xcd = id&7, qt = 31 - ((id>>3)&31), hb = (id>>8)*8 + xcd
__global__ __launch_bounds__(256) void k_attn3(const bf16* __restrict__ qa, const bf16* __restrict__ ka,
                                               const bf16* __restrict__ vt, bf16* __restrict__ y) {
  const int id = blockIdx.x;
  const int hb = ((id >> 8) << 3) + (id & 7);   // 0..31, constant per XCD group
  const int qt = 31 - ((id >> 3) & 31);         // long blocks first
  const int h = hb & 15, b_ = hb >> 4;
  const int q0 = qt * 64;
  __shared__ short Ks[64 * 136];
  __shared__ short Vts[128 * 72];
  __shared__ short Ps[4 * 16 * 72];
  const int t = threadIdx.x, lane = t & 63, g = lane >> 4, c16 = lane & 15, wv = t >> 6;
  const size_t hbq = (size_t)(b_ * cNH + h) * cS;
  const bf16* vb = vt + (size_t)(b_ * cNH + h) * (size_t)(cHD * cS);
  short8 qf[4];
  {
    const bf16* qsrc = qa + (hbq + q0 + wv * 16 + c16) * cHD;
#pragma unroll
    for (int ks = 0; ks < 4; ++ks) qf[ks] = *(const short8*)(qsrc + ks * 32 + g * 8);
  }
  f32x4 o[8];
  const f32x4 zero4 = {0.f, 0.f, 0.f, 0.f};
#pragma unroll
  for (int i = 0; i < 8; ++i) o[i] = zero4;
  float m[4], l[4];
#pragma unroll
  for (int r = 0; r < 4; ++r) { m[r] = -1e30f; l[r] = 0.f; }

  const int r = t >> 2, seg = (t & 3) * 32;
  const int dv = t >> 1, seg2 = (t & 1) * 32;
  uint4 kp0, kp1, kp2, kp3, vp0, vp1, vp2, vp3;
  {
    const bf16* ksrc = ka + (hbq + r) * cHD + seg;
    kp0 = *(const uint4*)ksrc; kp1 = *(const uint4*)(ksrc + 8);
    kp2 = *(const uint4*)(ksrc + 16); kp3 = *(const uint4*)(ksrc + 24);
    const bf16* vsrc = vb + (size_t)dv * cS + seg2;
    vp0 = *(const uint4*)vsrc; vp1 = *(const uint4*)(vsrc + 8);
    vp2 = *(const uint4*)(vsrc + 16); vp3 = *(const uint4*)(vsrc + 24);
  }

  for (int kt = 0; kt <= qt; ++kt) {
    __syncthreads();
    {
      short* kd = &Ks[r * 136 + seg];
      *(uint4*)kd = kp0; *(uint4*)(kd + 8) = kp1;
      *(uint4*)(kd + 16) = kp2; *(uint4*)(kd + 24) = kp3;
      short* vd = &Vts[dv * 72 + seg2];
      *(uint4*)vd = vp0; *(uint4*)(vd + 8) = vp1;
      *(uint4*)(vd + 16) = vp2; *(uint4*)(vd + 24) = vp3;
    }
    __syncthreads();
    if (kt < qt) {  // prefetch next tile; latency hides under compute below
      const bf16* ksrc = ka + (hbq + (kt + 1) * 64 + r) * cHD + seg;
      kp0 = *(const uint4*)ksrc; kp1 = *(const uint4*)(ksrc + 8);
      kp2 = *(const uint4*)(ksrc + 16); kp3 = *(const uint4*)(ksrc + 24);
      const bf16* vsrc = vb + (size_t)dv * cS + (kt + 1) * 64 + seg2;
      vp0 = *(const uint4*)vsrc; vp1 = *(const uint4*)(vsrc + 8);
      vp2 = *(const uint4*)(vsrc + 16); vp3 = *(const uint4*)(vsrc + 24);
    }

    f32x4 s4[4];
#pragma unroll
    for (int ni = 0; ni < 4; ++ni) s4[ni] = zero4;
#pragma unroll
    for (int ks = 0; ks < 4; ++ks) {
#pragma unroll
      for (int ni = 0; ni < 4; ++ni) {
        short8 bb = *(const short8*)&Ks[(ni * 16 + c16) * 136 + ks * 32 + g * 8];
        s4[ni] = __builtin_amdgcn_mfma_f32_16x16x32_bf16(qf[ks], bb, s4[ni], 0, 0, 0);
      }
    }
    if (kt == qt) {
#pragma unroll
      for (int ni = 0; ni < 4; ++ni) {
        const int kv = kt * 64 + ni * 16 + c16;
#pragma unroll
        for (int rr = 0; rr < 4; ++rr) {
          const int qr = q0 + wv * 16 + g * 4 + rr;
          if (kv > qr) s4[ni][rr] = -1e9f;
        }
      }
    }
    float mx[4];
#pragma unroll
    for (int rr = 0; rr < 4; ++rr)
      mx[rr] = fmaxf(fmaxf(s4[0][rr], s4[1][rr]), fmaxf(s4[2][rr], s4[3][rr]));
#pragma unroll
    for (int d = 1; d < 16; d <<= 1)
#pragma unroll
      for (int rr = 0; rr < 4; ++rr) mx[rr] = fmaxf(mx[rr], __shfl_xor(mx[rr], d));
    float corr[4];
#pragma unroll
    for (int rr = 0; rr < 4; ++rr) {
      float mn = fmaxf(m[rr], mx[rr]);
      corr[rr] = __expf(m[rr] - mn);
      m[rr] = mn;
    }
    float psum[4] = {0.f, 0.f, 0.f, 0.f};
#pragma unroll
    for (int ni = 0; ni < 4; ++ni)
#pragma unroll
      for (int rr = 0; rr < 4; ++rr) {
        float p = __expf(s4[ni][rr] - m[rr]);
        s4[ni][rr] = p;
        psum[rr] += p;
      }
#pragma unroll
    for (int d = 1; d < 16; d <<= 1)
#pragma unroll
      for (int rr = 0; rr < 4; ++rr) psum[rr] += __shfl_xor(psum[rr], d);
#pragma unroll
    for (int rr = 0; rr < 4; ++rr) l[rr] = l[rr] * corr[rr] + psum[rr];
#pragma unroll
    for (int nf = 0; nf < 8; ++nf)
#pragma unroll
      for (int rr = 0; rr < 4; ++rr) o[nf][rr] *= corr[rr];
    short* pw = &Ps[wv * 1152];
#pragma unroll
    for (int ni = 0; ni < 4; ++ni)
#pragma unroll
      for (int rr = 0; rr < 4; ++rr)
        pw[(g * 4 + rr) * 72 + ni * 16 + c16] = (short)f2bu(s4[ni][rr]);
    // Ps is wave-private: no barrier needed.
#pragma unroll
    for (int ks2 = 0; ks2 < 2; ++ks2) {
      short8 a = *(const short8*)&pw[c16 * 72 + ks2 * 32 + g * 8];
#pragma unroll
      for (int nf = 0; nf < 8; ++nf) {
        short8 bb = *(const short8*)&Vts[(nf * 16 + c16) * 72 + ks2 * 32 + g * 8];
        o[nf] = __builtin_amdgcn_mfma_f32_16x16x32_bf16(a, bb, o[nf], 0, 0, 0);
      }
    }
  }
  float inv[4];
#pragma unroll
  for (int rr = 0; rr < 4; ++rr) inv[rr] = 1.f / l[rr];
#pragma unroll
  for (int nf = 0; nf < 8; ++nf)
#pragma unroll
    for (int rr = 0; rr < 4; ++rr) {
      const size_t row = (size_t)(b_ * cS) + q0 + wv * 16 + g * 4 + rr;
      y[row * cH + h * cHD + nf * 16 + c16] = f2b(o[nf][rr] * inv[rr]);
    }
}

}  // namespace

extern "C" void kernel_launch(void* const* d_in, const int* in_sizes, int n_in,
                              void* d_out, int out_size, void* d_ws, size_t ws_size,
                              hipStream_t stream) {
  (void)in_sizes; (void)n_in; (void)out_size; (void)ws_size;
  const float* x         = (const float*)d_in[0];
  const float* qkv_w     = (const float*)d_in[1];
  const float* q_norm_w  = (const float*)d_in[2];
  const float* k_norm_w  = (const float*)d_in[3];
  const float* qk_scale  = (const float*)d_in[4];
  const float* qk_offset = (const float*)d_in[5];
  const float* lr_w      = (const float*)d_in[6];
  const float* lr_b      = (const float*)d_in[7];
  const float* w0        = (const float*)d_in[8];
  const float* w1        = (const float*)d_in[9];
  const float* w2        = (const float*)d_in[10];
  const float* ttt_nw    = (const float*)d_in[11];
  const float* o_proj_w  = (const float*)d_in[12];
  float* out = (float*)d_out;

  // ---- workspace layout (bytes), total 143,851,520 (proven footprint) ----
  char* Wb = (char*)d_ws;
  bf16* qkvh = (bf16*)Wb;
  bf16* t0  = (bf16*)(Wb + 0UL);
  bf16* t1  = (bf16*)(Wb + 4194304UL);
  bf16* t2  = (bf16*)(Wb + 8388608UL);
  bf16* t3  = (bf16*)(Wb + 12582912UL);
  bf16* t4  = (bf16*)(Wb + 16777216UL);
  bf16* trH = (bf16*)(Wb + 20971520UL);
  bf16* trK = (bf16*)(Wb + 25165824UL);
  bf16* occ = (bf16*)(Wb + 29360128UL);
  bf16* w0b = (bf16*)(Wb + 33554432UL);   // contiguous mirrors
  bf16* w1b = (bf16*)(Wb + 37748736UL);
  bf16* w2b = (bf16*)(Wb + 41943040UL);
  bf16* opwb = (bf16*)(Wb + 0UL);         // after TTT loop (t-region dead)
  size_t off = 50331648UL;
  bf16* fqb = (bf16*)(Wb + off); off += 16777216UL;  // xb, then qa, then fq
  bf16* fkb = (bf16*)(Wb + off); off += 16777216UL;  // qkvwb(head), ka, fk
  bf16* fvb = (bf16*)(Wb + off); off += 16777216UL;  // qkvwb(tail), vt, fv
  float* w0s = (float*)(Wb + off); off += 8388608UL;
  float* w1s = (float*)(Wb + off); off += 8388608UL;
  float* w2s = (float*)(Wb + off); off += 8388608UL;
  float* lr0 = (float*)(Wb + off); off += 65536UL;
  float* lr1 = (float*)(Wb + off); off += 65536UL;
  float* lr2 = (float*)(Wb + off); off += 65536UL;
  bf16* y = (bf16*)(Wb + off); off += 16777216UL;
  float* ct  = (float*)(Wb + off); off += 524288UL;
  float* stb = (float*)(Wb + off); off += 524288UL;
  bf16* xb = fqb;
  bf16* qkvwb = fkb;
  bf16* qa = fqb;
  bf16* ka = fkb;
  bf16* vt = fvb;

  const float base_lr_inv = logf(expm1f(0.001f));
  dim3 blk(256);

  k_winit<<<dim3(8192, 3), blk, 0, stream>>>(w0, w1, w2, w0s, w1s, w2s);
  k_rope_tab<<<dim3(2048), dim3(64), 0, stream>>>(ct, stb);
  k_cvt<<<dim3(4096), blk, 0, stream>>>(x, xb);
  k_cvt<<<dim3(6144), blk, 0, stream>>>(qkv_w, qkvwb);
  k_mm<bf16, 0><<<dim3(48, 32, 1), blk, 0, stream>>>(xb, 2048, 0, qkvwb, 2048, 0, qkvh, 6144, 0, 2048);
  k_lr<<<dim3(4096), blk, 0, stream>>>(x, lr_w, lr_b, lr0, lr1, lr2, base_lr_inv);
  k_normrope<<<dim3(4096), blk, 0, stream>>>(qkvh, q_norm_w, k_norm_w, ct, stb, qa, ka);
  k_vtr<<<dim3(32, 16, 2), blk, 0, stream>>>(qkvh, vt);
  k_attn3<<<dim3(1024), blk, 0, stream>>>(qa, ka, vt, y);
  k_fqkv<<<dim3(4096), blk, 0, stream>>>(qkvh, qk_scale, qk_offset, fqb, fkb, fvb);
  k_cvt<<<dim3(3072), blk, 0, stream>>>(w0s, w0b);  // contiguous 6.29M-elem mirror block

  for (int c = 0; c < 4; ++c) {
    k_stage1<<<dim3(4, 4, 40), blk, 0, stream>>>(fqb, fkb, fvb, w0b, w1b, w2b,
                                                 t0, t1, t2, t3, t4, c);
    k_elem<<<dim3(8192), blk, 0, stream>>>(t0, t1, t2, t3, t4);
    k_octr<<<dim3(1152), blk, 0, stream>>>(t0, w1b, occ, t3, fkb, trH, trK, c);
    k_updna<<<dim3(4480), blk, 0, stream>>>(fvb, t2, t4, trH, trK, lr0, lr1, lr2,
                                            w0s, w1s, w2s, w0b, w1b, w2b, occ, ttt_nw, y, c);
  }
  k_cvt<<<dim3(2048), blk, 0, stream>>>(o_proj_w, opwb);
  k_mm<float, 0><<<dim3(16, 32, 1), blk, 0, stream>>>(y, 2048, 0, opwb, 2048, 0, out, 2048, 0, 2048);
}

// Round 8
// 896.239 us; speedup vs baseline: 5.8059x; 1.0048x over previous
//
#include <hip/hip_runtime.h>
#include <hip/hip_bf16.h>
#include <math.h>

using bf16 = __hip_bfloat16;

namespace {

constexpr int cH = 2048;
constexpr int cNH = 16;
constexpr int cHD = 128;
constexpr int cNFW = 4;
constexpr int cFD = 512;
constexpr int cS = 2048;
constexpr float cRSQRT_HD = 0.08838834764831845f;  // 1/sqrt(128)
constexpr long ZL_ = 262144;   // 512*512
constexpr long ZG_ = 1048576;  // 2048*512

typedef __attribute__((ext_vector_type(8))) short short8;
typedef __attribute__((ext_vector_type(4))) float f32x4;

__device__ __forceinline__ float sigmoidf_(float x) { return 1.0f / (1.0f + __expf(-x)); }
__device__ __forceinline__ float b2f(bf16 v) { return __bfloat162float(v); }
__device__ __forceinline__ bf16 f2b(float v) { return __float2bfloat16(v); }
__device__ __forceinline__ unsigned short f2bu(float f) {
  return __builtin_bit_cast(unsigned short, __float2bfloat16(f));
}

#if defined(__has_builtin)
#if __has_builtin(__builtin_amdgcn_global_load_lds)
#define HAVE_GLOAD 1
#endif
#endif

// async global->LDS: wave-uniform LDS base, HW adds lane*16B; per-lane global src
__device__ __forceinline__ void gload16(const bf16* g, short* ldsbase) {
#ifdef HAVE_GLOAD
  __builtin_amdgcn_global_load_lds((const __attribute__((address_space(1))) void*)g,
                                   (__attribute__((address_space(3))) void*)ldsbase, 16, 0, 0);
#else
  const int l = threadIdx.x & 63;
  *(uint4*)(ldsbase + l * 8) = *(const uint4*)g;
#endif
}

__device__ __forceinline__ void stage16(const bf16* src, short* dst) {
  *(uint4*)dst = *(const uint4*)src;
  *(uint4*)(dst + 8) = *(const uint4*)(src + 8);
}

__device__ __forceinline__ void store1(float* p, float v) { *p = v; }
__device__ __forceinline__ void store1(bf16* p, float v) { *p = f2b(v); }

// ---------------------------------------------------------------------------
// MFMA GEMM core: 128x128 tile, 4 waves (2x2 of 64x64), BK=32, linear LDS.
// AMODE 0: A [M][K] bf16 row-major (global_load_lds).
// AMODE 1: A [K][M] bf16, scalar-transposed staging with per-k scale.
// BMODE 0: B [N][K] bf16 (NT, global_load_lds). BMODE 1: B [K][N] (NN, scalar).
// ---------------------------------------------------------------------------
template <int AMODE, int BMODE>
__device__ __forceinline__ void mm_core(const bf16* __restrict__ Ab, int lda,
                                        const bf16* __restrict__ Bb, int ldb, int K,
                                        const float* __restrict__ sc,
                                        short* As, short* Bs, f32x4 acc[4][4]) {
  const int t = threadIdx.x, lane = t & 63, g = lane >> 4, c16 = lane & 15;
  const int wv = t >> 6, wm = (wv >> 1) * 64, wn = (wv & 1) * 64;
  for (int k0 = 0; k0 < K; k0 += 32) {
    __syncthreads();
    if constexpr (AMODE == 0) {
      const int ch = wv * 2;
      const bf16* g0 = Ab + (size_t)(ch * 16 + (lane >> 2)) * lda + k0 + (lane & 3) * 8;
      gload16(g0, &As[ch * 512]);
      gload16(g0 + (size_t)16 * lda, &As[ch * 512 + 512]);
    } else {
      const int kk = t >> 3, mseg = (t & 7) * 16;
      const float s = sc[k0 + kk];
      const bf16* p = Ab + (size_t)(k0 + kk) * lda + mseg;
#pragma unroll
      for (int i = 0; i < 16; ++i) As[(mseg + i) * 32 + kk] = (short)f2bu(b2f(p[i]) * s);
    }
    if constexpr (BMODE == 0) {
      const int ch = wv * 2;
      const bf16* g0 = Bb + (size_t)(ch * 16 + (lane >> 2)) * ldb + k0 + (lane & 3) * 8;
      gload16(g0, &Bs[ch * 512]);
      gload16(g0 + (size_t)16 * ldb, &Bs[ch * 512 + 512]);
    } else {
      const int kk = t >> 3, cseg = (t & 7) * 16;
      const short* p = (const short*)(Bb + (size_t)(k0 + kk) * ldb + cseg);
#pragma unroll
      for (int i = 0; i < 16; ++i) Bs[(cseg + i) * 32 + kk] = p[i];
    }
    __syncthreads();
    short8 af[4], bfr[4];
#pragma unroll
    for (int mi = 0; mi < 4; ++mi) af[mi] = *(const short8*)&As[(wm + mi * 16 + c16) * 32 + g * 8];
#pragma unroll
    for (int ni = 0; ni < 4; ++ni) bfr[ni] = *(const short8*)&Bs[(wn + ni * 16 + c16) * 32 + g * 8];
#pragma unroll
    for (int mi = 0; mi < 4; ++mi)
#pragma unroll
      for (int ni = 0; ni < 4; ++ni)
        acc[mi][ni] = __builtin_amdgcn_mfma_f32_16x16x32_bf16(af[mi], bfr[ni], acc[mi][ni], 0, 0, 0);
  }
}

template <bool ACC, bool MIR, typename TC>
__device__ __forceinline__ void mm_store(TC* Cb, bf16* Mb, int ldc, int rb, int cb, f32x4 acc[4][4]) {
  const int t = threadIdx.x, lane = t & 63, g = lane >> 4, c16 = lane & 15;
  const int wv = t >> 6, wm = (wv >> 1) * 64, wn = (wv & 1) * 64;
  const int rbase = rb + wm, cbase = cb + wn;
#pragma unroll
  for (int mi = 0; mi < 4; ++mi)
#pragma unroll
    for (int ni = 0; ni < 4; ++ni) {
      const int col = cbase + ni * 16 + c16;
#pragma unroll
      for (int r = 0; r < 4; ++r) {
        const int row = rbase + mi * 16 + g * 4 + r;
        TC* cp = Cb + (size_t)row * ldc + col;
        if constexpr (ACC) {
          float nv = *cp + acc[mi][ni][r];
          *cp = nv;
          if constexpr (MIR) Mb[(size_t)row * ldc + col] = f2b(nv);
        } else {
          store1(cp, acc[mi][ni][r]);
        }
      }
    }
}

// big GEMMs with bijective XCD swizzle (grid % 8 == 0)
template <typename TC, int BMODE>
__global__ __launch_bounds__(256) void k_mm(const bf16* __restrict__ A, int lda, long zsa,
                                            const bf16* __restrict__ B, int ldb, long zsb,
                                            TC* __restrict__ C, int ldc, long zsc, int K) {
  __shared__ short As[128 * 32];
  __shared__ short Bs[128 * 32];
  const int id = blockIdx.y * gridDim.x + blockIdx.x;
  const int nwg = gridDim.x * gridDim.y;
  const int swz = (id & 7) * (nwg >> 3) + (id >> 3);
  const int bx = swz % gridDim.x, by = swz / gridDim.x;
  const int z = blockIdx.z;
  const bf16* Ab = A + (size_t)z * zsa + (size_t)by * 128 * lda;
  const bf16* Bb = (BMODE == 0) ? (B + (size_t)z * zsb + (size_t)bx * 128 * ldb)
                                : (B + (size_t)z * zsb + bx * 128);
  f32x4 acc[4][4];
  const f32x4 zero4 = {0.f, 0.f, 0.f, 0.f};
#pragma unroll
  for (int i = 0; i < 4; ++i)
#pragma unroll
    for (int j = 0; j < 4; ++j) acc[i][j] = zero4;
  mm_core<0, BMODE>(Ab, lda, Bb, ldb, K, nullptr, As, Bs, acc);
  mm_store<false, false>(C + (size_t)z * zsc, (bf16*)nullptr, ldc, by * 128, bx * 128, acc);
}

// stage1+dh merged: z = bh*5+var: t0=q@w0^T t1=q@w2^T t2=k@w0^T t3=k@w2^T t4=v@w1
__global__ __launch_bounds__(256) void k_stage1(const bf16* __restrict__ fq, const bf16* __restrict__ fk,
                                                const bf16* __restrict__ fv,
                                                const bf16* __restrict__ w0b, const bf16* __restrict__ w1b,
                                                const bf16* __restrict__ w2b,
                                                bf16* t0, bf16* t1, bf16* t2, bf16* t3, bf16* t4, int chunk) {
  __shared__ short As[128 * 32];
  __shared__ short Bs[128 * 32];
  const int z = blockIdx.z, bh = z / 5, var = z % 5;
  const size_t choff = (size_t)chunk * 262144;
  const bf16* Ab = (var < 2 ? fq : (var < 4 ? fk : fv)) + (size_t)bh * ZG_ + choff +
                   (size_t)blockIdx.y * 128 * cFD;
  f32x4 acc[4][4];
  const f32x4 zero4 = {0.f, 0.f, 0.f, 0.f};
#pragma unroll
  for (int i = 0; i < 4; ++i)
#pragma unroll
    for (int j = 0; j < 4; ++j) acc[i][j] = zero4;
  bf16* C;
  if (var == 4) {
    const bf16* Bb = w1b + (size_t)bh * ZL_ + blockIdx.x * 128;
    C = t4 + (size_t)bh * ZL_;
    mm_core<0, 1>(Ab, cFD, Bb, cFD, cFD, nullptr, As, Bs, acc);
  } else {
    const bf16* Bb = (var & 1 ? w2b : w0b) + (size_t)bh * ZL_ + (size_t)blockIdx.x * 128 * cFD;
    C = (var == 0 ? t0 : var == 1 ? t1 : var == 2 ? t2 : t3) + (size_t)bh * ZL_;
    mm_core<0, 0>(Ab, cFD, Bb, cFD, cFD, nullptr, As, Bs, acc);
  }
  mm_store<false, false>(C, (bf16*)nullptr, cFD, blockIdx.y * 128, blockIdx.x * 128, acc);
}

// oc GEMM + 4 transposes merged, 1D grid 2176 (128 GEMM + 4*512 transpose)
__global__ __launch_bounds__(256) void k_octr(const bf16* __restrict__ t0, const bf16* __restrict__ w1b,
                                              bf16* __restrict__ occ,
                                              const bf16* __restrict__ t3, const bf16* __restrict__ fkb,
                                              const bf16* __restrict__ t2, const bf16* __restrict__ t4,
                                              bf16* trH, bf16* trK, bf16* trD1, bf16* trD2, int chunk) {
  __shared__ short Sh[8192];
  const int id = blockIdx.x, t = threadIdx.x;
  if (id < 128) {
    short* As = Sh;
    short* Bs = Sh + 4096;
    const int bh = id >> 4, by = (id >> 2) & 3, bx = id & 3;
    const bf16* Ab = t0 + (size_t)bh * ZL_ + (size_t)by * 128 * cFD;
    const bf16* Bb = w1b + (size_t)bh * ZL_ + (size_t)bx * 128 * cFD;
    f32x4 acc[4][4];
    const f32x4 zero4 = {0.f, 0.f, 0.f, 0.f};
#pragma unroll
    for (int i = 0; i < 4; ++i)
#pragma unroll
      for (int j = 0; j < 4; ++j) acc[i][j] = zero4;
    mm_core<0, 0>(Ab, cFD, Bb, cFD, cFD, nullptr, As, Bs, acc);
    mm_store<false, false>(occ + (size_t)bh * ZL_, (bf16*)nullptr, cFD, by * 128, bx * 128, acc);
  } else {
    short* Ts = Sh;  // 64*72 = 4608 shorts
    const int id2 = id - 128;
    const int var = id2 >> 9, bh = (id2 >> 6) & 7, by = (id2 >> 3) & 7, bx = id2 & 7;
    const size_t choff = (size_t)chunk * 262144;
    const bf16* src;
    bf16* dst;
    if (var == 0) { src = t3 + (size_t)bh * ZL_; dst = trH + (size_t)bh * ZL_; }
    else if (var == 1) { src = fkb + choff + (size_t)bh * ZG_; dst = trK + (size_t)bh * ZL_; }
    else if (var == 2) { src = t2 + (size_t)bh * ZL_; dst = trD1 + (size_t)bh * ZL_; }
    else { src = t4 + (size_t)bh * ZL_; dst = trD2 + (size_t)bh * ZL_; }
    {
      const int rr = t >> 2, cseg = (t & 3) * 16;
      const bf16* p = src + (size_t)(by * 64 + rr) * cFD + bx * 64 + cseg;
      stage16(p, &Ts[rr * 72 + cseg]);
    }
    __syncthreads();
    {
      const int oc_ = t >> 2, rseg = (t & 3) * 16;
      unsigned short u[16] __attribute__((aligned(16)));
#pragma unroll
      for (int i = 0; i < 16; ++i) u[i] = (unsigned short)Ts[(rseg + i) * 72 + oc_];
      bf16* dp = dst + (size_t)(bx * 64 + oc_) * cFD + by * 64 + rseg;
      *(uint4*)dp = *(uint4*)u;
      *(uint4*)(dp + 8) = *(uint4*)(u + 8);
    }
  }
}

// upd3 + norm_add merged, 1D grid 4480 (384 upd tiles + 4096 norm rows)
__global__ __launch_bounds__(256) void k_updna(const bf16* __restrict__ fvb,
                                               const bf16* __restrict__ trD1, const bf16* __restrict__ trD2,
                                               const bf16* __restrict__ trH, const bf16* __restrict__ trK,
                                               const float* __restrict__ lr1,
                                               float* w0s, float* w1s, float* w2s,
                                               bf16* w0b, bf16* w1b, bf16* w2b,
                                               const bf16* __restrict__ occ, const float* __restrict__ tw,
                                               bf16* __restrict__ y, int chunk) {
  __shared__ short Sh[8192];
  __shared__ float red[4];
  const int id = blockIdx.x, t = threadIdx.x;
  if (id < 384) {
    short* As = Sh;
    short* Bs = Sh + 4096;
    const int z = id >> 4, tile = id & 15, by = tile >> 2, bx = tile & 3;
    const int var = z >> 3, bh = z & 7;
    const size_t choff = (size_t)chunk * 262144;
    f32x4 acc[4][4];
    const f32x4 zero4 = {0.f, 0.f, 0.f, 0.f};
#pragma unroll
    for (int i = 0; i < 4; ++i)
#pragma unroll
      for (int j = 0; j < 4; ++j) acc[i][j] = zero4;
    float* W;
    bf16* M;
    const bf16* Bb;
    if (var == 0) {
      // w1 += (l1*fv)^T @ trH : A scalar-transposed with scale
      const bf16* Aa = fvb + choff + (size_t)bh * ZG_ + by * 128;
      const float* sc = lr1 + bh * 2048 + chunk * 512;
      Bb = trH + (size_t)bh * ZL_ + (size_t)bx * 128 * cFD;
      W = w1s + (size_t)bh * ZL_; M = w1b + (size_t)bh * ZL_;
      mm_core<1, 0>(Aa, cFD, Bb, cFD, cFD, sc, As, Bs, acc);
    } else {
      const bf16* Aa = ((var == 1) ? trD1 : trD2) + (size_t)bh * ZL_ + (size_t)by * 128 * cFD;
      Bb = trK + (size_t)bh * ZL_ + (size_t)bx * 128 * cFD;
      if (var == 1) { W = w0s + (size_t)bh * ZL_; M = w0b + (size_t)bh * ZL_; }
      else { W = w2s + (size_t)bh * ZL_; M = w2b + (size_t)bh * ZL_; }
      mm_core<0, 0>(Aa, cFD, Bb, cFD, cFD, nullptr, As, Bs, acc);
    }
    mm_store<true, true>(W, M, cFD, by * 128, bx * 128, acc);
  } else {
    const int rrow = id - 384;
    const int bh = rrow >> 9, rr = rrow & 511;
    const bf16* src = occ + ((size_t)bh * 512 + rr) * 512;
    float v0 = b2f(src[t]), v1 = b2f(src[t + 256]);
    float ss = v0 * v0 + v1 * v1;
    for (int d = 32; d; d >>= 1) ss += __shfl_down(ss, d);
    if ((t & 63) == 0) red[t >> 6] = ss;
    __syncthreads();
    const float rstd = rsqrtf((red[0] + red[1] + red[2] + red[3]) / cFD + 1e-6f);
    const int si = chunk * 512 + rr;
    bf16* dst = y + ((size_t)((bh >> 2) * cS) + si) * cH + (bh & 3) * cFD;
    dst[t] = f2b(b2f(dst[t]) + v0 * rstd * tw[t]);
    dst[t + 256] = f2b(b2f(dst[t + 256]) + v1 * rstd * tw[t + 256]);
  }
}

// ---- elementwise gates; folds lr0 into dh1 (t2), lr2 into dh2 (t4) ---------
__global__ __launch_bounds__(256) void k_elem(bf16* t0, const bf16* t1, bf16* t2, bf16* t3, bf16* t4,
                                              const float* __restrict__ lr0,
                                              const float* __restrict__ lr2, int chunk) {
  const size_t i = (size_t)blockIdx.x * 256 + threadIdx.x;
  const int bh = (int)(i >> 18), row = (int)((i >> 9) & 511);
  const float L0 = lr0[bh * 2048 + chunk * 512 + row];
  const float L2 = lr2[bh * 2048 + chunk * 512 + row];
  float hq1 = b2f(t0[i]), hq2 = b2f(t1[i]), g1 = b2f(t2[i]), g2 = b2f(t3[i]), dh = b2f(t4[i]);
  float s1 = sigmoidf_(hq1);
  t0[i] = f2b(hq1 * s1 * hq2);
  float sg = sigmoidf_(g1);
  float gate = g1 * sg;
  t3[i] = f2b(gate * g2);
  t4[i] = f2b(L2 * dh * gate);
  t2[i] = f2b(L0 * dh * g2 * (sg * (1.0f + g1 * (1.0f - sg))));
}

// --------------------------- fp32 -> bf16 flat convert ----------------------
__global__ __launch_bounds__(256) void k_cvt(const float* __restrict__ src, bf16* __restrict__ dst) {
  const size_t i = ((size_t)blockIdx.x * 256 + threadIdx.x) * 8;
  float4 a = *(const float4*)(src + i), b = *(const float4*)(src + i + 4);
  unsigned short u[8] __attribute__((aligned(16)));
  u[0] = f2bu(a.x); u[1] = f2bu(a.y); u[2] = f2bu(a.z); u[3] = f2bu(a.w);
  u[4] = f2bu(b.x); u[5] = f2bu(b.y); u[6] = f2bu(b.z); u[7] = f2bu(b.w);
  *(uint4*)(dst + i) = *(uint4*)u;
}

// --------------------------- state init ------------------------------------
__global__ __launch_bounds__(256) void k_winit(const float* __restrict__ w0, const float* __restrict__ w1,
                                               const float* __restrict__ w2,
                                               float* __restrict__ w0s, float* __restrict__ w1s,
                                               float* __restrict__ w2s) {
  const size_t i = (size_t)blockIdx.x * 256 + threadIdx.x;
  const int bh = (int)(i >> 18);
  const int f = bh & 3;
  const size_t off = i & 262143;
  const float* src; float* dst;
  if (blockIdx.y == 0) { src = w0; dst = w0s; }
  else if (blockIdx.y == 1) { src = w1; dst = w1s; }
  else { src = w2; dst = w2s; }
  dst[i] = src[(size_t)f * 262144 + off];
}

// --------------------------- rope table ------------------------------------
__global__ __launch_bounds__(64) void k_rope_tab(float* __restrict__ ct, float* __restrict__ stb) {
  const int si = blockIdx.x, j = threadIdx.x;
  float inv = powf(500000.0f, -(float)j / 64.0f);
  float ang = (float)si * inv;
  ct[(size_t)si * 64 + j] = cosf(ang);
  stb[(size_t)si * 64 + j] = sinf(ang);
}

// --------------------------- learning rates --------------------------------
__global__ __launch_bounds__(256) void k_lr(const float* __restrict__ x, const float* __restrict__ lr_w,
                                            const float* __restrict__ lr_b,
                                            float* lr0, float* lr1, float* lr2, float base) {
  const int token = blockIdx.x, b_ = token >> 11, si = token & 2047;
  const int wv = threadIdx.x >> 6, lane = threadIdx.x & 63;
  const float* xr = x + (size_t)token * cH;
#pragma unroll
  for (int jj = 0; jj < 3; ++jj) {
    const int j = wv * 3 + jj;
    const float* wr = lr_w + (size_t)j * cH;
    float s = 0.f;
    for (int k = lane; k < cH; k += 64) s += xr[k] * wr[k];
    for (int d = 32; d; d >>= 1) s += __shfl_down(s, d);
    if (lane == 0) {
      float v = s + lr_b[j] + base;
      float sp = (v > 15.f) ? v : log1pf(expf(v));
      const int tt = j >> 2, f = j & 3;
      float* dst = (tt == 0 ? lr0 : tt == 1 ? lr1 : lr2);
      dst[(size_t)(b_ * cNFW + f) * cS + si] = sp;
    }
  }
}

// ------------------ rmsnorm q/k in place + rope -> qa/ka --------------------
__global__ __launch_bounds__(256) void k_normrope(bf16* __restrict__ qkvh,
                                                  const float* __restrict__ qnw, const float* __restrict__ knw,
                                                  const float* __restrict__ ct, const float* __restrict__ stb,
                                                  bf16* __restrict__ qa, bf16* __restrict__ ka) {
  const int token = blockIdx.x, b_ = token >> 11, si = token & 2047;
  const int t = threadIdx.x;
  __shared__ float buf[cH];
  __shared__ float red[4];
  bf16* base = qkvh + (size_t)token * 3 * cH;
  for (int pass = 0; pass < 2; ++pass) {
    __syncthreads();
    bf16* src = base + pass * cH;
    const float* nw = pass ? knw : qnw;
    float ss = 0.f;
    for (int i = t; i < cH; i += 256) {
      float v = b2f(src[i]);
      buf[i] = v;
      ss += v * v;
    }
    for (int d = 32; d; d >>= 1) ss += __shfl_down(ss, d);
    if ((t & 63) == 0) red[t >> 6] = ss;
    __syncthreads();
    const float rstd = rsqrtf((red[0] + red[1] + red[2] + red[3]) / cH + 1e-6f);
    for (int i = t; i < cH; i += 256) {
      float v = buf[i] * rstd * nw[i];
      buf[i] = v;
      src[i] = f2b(v);
    }
    __syncthreads();
    bf16* dst = pass ? ka : qa;
    const float scale = pass ? 1.f : cRSQRT_HD;
    const int hh = t >> 4, j0 = (t & 15) * 4;
    const float* cr = ct + (size_t)si * 64 + j0;
    const float* sr = stb + (size_t)si * 64 + j0;
    bf16* drow = dst + ((size_t)(b_ * cNH + hh) * cS + si) * cHD;
    unsigned short u1[4] __attribute__((aligned(8))), u2[4] __attribute__((aligned(8)));
#pragma unroll
    for (int i = 0; i < 4; ++i) {
      float x1 = buf[hh * cHD + j0 + i], x2 = buf[hh * cHD + 64 + j0 + i];
      u1[i] = f2bu((x1 * cr[i] - x2 * sr[i]) * scale);
      u2[i] = f2bu((x2 * cr[i] + x1 * sr[i]) * scale);
    }
    *(uint2*)(drow + j0) = *(uint2*)u1;
    *(uint2*)(drow + 64 + j0) = *(uint2*)u2;
  }
}

// ------------------ V transpose: qkvh v-part -> vt[b,h,d,s] -----------------
__global__ __launch_bounds__(256) void k_vtr(const bf16* __restrict__ qkvh, bf16* __restrict__ vt) {
  const int tile = blockIdx.x, h = blockIdx.y, b_ = blockIdx.z;
  __shared__ short Ts[64 * 136];
  const int t = threadIdx.x;
  {
    const int r = t >> 2, seg = (t & 3) * 32;
    const bf16* src = qkvh + ((size_t)(b_ * cS) + tile * 64 + r) * 3 * cH + 2 * cH + h * cHD + seg;
    stage16(src, &Ts[r * 136 + seg]);
    stage16(src + 16, &Ts[r * 136 + seg + 16]);
  }
  __syncthreads();
  {
    const int d = t >> 1, seg2 = (t & 1) * 32;
    unsigned short u[32] __attribute__((aligned(16)));
#pragma unroll
    for (int i = 0; i < 32; ++i) u[i] = (unsigned short)Ts[(seg2 + i) * 136 + d];
    bf16* dp = vt + ((size_t)(b_ * cNH + h) * cHD + d) * cS + tile * 64 + seg2;
    *(uint4*)dp = *(uint4*)u;
    *(uint4*)(dp + 8) = *(uint4*)(u + 8);
    *(uint4*)(dp + 16) = *(uint4*)(u + 16);
    *(uint4*)(dp + 24) = *(uint4*)(u + 24);
  }
}

// ------------------ fq/fk/fv from normalized qkvh ---------------------------
__global__ __launch_bounds__(256) void k_fqkv(const bf16* __restrict__ qkvh,
                                              const float* __restrict__ qk_scale,
                                              const float* __restrict__ qk_offset,
                                              bf16* fq, bf16* fk, bf16* fv) {
  const int token = blockIdx.x, b_ = token >> 11, si = token & 2047;
  const int t = threadIdx.x;
  const bf16* base = qkvh + (size_t)token * 3 * cH;
#pragma unroll
  for (int pass = 0; pass < 2; ++pass) {
    const bf16* src = base + pass * cH;
    bf16* fdst = pass ? fk : fq;
    const int head = t >> 6, lane = t & 63;
    float f[8];
    float ss2 = 0.f;
#pragma unroll
    for (int k = 0; k < 8; ++k) {
      const int idx = head * cFD + lane + k * 64;
      float v = b2f(src[idx]);
      float u = v * qk_scale[idx * 2 + pass] + qk_offset[idx * 2 + pass];
      float fv_ = u * sigmoidf_(u);
      f[k] = fv_;
      ss2 += fv_ * fv_;
    }
    for (int d = 1; d < 64; d <<= 1) ss2 += __shfl_xor(ss2, d);
    const float sc2 = rsqrtf(ss2 + 1e-12f);
    bf16* dst = fdst + ((size_t)(b_ * cNFW + head) * cS + si) * cFD;
#pragma unroll
    for (int k = 0; k < 8; ++k) dst[lane + k * 64] = f2b(f[k] * sc2);
  }
  const bf16* vr = base + 2 * cH;
  for (int i = t; i < cH; i += 256) {
    float v = b2f(vr[i]);
    fv[((size_t)(b_ * cNFW + (i >> 9)) * cS + si) * cFD + (i & 511)] = f2b(v * sigmoidf_(v));
  }
}

// ------ attention: XCD-swizzled, reg prefetch, Ps-in-Ks, defer-max, setprio -
__global__ __launch_bounds__(256) void k_attn4(const bf16* __restrict__ qa, const bf16* __restrict__ ka,
                                               const bf16* __restrict__ vt, bf16* __restrict__ y) {
  const int id = blockIdx.x;
  const int hb = ((id >> 8) << 3) + (id & 7);
  const int qt = 31 - ((id >> 3) & 31);
  const int h = hb & 15, b_ = hb >> 4;
  const int q0 = qt * 64;
  __shared__ short Ks[64 * 136];   // Ps aliases into this after QK reads
  __shared__ short Vts[128 * 72];
  const int t = threadIdx.x, lane = t & 63, g = lane >> 4, c16 = lane & 15, wv = t >> 6;
  const size_t hbq = (size_t)(b_ * cNH + h) * cS;
  const bf16* vb = vt + (size_t)(b_ * cNH + h) * (size_t)(cHD * cS);
  short8 qf[4];
  {
    const bf16* qsrc = qa + (hbq + q0 + wv * 16 + c16) * cHD;
#pragma unroll
    for (int ks = 0; ks < 4; ++ks) qf[ks] = *(const short8*)(qsrc + ks * 32 + g * 8);
  }
  f32x4 o[8];
  const f32x4 zero4 = {0.f, 0.f, 0.f, 0.f};
#pragma unroll
  for (int i = 0; i < 8; ++i) o[i] = zero4;
  float m[4], l[4];
#pragma unroll
  for (int r = 0; r < 4; ++r) { m[r] = -1e30f; l[r] = 0.f; }

  const int r = t >> 2, seg = (t & 3) * 32;
  const int dv = t >> 1, seg2 = (t & 1) * 32;
  uint4 kp0, kp1, kp2, kp3, vp0, vp1, vp2, vp3;
  {
    const bf16* ksrc = ka + (hbq + r) * cHD + seg;
    kp0 = *(const uint4*)ksrc; kp1 = *(const uint4*)(ksrc + 8);
    kp2 = *(const uint4*)(ksrc + 16); kp3 = *(const uint4*)(ksrc + 24);
    const bf16* vsrc = vb + (size_t)dv * cS + seg2;
    vp0 = *(const uint4*)vsrc; vp1 = *(const uint4*)(vsrc + 8);
    vp2 = *(const uint4*)(vsrc + 16); vp3 = *(const uint4*)(vsrc + 24);
  }

  for (int kt = 0; kt <= qt; ++kt) {
    __syncthreads();   // previous iter's Ps/Vts reads done
    {
      short* kd = &Ks[r * 136 + seg];
      *(uint4*)kd = kp0; *(uint4*)(kd + 8) = kp1;
      *(uint4*)(kd + 16) = kp2; *(uint4*)(kd + 24) = kp3;
      short* vd = &Vts[dv * 72 + seg2];
      *(uint4*)vd = vp0; *(uint4*)(vd + 8) = vp1;
      *(uint4*)(vd + 16) = vp2; *(uint4*)(vd + 24) = vp3;
    }
    __syncthreads();
    if (kt < qt) {  // prefetch next tile; latency hides under compute below
      const bf16* ksrc = ka + (hbq + (kt + 1) * 64 + r) * cHD + seg;
      kp0 = *(const uint4*)ksrc; kp1 = *(const uint4*)(ksrc + 8);
      kp2 = *(const uint4*)(ksrc + 16); kp3 = *(const uint4*)(ksrc + 24);
      const bf16* vsrc = vb + (size_t)dv * cS + (kt + 1) * 64 + seg2;
      vp0 = *(const uint4*)vsrc; vp1 = *(const uint4*)(vsrc + 8);
      vp2 = *(const uint4*)(vsrc + 16); vp3 = *(const uint4*)(vsrc + 24);
    }

    f32x4 s4[4];
#pragma unroll
    for (int ni = 0; ni < 4; ++ni) s4[ni] = zero4;
    __builtin_amdgcn_s_setprio(1);
#pragma unroll
    for (int ks = 0; ks < 4; ++ks) {
#pragma unroll
      for (int ni = 0; ni < 4; ++ni) {
        short8 bb = *(const short8*)&Ks[(ni * 16 + c16) * 136 + ks * 32 + g * 8];
        s4[ni] = __builtin_amdgcn_mfma_f32_16x16x32_bf16(qf[ks], bb, s4[ni], 0, 0, 0);
      }
    }
    __builtin_amdgcn_s_setprio(0);
    __syncthreads();   // all QK reads of Ks done before Ps overwrite
    if (kt == qt) {
#pragma unroll
      for (int ni = 0; ni < 4; ++ni) {
        const int kv = kt * 64 + ni * 16 + c16;
#pragma unroll
        for (int rr = 0; rr < 4; ++rr) {
          const int qr = q0 + wv * 16 + g * 4 + rr;
          if (kv > qr) s4[ni][rr] = -1e9f;
        }
      }
    }
    float mx[4];
#pragma unroll
    for (int rr = 0; rr < 4; ++rr)
      mx[rr] = fmaxf(fmaxf(s4[0][rr], s4[1][rr]), fmaxf(s4[2][rr], s4[3][rr]));
#pragma unroll
    for (int d = 1; d < 16; d <<= 1)
#pragma unroll
      for (int rr = 0; rr < 4; ++rr) mx[rr] = fmaxf(mx[rr], __shfl_xor(mx[rr], d));
    // defer-max (T13): only rescale when max grows by > 8
    bool need = false;
#pragma unroll
    for (int rr = 0; rr < 4; ++rr) need |= (mx[rr] > m[rr] + 8.f);
    if (__any(need)) {
      float corr[4];
#pragma unroll
      for (int rr = 0; rr < 4; ++rr) {
        float mn = fmaxf(m[rr], mx[rr]);
        corr[rr] = __expf(m[rr] - mn);
        m[rr] = mn;
      }
#pragma unroll
      for (int rr = 0; rr < 4; ++rr) l[rr] *= corr[rr];
#pragma unroll
      for (int nf = 0; nf < 8; ++nf)
#pragma unroll
        for (int rr = 0; rr < 4; ++rr) o[nf][rr] *= corr[rr];
    }
    float psum[4] = {0.f, 0.f, 0.f, 0.f};
#pragma unroll
    for (int ni = 0; ni < 4; ++ni)
#pragma unroll
      for (int rr = 0; rr < 4; ++rr) {
        float p = __expf(s4[ni][rr] - m[rr]);
        s4[ni][rr] = p;
        psum[rr] += p;
      }
#pragma unroll
    for (int d = 1; d < 16; d <<= 1)
#pragma unroll
      for (int rr = 0; rr < 4; ++rr) psum[rr] += __shfl_xor(psum[rr], d);
#pragma unroll
    for (int rr = 0; rr < 4; ++rr) l[rr] += psum[rr];
    short* pw = &Ks[wv * 1152];   // Ps region aliased into Ks
#pragma unroll
    for (int ni = 0; ni < 4; ++ni)
#pragma unroll
      for (int rr = 0; rr < 4; ++rr)
        pw[(g * 4 + rr) * 72 + ni * 16 + c16] = (short)f2bu(s4[ni][rr]);
    // pw is wave-private: no barrier needed before reading it back.
    __builtin_amdgcn_s_setprio(1);
#pragma unroll
    for (int ks2 = 0; ks2 < 2; ++ks2) {
      short8 a = *(const short8*)&pw[c16 * 72 + ks2 * 32 + g * 8];
#pragma unroll
      for (int nf = 0; nf < 8; ++nf) {
        short8 bb = *(const short8*)&Vts[(nf * 16 + c16) * 72 + ks2 * 32 + g * 8];
        o[nf] = __builtin_amdgcn_mfma_f32_16x16x32_bf16(a, bb, o[nf], 0, 0, 0);
      }
    }
    __builtin_amdgcn_s_setprio(0);
  }
  float inv[4];
#pragma unroll
  for (int rr = 0; rr < 4; ++rr) inv[rr] = 1.f / l[rr];
#pragma unroll
  for (int nf = 0; nf < 8; ++nf)
#pragma unroll
    for (int rr = 0; rr < 4; ++rr) {
      const size_t row = (size_t)(b_ * cS) + q0 + wv * 16 + g * 4 + rr;
      y[row * cH + h * cHD + nf * 16 + c16] = f2b(o[nf][rr] * inv[rr]);
    }
}

}  // namespace

extern "C" void kernel_launch(void* const* d_in, const int* in_sizes, int n_in,
                              void* d_out, int out_size, void* d_ws, size_t ws_size,
                              hipStream_t stream) {
  (void)in_sizes; (void)n_in; (void)out_size; (void)ws_size;
  const float* x         = (const float*)d_in[0];
  const float* qkv_w     = (const float*)d_in[1];
  const float* q_norm_w  = (const float*)d_in[2];
  const float* k_norm_w  = (const float*)d_in[3];
  const float* qk_scale  = (const float*)d_in[4];
  const float* qk_offset = (const float*)d_in[5];
  const float* lr_w      = (const float*)d_in[6];
  const float* lr_b      = (const float*)d_in[7];
  const float* w0        = (const float*)d_in[8];
  const float* w1        = (const float*)d_in[9];
  const float* w2        = (const float*)d_in[10];
  const float* ttt_nw    = (const float*)d_in[11];
  const float* o_proj_w  = (const float*)d_in[12];
  float* out = (float*)d_out;

  // ---- workspace layout (bytes), total 143,851,520 (proven footprint) ----
  char* Wb = (char*)d_ws;
  bf16* qkvh = (bf16*)Wb;
  bf16* t0  = (bf16*)(Wb + 0UL);
  bf16* t1  = (bf16*)(Wb + 4194304UL);          // also trD1 destination
  bf16* t2  = (bf16*)(Wb + 8388608UL);
  bf16* t3  = (bf16*)(Wb + 12582912UL);
  bf16* t4  = (bf16*)(Wb + 16777216UL);
  bf16* trH = (bf16*)(Wb + 20971520UL);
  bf16* trK = (bf16*)(Wb + 25165824UL);
  bf16* occ = (bf16*)(Wb + 29360128UL);
  bf16* w0b = (bf16*)(Wb + 33554432UL);   // contiguous mirrors
  bf16* w1b = (bf16*)(Wb + 37748736UL);
  bf16* w2b = (bf16*)(Wb + 41943040UL);
  bf16* trD2 = (bf16*)(Wb + 46137344UL);  // spare 4MB slot
  bf16* trD1 = t1;                        // t1 dead after elem
  bf16* opwb = (bf16*)(Wb + 0UL);         // after TTT loop (t-region dead)
  size_t off = 50331648UL;
  bf16* fqb = (bf16*)(Wb + off); off += 16777216UL;  // xb, then qa, then fq
  bf16* fkb = (bf16*)(Wb + off); off += 16777216UL;  // qkvwb(head), ka, fk
  bf16* fvb = (bf16*)(Wb + off); off += 16777216UL;  // qkvwb(tail), vt, fv
  float* w0s = (float*)(Wb + off); off += 8388608UL;
  float* w1s = (float*)(Wb + off); off += 8388608UL;
  float* w2s = (float*)(Wb + off); off += 8388608UL;
  float* lr0 = (float*)(Wb + off); off += 65536UL;
  float* lr1 = (float*)(Wb + off); off += 65536UL;
  float* lr2 = (float*)(Wb + off); off += 65536UL;
  bf16* y = (bf16*)(Wb + off); off += 16777216UL;
  float* ct  = (float*)(Wb + off); off += 524288UL;
  float* stb = (float*)(Wb + off); off += 524288UL;
  bf16* xb = fqb;
  bf16* qkvwb = fkb;
  bf16* qa = fqb;
  bf16* ka = fkb;
  bf16* vt = fvb;

  const float base_lr_inv = logf(expm1f(0.001f));
  dim3 blk(256);

  k_winit<<<dim3(8192, 3), blk, 0, stream>>>(w0, w1, w2, w0s, w1s, w2s);
  k_rope_tab<<<dim3(2048), dim3(64), 0, stream>>>(ct, stb);
  k_cvt<<<dim3(4096), blk, 0, stream>>>(x, xb);
  k_cvt<<<dim3(6144), blk, 0, stream>>>(qkv_w, qkvwb);
  k_mm<bf16, 0><<<dim3(48, 32, 1), blk, 0, stream>>>(xb, 2048, 0, qkvwb, 2048, 0, qkvh, 6144, 0, 2048);
  k_lr<<<dim3(4096), blk, 0, stream>>>(x, lr_w, lr_b, lr0, lr1, lr2, base_lr_inv);
  k_normrope<<<dim3(4096), blk, 0, stream>>>(qkvh, q_norm_w, k_norm_w, ct, stb, qa, ka);
  k_vtr<<<dim3(32, 16, 2), blk, 0, stream>>>(qkvh, vt);
  k_attn4<<<dim3(1024), blk, 0, stream>>>(qa, ka, vt, y);
  k_fqkv<<<dim3(4096), blk, 0, stream>>>(qkvh, qk_scale, qk_offset, fqb, fkb, fvb);
  k_cvt<<<dim3(3072), blk, 0, stream>>>(w0s, w0b);  // contiguous 6.29M-elem mirror block

  for (int c = 0; c < 4; ++c) {
    k_stage1<<<dim3(4, 4, 40), blk, 0, stream>>>(fqb, fkb, fvb, w0b, w1b, w2b,
                                                 t0, t1, t2, t3, t4, c);
    k_elem<<<dim3(8192), blk, 0, stream>>>(t0, t1, t2, t3, t4, lr0, lr2, c);
    k_octr<<<dim3(2176), blk, 0, stream>>>(t0, w1b, occ, t3, fkb, t2, t4,
                                           trH, trK, trD1, trD2, c);
    k_updna<<<dim3(4480), blk, 0, stream>>>(fvb, trD1, trD2, trH, trK, lr1,
                                            w0s, w1s, w2s, w0b, w1b, w2b, occ, ttt_nw, y, c);
  }
  k_cvt<<<dim3(2048), blk, 0, stream>>>(o_proj_w, opwb);
  k_mm<float, 0><<<dim3(16, 32, 1), blk, 0, stream>>>(y, 2048, 0, opwb, 2048, 0, out, 2048, 0, 2048);
}

// Round 9
// 806.757 us; speedup vs baseline: 6.4498x; 1.1109x over previous
//
#include <hip/hip_runtime.h>
#include <hip/hip_bf16.h>
#include <math.h>

using bf16 = __hip_bfloat16;

namespace {

constexpr int cH = 2048;
constexpr int cNH = 16;
constexpr int cHD = 128;
constexpr int cNFW = 4;
constexpr int cFD = 512;
constexpr int cS = 2048;
constexpr float cRSQRT_HD = 0.08838834764831845f;  // 1/sqrt(128)
constexpr long ZL_ = 262144;   // 512*512
constexpr long ZG_ = 1048576;  // 2048*512

typedef __attribute__((ext_vector_type(8))) short short8;
typedef __attribute__((ext_vector_type(4))) float f32x4;

__device__ __forceinline__ float sigmoidf_(float x) { return 1.0f / (1.0f + __expf(-x)); }
__device__ __forceinline__ float b2f(bf16 v) { return __bfloat162float(v); }
__device__ __forceinline__ bf16 f2b(float v) { return __float2bfloat16(v); }
__device__ __forceinline__ unsigned short f2bu(float f) {
  return __builtin_bit_cast(unsigned short, __float2bfloat16(f));
}

#if defined(__has_builtin)
#if __has_builtin(__builtin_amdgcn_global_load_lds)
#define HAVE_GLOAD 1
#endif
#endif

__device__ __forceinline__ void gload16(const bf16* g, short* ldsbase) {
#ifdef HAVE_GLOAD
  __builtin_amdgcn_global_load_lds((const __attribute__((address_space(1))) void*)g,
                                   (__attribute__((address_space(3))) void*)ldsbase, 16, 0, 0);
#else
  const int l = threadIdx.x & 63;
  *(uint4*)(ldsbase + l * 8) = *(const uint4*)g;
#endif
}

__device__ __forceinline__ void stage16(const bf16* src, short* dst) {
  *(uint4*)dst = *(const uint4*)src;
  *(uint4*)(dst + 8) = *(const uint4*)(src + 8);
}

__device__ __forceinline__ void store1(float* p, float v) { *p = v; }
__device__ __forceinline__ void store1(bf16* p, float v) { *p = f2b(v); }

// ---------------------------------------------------------------------------
// MFMA GEMM core: 128x128 tile, 4 waves (2x2 of 64x64), BK=32, linear LDS.
// ---------------------------------------------------------------------------
template <int AMODE, int BMODE>
__device__ __forceinline__ void mm_core(const bf16* __restrict__ Ab, int lda,
                                        const bf16* __restrict__ Bb, int ldb, int K,
                                        const float* __restrict__ sc,
                                        short* As, short* Bs, f32x4 acc[4][4]) {
  const int t = threadIdx.x, lane = t & 63, g = lane >> 4, c16 = lane & 15;
  const int wv = t >> 6, wm = (wv >> 1) * 64, wn = (wv & 1) * 64;
  for (int k0 = 0; k0 < K; k0 += 32) {
    __syncthreads();
    if constexpr (AMODE == 0) {
      const int ch = wv * 2;
      const bf16* g0 = Ab + (size_t)(ch * 16 + (lane >> 2)) * lda + k0 + (lane & 3) * 8;
      gload16(g0, &As[ch * 512]);
      gload16(g0 + (size_t)16 * lda, &As[ch * 512 + 512]);
    } else {
      const int kk = t >> 3, mseg = (t & 7) * 16;
      const float s = sc[k0 + kk];
      const bf16* p = Ab + (size_t)(k0 + kk) * lda + mseg;
#pragma unroll
      for (int i = 0; i < 16; ++i) As[(mseg + i) * 32 + kk] = (short)f2bu(b2f(p[i]) * s);
    }
    if constexpr (BMODE == 0) {
      const int ch = wv * 2;
      const bf16* g0 = Bb + (size_t)(ch * 16 + (lane >> 2)) * ldb + k0 + (lane & 3) * 8;
      gload16(g0, &Bs[ch * 512]);
      gload16(g0 + (size_t)16 * ldb, &Bs[ch * 512 + 512]);
    } else {
      const int kk = t >> 3, cseg = (t & 7) * 16;
      const short* p = (const short*)(Bb + (size_t)(k0 + kk) * ldb + cseg);
#pragma unroll
      for (int i = 0; i < 16; ++i) Bs[(cseg + i) * 32 + kk] = p[i];
    }
    __syncthreads();
    short8 af[4], bfr[4];
#pragma unroll
    for (int mi = 0; mi < 4; ++mi) af[mi] = *(const short8*)&As[(wm + mi * 16 + c16) * 32 + g * 8];
#pragma unroll
    for (int ni = 0; ni < 4; ++ni) bfr[ni] = *(const short8*)&Bs[(wn + ni * 16 + c16) * 32 + g * 8];
#pragma unroll
    for (int mi = 0; mi < 4; ++mi)
#pragma unroll
      for (int ni = 0; ni < 4; ++ni)
        acc[mi][ni] = __builtin_amdgcn_mfma_f32_16x16x32_bf16(af[mi], bfr[ni], acc[mi][ni], 0, 0, 0);
  }
}

template <bool ACC, bool MIR, typename TC>
__device__ __forceinline__ void mm_store(TC* Cb, bf16* Mb, int ldc, int rb, int cb, f32x4 acc[4][4]) {
  const int t = threadIdx.x, lane = t & 63, g = lane >> 4, c16 = lane & 15;
  const int wv = t >> 6, wm = (wv >> 1) * 64, wn = (wv & 1) * 64;
  const int rbase = rb + wm, cbase = cb + wn;
#pragma unroll
  for (int mi = 0; mi < 4; ++mi)
#pragma unroll
    for (int ni = 0; ni < 4; ++ni) {
      const int col = cbase + ni * 16 + c16;
#pragma unroll
      for (int r = 0; r < 4; ++r) {
        const int row = rbase + mi * 16 + g * 4 + r;
        TC* cp = Cb + (size_t)row * ldc + col;
        if constexpr (ACC) {
          float nv = *cp + acc[mi][ni][r];
          *cp = nv;
          if constexpr (MIR) Mb[(size_t)row * ldc + col] = f2b(nv);
        } else {
          store1(cp, acc[mi][ni][r]);
        }
      }
    }
}

template <typename TC, int BMODE>
__global__ __launch_bounds__(256) void k_mm(const bf16* __restrict__ A, int lda, long zsa,
                                            const bf16* __restrict__ B, int ldb, long zsb,
                                            TC* __restrict__ C, int ldc, long zsc, int K) {
  __shared__ short As[128 * 32];
  __shared__ short Bs[128 * 32];
  const int z = blockIdx.z;
  const bf16* Ab = A + (size_t)z * zsa + (size_t)blockIdx.y * 128 * lda;
  const bf16* Bb = (BMODE == 0) ? (B + (size_t)z * zsb + (size_t)blockIdx.x * 128 * ldb)
                                : (B + (size_t)z * zsb + blockIdx.x * 128);
  f32x4 acc[4][4];
  const f32x4 zero4 = {0.f, 0.f, 0.f, 0.f};
#pragma unroll
  for (int i = 0; i < 4; ++i)
#pragma unroll
    for (int j = 0; j < 4; ++j) acc[i][j] = zero4;
  mm_core<0, BMODE>(Ab, lda, Bb, ldb, K, nullptr, As, Bs, acc);
  mm_store<false, false>(C + (size_t)z * zsc, (bf16*)nullptr, ldc, blockIdx.y * 128, blockIdx.x * 128, acc);
}

// ---------------------------------------------------------------------------
// Fused stage1 + gates: 64x64 tile, 5 GEMMs (q@w0^T,q@w2^T,k@w0^T,k@w2^T,v@w1),
// gates in-register, writes hq (normal) + hidden^T, (l0*dh1)^T, (l2*dh2)^T.
// Grid 512 = 8bh * 64 tiles.
// ---------------------------------------------------------------------------
__global__ __launch_bounds__(256) void k_fuse1(const bf16* __restrict__ fq, const bf16* __restrict__ fk,
                                               const bf16* __restrict__ fv,
                                               const bf16* __restrict__ w0b, const bf16* __restrict__ w1b,
                                               const bf16* __restrict__ w2b,
                                               bf16* __restrict__ hq, bf16* __restrict__ trH,
                                               bf16* __restrict__ trD1, bf16* __restrict__ trD2,
                                               const float* __restrict__ lr0, const float* __restrict__ lr2,
                                               int chunk) {
  __shared__ short S[12288];  // Aq0 Ak2048 Av4096 B0_6144 B2_8192 B1_10240 ; Ts aliases S
  const int id = blockIdx.x, bh = id >> 6, tile = id & 63, by = tile >> 3, bx = tile & 7;
  const int t = threadIdx.x, lane = t & 63, g = lane >> 4, c16 = lane & 15, wv = t >> 6;
  const int wm = (wv >> 1) * 32, wn = (wv & 1) * 32;
  const size_t choff = (size_t)chunk * 262144;
  const bf16* Aq = fq + (size_t)bh * ZG_ + choff + (size_t)(by * 64) * cFD;
  const bf16* Ak = fk + (size_t)bh * ZG_ + choff + (size_t)(by * 64) * cFD;
  const bf16* Av = fv + (size_t)bh * ZG_ + choff + (size_t)(by * 64) * cFD;
  const bf16* B0 = w0b + (size_t)bh * ZL_ + (size_t)(bx * 64) * cFD;
  const bf16* B2 = w2b + (size_t)bh * ZL_ + (size_t)(bx * 64) * cFD;
  const bf16* B1 = w1b + (size_t)bh * ZL_ + bx * 64;  // k-major [d][e], col offset

  f32x4 acc[5][2][2];
  const f32x4 zero4 = {0.f, 0.f, 0.f, 0.f};
#pragma unroll
  for (int v = 0; v < 5; ++v)
#pragma unroll
    for (int i = 0; i < 2; ++i)
#pragma unroll
      for (int j = 0; j < 2; ++j) acc[v][i][j] = zero4;

  const int srow = wv * 16 + (lane >> 2), scol = (lane & 3) * 8;
  for (int k0 = 0; k0 < 512; k0 += 32) {
    __syncthreads();
    gload16(Aq + (size_t)srow * cFD + k0 + scol, &S[0 + wv * 512]);
    gload16(Ak + (size_t)srow * cFD + k0 + scol, &S[2048 + wv * 512]);
    gload16(Av + (size_t)srow * cFD + k0 + scol, &S[4096 + wv * 512]);
    gload16(B0 + (size_t)srow * cFD + k0 + scol, &S[6144 + wv * 512]);
    gload16(B2 + (size_t)srow * cFD + k0 + scol, &S[8192 + wv * 512]);
    {  // B1: [32k][64e] -> Bs1[e][k]
      const int kk = t >> 3, e8 = (t & 7) * 8;
      const short* p = (const short*)(B1 + (size_t)(k0 + kk) * cFD + e8);
#pragma unroll
      for (int i = 0; i < 8; ++i) S[10240 + (e8 + i) * 32 + kk] = p[i];
    }
    __syncthreads();
    short8 aq[2], ak[2], av[2], b0[2], b2[2], b1[2];
#pragma unroll
    for (int mi = 0; mi < 2; ++mi) {
      const int ro = (wm + mi * 16 + c16) * 32 + g * 8;
      aq[mi] = *(const short8*)&S[0 + ro];
      ak[mi] = *(const short8*)&S[2048 + ro];
      av[mi] = *(const short8*)&S[4096 + ro];
    }
#pragma unroll
    for (int ni = 0; ni < 2; ++ni) {
      const int ro = (wn + ni * 16 + c16) * 32 + g * 8;
      b0[ni] = *(const short8*)&S[6144 + ro];
      b2[ni] = *(const short8*)&S[8192 + ro];
      b1[ni] = *(const short8*)&S[10240 + ro];
    }
#pragma unroll
    for (int mi = 0; mi < 2; ++mi)
#pragma unroll
      for (int ni = 0; ni < 2; ++ni) {
        acc[0][mi][ni] = __builtin_amdgcn_mfma_f32_16x16x32_bf16(aq[mi], b0[ni], acc[0][mi][ni], 0, 0, 0);
        acc[1][mi][ni] = __builtin_amdgcn_mfma_f32_16x16x32_bf16(aq[mi], b2[ni], acc[1][mi][ni], 0, 0, 0);
        acc[2][mi][ni] = __builtin_amdgcn_mfma_f32_16x16x32_bf16(ak[mi], b0[ni], acc[2][mi][ni], 0, 0, 0);
        acc[3][mi][ni] = __builtin_amdgcn_mfma_f32_16x16x32_bf16(ak[mi], b2[ni], acc[3][mi][ni], 0, 0, 0);
        acc[4][mi][ni] = __builtin_amdgcn_mfma_f32_16x16x32_bf16(av[mi], b1[ni], acc[4][mi][ni], 0, 0, 0);
      }
  }

  // gates in-register: acc0<-hq, acc1<-hidden, acc2<-l0*dh1, acc3<-l2*dh2
  float l0v[2][4], l2v[2][4];
#pragma unroll
  for (int mi = 0; mi < 2; ++mi)
#pragma unroll
    for (int r = 0; r < 4; ++r) {
      const int row = by * 64 + wm + mi * 16 + g * 4 + r;
      l0v[mi][r] = lr0[bh * 2048 + chunk * 512 + row];
      l2v[mi][r] = lr2[bh * 2048 + chunk * 512 + row];
    }
#pragma unroll
  for (int mi = 0; mi < 2; ++mi)
#pragma unroll
    for (int ni = 0; ni < 2; ++ni)
#pragma unroll
      for (int r = 0; r < 4; ++r) {
        float hq1 = acc[0][mi][ni][r], hq2 = acc[1][mi][ni][r];
        float g1 = acc[2][mi][ni][r], g2 = acc[3][mi][ni][r], dh = acc[4][mi][ni][r];
        acc[0][mi][ni][r] = hq1 * sigmoidf_(hq1) * hq2;
        float sg = sigmoidf_(g1);
        float gate = g1 * sg;
        acc[1][mi][ni][r] = gate * g2;
        acc[2][mi][ni][r] = l0v[mi][r] * dh * g2 * (sg * (1.0f + g1 * (1.0f - sg)));
        acc[3][mi][ni][r] = l2v[mi][r] * dh * gate;
      }

  // 4 write rounds via LDS (round 0 identity for hq; 1..3 transposed)
  short* Ts = S;  // 64*66 = 4224 shorts
  bf16* dst0 = hq + (size_t)bh * ZL_;
  bf16* dstT[3] = {trH + (size_t)bh * ZL_, trD1 + (size_t)bh * ZL_, trD2 + (size_t)bh * ZL_};
#pragma unroll
  for (int rd = 0; rd < 4; ++rd) {
    __syncthreads();
#pragma unroll
    for (int mi = 0; mi < 2; ++mi)
#pragma unroll
      for (int ni = 0; ni < 2; ++ni)
#pragma unroll
        for (int r = 0; r < 4; ++r) {
          const int row = wm + mi * 16 + g * 4 + r, col = wn + ni * 16 + c16;
          if (rd == 0) Ts[row * 66 + col] = (short)f2bu(acc[0][mi][ni][r]);
          else Ts[col * 66 + row] = (short)f2bu(acc[rd][mi][ni][r]);
        }
    __syncthreads();
    const int rr = t >> 2, cs = (t & 3) * 16;
    unsigned short u[16] __attribute__((aligned(16)));
#pragma unroll
    for (int i = 0; i < 16; ++i) u[i] = (unsigned short)Ts[rr * 66 + cs + i];
    bf16* dp = (rd == 0) ? (dst0 + (size_t)(by * 64 + rr) * cFD + bx * 64 + cs)
                         : (dstT[rd - 1] + (size_t)(bx * 64 + rr) * cFD + by * 64 + cs);
    *(uint4*)dp = *(uint4*)u;
    *(uint4*)(dp + 8) = *(uint4*)(u + 8);
  }
}

// oc GEMM + trK + trV(l1) merged, grid 1152
__global__ __launch_bounds__(256) void k_octr(const bf16* __restrict__ hq, const bf16* __restrict__ w1b,
                                              bf16* __restrict__ occ,
                                              const bf16* __restrict__ fkb, const bf16* __restrict__ fvb,
                                              bf16* trK, bf16* trV, const float* __restrict__ lr1,
                                              int chunk) {
  __shared__ short Sh[8192];
  const int id = blockIdx.x, t = threadIdx.x;
  const size_t choff = (size_t)chunk * 262144;
  if (id < 128) {
    short* As = Sh;
    short* Bs = Sh + 4096;
    const int bh = id >> 4, by = (id >> 2) & 3, bx = id & 3;
    const bf16* Ab = hq + (size_t)bh * ZL_ + (size_t)by * 128 * cFD;
    const bf16* Bb = w1b + (size_t)bh * ZL_ + (size_t)bx * 128 * cFD;
    f32x4 acc[4][4];
    const f32x4 zero4 = {0.f, 0.f, 0.f, 0.f};
#pragma unroll
    for (int i = 0; i < 4; ++i)
#pragma unroll
      for (int j = 0; j < 4; ++j) acc[i][j] = zero4;
    mm_core<0, 0>(Ab, cFD, Bb, cFD, cFD, nullptr, As, Bs, acc);
    mm_store<false, false>(occ + (size_t)bh * ZL_, (bf16*)nullptr, cFD, by * 128, bx * 128, acc);
  } else {
    short* Ts = Sh;  // 64*72
    const int id2 = id - 128;
    const int var = id2 >> 9, bh = (id2 >> 6) & 7, by = (id2 >> 3) & 7, bx = id2 & 7;
    const bf16* src = ((var == 0) ? fkb : fvb) + choff + (size_t)bh * ZG_;
    bf16* dst = ((var == 0) ? trK : trV) + (size_t)bh * ZL_;
    {
      const int rr = t >> 2, cseg = (t & 3) * 16;
      if (var == 0) {
        const bf16* p = src + (size_t)(by * 64 + rr) * cFD + bx * 64 + cseg;
        stage16(p, &Ts[rr * 72 + cseg]);
      } else {
        const float s = lr1[bh * 2048 + chunk * 512 + by * 64 + rr];
        const bf16* p = src + (size_t)(by * 64 + rr) * cFD + bx * 64 + cseg;
        unsigned short u[16] __attribute__((aligned(16)));
#pragma unroll
        for (int i = 0; i < 16; ++i) u[i] = f2bu(b2f(p[i]) * s);
        *(uint4*)&Ts[rr * 72 + cseg] = *(uint4*)u;
        *(uint4*)&Ts[rr * 72 + cseg + 8] = *(uint4*)(u + 8);
      }
    }
    __syncthreads();
    {
      const int oc_ = t >> 2, rseg = (t & 3) * 16;
      unsigned short u[16] __attribute__((aligned(16)));
#pragma unroll
      for (int i = 0; i < 16; ++i) u[i] = (unsigned short)Ts[(rseg + i) * 72 + oc_];
      bf16* dp = dst + (size_t)(bx * 64 + oc_) * cFD + by * 64 + rseg;
      *(uint4*)dp = *(uint4*)u;
      *(uint4*)(dp + 8) = *(uint4*)(u + 8);
    }
  }
}

// upd3 (all NT gload) + norm_add merged, grid 4480
__global__ __launch_bounds__(256) void k_updna(const bf16* __restrict__ trV, const bf16* __restrict__ trH,
                                               const bf16* __restrict__ trD1, const bf16* __restrict__ trD2,
                                               const bf16* __restrict__ trK,
                                               float* w0s, float* w1s, float* w2s,
                                               bf16* w0b, bf16* w1b, bf16* w2b,
                                               const bf16* __restrict__ occ, const float* __restrict__ tw,
                                               bf16* __restrict__ y, int chunk) {
  __shared__ short Sh[8192];
  __shared__ float red[4];
  const int id = blockIdx.x, t = threadIdx.x;
  if (id < 384) {
    short* As = Sh;
    short* Bs = Sh + 4096;
    const int z = id >> 4, tile = id & 15, by = tile >> 2, bx = tile & 3;
    const int var = z >> 3, bh = z & 7;
    const bf16 *Aa, *Bb;
    float* W;
    bf16* M;
    if (var == 0) {
      Aa = trV + (size_t)bh * ZL_ + (size_t)by * 128 * cFD;
      Bb = trH + (size_t)bh * ZL_ + (size_t)bx * 128 * cFD;
      W = w1s + (size_t)bh * ZL_; M = w1b + (size_t)bh * ZL_;
    } else if (var == 1) {
      Aa = trD1 + (size_t)bh * ZL_ + (size_t)by * 128 * cFD;
      Bb = trK + (size_t)bh * ZL_ + (size_t)bx * 128 * cFD;
      W = w0s + (size_t)bh * ZL_; M = w0b + (size_t)bh * ZL_;
    } else {
      Aa = trD2 + (size_t)bh * ZL_ + (size_t)by * 128 * cFD;
      Bb = trK + (size_t)bh * ZL_ + (size_t)bx * 128 * cFD;
      W = w2s + (size_t)bh * ZL_; M = w2b + (size_t)bh * ZL_;
    }
    f32x4 acc[4][4];
    const f32x4 zero4 = {0.f, 0.f, 0.f, 0.f};
#pragma unroll
    for (int i = 0; i < 4; ++i)
#pragma unroll
      for (int j = 0; j < 4; ++j) acc[i][j] = zero4;
    mm_core<0, 0>(Aa, cFD, Bb, cFD, cFD, nullptr, As, Bs, acc);
    mm_store<true, true>(W, M, cFD, by * 128, bx * 128, acc);
  } else {
    const int rrow = id - 384;
    const int bh = rrow >> 9, rr = rrow & 511;
    const bf16* src = occ + ((size_t)bh * 512 + rr) * 512;
    float v0 = b2f(src[t]), v1 = b2f(src[t + 256]);
    float ss = v0 * v0 + v1 * v1;
    for (int d = 32; d; d >>= 1) ss += __shfl_down(ss, d);
    if ((t & 63) == 0) red[t >> 6] = ss;
    __syncthreads();
    const float rstd = rsqrtf((red[0] + red[1] + red[2] + red[3]) / cFD + 1e-6f);
    const int si = chunk * 512 + rr;
    bf16* dst = y + ((size_t)((bh >> 2) * cS) + si) * cH + (bh & 3) * cFD;
    dst[t] = f2b(b2f(dst[t]) + v0 * rstd * tw[t]);
    dst[t + 256] = f2b(b2f(dst[t + 256]) + v1 * rstd * tw[t + 256]);
  }
}

// --------------------------- fp32 -> bf16 flat convert ----------------------
__global__ __launch_bounds__(256) void k_cvt(const float* __restrict__ src, bf16* __restrict__ dst) {
  const size_t i = ((size_t)blockIdx.x * 256 + threadIdx.x) * 8;
  float4 a = *(const float4*)(src + i), b = *(const float4*)(src + i + 4);
  unsigned short u[8] __attribute__((aligned(16)));
  u[0] = f2bu(a.x); u[1] = f2bu(a.y); u[2] = f2bu(a.z); u[3] = f2bu(a.w);
  u[4] = f2bu(b.x); u[5] = f2bu(b.y); u[6] = f2bu(b.z); u[7] = f2bu(b.w);
  *(uint4*)(dst + i) = *(uint4*)u;
}

// --------------------------- state init ------------------------------------
__global__ __launch_bounds__(256) void k_winit(const float* __restrict__ w0, const float* __restrict__ w1,
                                               const float* __restrict__ w2,
                                               float* __restrict__ w0s, float* __restrict__ w1s,
                                               float* __restrict__ w2s) {
  const size_t i = (size_t)blockIdx.x * 256 + threadIdx.x;
  const int bh = (int)(i >> 18);
  const int f = bh & 3;
  const size_t off = i & 262143;
  const float* src; float* dst;
  if (blockIdx.y == 0) { src = w0; dst = w0s; }
  else if (blockIdx.y == 1) { src = w1; dst = w1s; }
  else { src = w2; dst = w2s; }
  dst[i] = src[(size_t)f * 262144 + off];
}

// --------------------------- rope table ------------------------------------
__global__ __launch_bounds__(64) void k_rope_tab(float* __restrict__ ct, float* __restrict__ stb) {
  const int si = blockIdx.x, j = threadIdx.x;
  float inv = powf(500000.0f, -(float)j / 64.0f);
  float ang = (float)si * inv;
  ct[(size_t)si * 64 + j] = cosf(ang);
  stb[(size_t)si * 64 + j] = sinf(ang);
}

// --------------------------- learning rates --------------------------------
__global__ __launch_bounds__(256) void k_lr(const float* __restrict__ x, const float* __restrict__ lr_w,
                                            const float* __restrict__ lr_b,
                                            float* lr0, float* lr1, float* lr2, float base) {
  const int token = blockIdx.x, b_ = token >> 11, si = token & 2047;
  const int wv = threadIdx.x >> 6, lane = threadIdx.x & 63;
  const float* xr = x + (size_t)token * cH;
#pragma unroll
  for (int jj = 0; jj < 3; ++jj) {
    const int j = wv * 3 + jj;
    const float* wr = lr_w + (size_t)j * cH;
    float s = 0.f;
    for (int k = lane; k < cH; k += 64) s += xr[k] * wr[k];
    for (int d = 32; d; d >>= 1) s += __shfl_down(s, d);
    if (lane == 0) {
      float v = s + lr_b[j] + base;
      float sp = (v > 15.f) ? v : log1pf(expf(v));
      const int tt = j >> 2, f = j & 3;
      float* dst = (tt == 0 ? lr0 : tt == 1 ? lr1 : lr2);
      dst[(size_t)(b_ * cNFW + f) * cS + si] = sp;
    }
  }
}

// ------------------ rmsnorm q/k in place + rope -> qa/ka --------------------
__global__ __launch_bounds__(256) void k_normrope(bf16* __restrict__ qkvh,
                                                  const float* __restrict__ qnw, const float* __restrict__ knw,
                                                  const float* __restrict__ ct, const float* __restrict__ stb,
                                                  bf16* __restrict__ qa, bf16* __restrict__ ka) {
  const int token = blockIdx.x, b_ = token >> 11, si = token & 2047;
  const int t = threadIdx.x;
  __shared__ float buf[cH];
  __shared__ float red[4];
  bf16* base = qkvh + (size_t)token * 3 * cH;
  for (int pass = 0; pass < 2; ++pass) {
    __syncthreads();
    bf16* src = base + pass * cH;
    const float* nw = pass ? knw : qnw;
    float ss = 0.f;
    for (int i = t; i < cH; i += 256) {
      float v = b2f(src[i]);
      buf[i] = v;
      ss += v * v;
    }
    for (int d = 32; d; d >>= 1) ss += __shfl_down(ss, d);
    if ((t & 63) == 0) red[t >> 6] = ss;
    __syncthreads();
    const float rstd = rsqrtf((red[0] + red[1] + red[2] + red[3]) / cH + 1e-6f);
    for (int i = t; i < cH; i += 256) {
      float v = buf[i] * rstd * nw[i];
      buf[i] = v;
      src[i] = f2b(v);
    }
    __syncthreads();
    bf16* dst = pass ? ka : qa;
    const float scale = pass ? 1.f : cRSQRT_HD;
    const int hh = t >> 4, j0 = (t & 15) * 4;
    const float* cr = ct + (size_t)si * 64 + j0;
    const float* sr = stb + (size_t)si * 64 + j0;
    bf16* drow = dst + ((size_t)(b_ * cNH + hh) * cS + si) * cHD;
    unsigned short u1[4] __attribute__((aligned(8))), u2[4] __attribute__((aligned(8)));
#pragma unroll
    for (int i = 0; i < 4; ++i) {
      float x1 = buf[hh * cHD + j0 + i], x2 = buf[hh * cHD + 64 + j0 + i];
      u1[i] = f2bu((x1 * cr[i] - x2 * sr[i]) * scale);
      u2[i] = f2bu((x2 * cr[i] + x1 * sr[i]) * scale);
    }
    *(uint2*)(drow + j0) = *(uint2*)u1;
    *(uint2*)(drow + 64 + j0) = *(uint2*)u2;
  }
}

// ------------------ V transpose: qkvh v-part -> vt[b,h,d,s] -----------------
__global__ __launch_bounds__(256) void k_vtr(const bf16* __restrict__ qkvh, bf16* __restrict__ vt) {
  const int tile = blockIdx.x, h = blockIdx.y, b_ = blockIdx.z;
  __shared__ short Ts[64 * 136];
  const int t = threadIdx.x;
  {
    const int r = t >> 2, seg = (t & 3) * 32;
    const bf16* src = qkvh + ((size_t)(b_ * cS) + tile * 64 + r) * 3 * cH + 2 * cH + h * cHD + seg;
    stage16(src, &Ts[r * 136 + seg]);
    stage16(src + 16, &Ts[r * 136 + seg + 16]);
  }
  __syncthreads();
  {
    const int d = t >> 1, seg2 = (t & 1) * 32;
    unsigned short u[32] __attribute__((aligned(16)));
#pragma unroll
    for (int i = 0; i < 32; ++i) u[i] = (unsigned short)Ts[(seg2 + i) * 136 + d];
    bf16* dp = vt + ((size_t)(b_ * cNH + h) * cHD + d) * cS + tile * 64 + seg2;
    *(uint4*)dp = *(uint4*)u;
    *(uint4*)(dp + 8) = *(uint4*)(u + 8);
    *(uint4*)(dp + 16) = *(uint4*)(u + 16);
    *(uint4*)(dp + 24) = *(uint4*)(u + 24);
  }
}

// ------------------ fq/fk/fv from normalized qkvh ---------------------------
__global__ __launch_bounds__(256) void k_fqkv(const bf16* __restrict__ qkvh,
                                              const float* __restrict__ qk_scale,
                                              const float* __restrict__ qk_offset,
                                              bf16* fq, bf16* fk, bf16* fv) {
  const int token = blockIdx.x, b_ = token >> 11, si = token & 2047;
  const int t = threadIdx.x;
  const bf16* base = qkvh + (size_t)token * 3 * cH;
#pragma unroll
  for (int pass = 0; pass < 2; ++pass) {
    const bf16* src = base + pass * cH;
    bf16* fdst = pass ? fk : fq;
    const int head = t >> 6, lane = t & 63;
    float f[8];
    float ss2 = 0.f;
#pragma unroll
    for (int k = 0; k < 8; ++k) {
      const int idx = head * cFD + lane + k * 64;
      float v = b2f(src[idx]);
      float u = v * qk_scale[idx * 2 + pass] + qk_offset[idx * 2 + pass];
      float fv_ = u * sigmoidf_(u);
      f[k] = fv_;
      ss2 += fv_ * fv_;
    }
    for (int d = 1; d < 64; d <<= 1) ss2 += __shfl_xor(ss2, d);
    const float sc2 = rsqrtf(ss2 + 1e-12f);
    bf16* dst = fdst + ((size_t)(b_ * cNFW + head) * cS + si) * cFD;
#pragma unroll
    for (int k = 0; k < 8; ++k) dst[lane + k * 64] = f2b(f[k] * sc2);
  }
  const bf16* vr = base + 2 * cH;
  for (int i = t; i < cH; i += 256) {
    float v = b2f(vr[i]);
    fv[((size_t)(b_ * cNFW + (i >> 9)) * cS + si) * cFD + (i & 511)] = f2b(v * sigmoidf_(v));
  }
}

// ------ attention: XCD-swizzled, reg prefetch, Ps-in-Ks, defer-max, setprio -
__global__ __launch_bounds__(256) void k_attn4(const bf16* __restrict__ qa, const bf16* __restrict__ ka,
                                               const bf16* __restrict__ vt, bf16* __restrict__ y) {
  const int id = blockIdx.x;
  const int hb = ((id >> 8) << 3) + (id & 7);
  const int qt = 31 - ((id >> 3) & 31);
  const int h = hb & 15, b_ = hb >> 4;
  const int q0 = qt * 64;
  __shared__ short Ks[64 * 136];   // Ps aliases into this after QK reads
  __shared__ short Vts[128 * 72];
  const int t = threadIdx.x, lane = t & 63, g = lane >> 4, c16 = lane & 15, wv = t >> 6;
  const size_t hbq = (size_t)(b_ * cNH + h) * cS;
  const bf16* vb = vt + (size_t)(b_ * cNH + h) * (size_t)(cHD * cS);
  short8 qf[4];
  {
    const bf16* qsrc = qa + (hbq + q0 + wv * 16 + c16) * cHD;
#pragma unroll
    for (int ks = 0; ks < 4; ++ks) qf[ks] = *(const short8*)(qsrc + ks * 32 + g * 8);
  }
  f32x4 o[8];
  const f32x4 zero4 = {0.f, 0.f, 0.f, 0.f};
#pragma unroll
  for (int i = 0; i < 8; ++i) o[i] = zero4;
  float m[4], l[4];
#pragma unroll
  for (int r = 0; r < 4; ++r) { m[r] = -1e30f; l[r] = 0.f; }

  const int r = t >> 2, seg = (t & 3) * 32;
  const int dv = t >> 1, seg2 = (t & 1) * 32;
  uint4 kp0, kp1, kp2, kp3, vp0, vp1, vp2, vp3;
  {
    const bf16* ksrc = ka + (hbq + r) * cHD + seg;
    kp0 = *(const uint4*)ksrc; kp1 = *(const uint4*)(ksrc + 8);
    kp2 = *(const uint4*)(ksrc + 16); kp3 = *(const uint4*)(ksrc + 24);
    const bf16* vsrc = vb + (size_t)dv * cS + seg2;
    vp0 = *(const uint4*)vsrc; vp1 = *(const uint4*)(vsrc + 8);
    vp2 = *(const uint4*)(vsrc + 16); vp3 = *(const uint4*)(vsrc + 24);
  }

  for (int kt = 0; kt <= qt; ++kt) {
    __syncthreads();
    {
      short* kd = &Ks[r * 136 + seg];
      *(uint4*)kd = kp0; *(uint4*)(kd + 8) = kp1;
      *(uint4*)(kd + 16) = kp2; *(uint4*)(kd + 24) = kp3;
      short* vd = &Vts[dv * 72 + seg2];
      *(uint4*)vd = vp0; *(uint4*)(vd + 8) = vp1;
      *(uint4*)(vd + 16) = vp2; *(uint4*)(vd + 24) = vp3;
    }
    __syncthreads();
    if (kt < qt) {
      const bf16* ksrc = ka + (hbq + (kt + 1) * 64 + r) * cHD + seg;
      kp0 = *(const uint4*)ksrc; kp1 = *(const uint4*)(ksrc + 8);
      kp2 = *(const uint4*)(ksrc + 16); kp3 = *(const uint4*)(ksrc + 24);
      const bf16* vsrc = vb + (size_t)dv * cS + (kt + 1) * 64 + seg2;
      vp0 = *(const uint4*)vsrc; vp1 = *(const uint4*)(vsrc + 8);
      vp2 = *(const uint4*)(vsrc + 16); vp3 = *(const uint4*)(vsrc + 24);
    }

    f32x4 s4[4];
#pragma unroll
    for (int ni = 0; ni < 4; ++ni) s4[ni] = zero4;
    __builtin_amdgcn_s_setprio(1);
#pragma unroll
    for (int ks = 0; ks < 4; ++ks) {
#pragma unroll
      for (int ni = 0; ni < 4; ++ni) {
        short8 bb = *(const short8*)&Ks[(ni * 16 + c16) * 136 + ks * 32 + g * 8];
        s4[ni] = __builtin_amdgcn_mfma_f32_16x16x32_bf16(qf[ks], bb, s4[ni], 0, 0, 0);
      }
    }
    __builtin_amdgcn_s_setprio(0);
    __syncthreads();
    if (kt == qt) {
#pragma unroll
      for (int ni = 0; ni < 4; ++ni) {
        const int kv = kt * 64 + ni * 16 + c16;
#pragma unroll
        for (int rr = 0; rr < 4; ++rr) {
          const int qr = q0 + wv * 16 + g * 4 + rr;
          if (kv > qr) s4[ni][rr] = -1e9f;
        }
      }
    }
    float mx[4];
#pragma unroll
    for (int rr = 0; rr < 4; ++rr)
      mx[rr] = fmaxf(fmaxf(s4[0][rr], s4[1][rr]), fmaxf(s4[2][rr], s4[3][rr]));
#pragma unroll
    for (int d = 1; d < 16; d <<= 1)
#pragma unroll
      for (int rr = 0; rr < 4; ++rr) mx[rr] = fmaxf(mx[rr], __shfl_xor(mx[rr], d));
    bool need = false;
#pragma unroll
    for (int rr = 0; rr < 4; ++rr) need |= (mx[rr] > m[rr] + 8.f);
    if (__any(need)) {
      float corr[4];
#pragma unroll
      for (int rr = 0; rr < 4; ++rr) {
        float mn = fmaxf(m[rr], mx[rr]);
        corr[rr] = __expf(m[rr] - mn);
        m[rr] = mn;
      }
#pragma unroll
      for (int rr = 0; rr < 4; ++rr) l[rr] *= corr[rr];
#pragma unroll
      for (int nf = 0; nf < 8; ++nf)
#pragma unroll
        for (int rr = 0; rr < 4; ++rr) o[nf][rr] *= corr[rr];
    }
    float psum[4] = {0.f, 0.f, 0.f, 0.f};
#pragma unroll
    for (int ni = 0; ni < 4; ++ni)
#pragma unroll
      for (int rr = 0; rr < 4; ++rr) {
        float p = __expf(s4[ni][rr] - m[rr]);
        s4[ni][rr] = p;
        psum[rr] += p;
      }
#pragma unroll
    for (int d = 1; d < 16; d <<= 1)
#pragma unroll
      for (int rr = 0; rr < 4; ++rr) psum[rr] += __shfl_xor(psum[rr], d);
#pragma unroll
    for (int rr = 0; rr < 4; ++rr) l[rr] += psum[rr];
    short* pw = &Ks[wv * 1152];
#pragma unroll
    for (int ni = 0; ni < 4; ++ni)
#pragma unroll
      for (int rr = 0; rr < 4; ++rr)
        pw[(g * 4 + rr) * 72 + ni * 16 + c16] = (short)f2bu(s4[ni][rr]);
    __builtin_amdgcn_s_setprio(1);
#pragma unroll
    for (int ks2 = 0; ks2 < 2; ++ks2) {
      short8 a = *(const short8*)&pw[c16 * 72 + ks2 * 32 + g * 8];
#pragma unroll
      for (int nf = 0; nf < 8; ++nf) {
        short8 bb = *(const short8*)&Vts[(nf * 16 + c16) * 72 + ks2 * 32 + g * 8];
        o[nf] = __builtin_amdgcn_mfma_f32_16x16x32_bf16(a, bb, o[nf], 0, 0, 0);
      }
    }
    __builtin_amdgcn_s_setprio(0);
  }
  float inv[4];
#pragma unroll
  for (int rr = 0; rr < 4; ++rr) inv[rr] = 1.f / l[rr];
#pragma unroll
  for (int nf = 0; nf < 8; ++nf)
#pragma unroll
    for (int rr = 0; rr < 4; ++rr) {
      const size_t row = (size_t)(b_ * cS) + q0 + wv * 16 + g * 4 + rr;
      y[row * cH + h * cHD + nf * 16 + c16] = f2b(o[nf][rr] * inv[rr]);
    }
}

}  // namespace

extern "C" void kernel_launch(void* const* d_in, const int* in_sizes, int n_in,
                              void* d_out, int out_size, void* d_ws, size_t ws_size,
                              hipStream_t stream) {
  (void)in_sizes; (void)n_in; (void)out_size; (void)ws_size;
  const float* x         = (const float*)d_in[0];
  const float* qkv_w     = (const float*)d_in[1];
  const float* q_norm_w  = (const float*)d_in[2];
  const float* k_norm_w  = (const float*)d_in[3];
  const float* qk_scale  = (const float*)d_in[4];
  const float* qk_offset = (const float*)d_in[5];
  const float* lr_w      = (const float*)d_in[6];
  const float* lr_b      = (const float*)d_in[7];
  const float* w0        = (const float*)d_in[8];
  const float* w1        = (const float*)d_in[9];
  const float* w2        = (const float*)d_in[10];
  const float* ttt_nw    = (const float*)d_in[11];
  const float* o_proj_w  = (const float*)d_in[12];
  float* out = (float*)d_out;

  // ---- workspace layout (bytes), total 143,851,520 (proven footprint) ----
  char* Wb = (char*)d_ws;
  bf16* qkvh = (bf16*)Wb;                 // phase-1 only (50.3MB)
  bf16* hq   = (bf16*)(Wb + 0UL);         // TTT phase buffers:
  bf16* trH  = (bf16*)(Wb + 4194304UL);
  bf16* trD1 = (bf16*)(Wb + 8388608UL);
  bf16* trD2 = (bf16*)(Wb + 12582912UL);
  bf16* trK  = (bf16*)(Wb + 16777216UL);
  bf16* trV  = (bf16*)(Wb + 20971520UL);
  bf16* occ  = (bf16*)(Wb + 29360128UL);
  bf16* w0b  = (bf16*)(Wb + 33554432UL);  // contiguous mirrors
  bf16* w1b  = (bf16*)(Wb + 37748736UL);
  bf16* w2b  = (bf16*)(Wb + 41943040UL);
  bf16* opwb = (bf16*)(Wb + 0UL);         // after TTT loop
  size_t off = 50331648UL;
  bf16* fqb = (bf16*)(Wb + off); off += 16777216UL;
  bf16* fkb = (bf16*)(Wb + off); off += 16777216UL;
  bf16* fvb = (bf16*)(Wb + off); off += 16777216UL;
  float* w0s = (float*)(Wb + off); off += 8388608UL;
  float* w1s = (float*)(Wb + off); off += 8388608UL;
  float* w2s = (float*)(Wb + off); off += 8388608UL;
  float* lr0 = (float*)(Wb + off); off += 65536UL;
  float* lr1 = (float*)(Wb + off); off += 65536UL;
  float* lr2 = (float*)(Wb + off); off += 65536UL;
  bf16* y = (bf16*)(Wb + off); off += 16777216UL;
  float* ct  = (float*)(Wb + off); off += 524288UL;
  float* stb = (float*)(Wb + off); off += 524288UL;
  bf16* xb = fqb;
  bf16* qkvwb = fkb;
  bf16* qa = fqb;
  bf16* ka = fkb;
  bf16* vt = fvb;

  const float base_lr_inv = logf(expm1f(0.001f));
  dim3 blk(256);

  k_winit<<<dim3(8192, 3), blk, 0, stream>>>(w0, w1, w2, w0s, w1s, w2s);
  k_rope_tab<<<dim3(2048), dim3(64), 0, stream>>>(ct, stb);
  k_cvt<<<dim3(4096), blk, 0, stream>>>(x, xb);
  k_cvt<<<dim3(6144), blk, 0, stream>>>(qkv_w, qkvwb);
  k_mm<bf16, 0><<<dim3(48, 32, 1), blk, 0, stream>>>(xb, 2048, 0, qkvwb, 2048, 0, qkvh, 6144, 0, 2048);
  k_lr<<<dim3(4096), blk, 0, stream>>>(x, lr_w, lr_b, lr0, lr1, lr2, base_lr_inv);
  k_normrope<<<dim3(4096), blk, 0, stream>>>(qkvh, q_norm_w, k_norm_w, ct, stb, qa, ka);
  k_vtr<<<dim3(32, 16, 2), blk, 0, stream>>>(qkvh, vt);
  k_attn4<<<dim3(1024), blk, 0, stream>>>(qa, ka, vt, y);
  k_fqkv<<<dim3(4096), blk, 0, stream>>>(qkvh, qk_scale, qk_offset, fqb, fkb, fvb);
  k_cvt<<<dim3(3072), blk, 0, stream>>>(w0s, w0b);  // contiguous 6.29M-elem mirror block

  for (int c = 0; c < 4; ++c) {
    k_fuse1<<<dim3(512), blk, 0, stream>>>(fqb, fkb, fvb, w0b, w1b, w2b,
                                           hq, trH, trD1, trD2, lr0, lr2, c);
    k_octr<<<dim3(1152), blk, 0, stream>>>(hq, w1b, occ, fkb, fvb, trK, trV, lr1, c);
    k_updna<<<dim3(4480), blk, 0, stream>>>(trV, trH, trD1, trD2, trK,
                                            w0s, w1s, w2s, w0b, w1b, w2b, occ, ttt_nw, y, c);
  }
  k_cvt<<<dim3(2048), blk, 0, stream>>>(o_proj_w, opwb);
  k_mm<float, 0><<<dim3(16, 32, 1), blk, 0, stream>>>(y, 2048, 0, opwb, 2048, 0, out, 2048, 0, 2048);
}

// Round 10
// 743.507 us; speedup vs baseline: 6.9985x; 1.0851x over previous
//
#include <hip/hip_runtime.h>
#include <hip/hip_bf16.h>
#include <math.h>

using bf16 = __hip_bfloat16;

namespace {

constexpr int cH = 2048;
constexpr int cNH = 16;
constexpr int cHD = 128;
constexpr int cNFW = 4;
constexpr int cFD = 512;
constexpr int cS = 2048;
constexpr float cRSQRT_HD = 0.08838834764831845f;  // 1/sqrt(128)
constexpr long ZL_ = 262144;   // 512*512
constexpr long ZG_ = 1048576;  // 2048*512

typedef __attribute__((ext_vector_type(8))) short short8;
typedef __attribute__((ext_vector_type(4))) float f32x4;

__device__ __forceinline__ float sigmoidf_(float x) { return 1.0f / (1.0f + __expf(-x)); }
__device__ __forceinline__ float b2f(bf16 v) { return __bfloat162float(v); }
__device__ __forceinline__ bf16 f2b(float v) { return __float2bfloat16(v); }
__device__ __forceinline__ unsigned short f2bu(float f) {
  return __builtin_bit_cast(unsigned short, __float2bfloat16(f));
}

#if defined(__has_builtin)
#if __has_builtin(__builtin_amdgcn_global_load_lds)
#define HAVE_GLOAD 1
#endif
#endif

__device__ __forceinline__ void gload16(const bf16* g, short* ldsbase) {
#ifdef HAVE_GLOAD
  __builtin_amdgcn_global_load_lds((const __attribute__((address_space(1))) void*)g,
                                   (__attribute__((address_space(3))) void*)ldsbase, 16, 0, 0);
#else
  const int l = threadIdx.x & 63;
  *(uint4*)(ldsbase + l * 8) = *(const uint4*)g;
#endif
}

__device__ __forceinline__ void stage16(const bf16* src, short* dst) {
  *(uint4*)dst = *(const uint4*)src;
  *(uint4*)(dst + 8) = *(const uint4*)(src + 8);
}

__device__ __forceinline__ void store1(float* p, float v) { *p = v; }
__device__ __forceinline__ void store1(bf16* p, float v) { *p = f2b(v); }

// ---------------------------------------------------------------------------
// MFMA GEMM core: 128x128 tile, 4 waves (2x2 of 64x64), BK=32, linear LDS.
// ---------------------------------------------------------------------------
template <int AMODE, int BMODE>
__device__ __forceinline__ void mm_core(const bf16* __restrict__ Ab, int lda,
                                        const bf16* __restrict__ Bb, int ldb, int K,
                                        const float* __restrict__ sc,
                                        short* As, short* Bs, f32x4 acc[4][4]) {
  const int t = threadIdx.x, lane = t & 63, g = lane >> 4, c16 = lane & 15;
  const int wv = t >> 6, wm = (wv >> 1) * 64, wn = (wv & 1) * 64;
  for (int k0 = 0; k0 < K; k0 += 32) {
    __syncthreads();
    if constexpr (AMODE == 0) {
      const int ch = wv * 2;
      const bf16* g0 = Ab + (size_t)(ch * 16 + (lane >> 2)) * lda + k0 + (lane & 3) * 8;
      gload16(g0, &As[ch * 512]);
      gload16(g0 + (size_t)16 * lda, &As[ch * 512 + 512]);
    } else {
      const int kk = t >> 3, mseg = (t & 7) * 16;
      const float s = sc[k0 + kk];
      const bf16* p = Ab + (size_t)(k0 + kk) * lda + mseg;
#pragma unroll
      for (int i = 0; i < 16; ++i) As[(mseg + i) * 32 + kk] = (short)f2bu(b2f(p[i]) * s);
    }
    if constexpr (BMODE == 0) {
      const int ch = wv * 2;
      const bf16* g0 = Bb + (size_t)(ch * 16 + (lane >> 2)) * ldb + k0 + (lane & 3) * 8;
      gload16(g0, &Bs[ch * 512]);
      gload16(g0 + (size_t)16 * ldb, &Bs[ch * 512 + 512]);
    } else {
      const int kk = t >> 3, cseg = (t & 7) * 16;
      const short* p = (const short*)(Bb + (size_t)(k0 + kk) * ldb + cseg);
#pragma unroll
      for (int i = 0; i < 16; ++i) Bs[(cseg + i) * 32 + kk] = p[i];
    }
    __syncthreads();
    short8 af[4], bfr[4];
#pragma unroll
    for (int mi = 0; mi < 4; ++mi) af[mi] = *(const short8*)&As[(wm + mi * 16 + c16) * 32 + g * 8];
#pragma unroll
    for (int ni = 0; ni < 4; ++ni) bfr[ni] = *(const short8*)&Bs[(wn + ni * 16 + c16) * 32 + g * 8];
#pragma unroll
    for (int mi = 0; mi < 4; ++mi)
#pragma unroll
      for (int ni = 0; ni < 4; ++ni)
        acc[mi][ni] = __builtin_amdgcn_mfma_f32_16x16x32_bf16(af[mi], bfr[ni], acc[mi][ni], 0, 0, 0);
  }
}

template <bool ACC, bool MIR, typename TC>
__device__ __forceinline__ void mm_store(TC* Cb, bf16* Mb, int ldc, int rb, int cb, f32x4 acc[4][4]) {
  const int t = threadIdx.x, lane = t & 63, g = lane >> 4, c16 = lane & 15;
  const int wv = t >> 6, wm = (wv >> 1) * 64, wn = (wv & 1) * 64;
  const int rbase = rb + wm, cbase = cb + wn;
#pragma unroll
  for (int mi = 0; mi < 4; ++mi)
#pragma unroll
    for (int ni = 0; ni < 4; ++ni) {
      const int col = cbase + ni * 16 + c16;
#pragma unroll
      for (int r = 0; r < 4; ++r) {
        const int row = rbase + mi * 16 + g * 4 + r;
        TC* cp = Cb + (size_t)row * ldc + col;
        if constexpr (ACC) {
          float nv = *cp + acc[mi][ni][r];
          *cp = nv;
          if constexpr (MIR) Mb[(size_t)row * ldc + col] = f2b(nv);
        } else {
          store1(cp, acc[mi][ni][r]);
        }
      }
    }
}

template <typename TC, int BMODE>
__global__ __launch_bounds__(256) void k_mm(const bf16* __restrict__ A, int lda, long zsa,
                                            const bf16* __restrict__ B, int ldb, long zsb,
                                            TC* __restrict__ C, int ldc, long zsc, int K) {
  __shared__ short As[128 * 32];
  __shared__ short Bs[128 * 32];
  const int z = blockIdx.z;
  const bf16* Ab = A + (size_t)z * zsa + (size_t)blockIdx.y * 128 * lda;
  const bf16* Bb = (BMODE == 0) ? (B + (size_t)z * zsb + (size_t)blockIdx.x * 128 * ldb)
                                : (B + (size_t)z * zsb + blockIdx.x * 128);
  f32x4 acc[4][4];
  const f32x4 zero4 = {0.f, 0.f, 0.f, 0.f};
#pragma unroll
  for (int i = 0; i < 4; ++i)
#pragma unroll
    for (int j = 0; j < 4; ++j) acc[i][j] = zero4;
  mm_core<0, BMODE>(Ab, lda, Bb, ldb, K, nullptr, As, Bs, acc);
  mm_store<false, false>(C + (size_t)z * zsc, (bf16*)nullptr, ldc, blockIdx.y * 128, blockIdx.x * 128, acc);
}

// ---------------------------------------------------------------------------
// Fused stage1 + gates + (trK,trV transposes) + (prev-chunk norm-add).
// ids 0..511:   5-GEMM 64x64 tiles, gates in-register, writes hq + 3 transposed
// ids 512..1535: trK = fk_chunk^T ; trV = (l1*fv_chunk)^T
// ids 1536..5631 (only when chunk>0): rmsnorm+add of previous chunk's occ
// ---------------------------------------------------------------------------
__global__ __launch_bounds__(256) void k_fuse1(const bf16* __restrict__ fq, const bf16* __restrict__ fk,
                                               const bf16* __restrict__ fv,
                                               const bf16* __restrict__ w0b, const bf16* __restrict__ w1bc,
                                               const bf16* __restrict__ w2b,
                                               bf16* __restrict__ hq, bf16* __restrict__ trH,
                                               bf16* __restrict__ trD1, bf16* __restrict__ trD2,
                                               bf16* __restrict__ trK, bf16* __restrict__ trV,
                                               const float* __restrict__ lr0, const float* __restrict__ lr1,
                                               const float* __restrict__ lr2,
                                               const bf16* __restrict__ occPrev,
                                               const float* __restrict__ tw, bf16* __restrict__ y,
                                               int chunk) {
  __shared__ short S[12288];
  __shared__ float red[4];
  const int id = blockIdx.x, t = threadIdx.x;
  const size_t choff = (size_t)chunk * 262144;

  if (id < 512) {
    const int bh = id >> 6, tile = id & 63, by = tile >> 3, bx = tile & 7;
    const int lane = t & 63, g = lane >> 4, c16 = lane & 15, wv = t >> 6;
    const int wm = (wv >> 1) * 32, wn = (wv & 1) * 32;
    const bf16* Aq = fq + (size_t)bh * ZG_ + choff + (size_t)(by * 64) * cFD;
    const bf16* Ak = fk + (size_t)bh * ZG_ + choff + (size_t)(by * 64) * cFD;
    const bf16* Av = fv + (size_t)bh * ZG_ + choff + (size_t)(by * 64) * cFD;
    const bf16* B0 = w0b + (size_t)bh * ZL_ + (size_t)(bx * 64) * cFD;
    const bf16* B2 = w2b + (size_t)bh * ZL_ + (size_t)(bx * 64) * cFD;
    const bf16* B1 = w1bc + (size_t)bh * ZL_ + bx * 64;

    f32x4 acc[5][2][2];
    const f32x4 zero4 = {0.f, 0.f, 0.f, 0.f};
#pragma unroll
    for (int v = 0; v < 5; ++v)
#pragma unroll
      for (int i = 0; i < 2; ++i)
#pragma unroll
        for (int j = 0; j < 2; ++j) acc[v][i][j] = zero4;

    const int srow = wv * 16 + (lane >> 2), scol = (lane & 3) * 8;
    for (int k0 = 0; k0 < 512; k0 += 32) {
      __syncthreads();
      gload16(Aq + (size_t)srow * cFD + k0 + scol, &S[0 + wv * 512]);
      gload16(Ak + (size_t)srow * cFD + k0 + scol, &S[2048 + wv * 512]);
      gload16(Av + (size_t)srow * cFD + k0 + scol, &S[4096 + wv * 512]);
      gload16(B0 + (size_t)srow * cFD + k0 + scol, &S[6144 + wv * 512]);
      gload16(B2 + (size_t)srow * cFD + k0 + scol, &S[8192 + wv * 512]);
      {
        const int kk = t >> 3, e8 = (t & 7) * 8;
        const short* p = (const short*)(B1 + (size_t)(k0 + kk) * cFD + e8);
#pragma unroll
        for (int i = 0; i < 8; ++i) S[10240 + (e8 + i) * 32 + kk] = p[i];
      }
      __syncthreads();
      short8 aq[2], ak[2], av[2], b0[2], b2[2], b1[2];
#pragma unroll
      for (int mi = 0; mi < 2; ++mi) {
        const int ro = (wm + mi * 16 + c16) * 32 + g * 8;
        aq[mi] = *(const short8*)&S[0 + ro];
        ak[mi] = *(const short8*)&S[2048 + ro];
        av[mi] = *(const short8*)&S[4096 + ro];
      }
#pragma unroll
      for (int ni = 0; ni < 2; ++ni) {
        const int ro = (wn + ni * 16 + c16) * 32 + g * 8;
        b0[ni] = *(const short8*)&S[6144 + ro];
        b2[ni] = *(const short8*)&S[8192 + ro];
        b1[ni] = *(const short8*)&S[10240 + ro];
      }
#pragma unroll
      for (int mi = 0; mi < 2; ++mi)
#pragma unroll
        for (int ni = 0; ni < 2; ++ni) {
          acc[0][mi][ni] = __builtin_amdgcn_mfma_f32_16x16x32_bf16(aq[mi], b0[ni], acc[0][mi][ni], 0, 0, 0);
          acc[1][mi][ni] = __builtin_amdgcn_mfma_f32_16x16x32_bf16(aq[mi], b2[ni], acc[1][mi][ni], 0, 0, 0);
          acc[2][mi][ni] = __builtin_amdgcn_mfma_f32_16x16x32_bf16(ak[mi], b0[ni], acc[2][mi][ni], 0, 0, 0);
          acc[3][mi][ni] = __builtin_amdgcn_mfma_f32_16x16x32_bf16(ak[mi], b2[ni], acc[3][mi][ni], 0, 0, 0);
          acc[4][mi][ni] = __builtin_amdgcn_mfma_f32_16x16x32_bf16(av[mi], b1[ni], acc[4][mi][ni], 0, 0, 0);
        }
    }

    float l0v[2][4], l2v[2][4];
#pragma unroll
    for (int mi = 0; mi < 2; ++mi)
#pragma unroll
      for (int r = 0; r < 4; ++r) {
        const int row = by * 64 + wm + mi * 16 + g * 4 + r;
        l0v[mi][r] = lr0[bh * 2048 + chunk * 512 + row];
        l2v[mi][r] = lr2[bh * 2048 + chunk * 512 + row];
      }
#pragma unroll
    for (int mi = 0; mi < 2; ++mi)
#pragma unroll
      for (int ni = 0; ni < 2; ++ni)
#pragma unroll
        for (int r = 0; r < 4; ++r) {
          float hq1 = acc[0][mi][ni][r], hq2 = acc[1][mi][ni][r];
          float g1 = acc[2][mi][ni][r], g2 = acc[3][mi][ni][r], dh = acc[4][mi][ni][r];
          acc[0][mi][ni][r] = hq1 * sigmoidf_(hq1) * hq2;
          float sg = sigmoidf_(g1);
          float gate = g1 * sg;
          acc[1][mi][ni][r] = gate * g2;
          acc[2][mi][ni][r] = l0v[mi][r] * dh * g2 * (sg * (1.0f + g1 * (1.0f - sg)));
          acc[3][mi][ni][r] = l2v[mi][r] * dh * gate;
        }

    short* Ts = S;
    bf16* dst0 = hq + (size_t)bh * ZL_;
    bf16* dstT[3] = {trH + (size_t)bh * ZL_, trD1 + (size_t)bh * ZL_, trD2 + (size_t)bh * ZL_};
#pragma unroll
    for (int rd = 0; rd < 4; ++rd) {
      __syncthreads();
#pragma unroll
      for (int mi = 0; mi < 2; ++mi)
#pragma unroll
        for (int ni = 0; ni < 2; ++ni)
#pragma unroll
          for (int r = 0; r < 4; ++r) {
            const int row = wm + mi * 16 + g * 4 + r, col = wn + ni * 16 + c16;
            if (rd == 0) Ts[row * 66 + col] = (short)f2bu(acc[0][mi][ni][r]);
            else Ts[col * 66 + row] = (short)f2bu(acc[rd][mi][ni][r]);
          }
      __syncthreads();
      const int rr = t >> 2, cs = (t & 3) * 16;
      unsigned short u[16] __attribute__((aligned(16)));
#pragma unroll
      for (int i = 0; i < 16; ++i) u[i] = (unsigned short)Ts[rr * 66 + cs + i];
      bf16* dp = (rd == 0) ? (dst0 + (size_t)(by * 64 + rr) * cFD + bx * 64 + cs)
                           : (dstT[rd - 1] + (size_t)(bx * 64 + rr) * cFD + by * 64 + cs);
      *(uint4*)dp = *(uint4*)u;
      *(uint4*)(dp + 8) = *(uint4*)(u + 8);
    }
  } else if (id < 1536) {
    short* Ts = S;  // 64*72
    const int id2 = id - 512;
    const int var = id2 >> 9, bh = (id2 >> 6) & 7, by = (id2 >> 3) & 7, bx = id2 & 7;
    const bf16* src = ((var == 0) ? fk : fv) + choff + (size_t)bh * ZG_;
    bf16* dst = ((var == 0) ? trK : trV) + (size_t)bh * ZL_;
    {
      const int rr = t >> 2, cseg = (t & 3) * 16;
      if (var == 0) {
        stage16(src + (size_t)(by * 64 + rr) * cFD + bx * 64 + cseg, &Ts[rr * 72 + cseg]);
      } else {
        const float s = lr1[bh * 2048 + chunk * 512 + by * 64 + rr];
        const bf16* p = src + (size_t)(by * 64 + rr) * cFD + bx * 64 + cseg;
        unsigned short u[16] __attribute__((aligned(16)));
#pragma unroll
        for (int i = 0; i < 16; ++i) u[i] = f2bu(b2f(p[i]) * s);
        *(uint4*)&Ts[rr * 72 + cseg] = *(uint4*)u;
        *(uint4*)&Ts[rr * 72 + cseg + 8] = *(uint4*)(u + 8);
      }
    }
    __syncthreads();
    {
      const int oc_ = t >> 2, rseg = (t & 3) * 16;
      unsigned short u[16] __attribute__((aligned(16)));
#pragma unroll
      for (int i = 0; i < 16; ++i) u[i] = (unsigned short)Ts[(rseg + i) * 72 + oc_];
      bf16* dp = dst + (size_t)(bx * 64 + oc_) * cFD + by * 64 + rseg;
      *(uint4*)dp = *(uint4*)u;
      *(uint4*)(dp + 8) = *(uint4*)(u + 8);
    }
  } else {
    // norm-add for previous chunk's occ
    const int rrow = id - 1536;
    const int bh = rrow >> 9, rr = rrow & 511;
    const bf16* src = occPrev + ((size_t)bh * 512 + rr) * 512;
    float v0 = b2f(src[t]), v1 = b2f(src[t + 256]);
    float ss = v0 * v0 + v1 * v1;
    for (int d = 32; d; d >>= 1) ss += __shfl_down(ss, d);
    if ((t & 63) == 0) red[t >> 6] = ss;
    __syncthreads();
    const float rstd = rsqrtf((red[0] + red[1] + red[2] + red[3]) / cFD + 1e-6f);
    const int si = (chunk - 1) * 512 + rr;
    bf16* dst = y + ((size_t)((bh >> 2) * cS) + si) * cH + (bh & 3) * cFD;
    dst[t] = f2b(b2f(dst[t]) + v0 * rstd * tw[t]);
    dst[t + 256] = f2b(b2f(dst[t + 256]) + v1 * rstd * tw[t + 256]);
  }
}

// ---------------------------------------------------------------------------
// updna: ids 0..383 weight-update GEMMs (128² tiles, masters += and mirrors);
//        ids 384..895 oc = hq @ w1_cur^T (64² tiles) into occCur.
// Race-free: oc reads w1bc (current mirror); updates write w1bn (next mirror).
// ---------------------------------------------------------------------------
__global__ __launch_bounds__(256) void k_updna(const bf16* __restrict__ trV, const bf16* __restrict__ trH,
                                               const bf16* __restrict__ trD1, const bf16* __restrict__ trD2,
                                               const bf16* __restrict__ trK,
                                               const bf16* __restrict__ hq, const bf16* __restrict__ w1bc,
                                               float* w0s, float* w1s, float* w2s,
                                               bf16* w0b, bf16* w1bn, bf16* w2b,
                                               bf16* __restrict__ occCur) {
  __shared__ short Sh[8192];
  const int id = blockIdx.x, t = threadIdx.x;
  if (id < 384) {
    short* As = Sh;
    short* Bs = Sh + 4096;
    const int z = id >> 4, tile = id & 15, by = tile >> 2, bx = tile & 3;
    const int var = z >> 3, bh = z & 7;
    const bf16 *Aa, *Bb;
    float* W;
    bf16* M;
    if (var == 0) {
      Aa = trV + (size_t)bh * ZL_ + (size_t)by * 128 * cFD;
      Bb = trH + (size_t)bh * ZL_ + (size_t)bx * 128 * cFD;
      W = w1s + (size_t)bh * ZL_; M = w1bn + (size_t)bh * ZL_;
    } else if (var == 1) {
      Aa = trD1 + (size_t)bh * ZL_ + (size_t)by * 128 * cFD;
      Bb = trK + (size_t)bh * ZL_ + (size_t)bx * 128 * cFD;
      W = w0s + (size_t)bh * ZL_; M = w0b + (size_t)bh * ZL_;
    } else {
      Aa = trD2 + (size_t)bh * ZL_ + (size_t)by * 128 * cFD;
      Bb = trK + (size_t)bh * ZL_ + (size_t)bx * 128 * cFD;
      W = w2s + (size_t)bh * ZL_; M = w2b + (size_t)bh * ZL_;
    }
    f32x4 acc[4][4];
    const f32x4 zero4 = {0.f, 0.f, 0.f, 0.f};
#pragma unroll
    for (int i = 0; i < 4; ++i)
#pragma unroll
      for (int j = 0; j < 4; ++j) acc[i][j] = zero4;
    mm_core<0, 0>(Aa, cFD, Bb, cFD, cFD, nullptr, As, Bs, acc);
    mm_store<true, true>(W, M, cFD, by * 128, bx * 128, acc);
  } else {
    // oc: 64x64 tile GEMM, 4 waves each 32x32 quadrant
    const int id2 = id - 384;
    const int bh = id2 >> 6, tile = id2 & 63, by = tile >> 3, bx = tile & 7;
    const int lane = t & 63, g = lane >> 4, c16 = lane & 15, wv = t >> 6;
    const int wm = (wv >> 1) * 32, wn = (wv & 1) * 32;
    const bf16* Aa = hq + (size_t)bh * ZL_ + (size_t)(by * 64) * cFD;
    const bf16* Bb = w1bc + (size_t)bh * ZL_ + (size_t)(bx * 64) * cFD;
    short* As = Sh;        // 64x32
    short* Bs = Sh + 2048; // 64x32
    f32x4 acc[2][2];
    const f32x4 zero4 = {0.f, 0.f, 0.f, 0.f};
#pragma unroll
    for (int i = 0; i < 2; ++i)
#pragma unroll
      for (int j = 0; j < 2; ++j) acc[i][j] = zero4;
    for (int k0 = 0; k0 < 512; k0 += 32) {
      __syncthreads();
      {
        const int srow = wv * 16 + (lane >> 2), scol = (lane & 3) * 8;
        gload16(Aa + (size_t)srow * cFD + k0 + scol, &As[wv * 512]);
        gload16(Bb + (size_t)srow * cFD + k0 + scol, &Bs[wv * 512]);
      }
      __syncthreads();
      short8 af[2], bfr[2];
#pragma unroll
      for (int mi = 0; mi < 2; ++mi) af[mi] = *(const short8*)&As[(wm + mi * 16 + c16) * 32 + g * 8];
#pragma unroll
      for (int ni = 0; ni < 2; ++ni) bfr[ni] = *(const short8*)&Bs[(wn + ni * 16 + c16) * 32 + g * 8];
#pragma unroll
      for (int mi = 0; mi < 2; ++mi)
#pragma unroll
        for (int ni = 0; ni < 2; ++ni)
          acc[mi][ni] = __builtin_amdgcn_mfma_f32_16x16x32_bf16(af[mi], bfr[ni], acc[mi][ni], 0, 0, 0);
    }
    bf16* C = occCur + (size_t)bh * ZL_;
#pragma unroll
    for (int mi = 0; mi < 2; ++mi)
#pragma unroll
      for (int ni = 0; ni < 2; ++ni) {
        const int col = bx * 64 + wn + ni * 16 + c16;
#pragma unroll
        for (int r = 0; r < 4; ++r) {
          const int row = by * 64 + wm + mi * 16 + g * 4 + r;
          C[(size_t)row * cFD + col] = f2b(acc[mi][ni][r]);
        }
      }
  }
}

// standalone norm-add (final chunk)
__global__ __launch_bounds__(256) void k_norm(const bf16* __restrict__ occ,
                                              const float* __restrict__ tw, bf16* __restrict__ y,
                                              int chunk) {
  __shared__ float red[4];
  const int rrow = blockIdx.x;
  const int bh = rrow >> 9, rr = rrow & 511;
  const int t = threadIdx.x;
  const bf16* src = occ + ((size_t)bh * 512 + rr) * 512;
  float v0 = b2f(src[t]), v1 = b2f(src[t + 256]);
  float ss = v0 * v0 + v1 * v1;
  for (int d = 32; d; d >>= 1) ss += __shfl_down(ss, d);
  if ((t & 63) == 0) red[t >> 6] = ss;
  __syncthreads();
  const float rstd = rsqrtf((red[0] + red[1] + red[2] + red[3]) / cFD + 1e-6f);
  const int si = chunk * 512 + rr;
  bf16* dst = y + ((size_t)((bh >> 2) * cS) + si) * cH + (bh & 3) * cFD;
  dst[t] = f2b(b2f(dst[t]) + v0 * rstd * tw[t]);
  dst[t + 256] = f2b(b2f(dst[t + 256]) + v1 * rstd * tw[t + 256]);
}

// --------------------------- fp32 -> bf16 flat convert ----------------------
__global__ __launch_bounds__(256) void k_cvt(const float* __restrict__ src, bf16* __restrict__ dst) {
  const size_t i = ((size_t)blockIdx.x * 256 + threadIdx.x) * 8;
  float4 a = *(const float4*)(src + i), b = *(const float4*)(src + i + 4);
  unsigned short u[8] __attribute__((aligned(16)));
  u[0] = f2bu(a.x); u[1] = f2bu(a.y); u[2] = f2bu(a.z); u[3] = f2bu(a.w);
  u[4] = f2bu(b.x); u[5] = f2bu(b.y); u[6] = f2bu(b.z); u[7] = f2bu(b.w);
  *(uint4*)(dst + i) = *(uint4*)u;
}

// --------------------------- state init ------------------------------------
__global__ __launch_bounds__(256) void k_winit(const float* __restrict__ w0, const float* __restrict__ w1,
                                               const float* __restrict__ w2,
                                               float* __restrict__ w0s, float* __restrict__ w1s,
                                               float* __restrict__ w2s) {
  const size_t i = (size_t)blockIdx.x * 256 + threadIdx.x;
  const int bh = (int)(i >> 18);
  const int f = bh & 3;
  const size_t off = i & 262143;
  const float* src; float* dst;
  if (blockIdx.y == 0) { src = w0; dst = w0s; }
  else if (blockIdx.y == 1) { src = w1; dst = w1s; }
  else { src = w2; dst = w2s; }
  dst[i] = src[(size_t)f * 262144 + off];
}

// --------------------------- rope table ------------------------------------
__global__ __launch_bounds__(64) void k_rope_tab(float* __restrict__ ct, float* __restrict__ stb) {
  const int si = blockIdx.x, j = threadIdx.x;
  float inv = powf(500000.0f, -(float)j / 64.0f);
  float ang = (float)si * inv;
  ct[(size_t)si * 64 + j] = cosf(ang);
  stb[(size_t)si * 64 + j] = sinf(ang);
}

// --------------------------- learning rates --------------------------------
__global__ __launch_bounds__(256) void k_lr(const float* __restrict__ x, const float* __restrict__ lr_w,
                                            const float* __restrict__ lr_b,
                                            float* lr0, float* lr1, float* lr2, float base) {
  const int token = blockIdx.x, b_ = token >> 11, si = token & 2047;
  const int wv = threadIdx.x >> 6, lane = threadIdx.x & 63;
  const float* xr = x + (size_t)token * cH;
#pragma unroll
  for (int jj = 0; jj < 3; ++jj) {
    const int j = wv * 3 + jj;
    const float* wr = lr_w + (size_t)j * cH;
    float s = 0.f;
    for (int k = lane; k < cH; k += 64) s += xr[k] * wr[k];
    for (int d = 32; d; d >>= 1) s += __shfl_down(s, d);
    if (lane == 0) {
      float v = s + lr_b[j] + base;
      float sp = (v > 15.f) ? v : log1pf(expf(v));
      const int tt = j >> 2, f = j & 3;
      float* dst = (tt == 0 ? lr0 : tt == 1 ? lr1 : lr2);
      dst[(size_t)(b_ * cNFW + f) * cS + si] = sp;
    }
  }
}

// ------------------ rmsnorm q/k in place + rope -> qa/ka --------------------
__global__ __launch_bounds__(256) void k_normrope(bf16* __restrict__ qkvh,
                                                  const float* __restrict__ qnw, const float* __restrict__ knw,
                                                  const float* __restrict__ ct, const float* __restrict__ stb,
                                                  bf16* __restrict__ qa, bf16* __restrict__ ka) {
  const int token = blockIdx.x, b_ = token >> 11, si = token & 2047;
  const int t = threadIdx.x;
  __shared__ float buf[cH];
  __shared__ float red[4];
  bf16* base = qkvh + (size_t)token * 3 * cH;
  for (int pass = 0; pass < 2; ++pass) {
    __syncthreads();
    bf16* src = base + pass * cH;
    const float* nw = pass ? knw : qnw;
    float ss = 0.f;
    for (int i = t; i < cH; i += 256) {
      float v = b2f(src[i]);
      buf[i] = v;
      ss += v * v;
    }
    for (int d = 32; d; d >>= 1) ss += __shfl_down(ss, d);
    if ((t & 63) == 0) red[t >> 6] = ss;
    __syncthreads();
    const float rstd = rsqrtf((red[0] + red[1] + red[2] + red[3]) / cH + 1e-6f);
    for (int i = t; i < cH; i += 256) {
      float v = buf[i] * rstd * nw[i];
      buf[i] = v;
      src[i] = f2b(v);
    }
    __syncthreads();
    bf16* dst = pass ? ka : qa;
    const float scale = pass ? 1.f : cRSQRT_HD;
    const int hh = t >> 4, j0 = (t & 15) * 4;
    const float* cr = ct + (size_t)si * 64 + j0;
    const float* sr = stb + (size_t)si * 64 + j0;
    bf16* drow = dst + ((size_t)(b_ * cNH + hh) * cS + si) * cHD;
    unsigned short u1[4] __attribute__((aligned(8))), u2[4] __attribute__((aligned(8)));
#pragma unroll
    for (int i = 0; i < 4; ++i) {
      float x1 = buf[hh * cHD + j0 + i], x2 = buf[hh * cHD + 64 + j0 + i];
      u1[i] = f2bu((x1 * cr[i] - x2 * sr[i]) * scale);
      u2[i] = f2bu((x2 * cr[i] + x1 * sr[i]) * scale);
    }
    *(uint2*)(drow + j0) = *(uint2*)u1;
    *(uint2*)(drow + 64 + j0) = *(uint2*)u2;
  }
}

// ------------------ V transpose: qkvh v-part -> vt[b,h,d,s] -----------------
__global__ __launch_bounds__(256) void k_vtr(const bf16* __restrict__ qkvh, bf16* __restrict__ vt) {
  const int tile = blockIdx.x, h = blockIdx.y, b_ = blockIdx.z;
  __shared__ short Ts[64 * 136];
  const int t = threadIdx.x;
  {
    const int r = t >> 2, seg = (t & 3) * 32;
    const bf16* src = qkvh + ((size_t)(b_ * cS) + tile * 64 + r) * 3 * cH + 2 * cH + h * cHD + seg;
    stage16(src, &Ts[r * 136 + seg]);
    stage16(src + 16, &Ts[r * 136 + seg + 16]);
  }
  __syncthreads();
  {
    const int d = t >> 1, seg2 = (t & 1) * 32;
    unsigned short u[32] __attribute__((aligned(16)));
#pragma unroll
    for (int i = 0; i < 32; ++i) u[i] = (unsigned short)Ts[(seg2 + i) * 136 + d];
    bf16* dp = vt + ((size_t)(b_ * cNH + h) * cHD + d) * cS + tile * 64 + seg2;
    *(uint4*)dp = *(uint4*)u;
    *(uint4*)(dp + 8) = *(uint4*)(u + 8);
    *(uint4*)(dp + 16) = *(uint4*)(u + 16);
    *(uint4*)(dp + 24) = *(uint4*)(u + 24);
  }
}

// ------------------ fq/fk/fv from normalized qkvh ---------------------------
__global__ __launch_bounds__(256) void k_fqkv(const bf16* __restrict__ qkvh,
                                              const float* __restrict__ qk_scale,
                                              const float* __restrict__ qk_offset,
                                              bf16* fq, bf16* fk, bf16* fv) {
  const int token = blockIdx.x, b_ = token >> 11, si = token & 2047;
  const int t = threadIdx.x;
  const bf16* base = qkvh + (size_t)token * 3 * cH;
#pragma unroll
  for (int pass = 0; pass < 2; ++pass) {
    const bf16* src = base + pass * cH;
    bf16* fdst = pass ? fk : fq;
    const int head = t >> 6, lane = t & 63;
    float f[8];
    float ss2 = 0.f;
#pragma unroll
    for (int k = 0; k < 8; ++k) {
      const int idx = head * cFD + lane + k * 64;
      float v = b2f(src[idx]);
      float u = v * qk_scale[idx * 2 + pass] + qk_offset[idx * 2 + pass];
      float fv_ = u * sigmoidf_(u);
      f[k] = fv_;
      ss2 += fv_ * fv_;
    }
    for (int d = 1; d < 64; d <<= 1) ss2 += __shfl_xor(ss2, d);
    const float sc2 = rsqrtf(ss2 + 1e-12f);
    bf16* dst = fdst + ((size_t)(b_ * cNFW + head) * cS + si) * cFD;
#pragma unroll
    for (int k = 0; k < 8; ++k) dst[lane + k * 64] = f2b(f[k] * sc2);
  }
  const bf16* vr = base + 2 * cH;
  for (int i = t; i < cH; i += 256) {
    float v = b2f(vr[i]);
    fv[((size_t)(b_ * cNFW + (i >> 9)) * cS + si) * cFD + (i & 511)] = f2b(v * sigmoidf_(v));
  }
}

// ------ attention: paired q-tiles (uniform work), XCD-swizzled, prefetch ----
__global__ __launch_bounds__(256) void k_attn5(const bf16* __restrict__ qa, const bf16* __restrict__ ka,
                                               const bf16* __restrict__ vt, bf16* __restrict__ y) {
  const int id = blockIdx.x;            // 0..511
  const int xcd = id & 7;
  const int j = id >> 3;                // 0..63
  const int p = j & 15;
  const int hb = (j >> 4) * 8 + xcd;    // 0..31
  const int h = hb & 15, b_ = hb >> 4;
  __shared__ short Ks[64 * 136];        // Ps aliases into this after QK reads
  __shared__ short Vts[128 * 72];
  const int t = threadIdx.x, lane = t & 63, g = lane >> 4, c16 = lane & 15, wv = t >> 6;
  const size_t hbq = (size_t)(b_ * cNH + h) * cS;
  const bf16* vb = vt + (size_t)(b_ * cNH + h) * (size_t)(cHD * cS);
  const int r = t >> 2, seg = (t & 3) * 32;
  const int dv = t >> 1, seg2 = (t & 1) * 32;
  const f32x4 zero4 = {0.f, 0.f, 0.f, 0.f};

  for (int half = 0; half < 2; ++half) {
    const int qt = half ? p : 31 - p;
    const int q0 = qt * 64;
    short8 qf[4];
    {
      const bf16* qsrc = qa + (hbq + q0 + wv * 16 + c16) * cHD;
#pragma unroll
      for (int ks = 0; ks < 4; ++ks) qf[ks] = *(const short8*)(qsrc + ks * 32 + g * 8);
    }
    f32x4 o[8];
#pragma unroll
    for (int i = 0; i < 8; ++i) o[i] = zero4;
    float m[4], l[4];
#pragma unroll
    for (int rr = 0; rr < 4; ++rr) { m[rr] = -1e30f; l[rr] = 0.f; }

    uint4 kp0, kp1, kp2, kp3, vp0, vp1, vp2, vp3;
    {
      const bf16* ksrc = ka + (hbq + r) * cHD + seg;
      kp0 = *(const uint4*)ksrc; kp1 = *(const uint4*)(ksrc + 8);
      kp2 = *(const uint4*)(ksrc + 16); kp3 = *(const uint4*)(ksrc + 24);
      const bf16* vsrc = vb + (size_t)dv * cS + seg2;
      vp0 = *(const uint4*)vsrc; vp1 = *(const uint4*)(vsrc + 8);
      vp2 = *(const uint4*)(vsrc + 16); vp3 = *(const uint4*)(vsrc + 24);
    }

    for (int kt = 0; kt <= qt; ++kt) {
      __syncthreads();
      {
        short* kd = &Ks[r * 136 + seg];
        *(uint4*)kd = kp0; *(uint4*)(kd + 8) = kp1;
        *(uint4*)(kd + 16) = kp2; *(uint4*)(kd + 24) = kp3;
        short* vd = &Vts[dv * 72 + seg2];
        *(uint4*)vd = vp0; *(uint4*)(vd + 8) = vp1;
        *(uint4*)(vd + 16) = vp2; *(uint4*)(vd + 24) = vp3;
      }
      __syncthreads();
      if (kt < qt) {
        const bf16* ksrc = ka + (hbq + (kt + 1) * 64 + r) * cHD + seg;
        kp0 = *(const uint4*)ksrc; kp1 = *(const uint4*)(ksrc + 8);
        kp2 = *(const uint4*)(ksrc + 16); kp3 = *(const uint4*)(ksrc + 24);
        const bf16* vsrc = vb + (size_t)dv * cS + (kt + 1) * 64 + seg2;
        vp0 = *(const uint4*)vsrc; vp1 = *(const uint4*)(vsrc + 8);
        vp2 = *(const uint4*)(vsrc + 16); vp3 = *(const uint4*)(vsrc + 24);
      } else if (half == 0) {
        // prefetch first tile of second half
        const bf16* ksrc = ka + (hbq + r) * cHD + seg;
        kp0 = *(const uint4*)ksrc; kp1 = *(const uint4*)(ksrc + 8);
        kp2 = *(const uint4*)(ksrc + 16); kp3 = *(const uint4*)(ksrc + 24);
        const bf16* vsrc = vb + (size_t)dv * cS + seg2;
        vp0 = *(const uint4*)vsrc; vp1 = *(const uint4*)(vsrc + 8);
        vp2 = *(const uint4*)(vsrc + 16); vp3 = *(const uint4*)(vsrc + 24);
      }

      f32x4 s4[4];
#pragma unroll
      for (int ni = 0; ni < 4; ++ni) s4[ni] = zero4;
      __builtin_amdgcn_s_setprio(1);
#pragma unroll
      for (int ks = 0; ks < 4; ++ks) {
#pragma unroll
        for (int ni = 0; ni < 4; ++ni) {
          short8 bb = *(const short8*)&Ks[(ni * 16 + c16) * 136 + ks * 32 + g * 8];
          s4[ni] = __builtin_amdgcn_mfma_f32_16x16x32_bf16(qf[ks], bb, s4[ni], 0, 0, 0);
        }
      }
      __builtin_amdgcn_s_setprio(0);
      __syncthreads();
      if (kt == qt) {
#pragma unroll
        for (int ni = 0; ni < 4; ++ni) {
          const int kv = kt * 64 + ni * 16 + c16;
#pragma unroll
          for (int rr = 0; rr < 4; ++rr) {
            const int qr = q0 + wv * 16 + g * 4 + rr;
            if (kv > qr) s4[ni][rr] = -1e9f;
          }
        }
      }
      float mx[4];
#pragma unroll
      for (int rr = 0; rr < 4; ++rr)
        mx[rr] = fmaxf(fmaxf(s4[0][rr], s4[1][rr]), fmaxf(s4[2][rr], s4[3][rr]));
#pragma unroll
      for (int d = 1; d < 16; d <<= 1)
#pragma unroll
        for (int rr = 0; rr < 4; ++rr) mx[rr] = fmaxf(mx[rr], __shfl_xor(mx[rr], d));
      bool need = false;
#pragma unroll
      for (int rr = 0; rr < 4; ++rr) need |= (mx[rr] > m[rr] + 8.f);
      if (__any(need)) {
        float corr[4];
#pragma unroll
        for (int rr = 0; rr < 4; ++rr) {
          float mn = fmaxf(m[rr], mx[rr]);
          corr[rr] = __expf(m[rr] - mn);
          m[rr] = mn;
        }
#pragma unroll
        for (int rr = 0; rr < 4; ++rr) l[rr] *= corr[rr];
#pragma unroll
        for (int nf = 0; nf < 8; ++nf)
#pragma unroll
          for (int rr = 0; rr < 4; ++rr) o[nf][rr] *= corr[rr];
      }
      float psum[4] = {0.f, 0.f, 0.f, 0.f};
#pragma unroll
      for (int ni = 0; ni < 4; ++ni)
#pragma unroll
        for (int rr = 0; rr < 4; ++rr) {
          float pp = __expf(s4[ni][rr] - m[rr]);
          s4[ni][rr] = pp;
          psum[rr] += pp;
        }
#pragma unroll
      for (int d = 1; d < 16; d <<= 1)
#pragma unroll
        for (int rr = 0; rr < 4; ++rr) psum[rr] += __shfl_xor(psum[rr], d);
#pragma unroll
      for (int rr = 0; rr < 4; ++rr) l[rr] += psum[rr];
      short* pw = &Ks[wv * 1152];
#pragma unroll
      for (int ni = 0; ni < 4; ++ni)
#pragma unroll
        for (int rr = 0; rr < 4; ++rr)
          pw[(g * 4 + rr) * 72 + ni * 16 + c16] = (short)f2bu(s4[ni][rr]);
      __builtin_amdgcn_s_setprio(1);
#pragma unroll
      for (int ks2 = 0; ks2 < 2; ++ks2) {
        short8 a = *(const short8*)&pw[c16 * 72 + ks2 * 32 + g * 8];
#pragma unroll
        for (int nf = 0; nf < 8; ++nf) {
          short8 bb = *(const short8*)&Vts[(nf * 16 + c16) * 72 + ks2 * 32 + g * 8];
          o[nf] = __builtin_amdgcn_mfma_f32_16x16x32_bf16(a, bb, o[nf], 0, 0, 0);
        }
      }
      __builtin_amdgcn_s_setprio(0);
    }
    float inv[4];
#pragma unroll
    for (int rr = 0; rr < 4; ++rr) inv[rr] = 1.f / l[rr];
#pragma unroll
    for (int nf = 0; nf < 8; ++nf)
#pragma unroll
      for (int rr = 0; rr < 4; ++rr) {
        const size_t row = (size_t)(b_ * cS) + q0 + wv * 16 + g * 4 + rr;
        y[row * cH + h * cHD + nf * 16 + c16] = f2b(o[nf][rr] * inv[rr]);
      }
  }
}

}  // namespace

extern "C" void kernel_launch(void* const* d_in, const int* in_sizes, int n_in,
                              void* d_out, int out_size, void* d_ws, size_t ws_size,
                              hipStream_t stream) {
  (void)in_sizes; (void)n_in; (void)out_size; (void)ws_size;
  const float* x         = (const float*)d_in[0];
  const float* qkv_w     = (const float*)d_in[1];
  const float* q_norm_w  = (const float*)d_in[2];
  const float* k_norm_w  = (const float*)d_in[3];
  const float* qk_scale  = (const float*)d_in[4];
  const float* qk_offset = (const float*)d_in[5];
  const float* lr_w      = (const float*)d_in[6];
  const float* lr_b      = (const float*)d_in[7];
  const float* w0        = (const float*)d_in[8];
  const float* w1        = (const float*)d_in[9];
  const float* w2        = (const float*)d_in[10];
  const float* ttt_nw    = (const float*)d_in[11];
  const float* o_proj_w  = (const float*)d_in[12];
  float* out = (float*)d_out;

  // ---- workspace layout (bytes), total 143,851,520 (proven footprint) ----
  char* Wb = (char*)d_ws;
  bf16* qkvh = (bf16*)Wb;                 // phase-1 only (50.3MB)
  bf16* hq   = (bf16*)(Wb + 0UL);         // TTT phase buffers:
  bf16* trH  = (bf16*)(Wb + 4194304UL);
  bf16* trD1 = (bf16*)(Wb + 8388608UL);
  bf16* trD2 = (bf16*)(Wb + 12582912UL);
  bf16* trK  = (bf16*)(Wb + 16777216UL);
  bf16* trV  = (bf16*)(Wb + 20971520UL);
  bf16* occA = (bf16*)(Wb + 25165824UL);
  bf16* occB = (bf16*)(Wb + 29360128UL);
  bf16* w0b  = (bf16*)(Wb + 33554432UL);  // contiguous mirrors w0b,w1b0,w2b
  bf16* w1b0 = (bf16*)(Wb + 37748736UL);
  bf16* w2b  = (bf16*)(Wb + 41943040UL);
  bf16* w1b1 = (bf16*)(Wb + 46137344UL);  // w1 mirror ping-pong partner
  bf16* opwb = (bf16*)(Wb + 0UL);         // after TTT loop
  size_t off = 50331648UL;
  bf16* fqb = (bf16*)(Wb + off); off += 16777216UL;
  bf16* fkb = (bf16*)(Wb + off); off += 16777216UL;
  bf16* fvb = (bf16*)(Wb + off); off += 16777216UL;
  float* w0s = (float*)(Wb + off); off += 8388608UL;
  float* w1s = (float*)(Wb + off); off += 8388608UL;
  float* w2s = (float*)(Wb + off); off += 8388608UL;
  float* lr0 = (float*)(Wb + off); off += 65536UL;
  float* lr1 = (float*)(Wb + off); off += 65536UL;
  float* lr2 = (float*)(Wb + off); off += 65536UL;
  bf16* y = (bf16*)(Wb + off); off += 16777216UL;
  float* ct  = (float*)(Wb + off); off += 524288UL;
  float* stb = (float*)(Wb + off); off += 524288UL;
  bf16* xb = fqb;
  bf16* qkvwb = fkb;
  bf16* qa = fqb;
  bf16* ka = fkb;
  bf16* vt = fvb;
  bf16* w1m[2] = {w1b0, w1b1};
  bf16* occb[2] = {occA, occB};

  const float base_lr_inv = logf(expm1f(0.001f));
  dim3 blk(256);

  k_winit<<<dim3(8192, 3), blk, 0, stream>>>(w0, w1, w2, w0s, w1s, w2s);
  k_rope_tab<<<dim3(2048), dim3(64), 0, stream>>>(ct, stb);
  k_cvt<<<dim3(4096), blk, 0, stream>>>(x, xb);
  k_cvt<<<dim3(6144), blk, 0, stream>>>(qkv_w, qkvwb);
  k_mm<bf16, 0><<<dim3(48, 32, 1), blk, 0, stream>>>(xb, 2048, 0, qkvwb, 2048, 0, qkvh, 6144, 0, 2048);
  k_lr<<<dim3(4096), blk, 0, stream>>>(x, lr_w, lr_b, lr0, lr1, lr2, base_lr_inv);
  k_normrope<<<dim3(4096), blk, 0, stream>>>(qkvh, q_norm_w, k_norm_w, ct, stb, qa, ka);
  k_vtr<<<dim3(32, 16, 2), blk, 0, stream>>>(qkvh, vt);
  k_attn5<<<dim3(512), blk, 0, stream>>>(qa, ka, vt, y);
  k_fqkv<<<dim3(4096), blk, 0, stream>>>(qkvh, qk_scale, qk_offset, fqb, fkb, fvb);
  k_cvt<<<dim3(3072), blk, 0, stream>>>(w0s, w0b);  // fills w0b, w1b0, w2b

  for (int c = 0; c < 4; ++c) {
    const int g1 = (c == 0) ? 1536 : 5632;
    k_fuse1<<<dim3(g1), blk, 0, stream>>>(fqb, fkb, fvb, w0b, w1m[c & 1], w2b,
                                          hq, trH, trD1, trD2, trK, trV,
                                          lr0, lr1, lr2,
                                          (c == 0) ? occb[0] : occb[(c - 1) & 1],
                                          ttt_nw, y, c);
    k_updna<<<dim3(896), blk, 0, stream>>>(trV, trH, trD1, trD2, trK, hq, w1m[c & 1],
                                           w0s, w1s, w2s, w0b, w1m[(c + 1) & 1], w2b,
                                           occb[c & 1]);
  }
  k_norm<<<dim3(4096), blk, 0, stream>>>(occb[1], ttt_nw, y, 3);
  k_cvt<<<dim3(2048), blk, 0, stream>>>(o_proj_w, opwb);
  k_mm<float, 0><<<dim3(16, 32, 1), blk, 0, stream>>>(y, 2048, 0, opwb, 2048, 0, out, 2048, 0, 2048);
}

// Round 11
// 726.260 us; speedup vs baseline: 7.1647x; 1.0237x over previous
//
#include <hip/hip_runtime.h>
#include <hip/hip_bf16.h>
#include <math.h>

using bf16 = __hip_bfloat16;

namespace {

constexpr int cH = 2048;
constexpr int cNH = 16;
constexpr int cHD = 128;
constexpr int cNFW = 4;
constexpr int cFD = 512;
constexpr int cS = 2048;
constexpr float cRSQRT_HD = 0.08838834764831845f;  // 1/sqrt(128)
constexpr long ZL_ = 262144;   // 512*512
constexpr long ZG_ = 1048576;  // 2048*512

typedef __attribute__((ext_vector_type(8))) short short8;
typedef __attribute__((ext_vector_type(4))) float f32x4;

__device__ __forceinline__ float sigmoidf_(float x) { return 1.0f / (1.0f + __expf(-x)); }
__device__ __forceinline__ float b2f(bf16 v) { return __bfloat162float(v); }
__device__ __forceinline__ bf16 f2b(float v) { return __float2bfloat16(v); }
__device__ __forceinline__ unsigned short f2bu(float f) {
  return __builtin_bit_cast(unsigned short, __float2bfloat16(f));
}

#if defined(__has_builtin)
#if __has_builtin(__builtin_amdgcn_global_load_lds)
#define HAVE_GLOAD 1
#endif
#endif

__device__ __forceinline__ void gload16(const bf16* g, short* ldsbase) {
#ifdef HAVE_GLOAD
  __builtin_amdgcn_global_load_lds((const __attribute__((address_space(1))) void*)g,
                                   (__attribute__((address_space(3))) void*)ldsbase, 16, 0, 0);
#else
  const int l = threadIdx.x & 63;
  *(uint4*)(ldsbase + l * 8) = *(const uint4*)g;
#endif
}

__device__ __forceinline__ void stage16(const bf16* src, short* dst) {
  *(uint4*)dst = *(const uint4*)src;
  *(uint4*)(dst + 8) = *(const uint4*)(src + 8);
}

__device__ __forceinline__ void store1(float* p, float v) { *p = v; }
__device__ __forceinline__ void store1(bf16* p, float v) { *p = f2b(v); }

// ---------------------------------------------------------------------------
// MFMA GEMM core: 128x128 tile, 4 waves (2x2 of 64x64), BK=32, linear LDS.
// ---------------------------------------------------------------------------
template <int AMODE, int BMODE>
__device__ __forceinline__ void mm_core(const bf16* __restrict__ Ab, int lda,
                                        const bf16* __restrict__ Bb, int ldb, int K,
                                        const float* __restrict__ sc,
                                        short* As, short* Bs, f32x4 acc[4][4]) {
  const int t = threadIdx.x, lane = t & 63, g = lane >> 4, c16 = lane & 15;
  const int wv = t >> 6, wm = (wv >> 1) * 64, wn = (wv & 1) * 64;
  for (int k0 = 0; k0 < K; k0 += 32) {
    __syncthreads();
    if constexpr (AMODE == 0) {
      const int ch = wv * 2;
      const bf16* g0 = Ab + (size_t)(ch * 16 + (lane >> 2)) * lda + k0 + (lane & 3) * 8;
      gload16(g0, &As[ch * 512]);
      gload16(g0 + (size_t)16 * lda, &As[ch * 512 + 512]);
    } else {
      const int kk = t >> 3, mseg = (t & 7) * 16;
      const float s = sc[k0 + kk];
      const bf16* p = Ab + (size_t)(k0 + kk) * lda + mseg;
#pragma unroll
      for (int i = 0; i < 16; ++i) As[(mseg + i) * 32 + kk] = (short)f2bu(b2f(p[i]) * s);
    }
    if constexpr (BMODE == 0) {
      const int ch = wv * 2;
      const bf16* g0 = Bb + (size_t)(ch * 16 + (lane >> 2)) * ldb + k0 + (lane & 3) * 8;
      gload16(g0, &Bs[ch * 512]);
      gload16(g0 + (size_t)16 * ldb, &Bs[ch * 512 + 512]);
    } else {
      const int kk = t >> 3, cseg = (t & 7) * 16;
      const short* p = (const short*)(Bb + (size_t)(k0 + kk) * ldb + cseg);
#pragma unroll
      for (int i = 0; i < 16; ++i) Bs[(cseg + i) * 32 + kk] = p[i];
    }
    __syncthreads();
    short8 af[4], bfr[4];
#pragma unroll
    for (int mi = 0; mi < 4; ++mi) af[mi] = *(const short8*)&As[(wm + mi * 16 + c16) * 32 + g * 8];
#pragma unroll
    for (int ni = 0; ni < 4; ++ni) bfr[ni] = *(const short8*)&Bs[(wn + ni * 16 + c16) * 32 + g * 8];
#pragma unroll
    for (int mi = 0; mi < 4; ++mi)
#pragma unroll
      for (int ni = 0; ni < 4; ++ni)
        acc[mi][ni] = __builtin_amdgcn_mfma_f32_16x16x32_bf16(af[mi], bfr[ni], acc[mi][ni], 0, 0, 0);
  }
}

template <bool ACC, bool MIR, typename TC>
__device__ __forceinline__ void mm_store(TC* Cb, bf16* Mb, int ldc, int rb, int cb, f32x4 acc[4][4]) {
  const int t = threadIdx.x, lane = t & 63, g = lane >> 4, c16 = lane & 15;
  const int wv = t >> 6, wm = (wv >> 1) * 64, wn = (wv & 1) * 64;
  const int rbase = rb + wm, cbase = cb + wn;
#pragma unroll
  for (int mi = 0; mi < 4; ++mi)
#pragma unroll
    for (int ni = 0; ni < 4; ++ni) {
      const int col = cbase + ni * 16 + c16;
#pragma unroll
      for (int r = 0; r < 4; ++r) {
        const int row = rbase + mi * 16 + g * 4 + r;
        TC* cp = Cb + (size_t)row * ldc + col;
        if constexpr (ACC) {
          float nv = *cp + acc[mi][ni][r];
          *cp = nv;
          if constexpr (MIR) Mb[(size_t)row * ldc + col] = f2b(nv);
        } else {
          store1(cp, acc[mi][ni][r]);
        }
      }
    }
}

template <typename TC, int BMODE>
__global__ __launch_bounds__(256) void k_mm(const bf16* __restrict__ A, int lda, long zsa,
                                            const bf16* __restrict__ B, int ldb, long zsb,
                                            TC* __restrict__ C, int ldc, long zsc, int K) {
  __shared__ short As[128 * 32];
  __shared__ short Bs[128 * 32];
  const int z = blockIdx.z;
  const bf16* Ab = A + (size_t)z * zsa + (size_t)blockIdx.y * 128 * lda;
  const bf16* Bb = (BMODE == 0) ? (B + (size_t)z * zsb + (size_t)blockIdx.x * 128 * ldb)
                                : (B + (size_t)z * zsb + blockIdx.x * 128);
  f32x4 acc[4][4];
  const f32x4 zero4 = {0.f, 0.f, 0.f, 0.f};
#pragma unroll
  for (int i = 0; i < 4; ++i)
#pragma unroll
    for (int j = 0; j < 4; ++j) acc[i][j] = zero4;
  mm_core<0, BMODE>(Ab, lda, Bb, ldb, K, nullptr, As, Bs, acc);
  mm_store<false, false>(C + (size_t)z * zsc, (bf16*)nullptr, ldc, blockIdx.y * 128, blockIdx.x * 128, acc);
}

// ---------------------------------------------------------------------------
// Fused stage1 + gates + (trK,trV transposes) + (prev-chunk norm-add).
// ---------------------------------------------------------------------------
__global__ __launch_bounds__(256) void k_fuse1(const bf16* __restrict__ fq, const bf16* __restrict__ fk,
                                               const bf16* __restrict__ fv,
                                               const bf16* __restrict__ w0b, const bf16* __restrict__ w1bc,
                                               const bf16* __restrict__ w2b,
                                               bf16* __restrict__ hq, bf16* __restrict__ trH,
                                               bf16* __restrict__ trD1, bf16* __restrict__ trD2,
                                               bf16* __restrict__ trK, bf16* __restrict__ trV,
                                               const float* __restrict__ lr0, const float* __restrict__ lr1,
                                               const float* __restrict__ lr2,
                                               const bf16* __restrict__ occPrev,
                                               const float* __restrict__ tw, bf16* __restrict__ y,
                                               int chunk) {
  __shared__ short S[12800];  // Aq0 Ak2048 Av4096 B0_6144 B2_8192 B1_10240(stride40)
  __shared__ float red[4];
  const int id = blockIdx.x, t = threadIdx.x;
  const size_t choff = (size_t)chunk * 262144;

  if (id < 512) {
    const int bh = id >> 6, tile = id & 63, by = tile >> 3, bx = tile & 7;
    const int lane = t & 63, g = lane >> 4, c16 = lane & 15, wv = t >> 6;
    const int wm = (wv >> 1) * 32, wn = (wv & 1) * 32;
    const bf16* Aq = fq + (size_t)bh * ZG_ + choff + (size_t)(by * 64) * cFD;
    const bf16* Ak = fk + (size_t)bh * ZG_ + choff + (size_t)(by * 64) * cFD;
    const bf16* Av = fv + (size_t)bh * ZG_ + choff + (size_t)(by * 64) * cFD;
    const bf16* B0 = w0b + (size_t)bh * ZL_ + (size_t)(bx * 64) * cFD;
    const bf16* B2 = w2b + (size_t)bh * ZL_ + (size_t)(bx * 64) * cFD;
    const bf16* B1 = w1bc + (size_t)bh * ZL_ + bx * 64;

    f32x4 acc[5][2][2];
    const f32x4 zero4 = {0.f, 0.f, 0.f, 0.f};
#pragma unroll
    for (int v = 0; v < 5; ++v)
#pragma unroll
      for (int i = 0; i < 2; ++i)
#pragma unroll
        for (int j = 0; j < 2; ++j) acc[v][i][j] = zero4;

    const int srow = wv * 16 + (lane >> 2), scol = (lane & 3) * 8;
    for (int k0 = 0; k0 < 512; k0 += 32) {
      __syncthreads();
      gload16(Aq + (size_t)srow * cFD + k0 + scol, &S[0 + wv * 512]);
      gload16(Ak + (size_t)srow * cFD + k0 + scol, &S[2048 + wv * 512]);
      gload16(Av + (size_t)srow * cFD + k0 + scol, &S[4096 + wv * 512]);
      gload16(B0 + (size_t)srow * cFD + k0 + scol, &S[6144 + wv * 512]);
      gload16(B2 + (size_t)srow * cFD + k0 + scol, &S[8192 + wv * 512]);
      {  // B1: [32k][64e] -> S1[e][k], stride 40 (bank-spread), coalesced reads
        const int e = t & 63, kg = t >> 6;  // kg 0..3, 8 k each
        unsigned short u[8] __attribute__((aligned(16)));
#pragma unroll
        for (int i = 0; i < 8; ++i)
          u[i] = *(const unsigned short*)(B1 + (size_t)(k0 + kg * 8 + i) * cFD + e);
        *(uint4*)&S[10240 + e * 40 + kg * 8] = *(uint4*)u;
      }
      __syncthreads();
      short8 aq[2], ak[2], av[2], b0[2], b2[2], b1[2];
#pragma unroll
      for (int mi = 0; mi < 2; ++mi) {
        const int ro = (wm + mi * 16 + c16) * 32 + g * 8;
        aq[mi] = *(const short8*)&S[0 + ro];
        ak[mi] = *(const short8*)&S[2048 + ro];
        av[mi] = *(const short8*)&S[4096 + ro];
      }
#pragma unroll
      for (int ni = 0; ni < 2; ++ni) {
        const int ro = (wn + ni * 16 + c16) * 32 + g * 8;
        b0[ni] = *(const short8*)&S[6144 + ro];
        b2[ni] = *(const short8*)&S[8192 + ro];
        b1[ni] = *(const short8*)&S[10240 + (wn + ni * 16 + c16) * 40 + g * 8];
      }
#pragma unroll
      for (int mi = 0; mi < 2; ++mi)
#pragma unroll
        for (int ni = 0; ni < 2; ++ni) {
          acc[0][mi][ni] = __builtin_amdgcn_mfma_f32_16x16x32_bf16(aq[mi], b0[ni], acc[0][mi][ni], 0, 0, 0);
          acc[1][mi][ni] = __builtin_amdgcn_mfma_f32_16x16x32_bf16(aq[mi], b2[ni], acc[1][mi][ni], 0, 0, 0);
          acc[2][mi][ni] = __builtin_amdgcn_mfma_f32_16x16x32_bf16(ak[mi], b0[ni], acc[2][mi][ni], 0, 0, 0);
          acc[3][mi][ni] = __builtin_amdgcn_mfma_f32_16x16x32_bf16(ak[mi], b2[ni], acc[3][mi][ni], 0, 0, 0);
          acc[4][mi][ni] = __builtin_amdgcn_mfma_f32_16x16x32_bf16(av[mi], b1[ni], acc[4][mi][ni], 0, 0, 0);
        }
    }

    float l0v[2][4], l2v[2][4];
#pragma unroll
    for (int mi = 0; mi < 2; ++mi)
#pragma unroll
      for (int r = 0; r < 4; ++r) {
        const int row = by * 64 + wm + mi * 16 + g * 4 + r;
        l0v[mi][r] = lr0[bh * 2048 + chunk * 512 + row];
        l2v[mi][r] = lr2[bh * 2048 + chunk * 512 + row];
      }
#pragma unroll
    for (int mi = 0; mi < 2; ++mi)
#pragma unroll
      for (int ni = 0; ni < 2; ++ni)
#pragma unroll
        for (int r = 0; r < 4; ++r) {
          float hq1 = acc[0][mi][ni][r], hq2 = acc[1][mi][ni][r];
          float g1 = acc[2][mi][ni][r], g2 = acc[3][mi][ni][r], dh = acc[4][mi][ni][r];
          acc[0][mi][ni][r] = hq1 * sigmoidf_(hq1) * hq2;
          float sg = sigmoidf_(g1);
          float gate = g1 * sg;
          acc[1][mi][ni][r] = gate * g2;
          acc[2][mi][ni][r] = l0v[mi][r] * dh * g2 * (sg * (1.0f + g1 * (1.0f - sg)));
          acc[3][mi][ni][r] = l2v[mi][r] * dh * gate;
        }

    short* Ts = S;
    bf16* dst0 = hq + (size_t)bh * ZL_;
    bf16* dstT[3] = {trH + (size_t)bh * ZL_, trD1 + (size_t)bh * ZL_, trD2 + (size_t)bh * ZL_};
#pragma unroll
    for (int rd = 0; rd < 4; ++rd) {
      __syncthreads();
#pragma unroll
      for (int mi = 0; mi < 2; ++mi)
#pragma unroll
        for (int ni = 0; ni < 2; ++ni)
#pragma unroll
          for (int r = 0; r < 4; ++r) {
            const int row = wm + mi * 16 + g * 4 + r, col = wn + ni * 16 + c16;
            if (rd == 0) Ts[row * 66 + col] = (short)f2bu(acc[0][mi][ni][r]);
            else Ts[col * 66 + row] = (short)f2bu(acc[rd][mi][ni][r]);
          }
      __syncthreads();
      const int rr = t >> 2, cs = (t & 3) * 16;
      unsigned short u[16] __attribute__((aligned(16)));
#pragma unroll
      for (int i = 0; i < 16; ++i) u[i] = (unsigned short)Ts[rr * 66 + cs + i];
      bf16* dp = (rd == 0) ? (dst0 + (size_t)(by * 64 + rr) * cFD + bx * 64 + cs)
                           : (dstT[rd - 1] + (size_t)(bx * 64 + rr) * cFD + by * 64 + cs);
      *(uint4*)dp = *(uint4*)u;
      *(uint4*)(dp + 8) = *(uint4*)(u + 8);
    }
  } else if (id < 1536) {
    short* Ts = S;  // 64*72
    const int id2 = id - 512;
    const int var = id2 >> 9, bh = (id2 >> 6) & 7, by = (id2 >> 3) & 7, bx = id2 & 7;
    const bf16* src = ((var == 0) ? fk : fv) + choff + (size_t)bh * ZG_;
    bf16* dst = ((var == 0) ? trK : trV) + (size_t)bh * ZL_;
    {
      const int rr = t >> 2, cseg = (t & 3) * 16;
      if (var == 0) {
        stage16(src + (size_t)(by * 64 + rr) * cFD + bx * 64 + cseg, &Ts[rr * 72 + cseg]);
      } else {
        const float s = lr1[bh * 2048 + chunk * 512 + by * 64 + rr];
        const bf16* p = src + (size_t)(by * 64 + rr) * cFD + bx * 64 + cseg;
        unsigned short u[16] __attribute__((aligned(16)));
#pragma unroll
        for (int i = 0; i < 16; ++i) u[i] = f2bu(b2f(p[i]) * s);
        *(uint4*)&Ts[rr * 72 + cseg] = *(uint4*)u;
        *(uint4*)&Ts[rr * 72 + cseg + 8] = *(uint4*)(u + 8);
      }
    }
    __syncthreads();
    {
      const int oc_ = t >> 2, rseg = (t & 3) * 16;
      unsigned short u[16] __attribute__((aligned(16)));
#pragma unroll
      for (int i = 0; i < 16; ++i) u[i] = (unsigned short)Ts[(rseg + i) * 72 + oc_];
      bf16* dp = dst + (size_t)(bx * 64 + oc_) * cFD + by * 64 + rseg;
      *(uint4*)dp = *(uint4*)u;
      *(uint4*)(dp + 8) = *(uint4*)(u + 8);
    }
  } else {
    const int rrow = id - 1536;
    const int bh = rrow >> 9, rr = rrow & 511;
    const bf16* src = occPrev + ((size_t)bh * 512 + rr) * 512;
    float v0 = b2f(src[t]), v1 = b2f(src[t + 256]);
    float ss = v0 * v0 + v1 * v1;
    for (int d = 32; d; d >>= 1) ss += __shfl_down(ss, d);
    if ((t & 63) == 0) red[t >> 6] = ss;
    __syncthreads();
    const float rstd = rsqrtf((red[0] + red[1] + red[2] + red[3]) / cFD + 1e-6f);
    const int si = (chunk - 1) * 512 + rr;
    bf16* dst = y + ((size_t)((bh >> 2) * cS) + si) * cH + (bh & 3) * cFD;
    dst[t] = f2b(b2f(dst[t]) + v0 * rstd * tw[t]);
    dst[t + 256] = f2b(b2f(dst[t + 256]) + v1 * rstd * tw[t + 256]);
  }
}

// ---------------------------------------------------------------------------
// updna: ids 0..383 weight-update GEMMs; ids 384..895 oc = hq @ w1_cur^T.
// ---------------------------------------------------------------------------
__global__ __launch_bounds__(256) void k_updna(const bf16* __restrict__ trV, const bf16* __restrict__ trH,
                                               const bf16* __restrict__ trD1, const bf16* __restrict__ trD2,
                                               const bf16* __restrict__ trK,
                                               const bf16* __restrict__ hq, const bf16* __restrict__ w1bc,
                                               float* w0s, float* w1s, float* w2s,
                                               bf16* w0b, bf16* w1bn, bf16* w2b,
                                               bf16* __restrict__ occCur) {
  __shared__ short Sh[8192];
  const int id = blockIdx.x, t = threadIdx.x;
  if (id < 384) {
    short* As = Sh;
    short* Bs = Sh + 4096;
    const int z = id >> 4, tile = id & 15, by = tile >> 2, bx = tile & 3;
    const int var = z >> 3, bh = z & 7;
    const bf16 *Aa, *Bb;
    float* W;
    bf16* M;
    if (var == 0) {
      Aa = trV + (size_t)bh * ZL_ + (size_t)by * 128 * cFD;
      Bb = trH + (size_t)bh * ZL_ + (size_t)bx * 128 * cFD;
      W = w1s + (size_t)bh * ZL_; M = w1bn + (size_t)bh * ZL_;
    } else if (var == 1) {
      Aa = trD1 + (size_t)bh * ZL_ + (size_t)by * 128 * cFD;
      Bb = trK + (size_t)bh * ZL_ + (size_t)bx * 128 * cFD;
      W = w0s + (size_t)bh * ZL_; M = w0b + (size_t)bh * ZL_;
    } else {
      Aa = trD2 + (size_t)bh * ZL_ + (size_t)by * 128 * cFD;
      Bb = trK + (size_t)bh * ZL_ + (size_t)bx * 128 * cFD;
      W = w2s + (size_t)bh * ZL_; M = w2b + (size_t)bh * ZL_;
    }
    f32x4 acc[4][4];
    const f32x4 zero4 = {0.f, 0.f, 0.f, 0.f};
#pragma unroll
    for (int i = 0; i < 4; ++i)
#pragma unroll
      for (int j = 0; j < 4; ++j) acc[i][j] = zero4;
    mm_core<0, 0>(Aa, cFD, Bb, cFD, cFD, nullptr, As, Bs, acc);
    mm_store<true, true>(W, M, cFD, by * 128, bx * 128, acc);
  } else {
    const int id2 = id - 384;
    const int bh = id2 >> 6, tile = id2 & 63, by = tile >> 3, bx = tile & 7;
    const int lane = t & 63, g = lane >> 4, c16 = lane & 15, wv = t >> 6;
    const int wm = (wv >> 1) * 32, wn = (wv & 1) * 32;
    const bf16* Aa = hq + (size_t)bh * ZL_ + (size_t)(by * 64) * cFD;
    const bf16* Bb = w1bc + (size_t)bh * ZL_ + (size_t)(bx * 64) * cFD;
    short* As = Sh;
    short* Bs = Sh + 2048;
    f32x4 acc[2][2];
    const f32x4 zero4 = {0.f, 0.f, 0.f, 0.f};
#pragma unroll
    for (int i = 0; i < 2; ++i)
#pragma unroll
      for (int j = 0; j < 2; ++j) acc[i][j] = zero4;
    for (int k0 = 0; k0 < 512; k0 += 32) {
      __syncthreads();
      {
        const int srow = wv * 16 + (lane >> 2), scol = (lane & 3) * 8;
        gload16(Aa + (size_t)srow * cFD + k0 + scol, &As[wv * 512]);
        gload16(Bb + (size_t)srow * cFD + k0 + scol, &Bs[wv * 512]);
      }
      __syncthreads();
      short8 af[2], bfr[2];
#pragma unroll
      for (int mi = 0; mi < 2; ++mi) af[mi] = *(const short8*)&As[(wm + mi * 16 + c16) * 32 + g * 8];
#pragma unroll
      for (int ni = 0; ni < 2; ++ni) bfr[ni] = *(const short8*)&Bs[(wn + ni * 16 + c16) * 32 + g * 8];
#pragma unroll
      for (int mi = 0; mi < 2; ++mi)
#pragma unroll
        for (int ni = 0; ni < 2; ++ni)
          acc[mi][ni] = __builtin_amdgcn_mfma_f32_16x16x32_bf16(af[mi], bfr[ni], acc[mi][ni], 0, 0, 0);
    }
    bf16* C = occCur + (size_t)bh * ZL_;
#pragma unroll
    for (int mi = 0; mi < 2; ++mi)
#pragma unroll
      for (int ni = 0; ni < 2; ++ni) {
        const int col = bx * 64 + wn + ni * 16 + c16;
#pragma unroll
        for (int r = 0; r < 4; ++r) {
          const int row = by * 64 + wm + mi * 16 + g * 4 + r;
          C[(size_t)row * cFD + col] = f2b(acc[mi][ni][r]);
        }
      }
  }
}

// tail: ids 0..4095 final norm-add; 4096..6143 cvt o_proj_w -> opwb
__global__ __launch_bounds__(256) void k_normcvt(const bf16* __restrict__ occ,
                                                 const float* __restrict__ tw, bf16* __restrict__ y,
                                                 const float* __restrict__ opw, bf16* __restrict__ opwb,
                                                 int chunk) {
  __shared__ float red[4];
  const int id = blockIdx.x, t = threadIdx.x;
  if (id < 4096) {
    const int bh = id >> 9, rr = id & 511;
    const bf16* src = occ + ((size_t)bh * 512 + rr) * 512;
    float v0 = b2f(src[t]), v1 = b2f(src[t + 256]);
    float ss = v0 * v0 + v1 * v1;
    for (int d = 32; d; d >>= 1) ss += __shfl_down(ss, d);
    if ((t & 63) == 0) red[t >> 6] = ss;
    __syncthreads();
    const float rstd = rsqrtf((red[0] + red[1] + red[2] + red[3]) / cFD + 1e-6f);
    const int si = chunk * 512 + rr;
    bf16* dst = y + ((size_t)((bh >> 2) * cS) + si) * cH + (bh & 3) * cFD;
    dst[t] = f2b(b2f(dst[t]) + v0 * rstd * tw[t]);
    dst[t + 256] = f2b(b2f(dst[t + 256]) + v1 * rstd * tw[t + 256]);
  } else {
    const size_t i = ((size_t)(id - 4096) * 256 + t) * 8;
    float4 a = *(const float4*)(opw + i), b = *(const float4*)(opw + i + 4);
    unsigned short u[8] __attribute__((aligned(16)));
    u[0] = f2bu(a.x); u[1] = f2bu(a.y); u[2] = f2bu(a.z); u[3] = f2bu(a.w);
    u[4] = f2bu(b.x); u[5] = f2bu(b.y); u[6] = f2bu(b.z); u[7] = f2bu(b.w);
    *(uint4*)(opwb + i) = *(uint4*)u;
  }
}

// --------------------------- fp32 -> bf16 flat convert ----------------------
__global__ __launch_bounds__(256) void k_cvt(const float* __restrict__ src, bf16* __restrict__ dst) {
  const size_t i = ((size_t)blockIdx.x * 256 + threadIdx.x) * 8;
  float4 a = *(const float4*)(src + i), b = *(const float4*)(src + i + 4);
  unsigned short u[8] __attribute__((aligned(16)));
  u[0] = f2bu(a.x); u[1] = f2bu(a.y); u[2] = f2bu(a.z); u[3] = f2bu(a.w);
  u[4] = f2bu(b.x); u[5] = f2bu(b.y); u[6] = f2bu(b.z); u[7] = f2bu(b.w);
  *(uint4*)(dst + i) = *(uint4*)u;
}

// --- merged prep: cvt x, cvt qkv_w, winit (f4), rope table, lr projections --
__global__ __launch_bounds__(256) void k_prep(const float* __restrict__ x, const float* __restrict__ qkv_w,
                                              const float* __restrict__ w0, const float* __restrict__ w1,
                                              const float* __restrict__ w2,
                                              const float* __restrict__ lr_w, const float* __restrict__ lr_b,
                                              bf16* __restrict__ xb, bf16* __restrict__ qkvwb,
                                              float* __restrict__ w0s, float* __restrict__ w1s,
                                              float* __restrict__ w2s,
                                              float* __restrict__ ct, float* __restrict__ stb,
                                              float* lr0, float* lr1, float* lr2, float base) {
  const int id = blockIdx.x, t = threadIdx.x;
  if (id < 4096) {
    const size_t i = ((size_t)id * 256 + t) * 8;
    float4 a = *(const float4*)(x + i), b = *(const float4*)(x + i + 4);
    unsigned short u[8] __attribute__((aligned(16)));
    u[0] = f2bu(a.x); u[1] = f2bu(a.y); u[2] = f2bu(a.z); u[3] = f2bu(a.w);
    u[4] = f2bu(b.x); u[5] = f2bu(b.y); u[6] = f2bu(b.z); u[7] = f2bu(b.w);
    *(uint4*)(xb + i) = *(uint4*)u;
  } else if (id < 10240) {
    const size_t i = ((size_t)(id - 4096) * 256 + t) * 8;
    float4 a = *(const float4*)(qkv_w + i), b = *(const float4*)(qkv_w + i + 4);
    unsigned short u[8] __attribute__((aligned(16)));
    u[0] = f2bu(a.x); u[1] = f2bu(a.y); u[2] = f2bu(a.z); u[3] = f2bu(a.w);
    u[4] = f2bu(b.x); u[5] = f2bu(b.y); u[6] = f2bu(b.z); u[7] = f2bu(b.w);
    *(uint4*)(qkvwb + i) = *(uint4*)u;
  } else if (id < 16384) {
    const int sub = id - 10240;
    const int w = sub >> 11, blk = sub & 2047;
    const size_t i = ((size_t)blk * 256 + t) * 4;
    const int f = (int)((i >> 18) & 3);
    const size_t off = i & 262143;
    const float* src = (w == 0) ? w0 : (w == 1) ? w1 : w2;
    float* dst = (w == 0) ? w0s : (w == 1) ? w1s : w2s;
    *(float4*)(dst + i) = *(const float4*)(src + (size_t)f * 262144 + off);
  } else if (id < 16896) {
    const int gid = (id - 16384) * 256 + t;
    const int si = gid >> 6, jj = gid & 63;
    float inv = powf(500000.0f, -(float)jj / 64.0f);
    float ang = (float)si * inv;
    ct[(size_t)si * 64 + jj] = cosf(ang);
    stb[(size_t)si * 64 + jj] = sinf(ang);
  } else {
    const int token = id - 16896, b_ = token >> 11, si = token & 2047;
    const int wv = t >> 6, lane = t & 63;
    const float* xr = x + (size_t)token * cH;
#pragma unroll
    for (int jj = 0; jj < 3; ++jj) {
      const int j = wv * 3 + jj;
      const float* wr = lr_w + (size_t)j * cH;
      float s = 0.f;
      for (int k = lane; k < cH; k += 64) s += xr[k] * wr[k];
      for (int d = 32; d; d >>= 1) s += __shfl_down(s, d);
      if (lane == 0) {
        float v = s + lr_b[j] + base;
        float sp = (v > 15.f) ? v : log1pf(expf(v));
        const int tt = j >> 2, f = j & 3;
        float* dst = (tt == 0 ? lr0 : tt == 1 ? lr1 : lr2);
        dst[(size_t)(b_ * cNFW + f) * cS + si] = sp;
      }
    }
  }
}

// ------------------ rmsnorm q/k in place + rope -> qa/ka --------------------
__global__ __launch_bounds__(256) void k_normrope(bf16* __restrict__ qkvh,
                                                  const float* __restrict__ qnw, const float* __restrict__ knw,
                                                  const float* __restrict__ ct, const float* __restrict__ stb,
                                                  bf16* __restrict__ qa, bf16* __restrict__ ka) {
  const int token = blockIdx.x, b_ = token >> 11, si = token & 2047;
  const int t = threadIdx.x;
  __shared__ float buf[cH];
  __shared__ float red[4];
  bf16* base = qkvh + (size_t)token * 3 * cH;
  for (int pass = 0; pass < 2; ++pass) {
    __syncthreads();
    bf16* src = base + pass * cH;
    const float* nw = pass ? knw : qnw;
    float ss = 0.f;
    for (int i = t; i < cH; i += 256) {
      float v = b2f(src[i]);
      buf[i] = v;
      ss += v * v;
    }
    for (int d = 32; d; d >>= 1) ss += __shfl_down(ss, d);
    if ((t & 63) == 0) red[t >> 6] = ss;
    __syncthreads();
    const float rstd = rsqrtf((red[0] + red[1] + red[2] + red[3]) / cH + 1e-6f);
    for (int i = t; i < cH; i += 256) {
      float v = buf[i] * rstd * nw[i];
      buf[i] = v;
      src[i] = f2b(v);
    }
    __syncthreads();
    bf16* dst = pass ? ka : qa;
    const float scale = pass ? 1.f : cRSQRT_HD;
    const int hh = t >> 4, j0 = (t & 15) * 4;
    const float* cr = ct + (size_t)si * 64 + j0;
    const float* sr = stb + (size_t)si * 64 + j0;
    bf16* drow = dst + ((size_t)(b_ * cNH + hh) * cS + si) * cHD;
    unsigned short u1[4] __attribute__((aligned(8))), u2[4] __attribute__((aligned(8)));
#pragma unroll
    for (int i = 0; i < 4; ++i) {
      float x1 = buf[hh * cHD + j0 + i], x2 = buf[hh * cHD + 64 + j0 + i];
      u1[i] = f2bu((x1 * cr[i] - x2 * sr[i]) * scale);
      u2[i] = f2bu((x2 * cr[i] + x1 * sr[i]) * scale);
    }
    *(uint2*)(drow + j0) = *(uint2*)u1;
    *(uint2*)(drow + 64 + j0) = *(uint2*)u2;
  }
}

// ------------------ V transpose: qkvh v-part -> vt[b,h,d,s] -----------------
__global__ __launch_bounds__(256) void k_vtr(const bf16* __restrict__ qkvh, bf16* __restrict__ vt) {
  const int tile = blockIdx.x, h = blockIdx.y, b_ = blockIdx.z;
  __shared__ short Ts[64 * 136];
  const int t = threadIdx.x;
  {
    const int r = t >> 2, seg = (t & 3) * 32;
    const bf16* src = qkvh + ((size_t)(b_ * cS) + tile * 64 + r) * 3 * cH + 2 * cH + h * cHD + seg;
    stage16(src, &Ts[r * 136 + seg]);
    stage16(src + 16, &Ts[r * 136 + seg + 16]);
  }
  __syncthreads();
  {
    const int d = t >> 1, seg2 = (t & 1) * 32;
    unsigned short u[32] __attribute__((aligned(16)));
#pragma unroll
    for (int i = 0; i < 32; ++i) u[i] = (unsigned short)Ts[(seg2 + i) * 136 + d];
    bf16* dp = vt + ((size_t)(b_ * cNH + h) * cHD + d) * cS + tile * 64 + seg2;
    *(uint4*)dp = *(uint4*)u;
    *(uint4*)(dp + 8) = *(uint4*)(u + 8);
    *(uint4*)(dp + 16) = *(uint4*)(u + 16);
    *(uint4*)(dp + 24) = *(uint4*)(u + 24);
  }
}

// ------------------ fq/fk/fv from normalized qkvh ---------------------------
__global__ __launch_bounds__(256) void k_fqkv(const bf16* __restrict__ qkvh,
                                              const float* __restrict__ qk_scale,
                                              const float* __restrict__ qk_offset,
                                              bf16* fq, bf16* fk, bf16* fv) {
  const int token = blockIdx.x, b_ = token >> 11, si = token & 2047;
  const int t = threadIdx.x;
  const bf16* base = qkvh + (size_t)token * 3 * cH;
#pragma unroll
  for (int pass = 0; pass < 2; ++pass) {
    const bf16* src = base + pass * cH;
    bf16* fdst = pass ? fk : fq;
    const int head = t >> 6, lane = t & 63;
    float f[8];
    float ss2 = 0.f;
#pragma unroll
    for (int k = 0; k < 8; ++k) {
      const int idx = head * cFD + lane + k * 64;
      float v = b2f(src[idx]);
      float u = v * qk_scale[idx * 2 + pass] + qk_offset[idx * 2 + pass];
      float fv_ = u * sigmoidf_(u);
      f[k] = fv_;
      ss2 += fv_ * fv_;
    }
    for (int d = 1; d < 64; d <<= 1) ss2 += __shfl_xor(ss2, d);
    const float sc2 = rsqrtf(ss2 + 1e-12f);
    bf16* dst = fdst + ((size_t)(b_ * cNFW + head) * cS + si) * cFD;
#pragma unroll
    for (int k = 0; k < 8; ++k) dst[lane + k * 64] = f2b(f[k] * sc2);
  }
  const bf16* vr = base + 2 * cH;
  for (int i = t; i < cH; i += 256) {
    float v = b2f(vr[i]);
    fv[((size_t)(b_ * cNFW + (i >> 9)) * cS + si) * cFD + (i & 511)] = f2b(v * sigmoidf_(v));
  }
}

// -- attention: 128-row q blocks, 8 waves, paired tiles, XCD swizzle ---------
__global__ __launch_bounds__(512) void k_attn6(const bf16* __restrict__ qa, const bf16* __restrict__ ka,
                                               const bf16* __restrict__ vt, bf16* __restrict__ y) {
  const int id = blockIdx.x;            // 0..255
  const int xcd = id & 7;
  const int j = id >> 3;                // 0..31
  const int p = j & 7;                  // pair 0..7
  const int hb = (j >> 3) * 8 + xcd;    // 0..31
  const int h = hb & 15, b_ = hb >> 4;
  __shared__ short KsP[9216];           // K tile 64x136 (8704) + per-wave Ps (8x1152)
  __shared__ short Vts[128 * 72];
  const int t = threadIdx.x, lane = t & 63, g = lane >> 4, c16 = lane & 15, wv = t >> 6;
  const size_t hbq = (size_t)(b_ * cNH + h) * cS;
  const bf16* vb = vt + (size_t)(b_ * cNH + h) * (size_t)(cHD * cS);
  const int r = t >> 3, seg = (t & 7) * 16;     // K staging: 64 rows x 128 d
  const int dv = t >> 2, seg2 = (t & 3) * 16;   // V staging: 128 d x 64 kv
  const f32x4 zero4 = {0.f, 0.f, 0.f, 0.f};

  for (int half = 0; half < 2; ++half) {
    const int qt = half ? p : 15 - p;   // 128-row q tile
    const int q0 = qt * 128;
    const int nkt = 2 * qt + 2;
    short8 qf[4];
    {
      const bf16* qsrc = qa + (hbq + q0 + wv * 16 + c16) * cHD;
#pragma unroll
      for (int ks = 0; ks < 4; ++ks) qf[ks] = *(const short8*)(qsrc + ks * 32 + g * 8);
    }
    f32x4 o[8];
#pragma unroll
    for (int i = 0; i < 8; ++i) o[i] = zero4;
    float m[4], l[4];
#pragma unroll
    for (int rr = 0; rr < 4; ++rr) { m[rr] = -1e30f; l[rr] = 0.f; }

    uint4 kp0, kp1, vp0, vp1;
    {
      const bf16* ksrc = ka + (hbq + r) * cHD + seg;
      kp0 = *(const uint4*)ksrc; kp1 = *(const uint4*)(ksrc + 8);
      const bf16* vsrc = vb + (size_t)dv * cS + seg2;
      vp0 = *(const uint4*)vsrc; vp1 = *(const uint4*)(vsrc + 8);
    }

    for (int kt = 0; kt < nkt; ++kt) {
      __syncthreads();
      {
        short* kd = &KsP[r * 136 + seg];
        *(uint4*)kd = kp0; *(uint4*)(kd + 8) = kp1;
        short* vd = &Vts[dv * 72 + seg2];
        *(uint4*)vd = vp0; *(uint4*)(vd + 8) = vp1;
      }
      __syncthreads();
      if (kt + 1 < nkt) {
        const bf16* ksrc = ka + (hbq + (kt + 1) * 64 + r) * cHD + seg;
        kp0 = *(const uint4*)ksrc; kp1 = *(const uint4*)(ksrc + 8);
        const bf16* vsrc = vb + (size_t)dv * cS + (kt + 1) * 64 + seg2;
        vp0 = *(const uint4*)vsrc; vp1 = *(const uint4*)(vsrc + 8);
      } else if (half == 0) {
        const bf16* ksrc = ka + (hbq + r) * cHD + seg;
        kp0 = *(const uint4*)ksrc; kp1 = *(const uint4*)(ksrc + 8);
        const bf16* vsrc = vb + (size_t)dv * cS + seg2;
        vp0 = *(const uint4*)vsrc; vp1 = *(const uint4*)(vsrc + 8);
      }

      f32x4 s4[4];
#pragma unroll
      for (int ni = 0; ni < 4; ++ni) s4[ni] = zero4;
      __builtin_amdgcn_s_setprio(1);
#pragma unroll
      for (int ks = 0; ks < 4; ++ks) {
#pragma unroll
        for (int ni = 0; ni < 4; ++ni) {
          short8 bb = *(const short8*)&KsP[(ni * 16 + c16) * 136 + ks * 32 + g * 8];
          s4[ni] = __builtin_amdgcn_mfma_f32_16x16x32_bf16(qf[ks], bb, s4[ni], 0, 0, 0);
        }
      }
      __builtin_amdgcn_s_setprio(0);
      __syncthreads();   // all QK reads of KsP done before Ps overwrite
      if (kt * 64 + 64 > q0) {
#pragma unroll
        for (int ni = 0; ni < 4; ++ni) {
          const int kv = kt * 64 + ni * 16 + c16;
#pragma unroll
          for (int rr = 0; rr < 4; ++rr) {
            const int qr = q0 + wv * 16 + g * 4 + rr;
            if (kv > qr) s4[ni][rr] = -1e9f;
          }
        }
      }
      float mx[4];
#pragma unroll
      for (int rr = 0; rr < 4; ++rr)
        mx[rr] = fmaxf(fmaxf(s4[0][rr], s4[1][rr]), fmaxf(s4[2][rr], s4[3][rr]));
#pragma unroll
      for (int d = 1; d < 16; d <<= 1)
#pragma unroll
        for (int rr = 0; rr < 4; ++rr) mx[rr] = fmaxf(mx[rr], __shfl_xor(mx[rr], d));
      bool need = false;
#pragma unroll
      for (int rr = 0; rr < 4; ++rr) need |= (mx[rr] > m[rr] + 8.f);
      if (__any(need)) {
        float corr[4];
#pragma unroll
        for (int rr = 0; rr < 4; ++rr) {
          float mn = fmaxf(m[rr], mx[rr]);
          corr[rr] = __expf(m[rr] - mn);
          m[rr] = mn;
        }
#pragma unroll
        for (int rr = 0; rr < 4; ++rr) l[rr] *= corr[rr];
#pragma unroll
        for (int nf = 0; nf < 8; ++nf)
#pragma unroll
          for (int rr = 0; rr < 4; ++rr) o[nf][rr] *= corr[rr];
      }
      float psum[4] = {0.f, 0.f, 0.f, 0.f};
#pragma unroll
      for (int ni = 0; ni < 4; ++ni)
#pragma unroll
        for (int rr = 0; rr < 4; ++rr) {
          float pp = __expf(s4[ni][rr] - m[rr]);
          s4[ni][rr] = pp;
          psum[rr] += pp;
        }
#pragma unroll
      for (int d = 1; d < 16; d <<= 1)
#pragma unroll
        for (int rr = 0; rr < 4; ++rr) psum[rr] += __shfl_xor(psum[rr], d);
#pragma unroll
      for (int rr = 0; rr < 4; ++rr) l[rr] += psum[rr];
      short* pw = &KsP[wv * 1152];
#pragma unroll
      for (int ni = 0; ni < 4; ++ni)
#pragma unroll
        for (int rr = 0; rr < 4; ++rr)
          pw[(g * 4 + rr) * 72 + ni * 16 + c16] = (short)f2bu(s4[ni][rr]);
      // pw is wave-private: no barrier before reading it back
      __builtin_amdgcn_s_setprio(1);
#pragma unroll
      for (int ks2 = 0; ks2 < 2; ++ks2) {
        short8 a = *(const short8*)&pw[c16 * 72 + ks2 * 32 + g * 8];
#pragma unroll
        for (int nf = 0; nf < 8; ++nf) {
          short8 bb = *(const short8*)&Vts[(nf * 16 + c16) * 72 + ks2 * 32 + g * 8];
          o[nf] = __builtin_amdgcn_mfma_f32_16x16x32_bf16(a, bb, o[nf], 0, 0, 0);
        }
      }
      __builtin_amdgcn_s_setprio(0);
    }
    float inv[4];
#pragma unroll
    for (int rr = 0; rr < 4; ++rr) inv[rr] = 1.f / l[rr];
#pragma unroll
    for (int nf = 0; nf < 8; ++nf)
#pragma unroll
      for (int rr = 0; rr < 4; ++rr) {
        const size_t row = (size_t)(b_ * cS) + q0 + wv * 16 + g * 4 + rr;
        y[row * cH + h * cHD + nf * 16 + c16] = f2b(o[nf][rr] * inv[rr]);
      }
  }
}

}  // namespace

extern "C" void kernel_launch(void* const* d_in, const int* in_sizes, int n_in,
                              void* d_out, int out_size, void* d_ws, size_t ws_size,
                              hipStream_t stream) {
  (void)in_sizes; (void)n_in; (void)out_size; (void)ws_size;
  const float* x         = (const float*)d_in[0];
  const float* qkv_w     = (const float*)d_in[1];
  const float* q_norm_w  = (const float*)d_in[2];
  const float* k_norm_w  = (const float*)d_in[3];
  const float* qk_scale  = (const float*)d_in[4];
  const float* qk_offset = (const float*)d_in[5];
  const float* lr_w      = (const float*)d_in[6];
  const float* lr_b      = (const float*)d_in[7];
  const float* w0        = (const float*)d_in[8];
  const float* w1        = (const float*)d_in[9];
  const float* w2        = (const float*)d_in[10];
  const float* ttt_nw    = (const float*)d_in[11];
  const float* o_proj_w  = (const float*)d_in[12];
  float* out = (float*)d_out;

  // ---- workspace layout (bytes), total 143,851,520 (proven footprint) ----
  char* Wb = (char*)d_ws;
  bf16* qkvh = (bf16*)Wb;                 // phase-1 only (50.3MB)
  bf16* hq   = (bf16*)(Wb + 0UL);         // TTT phase buffers:
  bf16* trH  = (bf16*)(Wb + 4194304UL);
  bf16* trD1 = (bf16*)(Wb + 8388608UL);
  bf16* trD2 = (bf16*)(Wb + 12582912UL);
  bf16* trK  = (bf16*)(Wb + 16777216UL);
  bf16* trV  = (bf16*)(Wb + 20971520UL);
  bf16* occA = (bf16*)(Wb + 25165824UL);
  bf16* occB = (bf16*)(Wb + 29360128UL);
  bf16* w0b  = (bf16*)(Wb + 33554432UL);  // contiguous mirrors w0b,w1b0,w2b
  bf16* w1b0 = (bf16*)(Wb + 37748736UL);
  bf16* w2b  = (bf16*)(Wb + 41943040UL);
  bf16* w1b1 = (bf16*)(Wb + 46137344UL);  // w1 mirror ping-pong partner
  bf16* opwb = (bf16*)(Wb + 0UL);         // after TTT loop
  size_t off = 50331648UL;
  bf16* fqb = (bf16*)(Wb + off); off += 16777216UL;
  bf16* fkb = (bf16*)(Wb + off); off += 16777216UL;
  bf16* fvb = (bf16*)(Wb + off); off += 16777216UL;
  float* w0s = (float*)(Wb + off); off += 8388608UL;
  float* w1s = (float*)(Wb + off); off += 8388608UL;
  float* w2s = (float*)(Wb + off); off += 8388608UL;
  float* lr0 = (float*)(Wb + off); off += 65536UL;
  float* lr1 = (float*)(Wb + off); off += 65536UL;
  float* lr2 = (float*)(Wb + off); off += 65536UL;
  bf16* y = (bf16*)(Wb + off); off += 16777216UL;
  float* ct  = (float*)(Wb + off); off += 524288UL;
  float* stb = (float*)(Wb + off); off += 524288UL;
  bf16* xb = fqb;
  bf16* qkvwb = fkb;
  bf16* qa = fqb;
  bf16* ka = fkb;
  bf16* vt = fvb;
  bf16* w1m[2] = {w1b0, w1b1};
  bf16* occb[2] = {occA, occB};

  const float base_lr_inv = logf(expm1f(0.001f));
  dim3 blk(256);

  k_prep<<<dim3(20992), blk, 0, stream>>>(x, qkv_w, w0, w1, w2, lr_w, lr_b,
                                          xb, qkvwb, w0s, w1s, w2s, ct, stb,
                                          lr0, lr1, lr2, base_lr_inv);
  k_mm<bf16, 0><<<dim3(48, 32, 1), blk, 0, stream>>>(xb, 2048, 0, qkvwb, 2048, 0, qkvh, 6144, 0, 2048);
  k_normrope<<<dim3(4096), blk, 0, stream>>>(qkvh, q_norm_w, k_norm_w, ct, stb, qa, ka);
  k_vtr<<<dim3(32, 16, 2), blk, 0, stream>>>(qkvh, vt);
  k_attn6<<<dim3(256), dim3(512), 0, stream>>>(qa, ka, vt, y);
  k_fqkv<<<dim3(4096), blk, 0, stream>>>(qkvh, qk_scale, qk_offset, fqb, fkb, fvb);
  k_cvt<<<dim3(3072), blk, 0, stream>>>(w0s, w0b);  // contiguous 6.29M-elem mirror block

  for (int c = 0; c < 4; ++c) {
    const int g1 = (c == 0) ? 1536 : 5632;
    k_fuse1<<<dim3(g1), blk, 0, stream>>>(fqb, fkb, fvb, w0b, w1m[c & 1], w2b,
                                          hq, trH, trD1, trD2, trK, trV,
                                          lr0, lr1, lr2,
                                          (c == 0) ? occb[0] : occb[(c - 1) & 1],
                                          ttt_nw, y, c);
    k_updna<<<dim3(896), blk, 0, stream>>>(trV, trH, trD1, trD2, trK, hq, w1m[c & 1],
                                           w0s, w1s, w2s, w0b, w1m[(c + 1) & 1], w2b,
                                           occb[c & 1]);
  }
  k_normcvt<<<dim3(6144), blk, 0, stream>>>(occb[1], ttt_nw, y, o_proj_w, opwb, 3);
  k_mm<float, 0><<<dim3(16, 32, 1), blk, 0, stream>>>(y, 2048, 0, opwb, 2048, 0, out, 2048, 0, 2048);
}

// Round 13
// 714.021 us; speedup vs baseline: 7.2875x; 1.0171x over previous
//
#include <hip/hip_runtime.h>
#include <hip/hip_bf16.h>
#include <math.h>

using bf16 = __hip_bfloat16;

namespace {

constexpr int cH = 2048;
constexpr int cNH = 16;
constexpr int cHD = 128;
constexpr int cNFW = 4;
constexpr int cFD = 512;
constexpr int cS = 2048;
constexpr float cRSQRT_HD = 0.08838834764831845f;  // 1/sqrt(128)
constexpr long ZL_ = 262144;   // 512*512
constexpr long ZG_ = 1048576;  // 2048*512

typedef __attribute__((ext_vector_type(8))) short short8;
typedef __attribute__((ext_vector_type(4))) float f32x4;

__device__ __forceinline__ float sigmoidf_(float x) { return 1.0f / (1.0f + __expf(-x)); }
__device__ __forceinline__ float b2f(bf16 v) { return __bfloat162float(v); }
__device__ __forceinline__ bf16 f2b(float v) { return __float2bfloat16(v); }
__device__ __forceinline__ unsigned short f2bu(float f) {
  return __builtin_bit_cast(unsigned short, __float2bfloat16(f));
}
__device__ __forceinline__ float bu2f(unsigned u) { return __uint_as_float(u << 16); }

#if defined(__has_builtin)
#if __has_builtin(__builtin_amdgcn_global_load_lds)
#define HAVE_GLOAD 1
#endif
#endif

__device__ __forceinline__ void gload16(const bf16* g, short* ldsbase) {
#ifdef HAVE_GLOAD
  __builtin_amdgcn_global_load_lds((const __attribute__((address_space(1))) void*)g,
                                   (__attribute__((address_space(3))) void*)ldsbase, 16, 0, 0);
#else
  const int l = threadIdx.x & 63;
  *(uint4*)(ldsbase + l * 8) = *(const uint4*)g;
#endif
}

__device__ __forceinline__ void stage16(const bf16* src, short* dst) {
  *(uint4*)dst = *(const uint4*)src;
  *(uint4*)(dst + 8) = *(const uint4*)(src + 8);
}

__device__ __forceinline__ void store1(float* p, float v) { *p = v; }
__device__ __forceinline__ void store1(bf16* p, float v) { *p = f2b(v); }

// ---------------------------------------------------------------------------
// MFMA NT GEMM core: 128x128 tile, 4 waves (2x2 of 64x64), templated BK.
// A [M][K], B [N][K] bf16 row-major; global_load_lds staging, linear LDS.
// ---------------------------------------------------------------------------
template <int BK>
__device__ __forceinline__ void mm_core(const bf16* __restrict__ Ab, int lda,
                                        const bf16* __restrict__ Bb, int ldb, int K,
                                        short* As, short* Bs, f32x4 acc[4][4]) {
  const int t = threadIdx.x, lane = t & 63, g = lane >> 4, c16 = lane & 15;
  const int wv = t >> 6, wm = (wv >> 1) * 64, wn = (wv & 1) * 64;
  for (int k0 = 0; k0 < K; k0 += BK) {
    __syncthreads();
    if constexpr (BK == 32) {
      const int ch = wv * 2;
      const bf16* ga = Ab + (size_t)(ch * 16 + (lane >> 2)) * lda + k0 + (lane & 3) * 8;
      gload16(ga, &As[ch * 512]);
      gload16(ga + (size_t)16 * lda, &As[ch * 512 + 512]);
      const bf16* gb = Bb + (size_t)(ch * 16 + (lane >> 2)) * ldb + k0 + (lane & 3) * 8;
      gload16(gb, &Bs[ch * 512]);
      gload16(gb + (size_t)16 * ldb, &Bs[ch * 512 + 512]);
    } else {
#pragma unroll
      for (int i = 0; i < 4; ++i) {
        const int rbase = wv * 32 + i * 8;
        gload16(Ab + (size_t)(rbase + (lane >> 3)) * lda + k0 + (lane & 7) * 8, &As[rbase * 64]);
        gload16(Bb + (size_t)(rbase + (lane >> 3)) * ldb + k0 + (lane & 7) * 8, &Bs[rbase * 64]);
      }
    }
    __syncthreads();
    if constexpr (BK == 32) {
      short8 af[4], bfr[4];
#pragma unroll
      for (int mi = 0; mi < 4; ++mi) af[mi] = *(const short8*)&As[(wm + mi * 16 + c16) * 32 + g * 8];
#pragma unroll
      for (int ni = 0; ni < 4; ++ni) bfr[ni] = *(const short8*)&Bs[(wn + ni * 16 + c16) * 32 + g * 8];
#pragma unroll
      for (int mi = 0; mi < 4; ++mi)
#pragma unroll
        for (int ni = 0; ni < 4; ++ni)
          acc[mi][ni] = __builtin_amdgcn_mfma_f32_16x16x32_bf16(af[mi], bfr[ni], acc[mi][ni], 0, 0, 0);
    } else {
#pragma unroll
      for (int ks = 0; ks < 2; ++ks) {
        short8 af[4], bfr[4];
#pragma unroll
        for (int mi = 0; mi < 4; ++mi)
          af[mi] = *(const short8*)&As[(wm + mi * 16 + c16) * 64 + ks * 32 + g * 8];
#pragma unroll
        for (int ni = 0; ni < 4; ++ni)
          bfr[ni] = *(const short8*)&Bs[(wn + ni * 16 + c16) * 64 + ks * 32 + g * 8];
#pragma unroll
        for (int mi = 0; mi < 4; ++mi)
#pragma unroll
          for (int ni = 0; ni < 4; ++ni)
            acc[mi][ni] = __builtin_amdgcn_mfma_f32_16x16x32_bf16(af[mi], bfr[ni], acc[mi][ni], 0, 0, 0);
      }
    }
  }
}

template <bool ACC, bool MIR, typename TC>
__device__ __forceinline__ void mm_store(TC* Cb, bf16* Mb, int ldc, int rb, int cb, f32x4 acc[4][4]) {
  const int t = threadIdx.x, lane = t & 63, g = lane >> 4, c16 = lane & 15;
  const int wv = t >> 6, wm = (wv >> 1) * 64, wn = (wv & 1) * 64;
  const int rbase = rb + wm, cbase = cb + wn;
#pragma unroll
  for (int mi = 0; mi < 4; ++mi)
#pragma unroll
    for (int ni = 0; ni < 4; ++ni) {
      const int col = cbase + ni * 16 + c16;
#pragma unroll
      for (int r = 0; r < 4; ++r) {
        const int row = rbase + mi * 16 + g * 4 + r;
        TC* cp = Cb + (size_t)row * ldc + col;
        if constexpr (ACC) {
          float nv = *cp + acc[mi][ni][r];
          *cp = nv;
          if constexpr (MIR) Mb[(size_t)row * ldc + col] = f2b(nv);
        } else {
          store1(cp, acc[mi][ni][r]);
        }
      }
    }
}

template <typename TC>
__global__ __launch_bounds__(256) void k_mm(const bf16* __restrict__ A, int lda,
                                            const bf16* __restrict__ B, int ldb,
                                            TC* __restrict__ C, int ldc, int K) {
  __shared__ short As[128 * 64];
  __shared__ short Bs[128 * 64];
  const bf16* Ab = A + (size_t)blockIdx.y * 128 * lda;
  const bf16* Bb = B + (size_t)blockIdx.x * 128 * ldb;
  f32x4 acc[4][4];
  const f32x4 zero4 = {0.f, 0.f, 0.f, 0.f};
#pragma unroll
  for (int i = 0; i < 4; ++i)
#pragma unroll
    for (int j = 0; j < 4; ++j) acc[i][j] = zero4;
  mm_core<64>(Ab, lda, Bb, ldb, K, As, Bs, acc);
  mm_store<false, false>(C, (bf16*)nullptr, ldc, blockIdx.y * 128, blockIdx.x * 128, acc);
}

// ---------------------------------------------------------------------------
// Fused stage1 + gates + (trK,trV transposes) + (prev-chunk norm-add).
// B1 operand is the transposed w1 mirror (w1t) -> pure NT gload staging.
// ---------------------------------------------------------------------------
__global__ __launch_bounds__(256) void k_fuse1(const bf16* __restrict__ fq, const bf16* __restrict__ fk,
                                               const bf16* __restrict__ fv,
                                               const bf16* __restrict__ w0b, const bf16* __restrict__ w1t,
                                               const bf16* __restrict__ w2b,
                                               bf16* __restrict__ hq, bf16* __restrict__ trH,
                                               bf16* __restrict__ trD1, bf16* __restrict__ trD2,
                                               bf16* __restrict__ trK, bf16* __restrict__ trV,
                                               const float* __restrict__ lr0, const float* __restrict__ lr1,
                                               const float* __restrict__ lr2,
                                               const bf16* __restrict__ occ,
                                               const float* __restrict__ tw, bf16* __restrict__ y,
                                               int chunk) {
  __shared__ short S[12288];
  __shared__ float red[4];
  const int id = blockIdx.x, t = threadIdx.x;
  const size_t choff = (size_t)chunk * 262144;

  if (id < 512) {
    const int bh = id >> 6, tile = id & 63, by = tile >> 3, bx = tile & 7;
    const int lane = t & 63, g = lane >> 4, c16 = lane & 15, wv = t >> 6;
    const int wm = (wv >> 1) * 32, wn = (wv & 1) * 32;
    const bf16* Aq = fq + (size_t)bh * ZG_ + choff + (size_t)(by * 64) * cFD;
    const bf16* Ak = fk + (size_t)bh * ZG_ + choff + (size_t)(by * 64) * cFD;
    const bf16* Av = fv + (size_t)bh * ZG_ + choff + (size_t)(by * 64) * cFD;
    const bf16* B0 = w0b + (size_t)bh * ZL_ + (size_t)(bx * 64) * cFD;
    const bf16* B2 = w2b + (size_t)bh * ZL_ + (size_t)(bx * 64) * cFD;
    const bf16* B1 = w1t + (size_t)bh * ZL_ + (size_t)(bx * 64) * cFD;  // [e][d]

    f32x4 acc[5][2][2];
    const f32x4 zero4 = {0.f, 0.f, 0.f, 0.f};
#pragma unroll
    for (int v = 0; v < 5; ++v)
#pragma unroll
      for (int i = 0; i < 2; ++i)
#pragma unroll
        for (int j = 0; j < 2; ++j) acc[v][i][j] = zero4;

    const int srow = wv * 16 + (lane >> 2), scol = (lane & 3) * 8;
    for (int k0 = 0; k0 < 512; k0 += 32) {
      __syncthreads();
      gload16(Aq + (size_t)srow * cFD + k0 + scol, &S[0 + wv * 512]);
      gload16(Ak + (size_t)srow * cFD + k0 + scol, &S[2048 + wv * 512]);
      gload16(Av + (size_t)srow * cFD + k0 + scol, &S[4096 + wv * 512]);
      gload16(B0 + (size_t)srow * cFD + k0 + scol, &S[6144 + wv * 512]);
      gload16(B2 + (size_t)srow * cFD + k0 + scol, &S[8192 + wv * 512]);
      gload16(B1 + (size_t)srow * cFD + k0 + scol, &S[10240 + wv * 512]);
      __syncthreads();
      short8 aq[2], ak[2], av[2], b0[2], b2[2], b1[2];
#pragma unroll
      for (int mi = 0; mi < 2; ++mi) {
        const int ro = (wm + mi * 16 + c16) * 32 + g * 8;
        aq[mi] = *(const short8*)&S[0 + ro];
        ak[mi] = *(const short8*)&S[2048 + ro];
        av[mi] = *(const short8*)&S[4096 + ro];
      }
#pragma unroll
      for (int ni = 0; ni < 2; ++ni) {
        const int ro = (wn + ni * 16 + c16) * 32 + g * 8;
        b0[ni] = *(const short8*)&S[6144 + ro];
        b2[ni] = *(const short8*)&S[8192 + ro];
        b1[ni] = *(const short8*)&S[10240 + ro];
      }
#pragma unroll
      for (int mi = 0; mi < 2; ++mi)
#pragma unroll
        for (int ni = 0; ni < 2; ++ni) {
          acc[0][mi][ni] = __builtin_amdgcn_mfma_f32_16x16x32_bf16(aq[mi], b0[ni], acc[0][mi][ni], 0, 0, 0);
          acc[1][mi][ni] = __builtin_amdgcn_mfma_f32_16x16x32_bf16(aq[mi], b2[ni], acc[1][mi][ni], 0, 0, 0);
          acc[2][mi][ni] = __builtin_amdgcn_mfma_f32_16x16x32_bf16(ak[mi], b0[ni], acc[2][mi][ni], 0, 0, 0);
          acc[3][mi][ni] = __builtin_amdgcn_mfma_f32_16x16x32_bf16(ak[mi], b2[ni], acc[3][mi][ni], 0, 0, 0);
          acc[4][mi][ni] = __builtin_amdgcn_mfma_f32_16x16x32_bf16(av[mi], b1[ni], acc[4][mi][ni], 0, 0, 0);
        }
    }

    float l0v[2][4], l2v[2][4];
#pragma unroll
    for (int mi = 0; mi < 2; ++mi)
#pragma unroll
      for (int r = 0; r < 4; ++r) {
        const int row = by * 64 + wm + mi * 16 + g * 4 + r;
        l0v[mi][r] = lr0[bh * 2048 + chunk * 512 + row];
        l2v[mi][r] = lr2[bh * 2048 + chunk * 512 + row];
      }
#pragma unroll
    for (int mi = 0; mi < 2; ++mi)
#pragma unroll
      for (int ni = 0; ni < 2; ++ni)
#pragma unroll
        for (int r = 0; r < 4; ++r) {
          float hq1 = acc[0][mi][ni][r], hq2 = acc[1][mi][ni][r];
          float g1 = acc[2][mi][ni][r], g2 = acc[3][mi][ni][r], dh = acc[4][mi][ni][r];
          acc[0][mi][ni][r] = hq1 * sigmoidf_(hq1) * hq2;
          float sg = sigmoidf_(g1);
          float gate = g1 * sg;
          acc[1][mi][ni][r] = gate * g2;
          acc[2][mi][ni][r] = l0v[mi][r] * dh * g2 * (sg * (1.0f + g1 * (1.0f - sg)));
          acc[3][mi][ni][r] = l2v[mi][r] * dh * gate;
        }

    short* Ts = S;
    bf16* dst0 = hq + (size_t)bh * ZL_;
    bf16* dstT[3] = {trH + (size_t)bh * ZL_, trD1 + (size_t)bh * ZL_, trD2 + (size_t)bh * ZL_};
#pragma unroll
    for (int rd = 0; rd < 4; ++rd) {
      __syncthreads();
#pragma unroll
      for (int mi = 0; mi < 2; ++mi)
#pragma unroll
        for (int ni = 0; ni < 2; ++ni)
#pragma unroll
          for (int r = 0; r < 4; ++r) {
            const int row = wm + mi * 16 + g * 4 + r, col = wn + ni * 16 + c16;
            if (rd == 0) Ts[row * 66 + col] = (short)f2bu(acc[0][mi][ni][r]);
            else Ts[col * 66 + row] = (short)f2bu(acc[rd][mi][ni][r]);
          }
      __syncthreads();
      const int rr = t >> 2, cs = (t & 3) * 16;
      unsigned short u[16] __attribute__((aligned(16)));
#pragma unroll
      for (int i = 0; i < 16; ++i) u[i] = (unsigned short)Ts[rr * 66 + cs + i];
      bf16* dp = (rd == 0) ? (dst0 + (size_t)(by * 64 + rr) * cFD + bx * 64 + cs)
                           : (dstT[rd - 1] + (size_t)(bx * 64 + rr) * cFD + by * 64 + cs);
      *(uint4*)dp = *(uint4*)u;
      *(uint4*)(dp + 8) = *(uint4*)(u + 8);
    }
  } else if (id < 1536) {
    short* Ts = S;  // 64*72
    const int id2 = id - 512;
    const int var = id2 >> 9, bh = (id2 >> 6) & 7, by = (id2 >> 3) & 7, bx = id2 & 7;
    const bf16* src = ((var == 0) ? fk : fv) + choff + (size_t)bh * ZG_;
    bf16* dst = ((var == 0) ? trK : trV) + (size_t)bh * ZL_;
    {
      const int rr = t >> 2, cseg = (t & 3) * 16;
      if (var == 0) {
        stage16(src + (size_t)(by * 64 + rr) * cFD + bx * 64 + cseg, &Ts[rr * 72 + cseg]);
      } else {
        const float s = lr1[bh * 2048 + chunk * 512 + by * 64 + rr];
        const bf16* p = src + (size_t)(by * 64 + rr) * cFD + bx * 64 + cseg;
        unsigned short u[16] __attribute__((aligned(16)));
#pragma unroll
        for (int i = 0; i < 16; ++i) u[i] = f2bu(b2f(p[i]) * s);
        *(uint4*)&Ts[rr * 72 + cseg] = *(uint4*)u;
        *(uint4*)&Ts[rr * 72 + cseg + 8] = *(uint4*)(u + 8);
      }
    }
    __syncthreads();
    {
      const int oc_ = t >> 2, rseg = (t & 3) * 16;
      unsigned short u[16] __attribute__((aligned(16)));
#pragma unroll
      for (int i = 0; i < 16; ++i) u[i] = (unsigned short)Ts[(rseg + i) * 72 + oc_];
      bf16* dp = dst + (size_t)(bx * 64 + oc_) * cFD + by * 64 + rseg;
      *(uint4*)dp = *(uint4*)u;
      *(uint4*)(dp + 8) = *(uint4*)(u + 8);
    }
  } else {
    const int rrow = id - 1536;
    const int bh = rrow >> 9, rr = rrow & 511;
    const bf16* src = occ + ((size_t)bh * 512 + rr) * 512;
    float v0 = b2f(src[t]), v1 = b2f(src[t + 256]);
    float ss = v0 * v0 + v1 * v1;
    for (int d = 32; d; d >>= 1) ss += __shfl_down(ss, d);
    if ((t & 63) == 0) red[t >> 6] = ss;
    __syncthreads();
    const float rstd = rsqrtf((red[0] + red[1] + red[2] + red[3]) / cFD + 1e-6f);
    const int si = (chunk - 1) * 512 + rr;
    bf16* dst = y + ((size_t)((bh >> 2) * cS) + si) * cH + (bh & 3) * cFD;
    dst[t] = f2b(b2f(dst[t]) + v0 * rstd * tw[t]);
    dst[t + 256] = f2b(b2f(dst[t + 256]) + v1 * rstd * tw[t + 256]);
  }
}

// ---------------------------------------------------------------------------
// updna: ids 0..383 weight-update GEMMs (var0 also writes w1t transposed);
//        ids 384..511 oc = hq @ w1_cur^T (128^2 tiles).
// ---------------------------------------------------------------------------
__global__ __launch_bounds__(256) void k_updna(const bf16* __restrict__ trV, const bf16* __restrict__ trH,
                                               const bf16* __restrict__ trD1, const bf16* __restrict__ trD2,
                                               const bf16* __restrict__ trK,
                                               const bf16* __restrict__ hq, const bf16* __restrict__ w1bc,
                                               float* w0s, float* w1s, float* w2s,
                                               bf16* w0b, bf16* w1bn, bf16* w2b, bf16* w1t,
                                               bf16* __restrict__ occ) {
  __shared__ short Sh[8704];
  const int id = blockIdx.x, t = threadIdx.x;
  const int lane = t & 63, g = lane >> 4, c16 = lane & 15, wv = t >> 6;
  if (id < 384) {
    short* As = Sh;
    short* Bs = Sh + 4096;
    const int z = id >> 4, tile = id & 15, by = tile >> 2, bx = tile & 3;
    const int var = z >> 3, bh = z & 7;
    const bf16 *Aa, *Bb;
    if (var == 0) {
      Aa = trV + (size_t)bh * ZL_ + (size_t)by * 128 * cFD;
      Bb = trH + (size_t)bh * ZL_ + (size_t)bx * 128 * cFD;
    } else if (var == 1) {
      Aa = trD1 + (size_t)bh * ZL_ + (size_t)by * 128 * cFD;
      Bb = trK + (size_t)bh * ZL_ + (size_t)bx * 128 * cFD;
    } else {
      Aa = trD2 + (size_t)bh * ZL_ + (size_t)by * 128 * cFD;
      Bb = trK + (size_t)bh * ZL_ + (size_t)bx * 128 * cFD;
    }
    f32x4 acc[4][4];
    const f32x4 zero4 = {0.f, 0.f, 0.f, 0.f};
#pragma unroll
    for (int i = 0; i < 4; ++i)
#pragma unroll
      for (int j = 0; j < 4; ++j) acc[i][j] = zero4;
    mm_core<32>(Aa, cFD, Bb, cFD, cFD, As, Bs, acc);
    if (var == 1) {
      mm_store<true, true>(w0s + (size_t)bh * ZL_, w0b + (size_t)bh * ZL_, cFD, by * 128, bx * 128, acc);
    } else if (var == 2) {
      mm_store<true, true>(w2s + (size_t)bh * ZL_, w2b + (size_t)bh * ZL_, cFD, by * 128, bx * 128, acc);
    } else {
      // w1: update master + row-major mirror, keep nv in acc, then transpose to w1t
      float* W = w1s + (size_t)bh * ZL_;
      bf16* M = w1bn + (size_t)bh * ZL_;
      const int wm = (wv >> 1) * 64, wn = (wv & 1) * 64;
#pragma unroll
      for (int mi = 0; mi < 4; ++mi)
#pragma unroll
        for (int ni = 0; ni < 4; ++ni) {
          const int col = bx * 128 + wn + ni * 16 + c16;
#pragma unroll
          for (int r = 0; r < 4; ++r) {
            const int row = by * 128 + wm + mi * 16 + g * 4 + r;
            float nv = W[(size_t)row * cFD + col] + acc[mi][ni][r];
            W[(size_t)row * cFD + col] = nv;
            M[(size_t)row * cFD + col] = f2b(nv);
            acc[mi][ni][r] = nv;
          }
        }
      bf16* T = w1t + (size_t)bh * ZL_;
      short* Ts = Sh;  // 64 cc x 136
#pragma unroll
      for (int rd = 0; rd < 2; ++rd) {
        __syncthreads();
        if (wn == rd * 64) {
#pragma unroll
          for (int mi = 0; mi < 4; ++mi)
#pragma unroll
            for (int ni = 0; ni < 4; ++ni) {
              const int cc = ni * 16 + c16;
              unsigned short u[4] __attribute__((aligned(8)));
#pragma unroll
              for (int r = 0; r < 4; ++r) u[r] = f2bu(acc[mi][ni][r]);
              *(uint2*)&Ts[cc * 136 + wm + mi * 16 + g * 4] = *(uint2*)u;
            }
        }
        __syncthreads();
        const int cc = t >> 2, seg = (t & 3) * 32;
        unsigned short u[32] __attribute__((aligned(16)));
#pragma unroll
        for (int i = 0; i < 32; ++i) u[i] = (unsigned short)Ts[cc * 136 + seg + i];
        bf16* dp = T + (size_t)(bx * 128 + rd * 64 + cc) * cFD + by * 128 + seg;
        *(uint4*)dp = *(uint4*)u;
        *(uint4*)(dp + 8) = *(uint4*)(u + 8);
        *(uint4*)(dp + 16) = *(uint4*)(u + 16);
        *(uint4*)(dp + 24) = *(uint4*)(u + 24);
      }
    }
  } else {
    // oc: 128x128 tiles
    short* As = Sh;
    short* Bs = Sh + 4096;
    const int id2 = id - 384;
    const int bh = id2 >> 4, tile = id2 & 15, by = tile >> 2, bx = tile & 3;
    const bf16* Aa = hq + (size_t)bh * ZL_ + (size_t)by * 128 * cFD;
    const bf16* Bb = w1bc + (size_t)bh * ZL_ + (size_t)bx * 128 * cFD;
    f32x4 acc[4][4];
    const f32x4 zero4 = {0.f, 0.f, 0.f, 0.f};
#pragma unroll
    for (int i = 0; i < 4; ++i)
#pragma unroll
      for (int j = 0; j < 4; ++j) acc[i][j] = zero4;
    mm_core<32>(Aa, cFD, Bb, cFD, cFD, As, Bs, acc);
    mm_store<false, false>(occ + (size_t)bh * ZL_, (bf16*)nullptr, cFD, by * 128, bx * 128, acc);
  }
}

// tail: ids 0..4095 final norm-add; 4096..6143 cvt o_proj_w -> opwb
__global__ __launch_bounds__(256) void k_normcvt(const bf16* __restrict__ occ,
                                                 const float* __restrict__ tw, bf16* __restrict__ y,
                                                 const float* __restrict__ opw, bf16* __restrict__ opwb,
                                                 int chunk) {
  __shared__ float red[4];
  const int id = blockIdx.x, t = threadIdx.x;
  if (id < 4096) {
    const int bh = id >> 9, rr = id & 511;
    const bf16* src = occ + ((size_t)bh * 512 + rr) * 512;
    float v0 = b2f(src[t]), v1 = b2f(src[t + 256]);
    float ss = v0 * v0 + v1 * v1;
    for (int d = 32; d; d >>= 1) ss += __shfl_down(ss, d);
    if ((t & 63) == 0) red[t >> 6] = ss;
    __syncthreads();
    const float rstd = rsqrtf((red[0] + red[1] + red[2] + red[3]) / cFD + 1e-6f);
    const int si = chunk * 512 + rr;
    bf16* dst = y + ((size_t)((bh >> 2) * cS) + si) * cH + (bh & 3) * cFD;
    dst[t] = f2b(b2f(dst[t]) + v0 * rstd * tw[t]);
    dst[t + 256] = f2b(b2f(dst[t + 256]) + v1 * rstd * tw[t + 256]);
  } else {
    const size_t i = ((size_t)(id - 4096) * 256 + t) * 8;
    float4 a = *(const float4*)(opw + i), b = *(const float4*)(opw + i + 4);
    unsigned short u[8] __attribute__((aligned(16)));
    u[0] = f2bu(a.x); u[1] = f2bu(a.y); u[2] = f2bu(a.z); u[3] = f2bu(a.w);
    u[4] = f2bu(b.x); u[5] = f2bu(b.y); u[6] = f2bu(b.z); u[7] = f2bu(b.w);
    *(uint4*)(opwb + i) = *(uint4*)u;
  }
}

// --- merged prep: cvt x, cvt qkv_w, winit (f4), rope table, lr projections --
__global__ __launch_bounds__(256) void k_prep(const float* __restrict__ x, const float* __restrict__ qkv_w,
                                              const float* __restrict__ w0, const float* __restrict__ w1,
                                              const float* __restrict__ w2,
                                              const float* __restrict__ lr_w, const float* __restrict__ lr_b,
                                              bf16* __restrict__ xb, bf16* __restrict__ qkvwb,
                                              float* __restrict__ w0s, float* __restrict__ w1s,
                                              float* __restrict__ w2s,
                                              float* __restrict__ ct, float* __restrict__ stb,
                                              float* lr0, float* lr1, float* lr2, float base) {
  const int id = blockIdx.x, t = threadIdx.x;
  if (id < 4096) {
    const size_t i = ((size_t)id * 256 + t) * 8;
    float4 a = *(const float4*)(x + i), b = *(const float4*)(x + i + 4);
    unsigned short u[8] __attribute__((aligned(16)));
    u[0] = f2bu(a.x); u[1] = f2bu(a.y); u[2] = f2bu(a.z); u[3] = f2bu(a.w);
    u[4] = f2bu(b.x); u[5] = f2bu(b.y); u[6] = f2bu(b.z); u[7] = f2bu(b.w);
    *(uint4*)(xb + i) = *(uint4*)u;
  } else if (id < 10240) {
    const size_t i = ((size_t)(id - 4096) * 256 + t) * 8;
    float4 a = *(const float4*)(qkv_w + i), b = *(const float4*)(qkv_w + i + 4);
    unsigned short u[8] __attribute__((aligned(16)));
    u[0] = f2bu(a.x); u[1] = f2bu(a.y); u[2] = f2bu(a.z); u[3] = f2bu(a.w);
    u[4] = f2bu(b.x); u[5] = f2bu(b.y); u[6] = f2bu(b.z); u[7] = f2bu(b.w);
    *(uint4*)(qkvwb + i) = *(uint4*)u;
  } else if (id < 16384) {
    const int sub = id - 10240;
    const int w = sub >> 11, blk = sub & 2047;
    const size_t i = ((size_t)blk * 256 + t) * 4;
    const int f = (int)((i >> 18) & 3);
    const size_t off = i & 262143;
    const float* src = (w == 0) ? w0 : (w == 1) ? w1 : w2;
    float* dst = (w == 0) ? w0s : (w == 1) ? w1s : w2s;
    *(float4*)(dst + i) = *(const float4*)(src + (size_t)f * 262144 + off);
  } else if (id < 16896) {
    const int gid = (id - 16384) * 256 + t;
    const int si = gid >> 6, jj = gid & 63;
    float inv = powf(500000.0f, -(float)jj / 64.0f);
    float ang = (float)si * inv;
    ct[(size_t)si * 64 + jj] = cosf(ang);
    stb[(size_t)si * 64 + jj] = sinf(ang);
  } else {
    const int token = id - 16896, b_ = token >> 11, si = token & 2047;
    const int wv = t >> 6, lane = t & 63;
    const float* xr = x + (size_t)token * cH;
#pragma unroll
    for (int jj = 0; jj < 3; ++jj) {
      const int j = wv * 3 + jj;
      const float* wr = lr_w + (size_t)j * cH;
      float s = 0.f;
      for (int k = lane; k < cH; k += 64) s += xr[k] * wr[k];
      for (int d = 32; d; d >>= 1) s += __shfl_down(s, d);
      if (lane == 0) {
        float v = s + lr_b[j] + base;
        float sp = (v > 15.f) ? v : log1pf(expf(v));
        const int tt = j >> 2, f = j & 3;
        float* dst = (tt == 0 ? lr0 : tt == 1 ? lr1 : lr2);
        dst[(size_t)(b_ * cNFW + f) * cS + si] = sp;
      }
    }
  }
}

// --- k_post2: ids 0..4095 rmsnorm+rope (qkvh writeback); 4096..5119 vtr -----
__global__ __launch_bounds__(256) void k_post2(bf16* __restrict__ qkvh,
                                               const float* __restrict__ qnw, const float* __restrict__ knw,
                                               const float* __restrict__ ct, const float* __restrict__ stb,
                                               bf16* __restrict__ qa, bf16* __restrict__ ka,
                                               bf16* __restrict__ vt) {
  __shared__ short smem[8704];
  __shared__ float red[4];
  const int id = blockIdx.x, t = threadIdx.x;
  if (id < 4096) {
    float* buf = (float*)smem;
    const int token = id, b_ = token >> 11, si = token & 2047;
    bf16* base = qkvh + (size_t)token * 3 * cH;
    for (int pass = 0; pass < 2; ++pass) {
      __syncthreads();
      bf16* src = base + pass * cH;
      const float* nw = pass ? knw : qnw;
      float ss = 0.f;
      for (int i = t; i < cH; i += 256) {
        float v = b2f(src[i]);
        buf[i] = v;
        ss += v * v;
      }
      for (int d = 32; d; d >>= 1) ss += __shfl_down(ss, d);
      if ((t & 63) == 0) red[t >> 6] = ss;
      __syncthreads();
      const float rstd = rsqrtf((red[0] + red[1] + red[2] + red[3]) / cH + 1e-6f);
      for (int i = t; i < cH; i += 256) {
        float v = buf[i] * rstd * nw[i];
        buf[i] = v;
        src[i] = f2b(v);
      }
      __syncthreads();
      bf16* dst = pass ? ka : qa;
      const float scale = pass ? 1.f : cRSQRT_HD;
      const int hh = t >> 4, j0 = (t & 15) * 4;
      const float* cr = ct + (size_t)si * 64 + j0;
      const float* sr = stb + (size_t)si * 64 + j0;
      bf16* drow = dst + ((size_t)(b_ * cNH + hh) * cS + si) * cHD;
      unsigned short u1[4] __attribute__((aligned(8))), u2[4] __attribute__((aligned(8)));
#pragma unroll
      for (int i = 0; i < 4; ++i) {
        float x1 = buf[hh * cHD + j0 + i], x2 = buf[hh * cHD + 64 + j0 + i];
        u1[i] = f2bu((x1 * cr[i] - x2 * sr[i]) * scale);
        u2[i] = f2bu((x2 * cr[i] + x1 * sr[i]) * scale);
      }
      *(uint2*)(drow + j0) = *(uint2*)u1;
      *(uint2*)(drow + 64 + j0) = *(uint2*)u2;
    }
  } else {
    short* Ts = smem;  // 64*136
    const int id2 = id - 4096;
    const int tile = id2 & 31, h = (id2 >> 5) & 15, b_ = id2 >> 9;
    {
      const int r = t >> 2, seg = (t & 3) * 32;
      const bf16* src = qkvh + ((size_t)(b_ * cS) + tile * 64 + r) * 3 * cH + 2 * cH + h * cHD + seg;
      stage16(src, &Ts[r * 136 + seg]);
      stage16(src + 16, &Ts[r * 136 + seg + 16]);
    }
    __syncthreads();
    {
      const int d = t >> 1, seg2 = (t & 1) * 32;
      unsigned short u[32] __attribute__((aligned(16)));
#pragma unroll
      for (int i = 0; i < 32; ++i) u[i] = (unsigned short)Ts[(seg2 + i) * 136 + d];
      bf16* dp = vt + ((size_t)(b_ * cNH + h) * cHD + d) * cS + tile * 64 + seg2;
      *(uint4*)dp = *(uint4*)u;
      *(uint4*)(dp + 8) = *(uint4*)(u + 8);
      *(uint4*)(dp + 16) = *(uint4*)(u + 16);
      *(uint4*)(dp + 24) = *(uint4*)(u + 24);
    }
  }
}

// --- k_mid: ids 0..4095 fq/fk/fv from qkvh; 4096..7167 mirror cvt;
//            7168..7679 w1t init (transpose of fp32 master w1s) ---
__global__ __launch_bounds__(256) void k_mid(const bf16* __restrict__ qkvh,
                                             const float* __restrict__ qk_scale,
                                             const float* __restrict__ qk_offset,
                                             bf16* fq, bf16* fk, bf16* fv,
                                             const float* __restrict__ w0s_, bf16* __restrict__ w0b_,
                                             const float* __restrict__ w1s_, bf16* __restrict__ w1t_) {
  __shared__ short Ts[64 * 72];
  const int id = blockIdx.x, t = threadIdx.x;
  if (id < 4096) {
    const int token = id, b_ = token >> 11, si = token & 2047;
    const bf16* base = qkvh + (size_t)token * 3 * cH;
#pragma unroll
    for (int pass = 0; pass < 2; ++pass) {
      const bf16* src = base + pass * cH;
      bf16* fdst = pass ? fk : fq;
      const int head = t >> 6, lane = t & 63;
      float f[8];
      float ss2 = 0.f;
#pragma unroll
      for (int k = 0; k < 8; ++k) {
        const int idx = head * cFD + lane + k * 64;
        float v = b2f(src[idx]);
        float u = v * qk_scale[idx * 2 + pass] + qk_offset[idx * 2 + pass];
        float fv_ = u * sigmoidf_(u);
        f[k] = fv_;
        ss2 += fv_ * fv_;
      }
      for (int d = 1; d < 64; d <<= 1) ss2 += __shfl_xor(ss2, d);
      const float sc2 = rsqrtf(ss2 + 1e-12f);
      bf16* dst = fdst + ((size_t)(b_ * cNFW + head) * cS + si) * cFD;
#pragma unroll
      for (int k = 0; k < 8; ++k) dst[lane + k * 64] = f2b(f[k] * sc2);
    }
    const bf16* vr = base + 2 * cH;
    for (int i = t; i < cH; i += 256) {
      float v = b2f(vr[i]);
      fv[((size_t)(b_ * cNFW + (i >> 9)) * cS + si) * cFD + (i & 511)] = f2b(v * sigmoidf_(v));
    }
  } else if (id < 7168) {
    const size_t i = ((size_t)(id - 4096) * 256 + t) * 8;
    float4 a = *(const float4*)(w0s_ + i), b = *(const float4*)(w0s_ + i + 4);
    unsigned short u[8] __attribute__((aligned(16)));
    u[0] = f2bu(a.x); u[1] = f2bu(a.y); u[2] = f2bu(a.z); u[3] = f2bu(a.w);
    u[4] = f2bu(b.x); u[5] = f2bu(b.y); u[6] = f2bu(b.z); u[7] = f2bu(b.w);
    *(uint4*)(w0b_ + i) = *(uint4*)u;
  } else {
    const int id3 = id - 7168;
    const int bh = id3 >> 6, tile = id3 & 63, by = tile >> 3, bx = tile & 7;
    {
      const int rr = t >> 2, cseg = (t & 3) * 16;
      const float* p = w1s_ + (size_t)bh * ZL_ + (size_t)(by * 64 + rr) * cFD + bx * 64 + cseg;
      unsigned short u[16] __attribute__((aligned(16)));
#pragma unroll
      for (int i = 0; i < 16; ++i) u[i] = f2bu(p[i]);
      *(uint4*)&Ts[rr * 72 + cseg] = *(uint4*)u;
      *(uint4*)&Ts[rr * 72 + cseg + 8] = *(uint4*)(u + 8);
    }
    __syncthreads();
    {
      const int oc_ = t >> 2, rseg = (t & 3) * 16;
      unsigned short u[16] __attribute__((aligned(16)));
#pragma unroll
      for (int i = 0; i < 16; ++i) u[i] = (unsigned short)Ts[(rseg + i) * 72 + oc_];
      bf16* dp = w1t_ + (size_t)bh * ZL_ + (size_t)(bx * 64 + oc_) * cFD + by * 64 + rseg;
      *(uint4*)dp = *(uint4*)u;
      *(uint4*)(dp + 8) = *(uint4*)(u + 8);
    }
  }
}

// -- attention: 128-row q blocks, 8 waves, paired tiles, XCD swizzle ---------
__global__ __launch_bounds__(512) void k_attn6(const bf16* __restrict__ qa, const bf16* __restrict__ ka,
                                               const bf16* __restrict__ vt, bf16* __restrict__ y) {
  const int id = blockIdx.x;
  const int xcd = id & 7;
  const int j = id >> 3;
  const int p = j & 7;
  const int hb = (j >> 3) * 8 + xcd;
  const int h = hb & 15, b_ = hb >> 4;
  __shared__ short KsP[9216];
  __shared__ short Vts[128 * 72];
  const int t = threadIdx.x, lane = t & 63, g = lane >> 4, c16 = lane & 15, wv = t >> 6;
  const size_t hbq = (size_t)(b_ * cNH + h) * cS;
  const bf16* vb = vt + (size_t)(b_ * cNH + h) * (size_t)(cHD * cS);
  const int r = t >> 3, seg = (t & 7) * 16;
  const int dv = t >> 2, seg2 = (t & 3) * 16;
  const f32x4 zero4 = {0.f, 0.f, 0.f, 0.f};

  for (int half = 0; half < 2; ++half) {
    const int qt = half ? p : 15 - p;
    const int q0 = qt * 128;
    const int nkt = 2 * qt + 2;
    short8 qf[4];
    {
      const bf16* qsrc = qa + (hbq + q0 + wv * 16 + c16) * cHD;
#pragma unroll
      for (int ks = 0; ks < 4; ++ks) qf[ks] = *(const short8*)(qsrc + ks * 32 + g * 8);
    }
    f32x4 o[8];
#pragma unroll
    for (int i = 0; i < 8; ++i) o[i] = zero4;
    float m[4], l[4];
#pragma unroll
    for (int rr = 0; rr < 4; ++rr) { m[rr] = -1e30f; l[rr] = 0.f; }

    uint4 kp0, kp1, vp0, vp1;
    {
      const bf16* ksrc = ka + (hbq + r) * cHD + seg;
      kp0 = *(const uint4*)ksrc; kp1 = *(const uint4*)(ksrc + 8);
      const bf16* vsrc = vb + (size_t)dv * cS + seg2;
      vp0 = *(const uint4*)vsrc; vp1 = *(const uint4*)(vsrc + 8);
    }

    for (int kt = 0; kt < nkt; ++kt) {
      __syncthreads();
      {
        short* kd = &KsP[r * 136 + seg];
        *(uint4*)kd = kp0; *(uint4*)(kd + 8) = kp1;
        short* vd = &Vts[dv * 72 + seg2];
        *(uint4*)vd = vp0; *(uint4*)(vd + 8) = vp1;
      }
      __syncthreads();
      if (kt + 1 < nkt) {
        const bf16* ksrc = ka + (hbq + (kt + 1) * 64 + r) * cHD + seg;
        kp0 = *(const uint4*)ksrc; kp1 = *(const uint4*)(ksrc + 8);
        const bf16* vsrc = vb + (size_t)dv * cS + (kt + 1) * 64 + seg2;
        vp0 = *(const uint4*)vsrc; vp1 = *(const uint4*)(vsrc + 8);
      } else if (half == 0) {
        const bf16* ksrc = ka + (hbq + r) * cHD + seg;
        kp0 = *(const uint4*)ksrc; kp1 = *(const uint4*)(ksrc + 8);
        const bf16* vsrc = vb + (size_t)dv * cS + seg2;
        vp0 = *(const uint4*)vsrc; vp1 = *(const uint4*)(vsrc + 8);
      }

      f32x4 s4[4];
#pragma unroll
      for (int ni = 0; ni < 4; ++ni) s4[ni] = zero4;
      __builtin_amdgcn_s_setprio(1);
#pragma unroll
      for (int ks = 0; ks < 4; ++ks) {
#pragma unroll
        for (int ni = 0; ni < 4; ++ni) {
          short8 bb = *(const short8*)&KsP[(ni * 16 + c16) * 136 + ks * 32 + g * 8];
          s4[ni] = __builtin_amdgcn_mfma_f32_16x16x32_bf16(qf[ks], bb, s4[ni], 0, 0, 0);
        }
      }
      __builtin_amdgcn_s_setprio(0);
      __syncthreads();
      if (kt * 64 + 64 > q0) {
#pragma unroll
        for (int ni = 0; ni < 4; ++ni) {
          const int kv = kt * 64 + ni * 16 + c16;
#pragma unroll
          for (int rr = 0; rr < 4; ++rr) {
            const int qr = q0 + wv * 16 + g * 4 + rr;
            if (kv > qr) s4[ni][rr] = -1e9f;
          }
        }
      }
      float mx[4];
#pragma unroll
      for (int rr = 0; rr < 4; ++rr)
        mx[rr] = fmaxf(fmaxf(s4[0][rr], s4[1][rr]), fmaxf(s4[2][rr], s4[3][rr]));
#pragma unroll
      for (int d = 1; d < 16; d <<= 1)
#pragma unroll
        for (int rr = 0; rr < 4; ++rr) mx[rr] = fmaxf(mx[rr], __shfl_xor(mx[rr], d));
      bool need = false;
#pragma unroll
      for (int rr = 0; rr < 4; ++rr) need |= (mx[rr] > m[rr] + 8.f);
      if (__any(need)) {
        float corr[4];
#pragma unroll
        for (int rr = 0; rr < 4; ++rr) {
          float mn = fmaxf(m[rr], mx[rr]);
          corr[rr] = __expf(m[rr] - mn);
          m[rr] = mn;
        }
#pragma unroll
        for (int rr = 0; rr < 4; ++rr) l[rr] *= corr[rr];
#pragma unroll
        for (int nf = 0; nf < 8; ++nf)
#pragma unroll
          for (int rr = 0; rr < 4; ++rr) o[nf][rr] *= corr[rr];
      }
      float psum[4] = {0.f, 0.f, 0.f, 0.f};
#pragma unroll
      for (int ni = 0; ni < 4; ++ni)
#pragma unroll
        for (int rr = 0; rr < 4; ++rr) {
          float pp = __expf(s4[ni][rr] - m[rr]);
          s4[ni][rr] = pp;
          psum[rr] += pp;
        }
#pragma unroll
      for (int d = 1; d < 16; d <<= 1)
#pragma unroll
        for (int rr = 0; rr < 4; ++rr) psum[rr] += __shfl_xor(psum[rr], d);
#pragma unroll
      for (int rr = 0; rr < 4; ++rr) l[rr] += psum[rr];
      short* pw = &KsP[wv * 1152];
#pragma unroll
      for (int ni = 0; ni < 4; ++ni)
#pragma unroll
        for (int rr = 0; rr < 4; ++rr)
          pw[(g * 4 + rr) * 72 + ni * 16 + c16] = (short)f2bu(s4[ni][rr]);
      __builtin_amdgcn_s_setprio(1);
#pragma unroll
      for (int ks2 = 0; ks2 < 2; ++ks2) {
        short8 a = *(const short8*)&pw[c16 * 72 + ks2 * 32 + g * 8];
#pragma unroll
        for (int nf = 0; nf < 8; ++nf) {
          short8 bb = *(const short8*)&Vts[(nf * 16 + c16) * 72 + ks2 * 32 + g * 8];
          o[nf] = __builtin_amdgcn_mfma_f32_16x16x32_bf16(a, bb, o[nf], 0, 0, 0);
        }
      }
      __builtin_amdgcn_s_setprio(0);
    }
    float inv[4];
#pragma unroll
    for (int rr = 0; rr < 4; ++rr) inv[rr] = 1.f / l[rr];
#pragma unroll
    for (int nf = 0; nf < 8; ++nf)
#pragma unroll
      for (int rr = 0; rr < 4; ++rr) {
        const size_t row = (size_t)(b_ * cS) + q0 + wv * 16 + g * 4 + rr;
        y[row * cH + h * cHD + nf * 16 + c16] = f2b(o[nf][rr] * inv[rr]);
      }
  }
}

}  // namespace

extern "C" void kernel_launch(void* const* d_in, const int* in_sizes, int n_in,
                              void* d_out, int out_size, void* d_ws, size_t ws_size,
                              hipStream_t stream) {
  (void)in_sizes; (void)n_in; (void)out_size; (void)ws_size;
  const float* x         = (const float*)d_in[0];
  const float* qkv_w     = (const float*)d_in[1];
  const float* q_norm_w  = (const float*)d_in[2];
  const float* k_norm_w  = (const float*)d_in[3];
  const float* qk_scale  = (const float*)d_in[4];
  const float* qk_offset = (const float*)d_in[5];
  const float* lr_w      = (const float*)d_in[6];
  const float* lr_b      = (const float*)d_in[7];
  const float* w0        = (const float*)d_in[8];
  const float* w1        = (const float*)d_in[9];
  const float* w2        = (const float*)d_in[10];
  const float* ttt_nw    = (const float*)d_in[11];
  const float* o_proj_w  = (const float*)d_in[12];
  float* out = (float*)d_out;

  // ---- workspace layout (bytes), total 143,851,520 (proven footprint) ----
  char* Wb = (char*)d_ws;
  bf16* qkvh = (bf16*)Wb;                 // phase-1 only (50.3MB)
  bf16* hq   = (bf16*)(Wb + 0UL);         // TTT phase buffers:
  bf16* trH  = (bf16*)(Wb + 4194304UL);
  bf16* trD1 = (bf16*)(Wb + 8388608UL);
  bf16* trD2 = (bf16*)(Wb + 12582912UL);
  bf16* trK  = (bf16*)(Wb + 16777216UL);
  bf16* trV  = (bf16*)(Wb + 20971520UL);
  bf16* occ  = (bf16*)(Wb + 25165824UL);
  bf16* w1t  = (bf16*)(Wb + 29360128UL);  // transposed w1 mirror
  bf16* w0b  = (bf16*)(Wb + 33554432UL);  // contiguous mirrors w0b,w1b0,w2b
  bf16* w1b0 = (bf16*)(Wb + 37748736UL);
  bf16* w2b  = (bf16*)(Wb + 41943040UL);
  bf16* w1b1 = (bf16*)(Wb + 46137344UL);  // w1 row-major mirror ping-pong
  bf16* opwb = (bf16*)(Wb + 0UL);         // after TTT loop
  size_t off = 50331648UL;
  bf16* fqb = (bf16*)(Wb + off); off += 16777216UL;
  bf16* fkb = (bf16*)(Wb + off); off += 16777216UL;
  bf16* fvb = (bf16*)(Wb + off); off += 16777216UL;
  float* w0s = (float*)(Wb + off); off += 8388608UL;
  float* w1s = (float*)(Wb + off); off += 8388608UL;
  float* w2s = (float*)(Wb + off); off += 8388608UL;
  float* lr0 = (float*)(Wb + off); off += 65536UL;
  float* lr1 = (float*)(Wb + off); off += 65536UL;
  float* lr2 = (float*)(Wb + off); off += 65536UL;
  bf16* y = (bf16*)(Wb + off); off += 16777216UL;
  float* ct  = (float*)(Wb + off); off += 524288UL;
  float* stb = (float*)(Wb + off); off += 524288UL;
  bf16* xb = fqb;
  bf16* qkvwb = fkb;
  bf16* qa = fqb;
  bf16* ka = fkb;
  bf16* vt = fvb;
  bf16* w1m[2] = {w1b0, w1b1};

  const float base_lr_inv = logf(expm1f(0.001f));
  dim3 blk(256);

  k_prep<<<dim3(20992), blk, 0, stream>>>(x, qkv_w, w0, w1, w2, lr_w, lr_b,
                                          xb, qkvwb, w0s, w1s, w2s, ct, stb,
                                          lr0, lr1, lr2, base_lr_inv);
  k_mm<bf16><<<dim3(48, 32), blk, 0, stream>>>(xb, 2048, qkvwb, 2048, qkvh, 6144, 2048);
  k_post2<<<dim3(5120), blk, 0, stream>>>(qkvh, q_norm_w, k_norm_w, ct, stb, qa, ka, vt);
  k_attn6<<<dim3(256), dim3(512), 0, stream>>>(qa, ka, vt, y);
  // fq/fk/fv overwrite qa/ka/vt after attn; mirrors + w1t init in same launch
  k_mid<<<dim3(7680), blk, 0, stream>>>(qkvh, qk_scale, qk_offset, fqb, fkb, fvb,
                                        w0s, w0b, w1s, w1t);

  for (int c = 0; c < 4; ++c) {
    const int g1 = (c == 0) ? 1536 : 5632;
    k_fuse1<<<dim3(g1), blk, 0, stream>>>(fqb, fkb, fvb, w0b, w1t, w2b,
                                          hq, trH, trD1, trD2, trK, trV,
                                          lr0, lr1, lr2, occ, ttt_nw, y, c);
    k_updna<<<dim3(512), blk, 0, stream>>>(trV, trH, trD1, trD2, trK, hq, w1m[c & 1],
                                           w0s, w1s, w2s, w0b, w1m[(c + 1) & 1], w2b, w1t,
                                           occ);
  }
  k_normcvt<<<dim3(6144), blk, 0, stream>>>(occ, ttt_nw, y, o_proj_w, opwb, 3);
  k_mm<float><<<dim3(16, 32), blk, 0, stream>>>(y, 2048, opwb, 2048, out, 2048, 2048);
}

// Round 14
// 696.412 us; speedup vs baseline: 7.4718x; 1.0253x over previous
//
#include <hip/hip_runtime.h>
#include <hip/hip_bf16.h>
#include <math.h>

using bf16 = __hip_bfloat16;

namespace {

constexpr int cH = 2048;
constexpr int cNH = 16;
constexpr int cHD = 128;
constexpr int cNFW = 4;
constexpr int cFD = 512;
constexpr int cS = 2048;
constexpr float cRSQRT_HD = 0.08838834764831845f;  // 1/sqrt(128)
constexpr long ZL_ = 262144;   // 512*512
constexpr long ZG_ = 1048576;  // 2048*512

typedef __attribute__((ext_vector_type(8))) short short8;
typedef __attribute__((ext_vector_type(4))) float f32x4;

__device__ __forceinline__ float sigmoidf_(float x) { return 1.0f / (1.0f + __expf(-x)); }
__device__ __forceinline__ float b2f(bf16 v) { return __bfloat162float(v); }
__device__ __forceinline__ bf16 f2b(float v) { return __float2bfloat16(v); }
__device__ __forceinline__ unsigned short f2bu(float f) {
  return __builtin_bit_cast(unsigned short, __float2bfloat16(f));
}
__device__ __forceinline__ float bu2f(unsigned u) { return __uint_as_float(u << 16); }

#if defined(__has_builtin)
#if __has_builtin(__builtin_amdgcn_global_load_lds)
#define HAVE_GLOAD 1
#endif
#endif

__device__ __forceinline__ void gload16(const bf16* g, short* ldsbase) {
#ifdef HAVE_GLOAD
  __builtin_amdgcn_global_load_lds((const __attribute__((address_space(1))) void*)g,
                                   (__attribute__((address_space(3))) void*)ldsbase, 16, 0, 0);
#else
  const int l = threadIdx.x & 63;
  *(uint4*)(ldsbase + l * 8) = *(const uint4*)g;
#endif
}

__device__ __forceinline__ void stage16(const bf16* src, short* dst) {
  *(uint4*)dst = *(const uint4*)src;
  *(uint4*)(dst + 8) = *(const uint4*)(src + 8);
}

__device__ __forceinline__ void store1(float* p, float v) { *p = v; }
__device__ __forceinline__ void store1(bf16* p, float v) { *p = f2b(v); }

// ---------------------------------------------------------------------------
// MFMA NT GEMM core: 128x128 tile, 4 waves (2x2 of 64x64), BK=32, linear LDS.
// A [M][K], B [N][K] bf16 row-major; global_load_lds staging.
// ---------------------------------------------------------------------------
__device__ __forceinline__ void mm_core32(const bf16* __restrict__ Ab, int lda,
                                          const bf16* __restrict__ Bb, int ldb, int K,
                                          short* As, short* Bs, f32x4 acc[4][4]) {
  const int t = threadIdx.x, lane = t & 63, g = lane >> 4, c16 = lane & 15;
  const int wv = t >> 6, wm = (wv >> 1) * 64, wn = (wv & 1) * 64;
  for (int k0 = 0; k0 < K; k0 += 32) {
    __syncthreads();
    {
      const int ch = wv * 2;
      const bf16* ga = Ab + (size_t)(ch * 16 + (lane >> 2)) * lda + k0 + (lane & 3) * 8;
      gload16(ga, &As[ch * 512]);
      gload16(ga + (size_t)16 * lda, &As[ch * 512 + 512]);
      const bf16* gb = Bb + (size_t)(ch * 16 + (lane >> 2)) * ldb + k0 + (lane & 3) * 8;
      gload16(gb, &Bs[ch * 512]);
      gload16(gb + (size_t)16 * ldb, &Bs[ch * 512 + 512]);
    }
    __syncthreads();
    short8 af[4], bfr[4];
#pragma unroll
    for (int mi = 0; mi < 4; ++mi) af[mi] = *(const short8*)&As[(wm + mi * 16 + c16) * 32 + g * 8];
#pragma unroll
    for (int ni = 0; ni < 4; ++ni) bfr[ni] = *(const short8*)&Bs[(wn + ni * 16 + c16) * 32 + g * 8];
#pragma unroll
    for (int mi = 0; mi < 4; ++mi)
#pragma unroll
      for (int ni = 0; ni < 4; ++ni)
        acc[mi][ni] = __builtin_amdgcn_mfma_f32_16x16x32_bf16(af[mi], bfr[ni], acc[mi][ni], 0, 0, 0);
  }
}

template <bool ACC, bool MIR, typename TC>
__device__ __forceinline__ void mm_store(TC* Cb, bf16* Mb, int ldc, int rb, int cb, f32x4 acc[4][4]) {
  const int t = threadIdx.x, lane = t & 63, g = lane >> 4, c16 = lane & 15;
  const int wv = t >> 6, wm = (wv >> 1) * 64, wn = (wv & 1) * 64;
  const int rbase = rb + wm, cbase = cb + wn;
#pragma unroll
  for (int mi = 0; mi < 4; ++mi)
#pragma unroll
    for (int ni = 0; ni < 4; ++ni) {
      const int col = cbase + ni * 16 + c16;
#pragma unroll
      for (int r = 0; r < 4; ++r) {
        const int row = rbase + mi * 16 + g * 4 + r;
        TC* cp = Cb + (size_t)row * ldc + col;
        if constexpr (ACC) {
          float nv = *cp + acc[mi][ni][r];
          *cp = nv;
          if constexpr (MIR) Mb[(size_t)row * ldc + col] = f2b(nv);
        } else {
          store1(cp, acc[mi][ni][r]);
        }
      }
    }
}

template <typename TC>
__global__ __launch_bounds__(256) void k_mm(const bf16* __restrict__ A, int lda,
                                            const bf16* __restrict__ B, int ldb,
                                            TC* __restrict__ C, int ldc, int K) {
  __shared__ short As[128 * 32];
  __shared__ short Bs[128 * 32];
  const bf16* Ab = A + (size_t)blockIdx.y * 128 * lda;
  const bf16* Bb = B + (size_t)blockIdx.x * 128 * ldb;
  f32x4 acc[4][4];
  const f32x4 zero4 = {0.f, 0.f, 0.f, 0.f};
#pragma unroll
  for (int i = 0; i < 4; ++i)
#pragma unroll
    for (int j = 0; j < 4; ++j) acc[i][j] = zero4;
  mm_core32(Ab, lda, Bb, ldb, K, As, Bs, acc);
  mm_store<false, false>(C, (bf16*)nullptr, ldc, blockIdx.y * 128, blockIdx.x * 128, acc);
}

// ---------------------------------------------------------------------------
// Fused stage1 + gates + (trK,trV transposes) + (prev-chunk norm-add).
// B1 operand is the transposed w1 mirror (w1t) -> pure NT gload staging.
// ---------------------------------------------------------------------------
__global__ __launch_bounds__(256) void k_fuse1(const bf16* __restrict__ fq, const bf16* __restrict__ fk,
                                               const bf16* __restrict__ fv,
                                               const bf16* __restrict__ w0b, const bf16* __restrict__ w1t,
                                               const bf16* __restrict__ w2b,
                                               bf16* __restrict__ hq, bf16* __restrict__ trH,
                                               bf16* __restrict__ trD1, bf16* __restrict__ trD2,
                                               bf16* __restrict__ trK, bf16* __restrict__ trV,
                                               const float* __restrict__ lr0, const float* __restrict__ lr1,
                                               const float* __restrict__ lr2,
                                               const bf16* __restrict__ occ,
                                               const float* __restrict__ tw, bf16* __restrict__ y,
                                               int chunk) {
  __shared__ short S[12288];
  __shared__ float red[4];
  const int id = blockIdx.x, t = threadIdx.x;
  const size_t choff = (size_t)chunk * 262144;

  if (id < 512) {
    const int bh = id >> 6, tile = id & 63, by = tile >> 3, bx = tile & 7;
    const int lane = t & 63, g = lane >> 4, c16 = lane & 15, wv = t >> 6;
    const int wm = (wv >> 1) * 32, wn = (wv & 1) * 32;
    const bf16* Aq = fq + (size_t)bh * ZG_ + choff + (size_t)(by * 64) * cFD;
    const bf16* Ak = fk + (size_t)bh * ZG_ + choff + (size_t)(by * 64) * cFD;
    const bf16* Av = fv + (size_t)bh * ZG_ + choff + (size_t)(by * 64) * cFD;
    const bf16* B0 = w0b + (size_t)bh * ZL_ + (size_t)(bx * 64) * cFD;
    const bf16* B2 = w2b + (size_t)bh * ZL_ + (size_t)(bx * 64) * cFD;
    const bf16* B1 = w1t + (size_t)bh * ZL_ + (size_t)(bx * 64) * cFD;  // [e][d]

    f32x4 acc[5][2][2];
    const f32x4 zero4 = {0.f, 0.f, 0.f, 0.f};
#pragma unroll
    for (int v = 0; v < 5; ++v)
#pragma unroll
      for (int i = 0; i < 2; ++i)
#pragma unroll
        for (int j = 0; j < 2; ++j) acc[v][i][j] = zero4;

    const int srow = wv * 16 + (lane >> 2), scol = (lane & 3) * 8;
    for (int k0 = 0; k0 < 512; k0 += 32) {
      __syncthreads();
      gload16(Aq + (size_t)srow * cFD + k0 + scol, &S[0 + wv * 512]);
      gload16(Ak + (size_t)srow * cFD + k0 + scol, &S[2048 + wv * 512]);
      gload16(Av + (size_t)srow * cFD + k0 + scol, &S[4096 + wv * 512]);
      gload16(B0 + (size_t)srow * cFD + k0 + scol, &S[6144 + wv * 512]);
      gload16(B2 + (size_t)srow * cFD + k0 + scol, &S[8192 + wv * 512]);
      gload16(B1 + (size_t)srow * cFD + k0 + scol, &S[10240 + wv * 512]);
      __syncthreads();
      short8 aq[2], ak[2], av[2], b0[2], b2[2], b1[2];
#pragma unroll
      for (int mi = 0; mi < 2; ++mi) {
        const int ro = (wm + mi * 16 + c16) * 32 + g * 8;
        aq[mi] = *(const short8*)&S[0 + ro];
        ak[mi] = *(const short8*)&S[2048 + ro];
        av[mi] = *(const short8*)&S[4096 + ro];
      }
#pragma unroll
      for (int ni = 0; ni < 2; ++ni) {
        const int ro = (wn + ni * 16 + c16) * 32 + g * 8;
        b0[ni] = *(const short8*)&S[6144 + ro];
        b2[ni] = *(const short8*)&S[8192 + ro];
        b1[ni] = *(const short8*)&S[10240 + ro];
      }
#pragma unroll
      for (int mi = 0; mi < 2; ++mi)
#pragma unroll
        for (int ni = 0; ni < 2; ++ni) {
          acc[0][mi][ni] = __builtin_amdgcn_mfma_f32_16x16x32_bf16(aq[mi], b0[ni], acc[0][mi][ni], 0, 0, 0);
          acc[1][mi][ni] = __builtin_amdgcn_mfma_f32_16x16x32_bf16(aq[mi], b2[ni], acc[1][mi][ni], 0, 0, 0);
          acc[2][mi][ni] = __builtin_amdgcn_mfma_f32_16x16x32_bf16(ak[mi], b0[ni], acc[2][mi][ni], 0, 0, 0);
          acc[3][mi][ni] = __builtin_amdgcn_mfma_f32_16x16x32_bf16(ak[mi], b2[ni], acc[3][mi][ni], 0, 0, 0);
          acc[4][mi][ni] = __builtin_amdgcn_mfma_f32_16x16x32_bf16(av[mi], b1[ni], acc[4][mi][ni], 0, 0, 0);
        }
    }

    float l0v[2][4], l2v[2][4];
#pragma unroll
    for (int mi = 0; mi < 2; ++mi)
#pragma unroll
      for (int r = 0; r < 4; ++r) {
        const int row = by * 64 + wm + mi * 16 + g * 4 + r;
        l0v[mi][r] = lr0[bh * 2048 + chunk * 512 + row];
        l2v[mi][r] = lr2[bh * 2048 + chunk * 512 + row];
      }
#pragma unroll
    for (int mi = 0; mi < 2; ++mi)
#pragma unroll
      for (int ni = 0; ni < 2; ++ni)
#pragma unroll
        for (int r = 0; r < 4; ++r) {
          float hq1 = acc[0][mi][ni][r], hq2 = acc[1][mi][ni][r];
          float g1 = acc[2][mi][ni][r], g2 = acc[3][mi][ni][r], dh = acc[4][mi][ni][r];
          acc[0][mi][ni][r] = hq1 * sigmoidf_(hq1) * hq2;
          float sg = sigmoidf_(g1);
          float gate = g1 * sg;
          acc[1][mi][ni][r] = gate * g2;
          acc[2][mi][ni][r] = l0v[mi][r] * dh * g2 * (sg * (1.0f + g1 * (1.0f - sg)));
          acc[3][mi][ni][r] = l2v[mi][r] * dh * gate;
        }

    short* Ts = S;
    bf16* dst0 = hq + (size_t)bh * ZL_;
    bf16* dstT[3] = {trH + (size_t)bh * ZL_, trD1 + (size_t)bh * ZL_, trD2 + (size_t)bh * ZL_};
#pragma unroll
    for (int rd = 0; rd < 4; ++rd) {
      __syncthreads();
#pragma unroll
      for (int mi = 0; mi < 2; ++mi)
#pragma unroll
        for (int ni = 0; ni < 2; ++ni)
#pragma unroll
          for (int r = 0; r < 4; ++r) {
            const int row = wm + mi * 16 + g * 4 + r, col = wn + ni * 16 + c16;
            if (rd == 0) Ts[row * 66 + col] = (short)f2bu(acc[0][mi][ni][r]);
            else Ts[col * 66 + row] = (short)f2bu(acc[rd][mi][ni][r]);
          }
      __syncthreads();
      const int rr = t >> 2, cs = (t & 3) * 16;
      unsigned short u[16] __attribute__((aligned(16)));
#pragma unroll
      for (int i = 0; i < 16; ++i) u[i] = (unsigned short)Ts[rr * 66 + cs + i];
      bf16* dp = (rd == 0) ? (dst0 + (size_t)(by * 64 + rr) * cFD + bx * 64 + cs)
                           : (dstT[rd - 1] + (size_t)(bx * 64 + rr) * cFD + by * 64 + cs);
      *(uint4*)dp = *(uint4*)u;
      *(uint4*)(dp + 8) = *(uint4*)(u + 8);
    }
  } else if (id < 1536) {
    short* Ts = S;  // 64*72
    const int id2 = id - 512;
    const int var = id2 >> 9, bh = (id2 >> 6) & 7, by = (id2 >> 3) & 7, bx = id2 & 7;
    const bf16* src = ((var == 0) ? fk : fv) + choff + (size_t)bh * ZG_;
    bf16* dst = ((var == 0) ? trK : trV) + (size_t)bh * ZL_;
    {
      const int rr = t >> 2, cseg = (t & 3) * 16;
      if (var == 0) {
        stage16(src + (size_t)(by * 64 + rr) * cFD + bx * 64 + cseg, &Ts[rr * 72 + cseg]);
      } else {
        const float s = lr1[bh * 2048 + chunk * 512 + by * 64 + rr];
        const bf16* p = src + (size_t)(by * 64 + rr) * cFD + bx * 64 + cseg;
        unsigned short u[16] __attribute__((aligned(16)));
#pragma unroll
        for (int i = 0; i < 16; ++i) u[i] = f2bu(b2f(p[i]) * s);
        *(uint4*)&Ts[rr * 72 + cseg] = *(uint4*)u;
        *(uint4*)&Ts[rr * 72 + cseg + 8] = *(uint4*)(u + 8);
      }
    }
    __syncthreads();
    {
      const int oc_ = t >> 2, rseg = (t & 3) * 16;
      unsigned short u[16] __attribute__((aligned(16)));
#pragma unroll
      for (int i = 0; i < 16; ++i) u[i] = (unsigned short)Ts[(rseg + i) * 72 + oc_];
      bf16* dp = dst + (size_t)(bx * 64 + oc_) * cFD + by * 64 + rseg;
      *(uint4*)dp = *(uint4*)u;
      *(uint4*)(dp + 8) = *(uint4*)(u + 8);
    }
  } else {
    const int rrow = id - 1536;
    const int bh = rrow >> 9, rr = rrow & 511;
    const bf16* src = occ + ((size_t)bh * 512 + rr) * 512;
    float v0 = b2f(src[t]), v1 = b2f(src[t + 256]);
    float ss = v0 * v0 + v1 * v1;
    for (int d = 32; d; d >>= 1) ss += __shfl_down(ss, d);
    if ((t & 63) == 0) red[t >> 6] = ss;
    __syncthreads();
    const float rstd = rsqrtf((red[0] + red[1] + red[2] + red[3]) / cFD + 1e-6f);
    const int si = (chunk - 1) * 512 + rr;
    bf16* dst = y + ((size_t)((bh >> 2) * cS) + si) * cH + (bh & 3) * cFD;
    dst[t] = f2b(b2f(dst[t]) + v0 * rstd * tw[t]);
    dst[t + 256] = f2b(b2f(dst[t + 256]) + v1 * rstd * tw[t + 256]);
  }
}

// ---------------------------------------------------------------------------
// updna: ids 0..383 weight-update GEMMs (var0 also writes w1t transposed);
//        ids 384..511 oc = hq @ w1_cur^T (128^2 tiles).
// ---------------------------------------------------------------------------
__global__ __launch_bounds__(256) void k_updna(const bf16* __restrict__ trV, const bf16* __restrict__ trH,
                                               const bf16* __restrict__ trD1, const bf16* __restrict__ trD2,
                                               const bf16* __restrict__ trK,
                                               const bf16* __restrict__ hq, const bf16* __restrict__ w1bc,
                                               float* w0s, float* w1s, float* w2s,
                                               bf16* w0b, bf16* w1bn, bf16* w2b, bf16* w1t,
                                               bf16* __restrict__ occ) {
  __shared__ short Sh[8704];
  const int id = blockIdx.x, t = threadIdx.x;
  const int lane = t & 63, g = lane >> 4, c16 = lane & 15, wv = t >> 6;
  if (id < 384) {
    short* As = Sh;
    short* Bs = Sh + 4096;
    const int z = id >> 4, tile = id & 15, by = tile >> 2, bx = tile & 3;
    const int var = z >> 3, bh = z & 7;
    const bf16 *Aa, *Bb;
    if (var == 0) {
      Aa = trV + (size_t)bh * ZL_ + (size_t)by * 128 * cFD;
      Bb = trH + (size_t)bh * ZL_ + (size_t)bx * 128 * cFD;
    } else if (var == 1) {
      Aa = trD1 + (size_t)bh * ZL_ + (size_t)by * 128 * cFD;
      Bb = trK + (size_t)bh * ZL_ + (size_t)bx * 128 * cFD;
    } else {
      Aa = trD2 + (size_t)bh * ZL_ + (size_t)by * 128 * cFD;
      Bb = trK + (size_t)bh * ZL_ + (size_t)bx * 128 * cFD;
    }
    f32x4 acc[4][4];
    const f32x4 zero4 = {0.f, 0.f, 0.f, 0.f};
#pragma unroll
    for (int i = 0; i < 4; ++i)
#pragma unroll
      for (int j = 0; j < 4; ++j) acc[i][j] = zero4;
    mm_core32(Aa, cFD, Bb, cFD, cFD, As, Bs, acc);
    if (var == 1) {
      mm_store<true, true>(w0s + (size_t)bh * ZL_, w0b + (size_t)bh * ZL_, cFD, by * 128, bx * 128, acc);
    } else if (var == 2) {
      mm_store<true, true>(w2s + (size_t)bh * ZL_, w2b + (size_t)bh * ZL_, cFD, by * 128, bx * 128, acc);
    } else {
      // w1: update master + row-major mirror, keep nv in acc, then transpose to w1t
      float* W = w1s + (size_t)bh * ZL_;
      bf16* M = w1bn + (size_t)bh * ZL_;
      const int wm = (wv >> 1) * 64, wn = (wv & 1) * 64;
#pragma unroll
      for (int mi = 0; mi < 4; ++mi)
#pragma unroll
        for (int ni = 0; ni < 4; ++ni) {
          const int col = bx * 128 + wn + ni * 16 + c16;
#pragma unroll
          for (int r = 0; r < 4; ++r) {
            const int row = by * 128 + wm + mi * 16 + g * 4 + r;
            float nv = W[(size_t)row * cFD + col] + acc[mi][ni][r];
            W[(size_t)row * cFD + col] = nv;
            M[(size_t)row * cFD + col] = f2b(nv);
            acc[mi][ni][r] = nv;
          }
        }
      bf16* T = w1t + (size_t)bh * ZL_;
      short* Ts = Sh;  // 64 cc x 136
#pragma unroll
      for (int rd = 0; rd < 2; ++rd) {
        __syncthreads();
        if (wn == rd * 64) {
#pragma unroll
          for (int mi = 0; mi < 4; ++mi)
#pragma unroll
            for (int ni = 0; ni < 4; ++ni) {
              const int cc = ni * 16 + c16;
              unsigned short u[4] __attribute__((aligned(8)));
#pragma unroll
              for (int r = 0; r < 4; ++r) u[r] = f2bu(acc[mi][ni][r]);
              *(uint2*)&Ts[cc * 136 + wm + mi * 16 + g * 4] = *(uint2*)u;
            }
        }
        __syncthreads();
        const int cc = t >> 2, seg = (t & 3) * 32;
        unsigned short u[32] __attribute__((aligned(16)));
#pragma unroll
        for (int i = 0; i < 32; ++i) u[i] = (unsigned short)Ts[cc * 136 + seg + i];
        bf16* dp = T + (size_t)(bx * 128 + rd * 64 + cc) * cFD + by * 128 + seg;
        *(uint4*)dp = *(uint4*)u;
        *(uint4*)(dp + 8) = *(uint4*)(u + 8);
        *(uint4*)(dp + 16) = *(uint4*)(u + 16);
        *(uint4*)(dp + 24) = *(uint4*)(u + 24);
      }
    }
  } else {
    // oc: 128x128 tiles
    short* As = Sh;
    short* Bs = Sh + 4096;
    const int id2 = id - 384;
    const int bh = id2 >> 4, tile = id2 & 15, by = tile >> 2, bx = tile & 3;
    const bf16* Aa = hq + (size_t)bh * ZL_ + (size_t)by * 128 * cFD;
    const bf16* Bb = w1bc + (size_t)bh * ZL_ + (size_t)bx * 128 * cFD;
    f32x4 acc[4][4];
    const f32x4 zero4 = {0.f, 0.f, 0.f, 0.f};
#pragma unroll
    for (int i = 0; i < 4; ++i)
#pragma unroll
      for (int j = 0; j < 4; ++j) acc[i][j] = zero4;
    mm_core32(Aa, cFD, Bb, cFD, cFD, As, Bs, acc);
    mm_store<false, false>(occ + (size_t)bh * ZL_, (bf16*)nullptr, cFD, by * 128, bx * 128, acc);
  }
}

// tail: ids 0..4095 final norm-add; 4096..6143 cvt o_proj_w -> opwb
__global__ __launch_bounds__(256) void k_normcvt(const bf16* __restrict__ occ,
                                                 const float* __restrict__ tw, bf16* __restrict__ y,
                                                 const float* __restrict__ opw, bf16* __restrict__ opwb,
                                                 int chunk) {
  __shared__ float red[4];
  const int id = blockIdx.x, t = threadIdx.x;
  if (id < 4096) {
    const int bh = id >> 9, rr = id & 511;
    const bf16* src = occ + ((size_t)bh * 512 + rr) * 512;
    float v0 = b2f(src[t]), v1 = b2f(src[t + 256]);
    float ss = v0 * v0 + v1 * v1;
    for (int d = 32; d; d >>= 1) ss += __shfl_down(ss, d);
    if ((t & 63) == 0) red[t >> 6] = ss;
    __syncthreads();
    const float rstd = rsqrtf((red[0] + red[1] + red[2] + red[3]) / cFD + 1e-6f);
    const int si = chunk * 512 + rr;
    bf16* dst = y + ((size_t)((bh >> 2) * cS) + si) * cH + (bh & 3) * cFD;
    dst[t] = f2b(b2f(dst[t]) + v0 * rstd * tw[t]);
    dst[t + 256] = f2b(b2f(dst[t + 256]) + v1 * rstd * tw[t + 256]);
  } else {
    const size_t i = ((size_t)(id - 4096) * 256 + t) * 8;
    float4 a = *(const float4*)(opw + i), b = *(const float4*)(opw + i + 4);
    unsigned short u[8] __attribute__((aligned(16)));
    u[0] = f2bu(a.x); u[1] = f2bu(a.y); u[2] = f2bu(a.z); u[3] = f2bu(a.w);
    u[4] = f2bu(b.x); u[5] = f2bu(b.y); u[6] = f2bu(b.z); u[7] = f2bu(b.w);
    *(uint4*)(opwb + i) = *(uint4*)u;
  }
}

// --- merged prep: cvt x, cvt qkv_w, winit (f4), rope table, lr projections --
__global__ __launch_bounds__(256) void k_prep(const float* __restrict__ x, const float* __restrict__ qkv_w,
                                              const float* __restrict__ w0, const float* __restrict__ w1,
                                              const float* __restrict__ w2,
                                              const float* __restrict__ lr_w, const float* __restrict__ lr_b,
                                              bf16* __restrict__ xb, bf16* __restrict__ qkvwb,
                                              float* __restrict__ w0s, float* __restrict__ w1s,
                                              float* __restrict__ w2s,
                                              float* __restrict__ ct, float* __restrict__ stb,
                                              float* lr0, float* lr1, float* lr2, float base) {
  __shared__ float xbuf[cH];
  const int id = blockIdx.x, t = threadIdx.x;
  if (id < 4096) {
    const size_t i = ((size_t)id * 256 + t) * 8;
    float4 a = *(const float4*)(x + i), b = *(const float4*)(x + i + 4);
    unsigned short u[8] __attribute__((aligned(16)));
    u[0] = f2bu(a.x); u[1] = f2bu(a.y); u[2] = f2bu(a.z); u[3] = f2bu(a.w);
    u[4] = f2bu(b.x); u[5] = f2bu(b.y); u[6] = f2bu(b.z); u[7] = f2bu(b.w);
    *(uint4*)(xb + i) = *(uint4*)u;
  } else if (id < 10240) {
    const size_t i = ((size_t)(id - 4096) * 256 + t) * 8;
    float4 a = *(const float4*)(qkv_w + i), b = *(const float4*)(qkv_w + i + 4);
    unsigned short u[8] __attribute__((aligned(16)));
    u[0] = f2bu(a.x); u[1] = f2bu(a.y); u[2] = f2bu(a.z); u[3] = f2bu(a.w);
    u[4] = f2bu(b.x); u[5] = f2bu(b.y); u[6] = f2bu(b.z); u[7] = f2bu(b.w);
    *(uint4*)(qkvwb + i) = *(uint4*)u;
  } else if (id < 16384) {
    const int sub = id - 10240;
    const int w = sub >> 11, blk = sub & 2047;
    const size_t i = ((size_t)blk * 256 + t) * 4;
    const int f = (int)((i >> 18) & 3);
    const size_t off = i & 262143;
    const float* src = (w == 0) ? w0 : (w == 1) ? w1 : w2;
    float* dst = (w == 0) ? w0s : (w == 1) ? w1s : w2s;
    *(float4*)(dst + i) = *(const float4*)(src + (size_t)f * 262144 + off);
  } else if (id < 16896) {
    const int gid = (id - 16384) * 256 + t;
    const int si = gid >> 6, jj = gid & 63;
    float inv = powf(500000.0f, -(float)jj / 64.0f);
    float ang = (float)si * inv;
    ct[(size_t)si * 64 + jj] = cosf(ang);
    stb[(size_t)si * 64 + jj] = sinf(ang);
  } else {
    const int token = id - 16896, b_ = token >> 11, si = token & 2047;
    const int wv = t >> 6, lane = t & 63;
    const float* xr = x + (size_t)token * cH;
    for (int i = t; i < cH; i += 256) xbuf[i] = xr[i];
    __syncthreads();
#pragma unroll
    for (int jj = 0; jj < 3; ++jj) {
      const int j = wv * 3 + jj;
      const float* wr = lr_w + (size_t)j * cH;
      float s = 0.f;
      for (int k = lane; k < cH; k += 64) s += xbuf[k] * wr[k];
      for (int d = 32; d; d >>= 1) s += __shfl_down(s, d);
      if (lane == 0) {
        float v = s + lr_b[j] + base;
        float sp = (v > 15.f) ? v : log1pf(expf(v));
        const int tt = j >> 2, f = j & 3;
        float* dst = (tt == 0 ? lr0 : tt == 1 ? lr1 : lr2);
        dst[(size_t)(b_ * cNFW + f) * cS + si] = sp;
      }
    }
  }
}

// --- k_post2: ids 0..4095 rmsnorm+rope (qkvh writeback); 4096..5119 vtr -----
__global__ __launch_bounds__(256) void k_post2(bf16* __restrict__ qkvh,
                                               const float* __restrict__ qnw, const float* __restrict__ knw,
                                               const float* __restrict__ ct, const float* __restrict__ stb,
                                               bf16* __restrict__ qa, bf16* __restrict__ ka,
                                               bf16* __restrict__ vt) {
  __shared__ short smem[8704];
  __shared__ float red[4];
  const int id = blockIdx.x, t = threadIdx.x;
  if (id < 4096) {
    float* buf = (float*)smem;
    const int token = id, b_ = token >> 11, si = token & 2047;
    bf16* base = qkvh + (size_t)token * 3 * cH;
    for (int pass = 0; pass < 2; ++pass) {
      __syncthreads();
      bf16* src = base + pass * cH;
      const float* nw = pass ? knw : qnw;
      float ss = 0.f;
      for (int i = t; i < cH; i += 256) {
        float v = b2f(src[i]);
        buf[i] = v;
        ss += v * v;
      }
      for (int d = 32; d; d >>= 1) ss += __shfl_down(ss, d);
      if ((t & 63) == 0) red[t >> 6] = ss;
      __syncthreads();
      const float rstd = rsqrtf((red[0] + red[1] + red[2] + red[3]) / cH + 1e-6f);
      for (int i = t; i < cH; i += 256) {
        float v = buf[i] * rstd * nw[i];
        buf[i] = v;
        src[i] = f2b(v);
      }
      __syncthreads();
      bf16* dst = pass ? ka : qa;
      const float scale = pass ? 1.f : cRSQRT_HD;
      const int hh = t >> 4, j0 = (t & 15) * 4;
      const float* cr = ct + (size_t)si * 64 + j0;
      const float* sr = stb + (size_t)si * 64 + j0;
      bf16* drow = dst + ((size_t)(b_ * cNH + hh) * cS + si) * cHD;
      unsigned short u1[4] __attribute__((aligned(8))), u2[4] __attribute__((aligned(8)));
#pragma unroll
      for (int i = 0; i < 4; ++i) {
        float x1 = buf[hh * cHD + j0 + i], x2 = buf[hh * cHD + 64 + j0 + i];
        u1[i] = f2bu((x1 * cr[i] - x2 * sr[i]) * scale);
        u2[i] = f2bu((x2 * cr[i] + x1 * sr[i]) * scale);
      }
      *(uint2*)(drow + j0) = *(uint2*)u1;
      *(uint2*)(drow + 64 + j0) = *(uint2*)u2;
    }
  } else {
    short* Ts = smem;  // 64*136
    const int id2 = id - 4096;
    const int tile = id2 & 31, h = (id2 >> 5) & 15, b_ = id2 >> 9;
    {
      const int r = t >> 2, seg = (t & 3) * 32;
      const bf16* src = qkvh + ((size_t)(b_ * cS) + tile * 64 + r) * 3 * cH + 2 * cH + h * cHD + seg;
      stage16(src, &Ts[r * 136 + seg]);
      stage16(src + 16, &Ts[r * 136 + seg + 16]);
    }
    __syncthreads();
    {
      const int d = t >> 1, seg2 = (t & 1) * 32;
      unsigned short u[32] __attribute__((aligned(16)));
#pragma unroll
      for (int i = 0; i < 32; ++i) u[i] = (unsigned short)Ts[(seg2 + i) * 136 + d];
      bf16* dp = vt + ((size_t)(b_ * cNH + h) * cHD + d) * cS + tile * 64 + seg2;
      *(uint4*)dp = *(uint4*)u;
      *(uint4*)(dp + 8) = *(uint4*)(u + 8);
      *(uint4*)(dp + 16) = *(uint4*)(u + 16);
      *(uint4*)(dp + 24) = *(uint4*)(u + 24);
    }
  }
}

// --- k_mid: ids 0..4095 fq/fk/fv from qkvh; 4096..7167 mirror cvt;
//            7168..7679 w1t init (transpose of fp32 master w1s) ---
__global__ __launch_bounds__(256) void k_mid(const bf16* __restrict__ qkvh,
                                             const float* __restrict__ qk_scale,
                                             const float* __restrict__ qk_offset,
                                             bf16* fq, bf16* fk, bf16* fv,
                                             const float* __restrict__ w0s_, bf16* __restrict__ w0b_,
                                             const float* __restrict__ w1s_, bf16* __restrict__ w1t_) {
  __shared__ short Ts[64 * 72];
  const int id = blockIdx.x, t = threadIdx.x;
  if (id < 4096) {
    const int token = id, b_ = token >> 11, si = token & 2047;
    const bf16* base = qkvh + (size_t)token * 3 * cH;
#pragma unroll
    for (int pass = 0; pass < 2; ++pass) {
      const bf16* src = base + pass * cH;
      bf16* fdst = pass ? fk : fq;
      const int head = t >> 6, lane = t & 63;
      float f[8];
      float ss2 = 0.f;
#pragma unroll
      for (int k = 0; k < 8; ++k) {
        const int idx = head * cFD + lane + k * 64;
        float v = b2f(src[idx]);
        float u = v * qk_scale[idx * 2 + pass] + qk_offset[idx * 2 + pass];
        float fv_ = u * sigmoidf_(u);
        f[k] = fv_;
        ss2 += fv_ * fv_;
      }
      for (int d = 1; d < 64; d <<= 1) ss2 += __shfl_xor(ss2, d);
      const float sc2 = rsqrtf(ss2 + 1e-12f);
      bf16* dst = fdst + ((size_t)(b_ * cNFW + head) * cS + si) * cFD;
#pragma unroll
      for (int k = 0; k < 8; ++k) dst[lane + k * 64] = f2b(f[k] * sc2);
    }
    const bf16* vr = base + 2 * cH;
    for (int i = t; i < cH; i += 256) {
      float v = b2f(vr[i]);
      fv[((size_t)(b_ * cNFW + (i >> 9)) * cS + si) * cFD + (i & 511)] = f2b(v * sigmoidf_(v));
    }
  } else if (id < 7168) {
    const size_t i = ((size_t)(id - 4096) * 256 + t) * 8;
    float4 a = *(const float4*)(w0s_ + i), b = *(const float4*)(w0s_ + i + 4);
    unsigned short u[8] __attribute__((aligned(16)));
    u[0] = f2bu(a.x); u[1] = f2bu(a.y); u[2] = f2bu(a.z); u[3] = f2bu(a.w);
    u[4] = f2bu(b.x); u[5] = f2bu(b.y); u[6] = f2bu(b.z); u[7] = f2bu(b.w);
    *(uint4*)(w0b_ + i) = *(uint4*)u;
  } else {
    const int id3 = id - 7168;
    const int bh = id3 >> 6, tile = id3 & 63, by = tile >> 3, bx = tile & 7;
    {
      const int rr = t >> 2, cseg = (t & 3) * 16;
      const float* p = w1s_ + (size_t)bh * ZL_ + (size_t)(by * 64 + rr) * cFD + bx * 64 + cseg;
      unsigned short u[16] __attribute__((aligned(16)));
#pragma unroll
      for (int i = 0; i < 16; ++i) u[i] = f2bu(p[i]);
      *(uint4*)&Ts[rr * 72 + cseg] = *(uint4*)u;
      *(uint4*)&Ts[rr * 72 + cseg + 8] = *(uint4*)(u + 8);
    }
    __syncthreads();
    {
      const int oc_ = t >> 2, rseg = (t & 3) * 16;
      unsigned short u[16] __attribute__((aligned(16)));
#pragma unroll
      for (int i = 0; i < 16; ++i) u[i] = (unsigned short)Ts[(rseg + i) * 72 + oc_];
      bf16* dp = w1t_ + (size_t)bh * ZL_ + (size_t)(bx * 64 + oc_) * cFD + by * 64 + rseg;
      *(uint4*)dp = *(uint4*)u;
      *(uint4*)(dp + 8) = *(uint4*)(u + 8);
    }
  }
}

// -- attention: 128-row q blocks, 8 waves, paired tiles, XCD swizzle ---------
__global__ __launch_bounds__(512) void k_attn6(const bf16* __restrict__ qa, const bf16* __restrict__ ka,
                                               const bf16* __restrict__ vt, bf16* __restrict__ y) {
  const int id = blockIdx.x;
  const int xcd = id & 7;
  const int j = id >> 3;
  const int p = j & 7;
  const int hb = (j >> 3) * 8 + xcd;
  const int h = hb & 15, b_ = hb >> 4;
  __shared__ short KsP[9216];
  __shared__ short Vts[128 * 72];
  const int t = threadIdx.x, lane = t & 63, g = lane >> 4, c16 = lane & 15, wv = t >> 6;
  const size_t hbq = (size_t)(b_ * cNH + h) * cS;
  const bf16* vb = vt + (size_t)(b_ * cNH + h) * (size_t)(cHD * cS);
  const int r = t >> 3, seg = (t & 7) * 16;
  const int dv = t >> 2, seg2 = (t & 3) * 16;
  const f32x4 zero4 = {0.f, 0.f, 0.f, 0.f};

  for (int half = 0; half < 2; ++half) {
    const int qt = half ? p : 15 - p;
    const int q0 = qt * 128;
    const int nkt = 2 * qt + 2;
    short8 qf[4];
    {
      const bf16* qsrc = qa + (hbq + q0 + wv * 16 + c16) * cHD;
#pragma unroll
      for (int ks = 0; ks < 4; ++ks) qf[ks] = *(const short8*)(qsrc + ks * 32 + g * 8);
    }
    f32x4 o[8];
#pragma unroll
    for (int i = 0; i < 8; ++i) o[i] = zero4;
    float m[4], l[4];
#pragma unroll
    for (int rr = 0; rr < 4; ++rr) { m[rr] = -1e30f; l[rr] = 0.f; }

    uint4 kp0, kp1, vp0, vp1;
    {
      const bf16* ksrc = ka + (hbq + r) * cHD + seg;
      kp0 = *(const uint4*)ksrc; kp1 = *(const uint4*)(ksrc + 8);
      const bf16* vsrc = vb + (size_t)dv * cS + seg2;
      vp0 = *(const uint4*)vsrc; vp1 = *(const uint4*)(vsrc + 8);
    }

    for (int kt = 0; kt < nkt; ++kt) {
      __syncthreads();
      {
        short* kd = &KsP[r * 136 + seg];
        *(uint4*)kd = kp0; *(uint4*)(kd + 8) = kp1;
        short* vd = &Vts[dv * 72 + seg2];
        *(uint4*)vd = vp0; *(uint4*)(vd + 8) = vp1;
      }
      __syncthreads();
      if (kt + 1 < nkt) {
        const bf16* ksrc = ka + (hbq + (kt + 1) * 64 + r) * cHD + seg;
        kp0 = *(const uint4*)ksrc; kp1 = *(const uint4*)(ksrc + 8);
        const bf16* vsrc = vb + (size_t)dv * cS + (kt + 1) * 64 + seg2;
        vp0 = *(const uint4*)vsrc; vp1 = *(const uint4*)(vsrc + 8);
      } else if (half == 0) {
        const bf16* ksrc = ka + (hbq + r) * cHD + seg;
        kp0 = *(const uint4*)ksrc; kp1 = *(const uint4*)(ksrc + 8);
        const bf16* vsrc = vb + (size_t)dv * cS + seg2;
        vp0 = *(const uint4*)vsrc; vp1 = *(const uint4*)(vsrc + 8);
      }

      f32x4 s4[4];
#pragma unroll
      for (int ni = 0; ni < 4; ++ni) s4[ni] = zero4;
      __builtin_amdgcn_s_setprio(1);
#pragma unroll
      for (int ks = 0; ks < 4; ++ks) {
#pragma unroll
        for (int ni = 0; ni < 4; ++ni) {
          short8 bb = *(const short8*)&KsP[(ni * 16 + c16) * 136 + ks * 32 + g * 8];
          s4[ni] = __builtin_amdgcn_mfma_f32_16x16x32_bf16(qf[ks], bb, s4[ni], 0, 0, 0);
        }
      }
      __builtin_amdgcn_s_setprio(0);
      __syncthreads();
      if (kt * 64 + 64 > q0) {
#pragma unroll
        for (int ni = 0; ni < 4; ++ni) {
          const int kv = kt * 64 + ni * 16 + c16;
#pragma unroll
          for (int rr = 0; rr < 4; ++rr) {
            const int qr = q0 + wv * 16 + g * 4 + rr;
            if (kv > qr) s4[ni][rr] = -1e9f;
          }
        }
      }
      float mx[4];
#pragma unroll
      for (int rr = 0; rr < 4; ++rr)
        mx[rr] = fmaxf(fmaxf(s4[0][rr], s4[1][rr]), fmaxf(s4[2][rr], s4[3][rr]));
#pragma unroll
      for (int d = 1; d < 16; d <<= 1)
#pragma unroll
        for (int rr = 0; rr < 4; ++rr) mx[rr] = fmaxf(mx[rr], __shfl_xor(mx[rr], d));
      bool need = false;
#pragma unroll
      for (int rr = 0; rr < 4; ++rr) need |= (mx[rr] > m[rr] + 8.f);
      if (__any(need)) {
        float corr[4];
#pragma unroll
        for (int rr = 0; rr < 4; ++rr) {
          float mn = fmaxf(m[rr], mx[rr]);
          corr[rr] = __expf(m[rr] - mn);
          m[rr] = mn;
        }
#pragma unroll
        for (int rr = 0; rr < 4; ++rr) l[rr] *= corr[rr];
#pragma unroll
        for (int nf = 0; nf < 8; ++nf)
#pragma unroll
          for (int rr = 0; rr < 4; ++rr) o[nf][rr] *= corr[rr];
      }
      float psum[4] = {0.f, 0.f, 0.f, 0.f};
#pragma unroll
      for (int ni = 0; ni < 4; ++ni)
#pragma unroll
        for (int rr = 0; rr < 4; ++rr) {
          float pp = __expf(s4[ni][rr] - m[rr]);
          s4[ni][rr] = pp;
          psum[rr] += pp;
        }
#pragma unroll
      for (int d = 1; d < 16; d <<= 1)
#pragma unroll
        for (int rr = 0; rr < 4; ++rr) psum[rr] += __shfl_xor(psum[rr], d);
#pragma unroll
      for (int rr = 0; rr < 4; ++rr) l[rr] += psum[rr];
      short* pw = &KsP[wv * 1152];
#pragma unroll
      for (int ni = 0; ni < 4; ++ni)
#pragma unroll
        for (int rr = 0; rr < 4; ++rr)
          pw[(g * 4 + rr) * 72 + ni * 16 + c16] = (short)f2bu(s4[ni][rr]);
      __builtin_amdgcn_s_setprio(1);
#pragma unroll
      for (int ks2 = 0; ks2 < 2; ++ks2) {
        short8 a = *(const short8*)&pw[c16 * 72 + ks2 * 32 + g * 8];
#pragma unroll
        for (int nf = 0; nf < 8; ++nf) {
          short8 bb = *(const short8*)&Vts[(nf * 16 + c16) * 72 + ks2 * 32 + g * 8];
          o[nf] = __builtin_amdgcn_mfma_f32_16x16x32_bf16(a, bb, o[nf], 0, 0, 0);
        }
      }
      __builtin_amdgcn_s_setprio(0);
    }
    float inv[4];
#pragma unroll
    for (int rr = 0; rr < 4; ++rr) inv[rr] = 1.f / l[rr];
#pragma unroll
    for (int nf = 0; nf < 8; ++nf)
#pragma unroll
      for (int rr = 0; rr < 4; ++rr) {
        const size_t row = (size_t)(b_ * cS) + q0 + wv * 16 + g * 4 + rr;
        y[row * cH + h * cHD + nf * 16 + c16] = f2b(o[nf][rr] * inv[rr]);
      }
  }
}

}  // namespace

extern "C" void kernel_launch(void* const* d_in, const int* in_sizes, int n_in,
                              void* d_out, int out_size, void* d_ws, size_t ws_size,
                              hipStream_t stream) {
  (void)in_sizes; (void)n_in; (void)out_size; (void)ws_size;
  const float* x         = (const float*)d_in[0];
  const float* qkv_w     = (const float*)d_in[1];
  const float* q_norm_w  = (const float*)d_in[2];
  const float* k_norm_w  = (const float*)d_in[3];
  const float* qk_scale  = (const float*)d_in[4];
  const float* qk_offset = (const float*)d_in[5];
  const float* lr_w      = (const float*)d_in[6];
  const float* lr_b      = (const float*)d_in[7];
  const float* w0        = (const float*)d_in[8];
  const float* w1        = (const float*)d_in[9];
  const float* w2        = (const float*)d_in[10];
  const float* ttt_nw    = (const float*)d_in[11];
  const float* o_proj_w  = (const float*)d_in[12];
  float* out = (float*)d_out;

  // ---- workspace layout (bytes), total 143,851,520 (proven footprint) ----
  char* Wb = (char*)d_ws;
  bf16* qkvh = (bf16*)Wb;                 // phase-1 only (50.3MB)
  bf16* hq   = (bf16*)(Wb + 0UL);         // TTT phase buffers:
  bf16* trH  = (bf16*)(Wb + 4194304UL);
  bf16* trD1 = (bf16*)(Wb + 8388608UL);
  bf16* trD2 = (bf16*)(Wb + 12582912UL);
  bf16* trK  = (bf16*)(Wb + 16777216UL);
  bf16* trV  = (bf16*)(Wb + 20971520UL);
  bf16* occ  = (bf16*)(Wb + 25165824UL);
  bf16* w1t  = (bf16*)(Wb + 29360128UL);  // transposed w1 mirror
  bf16* w0b  = (bf16*)(Wb + 33554432UL);  // contiguous mirrors w0b,w1b0,w2b
  bf16* w1b0 = (bf16*)(Wb + 37748736UL);
  bf16* w2b  = (bf16*)(Wb + 41943040UL);
  bf16* w1b1 = (bf16*)(Wb + 46137344UL);  // w1 row-major mirror ping-pong
  bf16* opwb = (bf16*)(Wb + 0UL);         // after TTT loop
  size_t off = 50331648UL;
  bf16* fqb = (bf16*)(Wb + off); off += 16777216UL;
  bf16* fkb = (bf16*)(Wb + off); off += 16777216UL;
  bf16* fvb = (bf16*)(Wb + off); off += 16777216UL;
  float* w0s = (float*)(Wb + off); off += 8388608UL;
  float* w1s = (float*)(Wb + off); off += 8388608UL;
  float* w2s = (float*)(Wb + off); off += 8388608UL;
  float* lr0 = (float*)(Wb + off); off += 65536UL;
  float* lr1 = (float*)(Wb + off); off += 65536UL;
  float* lr2 = (float*)(Wb + off); off += 65536UL;
  bf16* y = (bf16*)(Wb + off); off += 16777216UL;
  float* ct  = (float*)(Wb + off); off += 524288UL;
  float* stb = (float*)(Wb + off); off += 524288UL;
  bf16* xb = fqb;
  bf16* qkvwb = fkb;
  bf16* qa = fqb;
  bf16* ka = fkb;
  bf16* vt = fvb;
  bf16* w1m[2] = {w1b0, w1b1};

  const float base_lr_inv = logf(expm1f(0.001f));
  dim3 blk(256);

  k_prep<<<dim3(20992), blk, 0, stream>>>(x, qkv_w, w0, w1, w2, lr_w, lr_b,
                                          xb, qkvwb, w0s, w1s, w2s, ct, stb,
                                          lr0, lr1, lr2, base_lr_inv);
  k_mm<bf16><<<dim3(48, 32), blk, 0, stream>>>(xb, 2048, qkvwb, 2048, qkvh, 6144, 2048);
  k_post2<<<dim3(5120), blk, 0, stream>>>(qkvh, q_norm_w, k_norm_w, ct, stb, qa, ka, vt);
  k_attn6<<<dim3(256), dim3(512), 0, stream>>>(qa, ka, vt, y);
  // fq/fk/fv overwrite qa/ka/vt after attn; mirrors + w1t init in same launch
  k_mid<<<dim3(7680), blk, 0, stream>>>(qkvh, qk_scale, qk_offset, fqb, fkb, fvb,
                                        w0s, w0b, w1s, w1t);

  for (int c = 0; c < 4; ++c) {
    const int g1 = (c == 0) ? 1536 : 5632;
    k_fuse1<<<dim3(g1), blk, 0, stream>>>(fqb, fkb, fvb, w0b, w1t, w2b,
                                          hq, trH, trD1, trD2, trK, trV,
                                          lr0, lr1, lr2, occ, ttt_nw, y, c);
    k_updna<<<dim3(512), blk, 0, stream>>>(trV, trH, trD1, trD2, trK, hq, w1m[c & 1],
                                           w0s, w1s, w2s, w0b, w1m[(c + 1) & 1], w2b, w1t,
                                           occ);
  }
  k_normcvt<<<dim3(6144), blk, 0, stream>>>(occ, ttt_nw, y, o_proj_w, opwb, 3);
  k_mm<float><<<dim3(16, 32), blk, 0, stream>>>(y, 2048, opwb, 2048, out, 2048, 2048);
}